// Round 1
// baseline (21015.244 us; speedup 1.0000x reference)
//
#include <hip/hip_runtime.h>
#include <hip/hip_bf16.h>

#define B_ 32
#define D_ 384
#define N_ 196
#define NH_ 8
#define HD_ 48
#define L_ 24

__device__ __forceinline__ float gelu_f(float v){
    return 0.5f * v * (1.0f + erff(v * 0.70710678118654752f));
}

// ---------------- LayerNorm over D=384, generic strided ----------------
__global__ __launch_bounds__(128) void ln384(const float* __restrict__ x, long xstride,
                                             const float* __restrict__ w, const float* __restrict__ b,
                                             float* __restrict__ y, long ystride){
    long row = blockIdx.x;
    int tid = threadIdx.x;
    const float* xr = x + row * xstride;
    float v0 = xr[tid], v1 = xr[tid + 128], v2 = xr[tid + 256];
    float s = v0 + v1 + v2;
    float ss = v0 * v0 + v1 * v1 + v2 * v2;
    for (int off = 32; off; off >>= 1){ s += __shfl_down(s, off); ss += __shfl_down(ss, off); }
    __shared__ float rs[2], rss[2];
    if ((tid & 63) == 0){ rs[tid >> 6] = s; rss[tid >> 6] = ss; }
    __syncthreads();
    float S = rs[0] + rs[1], SS = rss[0] + rss[1];
    float m = S * (1.0f / 384.0f);
    float var = SS * (1.0f / 384.0f) - m * m;
    float r = rsqrtf(var + 1e-5f);
    float* yr = y + row * ystride;
    yr[tid]       = (v0 - m) * r * w[tid]       + b[tid];
    yr[tid + 128] = (v1 - m) * r * w[tid + 128] + b[tid + 128];
    yr[tid + 256] = (v2 - m) * r * w[tid + 256] + b[tid + 256];
}

// LayerNorm writing transposed output: y[b, d, n]  (input rows are b*196+n)
__global__ __launch_bounds__(128) void ln384_t(const float* __restrict__ x,
                                               const float* __restrict__ w, const float* __restrict__ b,
                                               float* __restrict__ y){
    long row = blockIdx.x;
    int tid = threadIdx.x;
    const float* xr = x + row * 384;
    float v0 = xr[tid], v1 = xr[tid + 128], v2 = xr[tid + 256];
    float s = v0 + v1 + v2;
    float ss = v0 * v0 + v1 * v1 + v2 * v2;
    for (int off = 32; off; off >>= 1){ s += __shfl_down(s, off); ss += __shfl_down(ss, off); }
    __shared__ float rs[2], rss[2];
    if ((tid & 63) == 0){ rs[tid >> 6] = s; rss[tid >> 6] = ss; }
    __syncthreads();
    float S = rs[0] + rs[1], SS = rss[0] + rss[1];
    float m = S * (1.0f / 384.0f);
    float var = SS * (1.0f / 384.0f) - m * m;
    float r = rsqrtf(var + 1e-5f);
    int bb = (int)(row / 196), n = (int)(row % 196);
    float* yb = y + ((long)bb * 384) * 196 + n;
    yb[(long)tid * 196]         = (v0 - m) * r * w[tid]       + b[tid];
    yb[(long)(tid + 128) * 196] = (v1 - m) * r * w[tid + 128] + b[tid + 128];
    yb[(long)(tid + 256) * 196] = (v2 - m) * r * w[tid + 256] + b[tid + 256];
}

// ---------------- Tiled fp32 GEMM: C[M,N] = A[M,K] @ W[N,K]^T + bias ----------------
// MODE 0: C = acc+bias ; MODE 1: C = gelu(acc+bias) ; MODE 2: C += gamma[col]*(acc+bias)
template<int MODE>
__global__ __launch_bounds__(256) void gemm64(const float* __restrict__ A, long lda,
                                              const float* __restrict__ W,
                                              const float* __restrict__ bias,
                                              float* __restrict__ C, long ldc,
                                              const float* __restrict__ gamma,
                                              int M, int N, int K){
    __shared__ float As[16][68];
    __shared__ float Ws[16][68];
    const int tid = threadIdx.x;
    const int row0 = blockIdx.x * 64, col0 = blockIdx.y * 64;
    const int lm = tid >> 2;
    const int lk = (tid & 3) << 2;
    const int ty = tid >> 4, tx = tid & 15;
    float acc[4][4] = {};
    for (int k0 = 0; k0 < K; k0 += 16){
        int gr = row0 + lm;
        float4 va = make_float4(0.f, 0.f, 0.f, 0.f);
        if (gr < M) va = *reinterpret_cast<const float4*>(A + (long)gr * lda + k0 + lk);
        As[lk + 0][lm] = va.x; As[lk + 1][lm] = va.y; As[lk + 2][lm] = va.z; As[lk + 3][lm] = va.w;
        int gc = col0 + lm;
        float4 vw = make_float4(0.f, 0.f, 0.f, 0.f);
        if (gc < N) vw = *reinterpret_cast<const float4*>(W + (long)gc * K + k0 + lk);
        Ws[lk + 0][lm] = vw.x; Ws[lk + 1][lm] = vw.y; Ws[lk + 2][lm] = vw.z; Ws[lk + 3][lm] = vw.w;
        __syncthreads();
        #pragma unroll
        for (int kk = 0; kk < 16; kk++){
            float4 av = *reinterpret_cast<const float4*>(&As[kk][ty << 2]);
            float4 bv = *reinterpret_cast<const float4*>(&Ws[kk][tx << 2]);
            float a0 = av.x, a1 = av.y, a2 = av.z, a3 = av.w;
            float b0 = bv.x, b1 = bv.y, b2 = bv.z, b3 = bv.w;
            acc[0][0] += a0 * b0; acc[0][1] += a0 * b1; acc[0][2] += a0 * b2; acc[0][3] += a0 * b3;
            acc[1][0] += a1 * b0; acc[1][1] += a1 * b1; acc[1][2] += a1 * b2; acc[1][3] += a1 * b3;
            acc[2][0] += a2 * b0; acc[2][1] += a2 * b1; acc[2][2] += a2 * b2; acc[2][3] += a2 * b3;
            acc[3][0] += a3 * b0; acc[3][1] += a3 * b1; acc[3][2] += a3 * b2; acc[3][3] += a3 * b3;
        }
        __syncthreads();
    }
    #pragma unroll
    for (int i = 0; i < 4; i++){
        int row = row0 + (ty << 2) + i;
        if (row >= M) continue;
        #pragma unroll
        for (int j = 0; j < 4; j++){
            int col = col0 + (tx << 2) + j;
            if (col >= N) continue;
            float v = acc[i][j] + bias[col];
            if (MODE == 1) v = gelu_f(v);
            long ci = (long)row * ldc + col;
            if (MODE == 2) C[ci] += gamma[col] * v;
            else C[ci] = v;
        }
    }
}

// ---------------- Direct conv 3x3 stride2 pad1 + eval-BN (+ optional GELU) ----------------
__global__ __launch_bounds__(256) void conv3x3_s2(const float* __restrict__ in, const float* __restrict__ w,
                                                  const float* __restrict__ g, const float* __restrict__ bb,
                                                  float* __restrict__ out,
                                                  int Bn, int Ci, int Hi, int Wi, int Co, int Ho, int Wo,
                                                  int do_gelu, int bpp){
    extern __shared__ float ws_[];
    int blk = blockIdx.x;
    int pb = blk % bpp;
    int bc = blk / bpp;
    int co = bc % Co, b = bc / Co;
    for (int i = threadIdx.x; i < Ci * 9; i += 256) ws_[i] = w[(long)co * Ci * 9 + i];
    __syncthreads();
    int npix = Ho * Wo;
    int pix = pb * 256 + threadIdx.x;
    if (pix >= npix) return;
    int oy = pix / Wo, ox = pix % Wo;
    int iy0 = oy * 2 - 1, ix0 = ox * 2 - 1;
    const float* inb = in + (long)b * Ci * Hi * Wi;
    float acc = 0.f;
    for (int ci = 0; ci < Ci; ci++){
        const float* ip = inb + (long)ci * Hi * Wi;
        const float* wp = ws_ + ci * 9;
        #pragma unroll
        for (int ky = 0; ky < 3; ky++){
            int iy = iy0 + ky;
            if ((unsigned)iy >= (unsigned)Hi) continue;
            const float* iprow = ip + (long)iy * Wi;
            #pragma unroll
            for (int kx = 0; kx < 3; kx++){
                int ix = ix0 + kx;
                if ((unsigned)ix < (unsigned)Wi) acc += iprow[ix] * wp[ky * 3 + kx];
            }
        }
    }
    float scale = g[co] * rsqrtf(1.0f + 1e-5f);
    float v = acc * scale + bb[co];
    if (do_gelu) v = gelu_f(v);
    out[((long)(b * Co + co)) * npix + pix] = v;
}

// ---------------- positional embedding: pos[n, d] ----------------
__global__ __launch_bounds__(384) void pos_embed(const float* __restrict__ pw, const float* __restrict__ pb,
                                                 float* __restrict__ pos){
    __shared__ float p64[64];
    int n = blockIdx.x;
    int iy = n / 14, ix = n % 14;
    int t = threadIdx.x;
    if (t < 64){
        int axis = t >> 5;       // 0 -> y, 1 -> x
        int c = t & 31;
        int u = c >> 1;
        float coord = (axis == 0) ? (float)(iy + 1) : (float)(ix + 1);
        float val = coord / ((14.0f + 1e-6f) * 6.283185307179586f);
        float T = powf(10000.0f, (float)u / 16.0f);
        float a = val / T;
        p64[t] = (c & 1) ? cosf(a) : sinf(a);
    }
    __syncthreads();
    float acc = 0.f;
    const float* wr = pw + (long)t * 64;
    #pragma unroll 8
    for (int c = 0; c < 64; c++) acc += p64[c] * wr[c];
    pos[n * 384 + t] = acc + pb[t];
}

// t[b,n,d] = c4[b,d,n] + pos[n,d]
__global__ __launch_bounds__(256) void build_t(const float* __restrict__ c4, const float* __restrict__ pos,
                                               float* __restrict__ t){
    long i = (long)blockIdx.x * 256 + threadIdx.x;
    if (i >= (long)B_ * N_ * D_) return;
    int d = (int)(i % 384);
    long bn = i / 384;
    int n = (int)(bn % 196);
    int b = (int)(bn / 196);
    t[i] = c4[((long)b * 384 + d) * 196 + n] + pos[n * 384 + d];
}

// ---------------- XCA attention: one block per (b, head) ----------------
__global__ __launch_bounds__(256) void xca_attn(const float* __restrict__ qkv, const float* __restrict__ temp,
                                                float* __restrict__ o){
    int bh = blockIdx.x;
    int b = bh >> 3, h = bh & 7;
    __shared__ alignas(16) __hip_bfloat16 qs[48 * 196];
    __shared__ alignas(16) __hip_bfloat16 ks[48 * 196];
    __shared__ alignas(16) __hip_bfloat16 vs[48 * 196];
    __shared__ float inq[48], ink[48];
    int tid = threadIdx.x;
    const float* base = qkv + (long)b * 196 * 1152 + h * 48;
    for (int i = tid; i < 48 * 196; i += 256){
        int n = i / 48, d = i % 48;
        const float* p = base + (long)n * 1152;
        qs[d * 196 + n] = __float2bfloat16(p[d]);
        ks[d * 196 + n] = __float2bfloat16(p[384 + d]);
        vs[d * 196 + n] = __float2bfloat16(p[768 + d]);
    }
    __syncthreads();
    int wid = tid >> 6, lane = tid & 63;
    for (int r = wid; r < 48; r += 4){
        float sq = 0.f, sk = 0.f;
        for (int n = lane; n < 196; n += 64){
            float qv = __bfloat162float(qs[r * 196 + n]);
            float kv = __bfloat162float(ks[r * 196 + n]);
            sq += qv * qv; sk += kv * kv;
        }
        for (int off = 32; off; off >>= 1){ sq += __shfl_down(sq, off); sk += __shfl_down(sk, off); }
        if (lane == 0){
            inq[r] = 1.0f / fmaxf(sqrtf(sq), 1e-12f);
            ink[r] = 1.0f / fmaxf(sqrtf(sk), 1e-12f);
        }
    }
    __syncthreads();
    float tempv = temp[h];
    float rv[9];
    #pragma unroll
    for (int it = 0; it < 9; it++){
        int idx = tid + it * 256;
        int d = idx / 48, e = idx - d * 48;
        const __hip_bfloat16* qr = qs + d * 196;
        const __hip_bfloat16* kr = ks + e * 196;
        float s = 0.f;
        for (int n = 0; n < 196; n++) s += __bfloat162float(qr[n]) * __bfloat162float(kr[n]);
        rv[it] = s * inq[d] * ink[e] * tempv;
    }
    __syncthreads();
    float* at = reinterpret_cast<float*>(qs);   // overlay (9.4KB <= 18.8KB)
    #pragma unroll
    for (int it = 0; it < 9; it++){
        int idx = tid + it * 256;
        int d = idx / 48, e = idx - d * 48;
        at[d * 49 + e] = rv[it];
    }
    __syncthreads();
    if (tid < 48){
        float* row = at + tid * 49;
        float m = -1e30f;
        for (int e = 0; e < 48; e++) m = fmaxf(m, row[e]);
        float ssum = 0.f;
        for (int e = 0; e < 48; e++){ float ev = expf(row[e] - m); row[e] = ev; ssum += ev; }
        float inv = 1.0f / ssum;
        for (int e = 0; e < 48; e++) row[e] *= inv;
    }
    __syncthreads();
    for (int idx = tid; idx < 48 * 196; idx += 256){
        int d = idx % 48, n = idx / 48;
        const float* arow = at + d * 49;
        float s = 0.f;
        for (int e = 0; e < 48; e++) s += arow[e] * __bfloat162float(vs[e * 196 + n]);
        o[((long)b * 196 + n) * 384 + h * 48 + d] = s;
    }
}

// ---------------- LPI: both depthwise 3x3 convs fused, one block per (b, d) plane ----------------
__global__ __launch_bounds__(256) void lpi(const float* __restrict__ ht,
                                           const float* __restrict__ w1, const float* __restrict__ b1,
                                           const float* __restrict__ bng, const float* __restrict__ bnb,
                                           const float* __restrict__ w2, const float* __restrict__ b2,
                                           const float* __restrict__ g3, float* __restrict__ t){
    int bd = blockIdx.x;
    int d = bd % 384, b = bd / 384;
    __shared__ float p[16][16];
    __shared__ float p2[16][16];
    __shared__ float wA[9], wB[9];
    int tt = threadIdx.x;
    int yy = tt / 16, xx = tt % 16;
    p[yy][xx] = 0.f; p2[yy][xx] = 0.f;
    if (tt < 9){ wA[tt] = w1[d * 9 + tt]; wB[tt] = w2[d * 9 + tt]; }
    __syncthreads();
    if (tt < 196){
        int y = tt / 14, x = tt % 14;
        p[y + 1][x + 1] = ht[((long)b * 384 + d) * 196 + tt];
    }
    __syncthreads();
    if (tt < 196){
        int y = tt / 14, x = tt % 14;
        float a = 0.f;
        #pragma unroll
        for (int ky = 0; ky < 3; ky++)
            #pragma unroll
            for (int kx = 0; kx < 3; kx++)
                a += wA[ky * 3 + kx] * p[y + ky][x + kx];
        a += b1[d];
        a = gelu_f(a);
        a = a * (bng[d] * rsqrtf(1.0f + 1e-5f)) + bnb[d];
        p2[y + 1][x + 1] = a;
    }
    __syncthreads();
    if (tt < 196){
        int y = tt / 14, x = tt % 14;
        float a = 0.f;
        #pragma unroll
        for (int ky = 0; ky < 3; ky++)
            #pragma unroll
            for (int kx = 0; kx < 3; kx++)
                a += wB[ky * 3 + kx] * p2[y + ky][x + kx];
        a += b2[d];
        long ti = ((long)b * 196 + tt) * 384 + d;
        t[ti] += g3[d] * a;
    }
}

// ---------------- cls concat ----------------
__global__ __launch_bounds__(256) void concat_cls(const float* __restrict__ t, const float* __restrict__ clstok,
                                                  float* __restrict__ tc){
    long i = (long)blockIdx.x * 256 + threadIdx.x;
    if (i >= (long)B_ * 197 * 384) return;
    int d = (int)(i % 384);
    long bn = i / 384;
    int n = (int)(bn % 197);
    int b = (int)(bn / 197);
    tc[i] = (n == 0) ? clstok[d] : t[((long)b * 196 + (n - 1)) * 384 + d];
}

// ---------------- CA attention: one block per (b, head), cls query only ----------------
__global__ __launch_bounds__(256) void ca_attn(const float* __restrict__ qkv, float* __restrict__ clsp){
    int bh = blockIdx.x;
    int b = bh >> 3, h = bh & 7;
    const float* base = qkv + (long)b * 197 * 1152 + h * 48;
    __shared__ float q0[48];
    __shared__ float at[197];
    __shared__ float smax, ssum;
    int tid = threadIdx.x;
    if (tid < 48) q0[tid] = base[tid];
    __syncthreads();
    if (tid < 197){
        const float* kr = base + (long)tid * 1152 + 384;
        float s = 0.f;
        for (int d = 0; d < 48; d++) s += q0[d] * kr[d];
        at[tid] = s * rsqrtf(48.0f);
    }
    __syncthreads();
    if (tid == 0){
        float m = -1e30f;
        for (int n = 0; n < 197; n++) m = fmaxf(m, at[n]);
        smax = m;
    }
    __syncthreads();
    if (tid < 197) at[tid] = expf(at[tid] - smax);
    __syncthreads();
    if (tid == 0){
        float s = 0.f;
        for (int n = 0; n < 197; n++) s += at[n];
        ssum = s;
    }
    __syncthreads();
    if (tid < 48){
        const float* vb = base + 768 + tid;
        float s = 0.f;
        for (int n = 0; n < 197; n++) s += at[n] * vb[(long)n * 1152];
        clsp[b * 384 + h * 48 + tid] = s / ssum;
    }
}

// t update after CA attention: token0 += g1*proj(cls); others += g1*h
__global__ __launch_bounds__(256) void ca_update1(const float* __restrict__ clso, const float* __restrict__ hc,
                                                  const float* __restrict__ g1, float* __restrict__ tc){
    long i = (long)blockIdx.x * 256 + threadIdx.x;
    if (i >= (long)B_ * 197 * 384) return;
    int d = (int)(i % 384);
    long bn = i / 384;
    int n = (int)(bn % 197);
    int b = (int)(bn / 197);
    float add = (n == 0) ? clso[b * 384 + d] : hc[i];
    tc[i] += g1[d] * add;
}

// final CA update: token0 = g2*cls2 + hc ; others = 2*hc   (hc = LN2 output)
__global__ __launch_bounds__(256) void ca_update2(const float* __restrict__ cls2, const float* __restrict__ hc,
                                                  const float* __restrict__ g2, float* __restrict__ tc){
    long i = (long)blockIdx.x * 256 + threadIdx.x;
    if (i >= (long)B_ * 197 * 384) return;
    int d = (int)(i % 384);
    long bn = i / 384;
    int n = (int)(bn % 197);
    int b = (int)(bn / 197);
    float hv = hc[i];
    tc[i] = (n == 0) ? (g2[d] * cls2[b * 384 + d] + hv) : (hv + hv);
}

extern "C" void kernel_launch(void* const* d_in, const int* in_sizes, int n_in,
                              void* d_out, int out_size, void* d_ws, size_t ws_size,
                              hipStream_t stream){
    (void)in_sizes; (void)n_in; (void)out_size; (void)ws_size;
    const float* x      = (const float*)d_in[0];
    const float* clstok = (const float*)d_in[1];
    const float* pos_w  = (const float*)d_in[2];
    const float* pos_b  = (const float*)d_in[3];
    const float* pe_w[4] = {(const float*)d_in[4], (const float*)d_in[7], (const float*)d_in[10], (const float*)d_in[13]};
    const float* pe_g[4] = {(const float*)d_in[5], (const float*)d_in[8], (const float*)d_in[11], (const float*)d_in[14]};
    const float* pe_b[4] = {(const float*)d_in[6], (const float*)d_in[9], (const float*)d_in[12], (const float*)d_in[15]};
    const float* xqkv_w = (const float*)d_in[16];
    const float* xqkv_b = (const float*)d_in[17];
    const float* xproj_w = (const float*)d_in[18];
    const float* xproj_b = (const float*)d_in[19];
    const float* xtemp  = (const float*)d_in[20];
    const float* xn1_w = (const float*)d_in[21];
    const float* xn1_b = (const float*)d_in[22];
    const float* xn2_w = (const float*)d_in[23];
    const float* xn2_b = (const float*)d_in[24];
    const float* xn3_w = (const float*)d_in[25];
    const float* xn3_b = (const float*)d_in[26];
    const float* xfc1_w = (const float*)d_in[27];
    const float* xfc1_b = (const float*)d_in[28];
    const float* xfc2_w = (const float*)d_in[29];
    const float* xfc2_b = (const float*)d_in[30];
    const float* xlpi1_w = (const float*)d_in[31];
    const float* xlpi1_b = (const float*)d_in[32];
    const float* xlpi2_w = (const float*)d_in[33];
    const float* xlpi2_b = (const float*)d_in[34];
    const float* xbn_g = (const float*)d_in[35];
    const float* xbn_b = (const float*)d_in[36];
    const float* xg1 = (const float*)d_in[37];
    const float* xg2 = (const float*)d_in[38];
    const float* xg3 = (const float*)d_in[39];
    const float* cqkv_w = (const float*)d_in[40];
    const float* cqkv_b = (const float*)d_in[41];
    const float* cproj_w = (const float*)d_in[42];
    const float* cproj_b = (const float*)d_in[43];
    const float* cn1_w = (const float*)d_in[44];
    const float* cn1_b = (const float*)d_in[45];
    const float* cn2_w = (const float*)d_in[46];
    const float* cn2_b = (const float*)d_in[47];
    const float* cfc1_w = (const float*)d_in[48];
    const float* cfc1_b = (const float*)d_in[49];
    const float* cfc2_w = (const float*)d_in[50];
    const float* cfc2_b = (const float*)d_in[51];
    const float* cg1 = (const float*)d_in[52];
    const float* cg2 = (const float*)d_in[53];
    const float* norm_w = (const float*)d_in[54];
    const float* norm_b = (const float*)d_in[55];
    const float* head_w = (const float*)d_in[56];
    const float* head_b = (const float*)d_in[57];
    float* outp = (float*)d_out;

    // workspace layout (floats). Regions alias across phases.
    float* ws = (float*)d_ws;
    float* regA = ws;                       // 19,267,584 floats
    float* regB = ws + 19267584L;           //  9,633,792 floats
    float* t    = ws + 28901376L;           //  2,408,448
    float* pos  = ws + 31309824L;           //     75,264
    float* h    = ws + 31385088L;           //  2,408,448
    float* tc   = ws + 33793536L;           //  2,420,736
    float* hc   = ws + 36214272L;           //  2,420,736
    // aliases inside regA (transformer phase):
    float* qkv  = regA;                     //  7,225,344
    float* ht   = regA + 7225344L;          //  2,408,448
    float* o    = regA + 9633792L;          //  2,408,448
    float* clsp = regA + 12042240L;
    float* clso = clsp + 12288;
    float* f1c  = clso + 12288;
    float* cls2 = f1c + 49152;
    float* clsf = cls2 + 12288;
    float* f1   = regB;                     //  9,633,792 (exact)

    // ---- patch embed ----
    {
        // conv1: x[32,3,224,224] -> regA[32,48,112,112]
        int bpp = (112 * 112 + 255) / 256;
        conv3x3_s2<<<32 * 48 * bpp, 256, 3 * 9 * 4, stream>>>(x, pe_w[0], pe_g[0], pe_b[0], regA,
                                                              32, 3, 224, 224, 48, 112, 112, 1, bpp);
    }
    {
        int bpp = (56 * 56 + 255) / 256;
        conv3x3_s2<<<32 * 96 * bpp, 256, 48 * 9 * 4, stream>>>(regA, pe_w[1], pe_g[1], pe_b[1], regB,
                                                               32, 48, 112, 112, 96, 56, 56, 1, bpp);
    }
    {
        int bpp = (28 * 28 + 255) / 256;
        conv3x3_s2<<<32 * 192 * bpp, 256, 96 * 9 * 4, stream>>>(regB, pe_w[2], pe_g[2], pe_b[2], regA,
                                                                32, 96, 56, 56, 192, 28, 28, 1, bpp);
    }
    {
        int bpp = (14 * 14 + 255) / 256;
        conv3x3_s2<<<32 * 384 * bpp, 256, 192 * 9 * 4, stream>>>(regA, pe_w[3], pe_g[3], pe_b[3], regB,
                                                                 32, 192, 28, 28, 384, 14, 14, 0, bpp);
    }
    pos_embed<<<196, 384, 0, stream>>>(pos_w, pos_b, pos);
    build_t<<<(int)(((long)B_ * N_ * D_) / 256), 256, 0, stream>>>(regB, pos, t);

    // ---- 24 XCA layers ----
    const int M = B_ * N_;  // 6272
    for (int l = 0; l < L_; l++){
        ln384<<<M, 128, 0, stream>>>(t, 384, xn1_w + l * 384, xn1_b + l * 384, h, 384);
        {
            dim3 g((M + 63) / 64, 1152 / 64);
            gemm64<0><<<g, 256, 0, stream>>>(h, 384, xqkv_w + (long)l * 1152 * 384, xqkv_b + l * 1152,
                                             qkv, 1152, nullptr, M, 1152, 384);
        }
        xca_attn<<<B_ * NH_, 256, 0, stream>>>(qkv, xtemp + l * 8, o);
        {
            dim3 g((M + 63) / 64, 384 / 64);
            gemm64<2><<<g, 256, 0, stream>>>(o, 384, xproj_w + (long)l * 384 * 384, xproj_b + l * 384,
                                             t, 384, xg1 + l * 384, M, 384, 384);
        }
        ln384_t<<<M, 128, 0, stream>>>(t, xn3_w + l * 384, xn3_b + l * 384, ht);
        lpi<<<B_ * D_, 256, 0, stream>>>(ht, xlpi1_w + (long)l * 384 * 9, xlpi1_b + l * 384,
                                         xbn_g + l * 384, xbn_b + l * 384,
                                         xlpi2_w + (long)l * 384 * 9, xlpi2_b + l * 384,
                                         xg3 + l * 384, t);
        ln384<<<M, 128, 0, stream>>>(t, 384, xn2_w + l * 384, xn2_b + l * 384, h, 384);
        {
            dim3 g((M + 63) / 64, 1536 / 64);
            gemm64<1><<<g, 256, 0, stream>>>(h, 384, xfc1_w + (long)l * 1536 * 384, xfc1_b + l * 1536,
                                             f1, 1536, nullptr, M, 1536, 384);
        }
        {
            dim3 g((M + 63) / 64, 384 / 64);
            gemm64<2><<<g, 256, 0, stream>>>(f1, 1536, xfc2_w + (long)l * 384 * 1536, xfc2_b + l * 384,
                                             t, 384, xg2 + l * 384, M, 384, 1536);
        }
    }

    // ---- cls concat + 2 CA blocks ----
    const long NC = (long)B_ * 197 * 384;   // 2,420,736 (divisible by 256)
    concat_cls<<<(int)(NC / 256), 256, 0, stream>>>(t, clstok, tc);
    const int MC = B_ * 197;  // 6304
    for (int i = 0; i < 2; i++){
        ln384<<<MC, 128, 0, stream>>>(tc, 384, cn1_w + i * 384, cn1_b + i * 384, hc, 384);
        {
            dim3 g((MC + 63) / 64, 1152 / 64);
            gemm64<0><<<g, 256, 0, stream>>>(hc, 384, cqkv_w + (long)i * 1152 * 384, cqkv_b + i * 1152,
                                             qkv, 1152, nullptr, MC, 1152, 384);
        }
        ca_attn<<<B_ * NH_, 256, 0, stream>>>(qkv, clsp);
        {
            dim3 g(1, 384 / 64);
            gemm64<0><<<g, 256, 0, stream>>>(clsp, 384, cproj_w + (long)i * 384 * 384, cproj_b + i * 384,
                                             clso, 384, nullptr, 32, 384, 384);
        }
        ca_update1<<<(int)(NC / 256), 256, 0, stream>>>(clso, hc, cg1 + i * 384, tc);
        ln384<<<MC, 128, 0, stream>>>(tc, 384, cn2_w + i * 384, cn2_b + i * 384, hc, 384);
        {
            dim3 g(1, 1536 / 64);
            gemm64<1><<<g, 256, 0, stream>>>(hc, (long)197 * 384, cfc1_w + (long)i * 1536 * 384, cfc1_b + i * 1536,
                                             f1c, 1536, nullptr, 32, 1536, 384);
        }
        {
            dim3 g(1, 384 / 64);
            gemm64<0><<<g, 256, 0, stream>>>(f1c, 1536, cfc2_w + (long)i * 384 * 1536, cfc2_b + i * 384,
                                             cls2, 384, nullptr, 32, 384, 1536);
        }
        ca_update2<<<(int)(NC / 256), 256, 0, stream>>>(cls2, hc, cg2 + i * 384, tc);
    }

    // ---- final LN (cls token only) + head ----
    ln384<<<32, 128, 0, stream>>>(tc, (long)197 * 384, norm_w, norm_b, clsf, 384);
    {
        dim3 g(1, (1000 + 63) / 64);
        gemm64<0><<<g, 256, 0, stream>>>(clsf, 384, head_w, head_b, outp, 1000, nullptr, 32, 1000, 384);
    }
}

// Round 2
// 14066.412 us; speedup vs baseline: 1.4940x; 1.4940x over previous
//
#include <hip/hip_runtime.h>
#include <hip/hip_bf16.h>

#define B_ 32
#define D_ 384
#define N_ 196
#define NH_ 8
#define HD_ 48
#define L_ 24

__device__ __forceinline__ float gelu_f(float v){
    return 0.5f * v * (1.0f + erff(v * 0.70710678118654752f));
}

// ---------------- LayerNorm over D=384, generic strided ----------------
__global__ __launch_bounds__(128) void ln384(const float* __restrict__ x, long xstride,
                                             const float* __restrict__ w, const float* __restrict__ b,
                                             float* __restrict__ y, long ystride){
    long row = blockIdx.x;
    int tid = threadIdx.x;
    const float* xr = x + row * xstride;
    float v0 = xr[tid], v1 = xr[tid + 128], v2 = xr[tid + 256];
    float s = v0 + v1 + v2;
    float ss = v0 * v0 + v1 * v1 + v2 * v2;
    for (int off = 32; off; off >>= 1){ s += __shfl_down(s, off); ss += __shfl_down(ss, off); }
    __shared__ float rs[2], rss[2];
    if ((tid & 63) == 0){ rs[tid >> 6] = s; rss[tid >> 6] = ss; }
    __syncthreads();
    float S = rs[0] + rs[1], SS = rss[0] + rss[1];
    float m = S * (1.0f / 384.0f);
    float var = SS * (1.0f / 384.0f) - m * m;
    float r = rsqrtf(var + 1e-5f);
    float* yr = y + row * ystride;
    yr[tid]       = (v0 - m) * r * w[tid]       + b[tid];
    yr[tid + 128] = (v1 - m) * r * w[tid + 128] + b[tid + 128];
    yr[tid + 256] = (v2 - m) * r * w[tid + 256] + b[tid + 256];
}

// LayerNorm writing transposed output: y[b, d, n]  (input rows are b*196+n)
__global__ __launch_bounds__(128) void ln384_t(const float* __restrict__ x,
                                               const float* __restrict__ w, const float* __restrict__ b,
                                               float* __restrict__ y){
    long row = blockIdx.x;
    int tid = threadIdx.x;
    const float* xr = x + row * 384;
    float v0 = xr[tid], v1 = xr[tid + 128], v2 = xr[tid + 256];
    float s = v0 + v1 + v2;
    float ss = v0 * v0 + v1 * v1 + v2 * v2;
    for (int off = 32; off; off >>= 1){ s += __shfl_down(s, off); ss += __shfl_down(ss, off); }
    __shared__ float rs[2], rss[2];
    if ((tid & 63) == 0){ rs[tid >> 6] = s; rss[tid >> 6] = ss; }
    __syncthreads();
    float S = rs[0] + rs[1], SS = rss[0] + rss[1];
    float m = S * (1.0f / 384.0f);
    float var = SS * (1.0f / 384.0f) - m * m;
    float r = rsqrtf(var + 1e-5f);
    int bb = (int)(row / 196), n = (int)(row % 196);
    float* yb = y + ((long)bb * 384) * 196 + n;
    yb[(long)tid * 196]         = (v0 - m) * r * w[tid]       + b[tid];
    yb[(long)(tid + 128) * 196] = (v1 - m) * r * w[tid + 128] + b[tid + 128];
    yb[(long)(tid + 256) * 196] = (v2 - m) * r * w[tid + 256] + b[tid + 256];
}

// ---------------- Tiled fp32 GEMM: C[M,N] = A[M,K] @ W[N,K]^T + bias ----------------
// MODE 0: C = acc+bias ; MODE 1: C = gelu(acc+bias) ; MODE 2: C += gamma[col]*(acc+bias)
template<int MODE>
__global__ __launch_bounds__(256) void gemm64(const float* __restrict__ A, long lda,
                                              const float* __restrict__ W,
                                              const float* __restrict__ bias,
                                              float* __restrict__ C, long ldc,
                                              const float* __restrict__ gamma,
                                              int M, int N, int K){
    __shared__ float As[16][68];
    __shared__ float Ws[16][68];
    const int tid = threadIdx.x;
    const int row0 = blockIdx.x * 64, col0 = blockIdx.y * 64;
    const int lm = tid >> 2;
    const int lk = (tid & 3) << 2;
    const int ty = tid >> 4, tx = tid & 15;
    float acc[4][4] = {};
    for (int k0 = 0; k0 < K; k0 += 16){
        int gr = row0 + lm;
        float4 va = make_float4(0.f, 0.f, 0.f, 0.f);
        if (gr < M) va = *reinterpret_cast<const float4*>(A + (long)gr * lda + k0 + lk);
        As[lk + 0][lm] = va.x; As[lk + 1][lm] = va.y; As[lk + 2][lm] = va.z; As[lk + 3][lm] = va.w;
        int gc = col0 + lm;
        float4 vw = make_float4(0.f, 0.f, 0.f, 0.f);
        if (gc < N) vw = *reinterpret_cast<const float4*>(W + (long)gc * K + k0 + lk);
        Ws[lk + 0][lm] = vw.x; Ws[lk + 1][lm] = vw.y; Ws[lk + 2][lm] = vw.z; Ws[lk + 3][lm] = vw.w;
        __syncthreads();
        #pragma unroll
        for (int kk = 0; kk < 16; kk++){
            float4 av = *reinterpret_cast<const float4*>(&As[kk][ty << 2]);
            float4 bv = *reinterpret_cast<const float4*>(&Ws[kk][tx << 2]);
            float a0 = av.x, a1 = av.y, a2 = av.z, a3 = av.w;
            float b0 = bv.x, b1 = bv.y, b2 = bv.z, b3 = bv.w;
            acc[0][0] += a0 * b0; acc[0][1] += a0 * b1; acc[0][2] += a0 * b2; acc[0][3] += a0 * b3;
            acc[1][0] += a1 * b0; acc[1][1] += a1 * b1; acc[1][2] += a1 * b2; acc[1][3] += a1 * b3;
            acc[2][0] += a2 * b0; acc[2][1] += a2 * b1; acc[2][2] += a2 * b2; acc[2][3] += a2 * b3;
            acc[3][0] += a3 * b0; acc[3][1] += a3 * b1; acc[3][2] += a3 * b2; acc[3][3] += a3 * b3;
        }
        __syncthreads();
    }
    #pragma unroll
    for (int i = 0; i < 4; i++){
        int row = row0 + (ty << 2) + i;
        if (row >= M) continue;
        #pragma unroll
        for (int j = 0; j < 4; j++){
            int col = col0 + (tx << 2) + j;
            if (col >= N) continue;
            float v = acc[i][j] + bias[col];
            if (MODE == 1) v = gelu_f(v);
            long ci = (long)row * ldc + col;
            if (MODE == 2) C[ci] += gamma[col] * v;
            else C[ci] = v;
        }
    }
}

// ---------------- Implicit-GEMM conv 3x3 stride2 pad1 + eval-BN (+ optional GELU) ----------------
// Block: 64 output channels x (8x8) output pixels; K-loop over ci chunks of CIT.
// LDS: input patch tile [CIT][17][18] + weight chunk [CIT*9][64].
template<int CIT>
__global__ __launch_bounds__(256) void conv_ig(const float* __restrict__ in, const float* __restrict__ w,
                                               const float* __restrict__ g, const float* __restrict__ bb,
                                               float* __restrict__ out,
                                               int Ci, int Hi, int Wi, int Co, int Ho, int Wo,
                                               int do_gelu, int ntx){
    __shared__ float in_t[CIT][17][18];
    __shared__ float w_t[CIT * 9][64];
    const int tid = threadIdx.x;
    const int b   = blockIdx.z;
    const int co0 = blockIdx.y * 64;
    const int oy0 = (blockIdx.x / ntx) * 8;
    const int ox0 = (blockIdx.x % ntx) * 8;
    const int ty = tid >> 4, tx = tid & 15;
    const int py = tx >> 1, px0 = (tx & 1) << 2;   // 4 pixels: (py, px0..px0+3)
    float acc[4][4] = {};                          // [pixel][co]
    const float* inb = in + (long)b * Ci * Hi * Wi;
    for (int cc = 0; cc < Ci; cc += CIT){
        for (int idx = tid; idx < CIT * 289; idx += 256){
            int ci = idx / 289, rem = idx % 289;
            int r = rem / 17, c = rem % 17;
            int iy = oy0 * 2 - 1 + r, ix = ox0 * 2 - 1 + c;
            float v = 0.f;
            if ((unsigned)iy < (unsigned)Hi && (unsigned)ix < (unsigned)Wi)
                v = inb[((long)(cc + ci) * Hi + iy) * Wi + ix];
            in_t[ci][r][c] = v;
        }
        for (int idx = tid; idx < CIT * 9 * 64; idx += 256){
            int k = idx >> 6, j = idx & 63;
            int co = co0 + j;
            float v = 0.f;
            if (co < Co) v = w[((long)co * Ci + cc) * 9 + k];
            w_t[k][j] = v;
        }
        __syncthreads();
        #pragma unroll 2
        for (int ci = 0; ci < CIT; ci++){
            #pragma unroll
            for (int ky = 0; ky < 3; ky++){
                #pragma unroll
                for (int kx = 0; kx < 3; kx++){
                    float a0 = in_t[ci][py * 2 + ky][(px0 + 0) * 2 + kx];
                    float a1 = in_t[ci][py * 2 + ky][(px0 + 1) * 2 + kx];
                    float a2 = in_t[ci][py * 2 + ky][(px0 + 2) * 2 + kx];
                    float a3 = in_t[ci][py * 2 + ky][(px0 + 3) * 2 + kx];
                    float4 wv = *reinterpret_cast<const float4*>(&w_t[ci * 9 + ky * 3 + kx][ty << 2]);
                    acc[0][0] += a0 * wv.x; acc[0][1] += a0 * wv.y; acc[0][2] += a0 * wv.z; acc[0][3] += a0 * wv.w;
                    acc[1][0] += a1 * wv.x; acc[1][1] += a1 * wv.y; acc[1][2] += a1 * wv.z; acc[1][3] += a1 * wv.w;
                    acc[2][0] += a2 * wv.x; acc[2][1] += a2 * wv.y; acc[2][2] += a2 * wv.z; acc[2][3] += a2 * wv.w;
                    acc[3][0] += a3 * wv.x; acc[3][1] += a3 * wv.y; acc[3][2] += a3 * wv.z; acc[3][3] += a3 * wv.w;
                }
            }
        }
        __syncthreads();
    }
    const int oy = oy0 + py;
    #pragma unroll
    for (int j = 0; j < 4; j++){
        int co = co0 + (ty << 2) + j;
        if (co >= Co) continue;
        float scale = g[co] * rsqrtf(1.0f + 1e-5f);
        float bias = bb[co];
        float* ob = out + ((long)(b * Co + co) * Ho + oy) * Wo;
        #pragma unroll
        for (int pi = 0; pi < 4; pi++){
            int ox = ox0 + px0 + pi;
            if (oy < Ho && ox < Wo){
                float v = acc[pi][j] * scale + bias;
                if (do_gelu) v = gelu_f(v);
                ob[ox] = v;
            }
        }
    }
}

// ---------------- positional embedding: pos[n, d] ----------------
__global__ __launch_bounds__(384) void pos_embed(const float* __restrict__ pw, const float* __restrict__ pb,
                                                 float* __restrict__ pos){
    __shared__ float p64[64];
    int n = blockIdx.x;
    int iy = n / 14, ix = n % 14;
    int t = threadIdx.x;
    if (t < 64){
        int axis = t >> 5;       // 0 -> y, 1 -> x
        int c = t & 31;
        int u = c >> 1;
        float coord = (axis == 0) ? (float)(iy + 1) : (float)(ix + 1);
        float val = coord / ((14.0f + 1e-6f) * 6.283185307179586f);
        float T = powf(10000.0f, (float)u / 16.0f);
        float a = val / T;
        p64[t] = (c & 1) ? cosf(a) : sinf(a);
    }
    __syncthreads();
    float acc = 0.f;
    const float* wr = pw + (long)t * 64;
    #pragma unroll 8
    for (int c = 0; c < 64; c++) acc += p64[c] * wr[c];
    pos[n * 384 + t] = acc + pb[t];
}

// t[b,n,d] = c4[b,d,n] + pos[n,d]
__global__ __launch_bounds__(256) void build_t(const float* __restrict__ c4, const float* __restrict__ pos,
                                               float* __restrict__ t){
    long i = (long)blockIdx.x * 256 + threadIdx.x;
    if (i >= (long)B_ * N_ * D_) return;
    int d = (int)(i % 384);
    long bn = i / 384;
    int n = (int)(bn % 196);
    int b = (int)(bn / 196);
    t[i] = c4[((long)b * 384 + d) * 196 + n] + pos[n * 384 + d];
}

// ---------------- XCA attention: one block per (b, head) ----------------
__global__ __launch_bounds__(256) void xca_attn(const float* __restrict__ qkv, const float* __restrict__ temp,
                                                float* __restrict__ o){
    int bh = blockIdx.x;
    int b = bh >> 3, h = bh & 7;
    __shared__ alignas(16) __hip_bfloat16 qs[48 * 196];
    __shared__ alignas(16) __hip_bfloat16 ks[48 * 196];
    __shared__ alignas(16) __hip_bfloat16 vs[48 * 196];
    __shared__ float inq[48], ink[48];
    int tid = threadIdx.x;
    const float* base = qkv + (long)b * 196 * 1152 + h * 48;
    for (int i = tid; i < 48 * 196; i += 256){
        int n = i / 48, d = i % 48;
        const float* p = base + (long)n * 1152;
        qs[d * 196 + n] = __float2bfloat16(p[d]);
        ks[d * 196 + n] = __float2bfloat16(p[384 + d]);
        vs[d * 196 + n] = __float2bfloat16(p[768 + d]);
    }
    __syncthreads();
    int wid = tid >> 6, lane = tid & 63;
    for (int r = wid; r < 48; r += 4){
        float sq = 0.f, sk = 0.f;
        for (int n = lane; n < 196; n += 64){
            float qv = __bfloat162float(qs[r * 196 + n]);
            float kv = __bfloat162float(ks[r * 196 + n]);
            sq += qv * qv; sk += kv * kv;
        }
        for (int off = 32; off; off >>= 1){ sq += __shfl_down(sq, off); sk += __shfl_down(sk, off); }
        if (lane == 0){
            inq[r] = 1.0f / fmaxf(sqrtf(sq), 1e-12f);
            ink[r] = 1.0f / fmaxf(sqrtf(sk), 1e-12f);
        }
    }
    __syncthreads();
    float tempv = temp[h];
    float rv[9];
    #pragma unroll
    for (int it = 0; it < 9; it++){
        int idx = tid + it * 256;
        int d = idx / 48, e = idx - d * 48;
        const __hip_bfloat16* qr = qs + d * 196;
        const __hip_bfloat16* kr = ks + e * 196;
        float s = 0.f;
        for (int n = 0; n < 196; n++) s += __bfloat162float(qr[n]) * __bfloat162float(kr[n]);
        rv[it] = s * inq[d] * ink[e] * tempv;
    }
    __syncthreads();
    float* at = reinterpret_cast<float*>(qs);   // overlay (9.4KB <= 18.8KB)
    #pragma unroll
    for (int it = 0; it < 9; it++){
        int idx = tid + it * 256;
        int d = idx / 48, e = idx - d * 48;
        at[d * 49 + e] = rv[it];
    }
    __syncthreads();
    if (tid < 48){
        float* row = at + tid * 49;
        float m = -1e30f;
        for (int e = 0; e < 48; e++) m = fmaxf(m, row[e]);
        float ssum = 0.f;
        for (int e = 0; e < 48; e++){ float ev = expf(row[e] - m); row[e] = ev; ssum += ev; }
        float inv = 1.0f / ssum;
        for (int e = 0; e < 48; e++) row[e] *= inv;
    }
    __syncthreads();
    for (int idx = tid; idx < 48 * 196; idx += 256){
        int d = idx % 48, n = idx / 48;
        const float* arow = at + d * 49;
        float s = 0.f;
        for (int e = 0; e < 48; e++) s += arow[e] * __bfloat162float(vs[e * 196 + n]);
        o[((long)b * 196 + n) * 384 + h * 48 + d] = s;
    }
}

// ---------------- LPI: both depthwise 3x3 convs fused, one block per (b, d) plane ----------------
__global__ __launch_bounds__(256) void lpi(const float* __restrict__ ht,
                                           const float* __restrict__ w1, const float* __restrict__ b1,
                                           const float* __restrict__ bng, const float* __restrict__ bnb,
                                           const float* __restrict__ w2, const float* __restrict__ b2,
                                           const float* __restrict__ g3, float* __restrict__ t){
    int bd = blockIdx.x;
    int d = bd % 384, b = bd / 384;
    __shared__ float p[16][16];
    __shared__ float p2[16][16];
    __shared__ float wA[9], wB[9];
    int tt = threadIdx.x;
    int yy = tt / 16, xx = tt % 16;
    p[yy][xx] = 0.f; p2[yy][xx] = 0.f;
    if (tt < 9){ wA[tt] = w1[d * 9 + tt]; wB[tt] = w2[d * 9 + tt]; }
    __syncthreads();
    if (tt < 196){
        int y = tt / 14, x = tt % 14;
        p[y + 1][x + 1] = ht[((long)b * 384 + d) * 196 + tt];
    }
    __syncthreads();
    if (tt < 196){
        int y = tt / 14, x = tt % 14;
        float a = 0.f;
        #pragma unroll
        for (int ky = 0; ky < 3; ky++)
            #pragma unroll
            for (int kx = 0; kx < 3; kx++)
                a += wA[ky * 3 + kx] * p[y + ky][x + kx];
        a += b1[d];
        a = gelu_f(a);
        a = a * (bng[d] * rsqrtf(1.0f + 1e-5f)) + bnb[d];
        p2[y + 1][x + 1] = a;
    }
    __syncthreads();
    if (tt < 196){
        int y = tt / 14, x = tt % 14;
        float a = 0.f;
        #pragma unroll
        for (int ky = 0; ky < 3; ky++)
            #pragma unroll
            for (int kx = 0; kx < 3; kx++)
                a += wB[ky * 3 + kx] * p2[y + ky][x + kx];
        a += b2[d];
        long ti = ((long)b * 196 + tt) * 384 + d;
        t[ti] += g3[d] * a;
    }
}

// ---------------- cls concat ----------------
__global__ __launch_bounds__(256) void concat_cls(const float* __restrict__ t, const float* __restrict__ clstok,
                                                  float* __restrict__ tc){
    long i = (long)blockIdx.x * 256 + threadIdx.x;
    if (i >= (long)B_ * 197 * 384) return;
    int d = (int)(i % 384);
    long bn = i / 384;
    int n = (int)(bn % 197);
    int b = (int)(bn / 197);
    tc[i] = (n == 0) ? clstok[d] : t[((long)b * 196 + (n - 1)) * 384 + d];
}

// ---------------- CA attention: one block per (b, head), cls query only ----------------
__global__ __launch_bounds__(256) void ca_attn(const float* __restrict__ qkv, float* __restrict__ clsp){
    int bh = blockIdx.x;
    int b = bh >> 3, h = bh & 7;
    const float* base = qkv + (long)b * 197 * 1152 + h * 48;
    __shared__ float q0[48];
    __shared__ float at[197];
    __shared__ float smax, ssum;
    int tid = threadIdx.x;
    if (tid < 48) q0[tid] = base[tid];
    __syncthreads();
    if (tid < 197){
        const float* kr = base + (long)tid * 1152 + 384;
        float s = 0.f;
        for (int d = 0; d < 48; d++) s += q0[d] * kr[d];
        at[tid] = s * rsqrtf(48.0f);
    }
    __syncthreads();
    if (tid == 0){
        float m = -1e30f;
        for (int n = 0; n < 197; n++) m = fmaxf(m, at[n]);
        smax = m;
    }
    __syncthreads();
    if (tid < 197) at[tid] = expf(at[tid] - smax);
    __syncthreads();
    if (tid == 0){
        float s = 0.f;
        for (int n = 0; n < 197; n++) s += at[n];
        ssum = s;
    }
    __syncthreads();
    if (tid < 48){
        const float* vb = base + 768 + tid;
        float s = 0.f;
        for (int n = 0; n < 197; n++) s += at[n] * vb[(long)n * 1152];
        clsp[b * 384 + h * 48 + tid] = s / ssum;
    }
}

// t update after CA attention: token0 += g1*proj(cls); others += g1*h
__global__ __launch_bounds__(256) void ca_update1(const float* __restrict__ clso, const float* __restrict__ hc,
                                                  const float* __restrict__ g1, float* __restrict__ tc){
    long i = (long)blockIdx.x * 256 + threadIdx.x;
    if (i >= (long)B_ * 197 * 384) return;
    int d = (int)(i % 384);
    long bn = i / 384;
    int n = (int)(bn % 197);
    int b = (int)(bn / 197);
    float add = (n == 0) ? clso[b * 384 + d] : hc[i];
    tc[i] += g1[d] * add;
}

// final CA update: token0 = g2*cls2 + hc ; others = 2*hc   (hc = LN2 output)
__global__ __launch_bounds__(256) void ca_update2(const float* __restrict__ cls2, const float* __restrict__ hc,
                                                  const float* __restrict__ g2, float* __restrict__ tc){
    long i = (long)blockIdx.x * 256 + threadIdx.x;
    if (i >= (long)B_ * 197 * 384) return;
    int d = (int)(i % 384);
    long bn = i / 384;
    int n = (int)(bn % 197);
    int b = (int)(bn / 197);
    float hv = hc[i];
    tc[i] = (n == 0) ? (g2[d] * cls2[b * 384 + d] + hv) : (hv + hv);
}

extern "C" void kernel_launch(void* const* d_in, const int* in_sizes, int n_in,
                              void* d_out, int out_size, void* d_ws, size_t ws_size,
                              hipStream_t stream){
    (void)in_sizes; (void)n_in; (void)out_size; (void)ws_size;
    const float* x      = (const float*)d_in[0];
    const float* clstok = (const float*)d_in[1];
    const float* pos_w  = (const float*)d_in[2];
    const float* pos_b  = (const float*)d_in[3];
    const float* pe_w[4] = {(const float*)d_in[4], (const float*)d_in[7], (const float*)d_in[10], (const float*)d_in[13]};
    const float* pe_g[4] = {(const float*)d_in[5], (const float*)d_in[8], (const float*)d_in[11], (const float*)d_in[14]};
    const float* pe_b[4] = {(const float*)d_in[6], (const float*)d_in[9], (const float*)d_in[12], (const float*)d_in[15]};
    const float* xqkv_w = (const float*)d_in[16];
    const float* xqkv_b = (const float*)d_in[17];
    const float* xproj_w = (const float*)d_in[18];
    const float* xproj_b = (const float*)d_in[19];
    const float* xtemp  = (const float*)d_in[20];
    const float* xn1_w = (const float*)d_in[21];
    const float* xn1_b = (const float*)d_in[22];
    const float* xn2_w = (const float*)d_in[23];
    const float* xn2_b = (const float*)d_in[24];
    const float* xn3_w = (const float*)d_in[25];
    const float* xn3_b = (const float*)d_in[26];
    const float* xfc1_w = (const float*)d_in[27];
    const float* xfc1_b = (const float*)d_in[28];
    const float* xfc2_w = (const float*)d_in[29];
    const float* xfc2_b = (const float*)d_in[30];
    const float* xlpi1_w = (const float*)d_in[31];
    const float* xlpi1_b = (const float*)d_in[32];
    const float* xlpi2_w = (const float*)d_in[33];
    const float* xlpi2_b = (const float*)d_in[34];
    const float* xbn_g = (const float*)d_in[35];
    const float* xbn_b = (const float*)d_in[36];
    const float* xg1 = (const float*)d_in[37];
    const float* xg2 = (const float*)d_in[38];
    const float* xg3 = (const float*)d_in[39];
    const float* cqkv_w = (const float*)d_in[40];
    const float* cqkv_b = (const float*)d_in[41];
    const float* cproj_w = (const float*)d_in[42];
    const float* cproj_b = (const float*)d_in[43];
    const float* cn1_w = (const float*)d_in[44];
    const float* cn1_b = (const float*)d_in[45];
    const float* cn2_w = (const float*)d_in[46];
    const float* cn2_b = (const float*)d_in[47];
    const float* cfc1_w = (const float*)d_in[48];
    const float* cfc1_b = (const float*)d_in[49];
    const float* cfc2_w = (const float*)d_in[50];
    const float* cfc2_b = (const float*)d_in[51];
    const float* cg1 = (const float*)d_in[52];
    const float* cg2 = (const float*)d_in[53];
    const float* norm_w = (const float*)d_in[54];
    const float* norm_b = (const float*)d_in[55];
    const float* head_w = (const float*)d_in[56];
    const float* head_b = (const float*)d_in[57];
    float* outp = (float*)d_out;

    // workspace layout (floats). Regions alias across phases.
    float* ws = (float*)d_ws;
    float* regA = ws;                       // 19,267,584 floats
    float* regB = ws + 19267584L;           //  9,633,792 floats
    float* t    = ws + 28901376L;           //  2,408,448
    float* pos  = ws + 31309824L;           //     75,264
    float* h    = ws + 31385088L;           //  2,408,448
    float* tc   = ws + 33793536L;           //  2,420,736
    float* hc   = ws + 36214272L;           //  2,420,736
    // aliases inside regA (transformer phase):
    float* qkv  = regA;                     //  7,225,344
    float* ht   = regA + 7225344L;          //  2,408,448
    float* o    = regA + 9633792L;          //  2,408,448
    float* clsp = regA + 12042240L;
    float* clso = clsp + 12288;
    float* f1c  = clso + 12288;
    float* cls2 = f1c + 49152;
    float* clsf = cls2 + 12288;
    float* f1   = regB;                     //  9,633,792 (exact)

    // ---- patch embed (implicit-GEMM convs) ----
    {   // conv1: x[32,3,224,224] -> regA[32,48,112,112]
        dim3 g(14 * 14, 1, 32);
        conv_ig<3><<<g, 256, 0, stream>>>(x, pe_w[0], pe_g[0], pe_b[0], regA,
                                          3, 224, 224, 48, 112, 112, 1, 14);
    }
    {   // conv2: regA -> regB[32,96,56,56]
        dim3 g(7 * 7, 2, 32);
        conv_ig<8><<<g, 256, 0, stream>>>(regA, pe_w[1], pe_g[1], pe_b[1], regB,
                                          48, 112, 112, 96, 56, 56, 1, 7);
    }
    {   // conv3: regB -> regA[32,192,28,28]
        dim3 g(4 * 4, 3, 32);
        conv_ig<8><<<g, 256, 0, stream>>>(regB, pe_w[2], pe_g[2], pe_b[2], regA,
                                          96, 56, 56, 192, 28, 28, 1, 4);
    }
    {   // conv4: regA -> regB[32,384,14,14]  (no gelu)
        dim3 g(2 * 2, 6, 32);
        conv_ig<8><<<g, 256, 0, stream>>>(regA, pe_w[3], pe_g[3], pe_b[3], regB,
                                          192, 28, 28, 384, 14, 14, 0, 2);
    }
    pos_embed<<<196, 384, 0, stream>>>(pos_w, pos_b, pos);
    build_t<<<(int)(((long)B_ * N_ * D_) / 256), 256, 0, stream>>>(regB, pos, t);

    // ---- 24 XCA layers ----
    const int M = B_ * N_;  // 6272
    for (int l = 0; l < L_; l++){
        ln384<<<M, 128, 0, stream>>>(t, 384, xn1_w + l * 384, xn1_b + l * 384, h, 384);
        {
            dim3 g((M + 63) / 64, 1152 / 64);
            gemm64<0><<<g, 256, 0, stream>>>(h, 384, xqkv_w + (long)l * 1152 * 384, xqkv_b + l * 1152,
                                             qkv, 1152, nullptr, M, 1152, 384);
        }
        xca_attn<<<B_ * NH_, 256, 0, stream>>>(qkv, xtemp + l * 8, o);
        {
            dim3 g((M + 63) / 64, 384 / 64);
            gemm64<2><<<g, 256, 0, stream>>>(o, 384, xproj_w + (long)l * 384 * 384, xproj_b + l * 384,
                                             t, 384, xg1 + l * 384, M, 384, 384);
        }
        ln384_t<<<M, 128, 0, stream>>>(t, xn3_w + l * 384, xn3_b + l * 384, ht);
        lpi<<<B_ * D_, 256, 0, stream>>>(ht, xlpi1_w + (long)l * 384 * 9, xlpi1_b + l * 384,
                                         xbn_g + l * 384, xbn_b + l * 384,
                                         xlpi2_w + (long)l * 384 * 9, xlpi2_b + l * 384,
                                         xg3 + l * 384, t);
        ln384<<<M, 128, 0, stream>>>(t, 384, xn2_w + l * 384, xn2_b + l * 384, h, 384);
        {
            dim3 g((M + 63) / 64, 1536 / 64);
            gemm64<1><<<g, 256, 0, stream>>>(h, 384, xfc1_w + (long)l * 1536 * 384, xfc1_b + l * 1536,
                                             f1, 1536, nullptr, M, 1536, 384);
        }
        {
            dim3 g((M + 63) / 64, 384 / 64);
            gemm64<2><<<g, 256, 0, stream>>>(f1, 1536, xfc2_w + (long)l * 384 * 1536, xfc2_b + l * 384,
                                             t, 384, xg2 + l * 384, M, 384, 1536);
        }
    }

    // ---- cls concat + 2 CA blocks ----
    const long NC = (long)B_ * 197 * 384;   // 2,420,736 (divisible by 256)
    concat_cls<<<(int)(NC / 256), 256, 0, stream>>>(t, clstok, tc);
    const int MC = B_ * 197;  // 6304
    for (int i = 0; i < 2; i++){
        ln384<<<MC, 128, 0, stream>>>(tc, 384, cn1_w + i * 384, cn1_b + i * 384, hc, 384);
        {
            dim3 g((MC + 63) / 64, 1152 / 64);
            gemm64<0><<<g, 256, 0, stream>>>(hc, 384, cqkv_w + (long)i * 1152 * 384, cqkv_b + i * 1152,
                                             qkv, 1152, nullptr, MC, 1152, 384);
        }
        ca_attn<<<B_ * NH_, 256, 0, stream>>>(qkv, clsp);
        {
            dim3 g(1, 384 / 64);
            gemm64<0><<<g, 256, 0, stream>>>(clsp, 384, cproj_w + (long)i * 384 * 384, cproj_b + i * 384,
                                             clso, 384, nullptr, 32, 384, 384);
        }
        ca_update1<<<(int)(NC / 256), 256, 0, stream>>>(clso, hc, cg1 + i * 384, tc);
        ln384<<<MC, 128, 0, stream>>>(tc, 384, cn2_w + i * 384, cn2_b + i * 384, hc, 384);
        {
            dim3 g(1, 1536 / 64);
            gemm64<1><<<g, 256, 0, stream>>>(hc, (long)197 * 384, cfc1_w + (long)i * 1536 * 384, cfc1_b + i * 1536,
                                             f1c, 1536, nullptr, 32, 1536, 384);
        }
        {
            dim3 g(1, 384 / 64);
            gemm64<0><<<g, 256, 0, stream>>>(f1c, 1536, cfc2_w + (long)i * 384 * 1536, cfc2_b + i * 384,
                                             cls2, 384, nullptr, 32, 384, 1536);
        }
        ca_update2<<<(int)(NC / 256), 256, 0, stream>>>(cls2, hc, cg2 + i * 384, tc);
    }

    // ---- final LN (cls token only) + head ----
    ln384<<<32, 128, 0, stream>>>(tc, (long)197 * 384, norm_w, norm_b, clsf, 384);
    {
        dim3 g(1, (1000 + 63) / 64);
        gemm64<0><<<g, 256, 0, stream>>>(clsf, 384, head_w, head_b, outp, 1000, nullptr, 32, 1000, 384);
    }
}

// Round 3
// 8845.335 us; speedup vs baseline: 2.3759x; 1.5903x over previous
//
#include <hip/hip_runtime.h>
#include <hip/hip_bf16.h>

#define B_ 32
#define D_ 384
#define N_ 196
#define NH_ 8
#define HD_ 48
#define L_ 24

typedef __bf16 bf16x8 __attribute__((ext_vector_type(8)));
typedef __bf16 bf16x4 __attribute__((ext_vector_type(4)));
typedef float f32x4 __attribute__((ext_vector_type(4)));

__device__ __forceinline__ float gelu_f(float v){
    return 0.5f * v * (1.0f + erff(v * 0.70710678118654752f));
}

__device__ __forceinline__ bf16x4 cvt4(float4 v){
    bf16x4 r;
    r[0] = (__bf16)v.x; r[1] = (__bf16)v.y; r[2] = (__bf16)v.z; r[3] = (__bf16)v.w;
    return r;
}

// ---------------- LayerNorm over D=384, generic strided ----------------
__global__ __launch_bounds__(128) void ln384(const float* __restrict__ x, long xstride,
                                             const float* __restrict__ w, const float* __restrict__ b,
                                             float* __restrict__ y, long ystride){
    long row = blockIdx.x;
    int tid = threadIdx.x;
    const float* xr = x + row * xstride;
    float v0 = xr[tid], v1 = xr[tid + 128], v2 = xr[tid + 256];
    float s = v0 + v1 + v2;
    float ss = v0 * v0 + v1 * v1 + v2 * v2;
    for (int off = 32; off; off >>= 1){ s += __shfl_down(s, off); ss += __shfl_down(ss, off); }
    __shared__ float rs[2], rss[2];
    if ((tid & 63) == 0){ rs[tid >> 6] = s; rss[tid >> 6] = ss; }
    __syncthreads();
    float S = rs[0] + rs[1], SS = rss[0] + rss[1];
    float m = S * (1.0f / 384.0f);
    float var = SS * (1.0f / 384.0f) - m * m;
    float r = rsqrtf(var + 1e-5f);
    float* yr = y + row * ystride;
    yr[tid]       = (v0 - m) * r * w[tid]       + b[tid];
    yr[tid + 128] = (v1 - m) * r * w[tid + 128] + b[tid + 128];
    yr[tid + 256] = (v2 - m) * r * w[tid + 256] + b[tid + 256];
}

// LayerNorm writing transposed output: y[b, d, n]  (input rows are b*196+n)
__global__ __launch_bounds__(128) void ln384_t(const float* __restrict__ x,
                                               const float* __restrict__ w, const float* __restrict__ b,
                                               float* __restrict__ y){
    long row = blockIdx.x;
    int tid = threadIdx.x;
    const float* xr = x + row * 384;
    float v0 = xr[tid], v1 = xr[tid + 128], v2 = xr[tid + 256];
    float s = v0 + v1 + v2;
    float ss = v0 * v0 + v1 * v1 + v2 * v2;
    for (int off = 32; off; off >>= 1){ s += __shfl_down(s, off); ss += __shfl_down(ss, off); }
    __shared__ float rs[2], rss[2];
    if ((tid & 63) == 0){ rs[tid >> 6] = s; rss[tid >> 6] = ss; }
    __syncthreads();
    float S = rs[0] + rs[1], SS = rss[0] + rss[1];
    float m = S * (1.0f / 384.0f);
    float var = SS * (1.0f / 384.0f) - m * m;
    float r = rsqrtf(var + 1e-5f);
    int bb = (int)(row / 196), n = (int)(row % 196);
    float* yb = y + ((long)bb * 384) * 196 + n;
    yb[(long)tid * 196]         = (v0 - m) * r * w[tid]       + b[tid];
    yb[(long)(tid + 128) * 196] = (v1 - m) * r * w[tid + 128] + b[tid + 128];
    yb[(long)(tid + 256) * 196] = (v2 - m) * r * w[tid + 256] + b[tid + 256];
}

// ---------------- bf16 MFMA GEMM: C[M,N] = A[M,K] @ W[N,K]^T + bias ----------------
// A, W are fp32 in global; converted to bf16 while staging into LDS.
// Tile 128x128, BK=32, 4 waves (2x2), each wave 64x64 via 16x16x32 MFMA.
// Requires M%128==0, N%128==0, K%32==0.
// MODE 0: C = acc+bias ; MODE 1: C = gelu(acc+bias) ; MODE 2: C += gamma[col]*(acc+bias)
template<int MODE>
__global__ __launch_bounds__(256) void gemm_mfma(const float* __restrict__ A, long lda,
                                                 const float* __restrict__ W,
                                                 const float* __restrict__ bias,
                                                 float* __restrict__ C, long ldc,
                                                 const float* __restrict__ gamma,
                                                 int K){
    // LDS: A tile 128 rows x 32 bf16, row stride 80B (16B pad) -> 10240B each
    __shared__ __align__(16) char smem[20480];
    char* Ab = smem;
    char* Bb = smem + 10240;
    const int tid  = threadIdx.x;
    const int lane = tid & 63;
    const int wn   = (tid >> 6) & 1;
    const int wm   = tid >> 7;
    const int row0 = blockIdx.x * 128;
    const int col0 = blockIdx.y * 128;
    const int lrow = lane >> 4;     // 0..3
    const int lcol = lane & 15;     // 0..15
    f32x4 acc[4][4] = {};
    for (int k0 = 0; k0 < K; k0 += 32){
        // stage A and W tiles (each: 128 rows x 32 floats = 1024 float4; 4 per thread)
        #pragma unroll
        for (int i = 0; i < 4; i++){
            int p = i * 256 + tid;
            int r = p >> 3, kq = p & 7;
            float4 va = *reinterpret_cast<const float4*>(A + (long)(row0 + r) * lda + k0 + (kq << 2));
            *reinterpret_cast<bf16x4*>(Ab + r * 80 + (kq << 3)) = cvt4(va);
            float4 vw = *reinterpret_cast<const float4*>(W + (long)(col0 + r) * K + k0 + (kq << 2));
            *reinterpret_cast<bf16x4*>(Bb + r * 80 + (kq << 3)) = cvt4(vw);
        }
        __syncthreads();
        bf16x8 af[4], bf[4];
        #pragma unroll
        for (int m = 0; m < 4; m++){
            int r = wm * 64 + m * 16 + lcol;
            af[m] = *reinterpret_cast<const bf16x8*>(Ab + r * 80 + ((lane >> 4) << 4));
        }
        #pragma unroll
        for (int n = 0; n < 4; n++){
            int r = wn * 64 + n * 16 + lcol;
            bf[n] = *reinterpret_cast<const bf16x8*>(Bb + r * 80 + ((lane >> 4) << 4));
        }
        #pragma unroll
        for (int m = 0; m < 4; m++)
            #pragma unroll
            for (int n = 0; n < 4; n++)
                acc[m][n] = __builtin_amdgcn_mfma_f32_16x16x32_bf16(af[m], bf[n], acc[m][n], 0, 0, 0);
        __syncthreads();
    }
    #pragma unroll
    for (int m = 0; m < 4; m++){
        #pragma unroll
        for (int n = 0; n < 4; n++){
            int row = row0 + wm * 64 + m * 16 + lrow * 4;
            int col = col0 + wn * 64 + n * 16 + lcol;
            float bv = bias[col];
            #pragma unroll
            for (int j = 0; j < 4; j++){
                float v = acc[m][n][j] + bv;
                if (MODE == 1) v = gelu_f(v);
                long ci = (long)(row + j) * ldc + col;
                if (MODE == 2) C[ci] += gamma[col] * v;
                else C[ci] = v;
            }
        }
    }
}

// ---------------- Tiled fp32 GEMM (used for CA blocks / head) ----------------
template<int MODE>
__global__ __launch_bounds__(256) void gemm64(const float* __restrict__ A, long lda,
                                              const float* __restrict__ W,
                                              const float* __restrict__ bias,
                                              float* __restrict__ C, long ldc,
                                              const float* __restrict__ gamma,
                                              int M, int N, int K){
    __shared__ float As[16][68];
    __shared__ float Ws[16][68];
    const int tid = threadIdx.x;
    const int row0 = blockIdx.x * 64, col0 = blockIdx.y * 64;
    const int lm = tid >> 2;
    const int lk = (tid & 3) << 2;
    const int ty = tid >> 4, tx = tid & 15;
    float acc[4][4] = {};
    for (int k0 = 0; k0 < K; k0 += 16){
        int gr = row0 + lm;
        float4 va = make_float4(0.f, 0.f, 0.f, 0.f);
        if (gr < M) va = *reinterpret_cast<const float4*>(A + (long)gr * lda + k0 + lk);
        As[lk + 0][lm] = va.x; As[lk + 1][lm] = va.y; As[lk + 2][lm] = va.z; As[lk + 3][lm] = va.w;
        int gc = col0 + lm;
        float4 vw = make_float4(0.f, 0.f, 0.f, 0.f);
        if (gc < N) vw = *reinterpret_cast<const float4*>(W + (long)gc * K + k0 + lk);
        Ws[lk + 0][lm] = vw.x; Ws[lk + 1][lm] = vw.y; Ws[lk + 2][lm] = vw.z; Ws[lk + 3][lm] = vw.w;
        __syncthreads();
        #pragma unroll
        for (int kk = 0; kk < 16; kk++){
            float4 av = *reinterpret_cast<const float4*>(&As[kk][ty << 2]);
            float4 bv = *reinterpret_cast<const float4*>(&Ws[kk][tx << 2]);
            float a0 = av.x, a1 = av.y, a2 = av.z, a3 = av.w;
            float b0 = bv.x, b1 = bv.y, b2 = bv.z, b3 = bv.w;
            acc[0][0] += a0 * b0; acc[0][1] += a0 * b1; acc[0][2] += a0 * b2; acc[0][3] += a0 * b3;
            acc[1][0] += a1 * b0; acc[1][1] += a1 * b1; acc[1][2] += a1 * b2; acc[1][3] += a1 * b3;
            acc[2][0] += a2 * b0; acc[2][1] += a2 * b1; acc[2][2] += a2 * b2; acc[2][3] += a2 * b3;
            acc[3][0] += a3 * b0; acc[3][1] += a3 * b1; acc[3][2] += a3 * b2; acc[3][3] += a3 * b3;
        }
        __syncthreads();
    }
    #pragma unroll
    for (int i = 0; i < 4; i++){
        int row = row0 + (ty << 2) + i;
        if (row >= M) continue;
        #pragma unroll
        for (int j = 0; j < 4; j++){
            int col = col0 + (tx << 2) + j;
            if (col >= N) continue;
            float v = acc[i][j] + bias[col];
            if (MODE == 1) v = gelu_f(v);
            long ci = (long)row * ldc + col;
            if (MODE == 2) C[ci] += gamma[col] * v;
            else C[ci] = v;
        }
    }
}

// ---------------- Implicit-GEMM conv 3x3 stride2 pad1 + eval-BN (+ optional GELU) ----------------
template<int CIT>
__global__ __launch_bounds__(256) void conv_ig(const float* __restrict__ in, const float* __restrict__ w,
                                               const float* __restrict__ g, const float* __restrict__ bb,
                                               float* __restrict__ out,
                                               int Ci, int Hi, int Wi, int Co, int Ho, int Wo,
                                               int do_gelu, int ntx){
    __shared__ float in_t[CIT][17][18];
    __shared__ float w_t[CIT * 9][64];
    const int tid = threadIdx.x;
    const int b   = blockIdx.z;
    const int co0 = blockIdx.y * 64;
    const int oy0 = (blockIdx.x / ntx) * 8;
    const int ox0 = (blockIdx.x % ntx) * 8;
    const int ty = tid >> 4, tx = tid & 15;
    const int py = tx >> 1, px0 = (tx & 1) << 2;
    float acc[4][4] = {};
    const float* inb = in + (long)b * Ci * Hi * Wi;
    for (int cc = 0; cc < Ci; cc += CIT){
        for (int idx = tid; idx < CIT * 289; idx += 256){
            int ci = idx / 289, rem = idx % 289;
            int r = rem / 17, c = rem % 17;
            int iy = oy0 * 2 - 1 + r, ix = ox0 * 2 - 1 + c;
            float v = 0.f;
            if ((unsigned)iy < (unsigned)Hi && (unsigned)ix < (unsigned)Wi)
                v = inb[((long)(cc + ci) * Hi + iy) * Wi + ix];
            in_t[ci][r][c] = v;
        }
        for (int idx = tid; idx < CIT * 9 * 64; idx += 256){
            int k = idx >> 6, j = idx & 63;
            int co = co0 + j;
            float v = 0.f;
            if (co < Co) v = w[((long)co * Ci + cc) * 9 + k];
            w_t[k][j] = v;
        }
        __syncthreads();
        #pragma unroll 2
        for (int ci = 0; ci < CIT; ci++){
            #pragma unroll
            for (int ky = 0; ky < 3; ky++){
                #pragma unroll
                for (int kx = 0; kx < 3; kx++){
                    float a0 = in_t[ci][py * 2 + ky][(px0 + 0) * 2 + kx];
                    float a1 = in_t[ci][py * 2 + ky][(px0 + 1) * 2 + kx];
                    float a2 = in_t[ci][py * 2 + ky][(px0 + 2) * 2 + kx];
                    float a3 = in_t[ci][py * 2 + ky][(px0 + 3) * 2 + kx];
                    float4 wv = *reinterpret_cast<const float4*>(&w_t[ci * 9 + ky * 3 + kx][ty << 2]);
                    acc[0][0] += a0 * wv.x; acc[0][1] += a0 * wv.y; acc[0][2] += a0 * wv.z; acc[0][3] += a0 * wv.w;
                    acc[1][0] += a1 * wv.x; acc[1][1] += a1 * wv.y; acc[1][2] += a1 * wv.z; acc[1][3] += a1 * wv.w;
                    acc[2][0] += a2 * wv.x; acc[2][1] += a2 * wv.y; acc[2][2] += a2 * wv.z; acc[2][3] += a2 * wv.w;
                    acc[3][0] += a3 * wv.x; acc[3][1] += a3 * wv.y; acc[3][2] += a3 * wv.z; acc[3][3] += a3 * wv.w;
                }
            }
        }
        __syncthreads();
    }
    const int oy = oy0 + py;
    #pragma unroll
    for (int j = 0; j < 4; j++){
        int co = co0 + (ty << 2) + j;
        if (co >= Co) continue;
        float scale = g[co] * rsqrtf(1.0f + 1e-5f);
        float bias = bb[co];
        float* ob = out + ((long)(b * Co + co) * Ho + oy) * Wo;
        #pragma unroll
        for (int pi = 0; pi < 4; pi++){
            int ox = ox0 + px0 + pi;
            if (oy < Ho && ox < Wo){
                float v = acc[pi][j] * scale + bias;
                if (do_gelu) v = gelu_f(v);
                ob[ox] = v;
            }
        }
    }
}

// ---------------- positional embedding: pos[n, d] ----------------
__global__ __launch_bounds__(384) void pos_embed(const float* __restrict__ pw, const float* __restrict__ pb,
                                                 float* __restrict__ pos){
    __shared__ float p64[64];
    int n = blockIdx.x;
    int iy = n / 14, ix = n % 14;
    int t = threadIdx.x;
    if (t < 64){
        int axis = t >> 5;
        int c = t & 31;
        int u = c >> 1;
        float coord = (axis == 0) ? (float)(iy + 1) : (float)(ix + 1);
        float val = coord / ((14.0f + 1e-6f) * 6.283185307179586f);
        float T = powf(10000.0f, (float)u / 16.0f);
        float a = val / T;
        p64[t] = (c & 1) ? cosf(a) : sinf(a);
    }
    __syncthreads();
    float acc = 0.f;
    const float* wr = pw + (long)t * 64;
    #pragma unroll 8
    for (int c = 0; c < 64; c++) acc += p64[c] * wr[c];
    pos[n * 384 + t] = acc + pb[t];
}

// t[b,n,d] = c4[b,d,n] + pos[n,d]
__global__ __launch_bounds__(256) void build_t(const float* __restrict__ c4, const float* __restrict__ pos,
                                               float* __restrict__ t){
    long i = (long)blockIdx.x * 256 + threadIdx.x;
    if (i >= (long)B_ * N_ * D_) return;
    int d = (int)(i % 384);
    long bn = i / 384;
    int n = (int)(bn % 196);
    int b = (int)(bn / 196);
    t[i] = c4[((long)b * 384 + d) * 196 + n] + pos[n * 384 + d];
}

// ---------------- XCA attention: one block per (b, head) ----------------
__global__ __launch_bounds__(256) void xca_attn(const float* __restrict__ qkv, const float* __restrict__ temp,
                                                float* __restrict__ o){
    int bh = blockIdx.x;
    int b = bh >> 3, h = bh & 7;
    __shared__ alignas(16) __hip_bfloat16 qs[48 * 196];
    __shared__ alignas(16) __hip_bfloat16 ks[48 * 196];
    __shared__ alignas(16) __hip_bfloat16 vs[48 * 196];
    __shared__ float inq[48], ink[48];
    int tid = threadIdx.x;
    const float* base = qkv + (long)b * 196 * 1152 + h * 48;
    for (int i = tid; i < 48 * 196; i += 256){
        int n = i / 48, d = i % 48;
        const float* p = base + (long)n * 1152;
        qs[d * 196 + n] = __float2bfloat16(p[d]);
        ks[d * 196 + n] = __float2bfloat16(p[384 + d]);
        vs[d * 196 + n] = __float2bfloat16(p[768 + d]);
    }
    __syncthreads();
    int wid = tid >> 6, lane = tid & 63;
    for (int r = wid; r < 48; r += 4){
        float sq = 0.f, sk = 0.f;
        for (int n = lane; n < 196; n += 64){
            float qv = __bfloat162float(qs[r * 196 + n]);
            float kv = __bfloat162float(ks[r * 196 + n]);
            sq += qv * qv; sk += kv * kv;
        }
        for (int off = 32; off; off >>= 1){ sq += __shfl_down(sq, off); sk += __shfl_down(sk, off); }
        if (lane == 0){
            inq[r] = 1.0f / fmaxf(sqrtf(sq), 1e-12f);
            ink[r] = 1.0f / fmaxf(sqrtf(sk), 1e-12f);
        }
    }
    __syncthreads();
    float tempv = temp[h];
    float rv[9];
    #pragma unroll
    for (int it = 0; it < 9; it++){
        int idx = tid + it * 256;
        int d = idx / 48, e = idx - d * 48;
        const __hip_bfloat16* qr = qs + d * 196;
        const __hip_bfloat16* kr = ks + e * 196;
        float s = 0.f;
        for (int n = 0; n < 196; n++) s += __bfloat162float(qr[n]) * __bfloat162float(kr[n]);
        rv[it] = s * inq[d] * ink[e] * tempv;
    }
    __syncthreads();
    float* at = reinterpret_cast<float*>(qs);
    #pragma unroll
    for (int it = 0; it < 9; it++){
        int idx = tid + it * 256;
        int d = idx / 48, e = idx - d * 48;
        at[d * 49 + e] = rv[it];
    }
    __syncthreads();
    if (tid < 48){
        float* row = at + tid * 49;
        float m = -1e30f;
        for (int e = 0; e < 48; e++) m = fmaxf(m, row[e]);
        float ssum = 0.f;
        for (int e = 0; e < 48; e++){ float ev = expf(row[e] - m); row[e] = ev; ssum += ev; }
        float inv = 1.0f / ssum;
        for (int e = 0; e < 48; e++) row[e] *= inv;
    }
    __syncthreads();
    for (int idx = tid; idx < 48 * 196; idx += 256){
        int d = idx % 48, n = idx / 48;
        const float* arow = at + d * 49;
        float s = 0.f;
        for (int e = 0; e < 48; e++) s += arow[e] * __bfloat162float(vs[e * 196 + n]);
        o[((long)b * 196 + n) * 384 + h * 48 + d] = s;
    }
}

// ---------------- LPI ----------------
__global__ __launch_bounds__(256) void lpi(const float* __restrict__ ht,
                                           const float* __restrict__ w1, const float* __restrict__ b1,
                                           const float* __restrict__ bng, const float* __restrict__ bnb,
                                           const float* __restrict__ w2, const float* __restrict__ b2,
                                           const float* __restrict__ g3, float* __restrict__ t){
    int bd = blockIdx.x;
    int d = bd % 384, b = bd / 384;
    __shared__ float p[16][16];
    __shared__ float p2[16][16];
    __shared__ float wA[9], wB[9];
    int tt = threadIdx.x;
    int yy = tt / 16, xx = tt % 16;
    p[yy][xx] = 0.f; p2[yy][xx] = 0.f;
    if (tt < 9){ wA[tt] = w1[d * 9 + tt]; wB[tt] = w2[d * 9 + tt]; }
    __syncthreads();
    if (tt < 196){
        int y = tt / 14, x = tt % 14;
        p[y + 1][x + 1] = ht[((long)b * 384 + d) * 196 + tt];
    }
    __syncthreads();
    if (tt < 196){
        int y = tt / 14, x = tt % 14;
        float a = 0.f;
        #pragma unroll
        for (int ky = 0; ky < 3; ky++)
            #pragma unroll
            for (int kx = 0; kx < 3; kx++)
                a += wA[ky * 3 + kx] * p[y + ky][x + kx];
        a += b1[d];
        a = gelu_f(a);
        a = a * (bng[d] * rsqrtf(1.0f + 1e-5f)) + bnb[d];
        p2[y + 1][x + 1] = a;
    }
    __syncthreads();
    if (tt < 196){
        int y = tt / 14, x = tt % 14;
        float a = 0.f;
        #pragma unroll
        for (int ky = 0; ky < 3; ky++)
            #pragma unroll
            for (int kx = 0; kx < 3; kx++)
                a += wB[ky * 3 + kx] * p2[y + ky][x + kx];
        a += b2[d];
        long ti = ((long)b * 196 + tt) * 384 + d;
        t[ti] += g3[d] * a;
    }
}

// ---------------- cls concat ----------------
__global__ __launch_bounds__(256) void concat_cls(const float* __restrict__ t, const float* __restrict__ clstok,
                                                  float* __restrict__ tc){
    long i = (long)blockIdx.x * 256 + threadIdx.x;
    if (i >= (long)B_ * 197 * 384) return;
    int d = (int)(i % 384);
    long bn = i / 384;
    int n = (int)(bn % 197);
    int b = (int)(bn / 197);
    tc[i] = (n == 0) ? clstok[d] : t[((long)b * 196 + (n - 1)) * 384 + d];
}

// ---------------- CA attention ----------------
__global__ __launch_bounds__(256) void ca_attn(const float* __restrict__ qkv, float* __restrict__ clsp){
    int bh = blockIdx.x;
    int b = bh >> 3, h = bh & 7;
    const float* base = qkv + (long)b * 197 * 1152 + h * 48;
    __shared__ float q0[48];
    __shared__ float at[197];
    __shared__ float smax, ssum;
    int tid = threadIdx.x;
    if (tid < 48) q0[tid] = base[tid];
    __syncthreads();
    if (tid < 197){
        const float* kr = base + (long)tid * 1152 + 384;
        float s = 0.f;
        for (int d = 0; d < 48; d++) s += q0[d] * kr[d];
        at[tid] = s * rsqrtf(48.0f);
    }
    __syncthreads();
    if (tid == 0){
        float m = -1e30f;
        for (int n = 0; n < 197; n++) m = fmaxf(m, at[n]);
        smax = m;
    }
    __syncthreads();
    if (tid < 197) at[tid] = expf(at[tid] - smax);
    __syncthreads();
    if (tid == 0){
        float s = 0.f;
        for (int n = 0; n < 197; n++) s += at[n];
        ssum = s;
    }
    __syncthreads();
    if (tid < 48){
        const float* vb = base + 768 + tid;
        float s = 0.f;
        for (int n = 0; n < 197; n++) s += at[n] * vb[(long)n * 1152];
        clsp[b * 384 + h * 48 + tid] = s / ssum;
    }
}

__global__ __launch_bounds__(256) void ca_update1(const float* __restrict__ clso, const float* __restrict__ hc,
                                                  const float* __restrict__ g1, float* __restrict__ tc){
    long i = (long)blockIdx.x * 256 + threadIdx.x;
    if (i >= (long)B_ * 197 * 384) return;
    int d = (int)(i % 384);
    long bn = i / 384;
    int n = (int)(bn % 197);
    int b = (int)(bn / 197);
    float add = (n == 0) ? clso[b * 384 + d] : hc[i];
    tc[i] += g1[d] * add;
}

__global__ __launch_bounds__(256) void ca_update2(const float* __restrict__ cls2, const float* __restrict__ hc,
                                                  const float* __restrict__ g2, float* __restrict__ tc){
    long i = (long)blockIdx.x * 256 + threadIdx.x;
    if (i >= (long)B_ * 197 * 384) return;
    int d = (int)(i % 384);
    long bn = i / 384;
    int n = (int)(bn % 197);
    int b = (int)(bn / 197);
    float hv = hc[i];
    tc[i] = (n == 0) ? (g2[d] * cls2[b * 384 + d] + hv) : (hv + hv);
}

extern "C" void kernel_launch(void* const* d_in, const int* in_sizes, int n_in,
                              void* d_out, int out_size, void* d_ws, size_t ws_size,
                              hipStream_t stream){
    (void)in_sizes; (void)n_in; (void)out_size; (void)ws_size;
    const float* x      = (const float*)d_in[0];
    const float* clstok = (const float*)d_in[1];
    const float* pos_w  = (const float*)d_in[2];
    const float* pos_b  = (const float*)d_in[3];
    const float* pe_w[4] = {(const float*)d_in[4], (const float*)d_in[7], (const float*)d_in[10], (const float*)d_in[13]};
    const float* pe_g[4] = {(const float*)d_in[5], (const float*)d_in[8], (const float*)d_in[11], (const float*)d_in[14]};
    const float* pe_b[4] = {(const float*)d_in[6], (const float*)d_in[9], (const float*)d_in[12], (const float*)d_in[15]};
    const float* xqkv_w = (const float*)d_in[16];
    const float* xqkv_b = (const float*)d_in[17];
    const float* xproj_w = (const float*)d_in[18];
    const float* xproj_b = (const float*)d_in[19];
    const float* xtemp  = (const float*)d_in[20];
    const float* xn1_w = (const float*)d_in[21];
    const float* xn1_b = (const float*)d_in[22];
    const float* xn2_w = (const float*)d_in[23];
    const float* xn2_b = (const float*)d_in[24];
    const float* xn3_w = (const float*)d_in[25];
    const float* xn3_b = (const float*)d_in[26];
    const float* xfc1_w = (const float*)d_in[27];
    const float* xfc1_b = (const float*)d_in[28];
    const float* xfc2_w = (const float*)d_in[29];
    const float* xfc2_b = (const float*)d_in[30];
    const float* xlpi1_w = (const float*)d_in[31];
    const float* xlpi1_b = (const float*)d_in[32];
    const float* xlpi2_w = (const float*)d_in[33];
    const float* xlpi2_b = (const float*)d_in[34];
    const float* xbn_g = (const float*)d_in[35];
    const float* xbn_b = (const float*)d_in[36];
    const float* xg1 = (const float*)d_in[37];
    const float* xg2 = (const float*)d_in[38];
    const float* xg3 = (const float*)d_in[39];
    const float* cqkv_w = (const float*)d_in[40];
    const float* cqkv_b = (const float*)d_in[41];
    const float* cproj_w = (const float*)d_in[42];
    const float* cproj_b = (const float*)d_in[43];
    const float* cn1_w = (const float*)d_in[44];
    const float* cn1_b = (const float*)d_in[45];
    const float* cn2_w = (const float*)d_in[46];
    const float* cn2_b = (const float*)d_in[47];
    const float* cfc1_w = (const float*)d_in[48];
    const float* cfc1_b = (const float*)d_in[49];
    const float* cfc2_w = (const float*)d_in[50];
    const float* cfc2_b = (const float*)d_in[51];
    const float* cg1 = (const float*)d_in[52];
    const float* cg2 = (const float*)d_in[53];
    const float* norm_w = (const float*)d_in[54];
    const float* norm_b = (const float*)d_in[55];
    const float* head_w = (const float*)d_in[56];
    const float* head_b = (const float*)d_in[57];
    float* outp = (float*)d_out;

    float* ws = (float*)d_ws;
    float* regA = ws;
    float* regB = ws + 19267584L;
    float* t    = ws + 28901376L;
    float* pos  = ws + 31309824L;
    float* h    = ws + 31385088L;
    float* tc   = ws + 33793536L;
    float* hc   = ws + 36214272L;
    float* qkv  = regA;
    float* ht   = regA + 7225344L;
    float* o    = regA + 9633792L;
    float* clsp = regA + 12042240L;
    float* clso = clsp + 12288;
    float* f1c  = clso + 12288;
    float* cls2 = f1c + 49152;
    float* clsf = cls2 + 12288;
    float* f1   = regB;

    // ---- patch embed ----
    {
        dim3 g(14 * 14, 1, 32);
        conv_ig<3><<<g, 256, 0, stream>>>(x, pe_w[0], pe_g[0], pe_b[0], regA,
                                          3, 224, 224, 48, 112, 112, 1, 14);
    }
    {
        dim3 g(7 * 7, 2, 32);
        conv_ig<8><<<g, 256, 0, stream>>>(regA, pe_w[1], pe_g[1], pe_b[1], regB,
                                          48, 112, 112, 96, 56, 56, 1, 7);
    }
    {
        dim3 g(4 * 4, 3, 32);
        conv_ig<8><<<g, 256, 0, stream>>>(regB, pe_w[2], pe_g[2], pe_b[2], regA,
                                          96, 56, 56, 192, 28, 28, 1, 4);
    }
    {
        dim3 g(2 * 2, 6, 32);
        conv_ig<8><<<g, 256, 0, stream>>>(regA, pe_w[3], pe_g[3], pe_b[3], regB,
                                          192, 28, 28, 384, 14, 14, 0, 2);
    }
    pos_embed<<<196, 384, 0, stream>>>(pos_w, pos_b, pos);
    build_t<<<(int)(((long)B_ * N_ * D_) / 256), 256, 0, stream>>>(regB, pos, t);

    // ---- 24 XCA layers (MFMA GEMMs: M=6272, N/K multiples of 128/32) ----
    const int M = B_ * N_;  // 6272 = 49*128
    for (int l = 0; l < L_; l++){
        ln384<<<M, 128, 0, stream>>>(t, 384, xn1_w + l * 384, xn1_b + l * 384, h, 384);
        {
            dim3 g(49, 9);
            gemm_mfma<0><<<g, 256, 0, stream>>>(h, 384, xqkv_w + (long)l * 1152 * 384, xqkv_b + l * 1152,
                                                qkv, 1152, nullptr, 384);
        }
        xca_attn<<<B_ * NH_, 256, 0, stream>>>(qkv, xtemp + l * 8, o);
        {
            dim3 g(49, 3);
            gemm_mfma<2><<<g, 256, 0, stream>>>(o, 384, xproj_w + (long)l * 384 * 384, xproj_b + l * 384,
                                                t, 384, xg1 + l * 384, 384);
        }
        ln384_t<<<M, 128, 0, stream>>>(t, xn3_w + l * 384, xn3_b + l * 384, ht);
        lpi<<<B_ * D_, 256, 0, stream>>>(ht, xlpi1_w + (long)l * 384 * 9, xlpi1_b + l * 384,
                                         xbn_g + l * 384, xbn_b + l * 384,
                                         xlpi2_w + (long)l * 384 * 9, xlpi2_b + l * 384,
                                         xg3 + l * 384, t);
        ln384<<<M, 128, 0, stream>>>(t, 384, xn2_w + l * 384, xn2_b + l * 384, h, 384);
        {
            dim3 g(49, 12);
            gemm_mfma<1><<<g, 256, 0, stream>>>(h, 384, xfc1_w + (long)l * 1536 * 384, xfc1_b + l * 1536,
                                                f1, 1536, nullptr, 384);
        }
        {
            dim3 g(49, 3);
            gemm_mfma<2><<<g, 256, 0, stream>>>(f1, 1536, xfc2_w + (long)l * 384 * 1536, xfc2_b + l * 384,
                                                t, 384, xg2 + l * 384, 1536);
        }
    }

    // ---- cls concat + 2 CA blocks (fp32 gemm64: M=6304 not tile-aligned) ----
    const long NC = (long)B_ * 197 * 384;
    concat_cls<<<(int)(NC / 256), 256, 0, stream>>>(t, clstok, tc);
    const int MC = B_ * 197;  // 6304
    for (int i = 0; i < 2; i++){
        ln384<<<MC, 128, 0, stream>>>(tc, 384, cn1_w + i * 384, cn1_b + i * 384, hc, 384);
        {
            dim3 g((MC + 63) / 64, 1152 / 64);
            gemm64<0><<<g, 256, 0, stream>>>(hc, 384, cqkv_w + (long)i * 1152 * 384, cqkv_b + i * 1152,
                                             qkv, 1152, nullptr, MC, 1152, 384);
        }
        ca_attn<<<B_ * NH_, 256, 0, stream>>>(qkv, clsp);
        {
            dim3 g(1, 384 / 64);
            gemm64<0><<<g, 256, 0, stream>>>(clsp, 384, cproj_w + (long)i * 384 * 384, cproj_b + i * 384,
                                             clso, 384, nullptr, 32, 384, 384);
        }
        ca_update1<<<(int)(NC / 256), 256, 0, stream>>>(clso, hc, cg1 + i * 384, tc);
        ln384<<<MC, 128, 0, stream>>>(tc, 384, cn2_w + i * 384, cn2_b + i * 384, hc, 384);
        {
            dim3 g(1, 1536 / 64);
            gemm64<1><<<g, 256, 0, stream>>>(hc, (long)197 * 384, cfc1_w + (long)i * 1536 * 384, cfc1_b + i * 1536,
                                             f1c, 1536, nullptr, 32, 1536, 384);
        }
        {
            dim3 g(1, 384 / 64);
            gemm64<0><<<g, 256, 0, stream>>>(f1c, 1536, cfc2_w + (long)i * 384 * 1536, cfc2_b + i * 384,
                                             cls2, 384, nullptr, 32, 384, 1536);
        }
        ca_update2<<<(int)(NC / 256), 256, 0, stream>>>(cls2, hc, cg2 + i * 384, tc);
    }

    // ---- final LN (cls token only) + head ----
    ln384<<<32, 128, 0, stream>>>(tc, (long)197 * 384, norm_w, norm_b, clsf, 384);
    {
        dim3 g(1, (1000 + 63) / 64);
        gemm64<0><<<g, 256, 0, stream>>>(clsf, 384, head_w, head_b, outp, 1000, nullptr, 32, 1000, 384);
    }
}

// Round 4
// 6528.263 us; speedup vs baseline: 3.2191x; 1.3549x over previous
//
#include <hip/hip_runtime.h>
#include <hip/hip_bf16.h>

#define B_ 32
#define D_ 384
#define N_ 196
#define NH_ 8
#define HD_ 48
#define L_ 24

typedef __bf16 bf16x8 __attribute__((ext_vector_type(8)));
typedef __bf16 bf16x4 __attribute__((ext_vector_type(4)));
typedef float f32x4 __attribute__((ext_vector_type(4)));

__device__ __forceinline__ float gelu_f(float v){
    return 0.5f * v * (1.0f + erff(v * 0.70710678118654752f));
}

// ---------------- fp32 -> bf16 bulk convert ----------------
__global__ __launch_bounds__(256) void cvt_bf(const float* __restrict__ s, __bf16* __restrict__ d, long n){
    long i = ((long)blockIdx.x * 256 + threadIdx.x) * 8;
    if (i >= n) return;
    float4 a = *reinterpret_cast<const float4*>(s + i);
    float4 b = *reinterpret_cast<const float4*>(s + i + 4);
    bf16x8 r;
    r[0] = (__bf16)a.x; r[1] = (__bf16)a.y; r[2] = (__bf16)a.z; r[3] = (__bf16)a.w;
    r[4] = (__bf16)b.x; r[5] = (__bf16)b.y; r[6] = (__bf16)b.z; r[7] = (__bf16)b.w;
    *reinterpret_cast<bf16x8*>(d + i) = r;
}

// ---------------- LayerNorm over D=384, fp32 out, generic strided ----------------
__global__ __launch_bounds__(128) void ln384(const float* __restrict__ x, long xstride,
                                             const float* __restrict__ w, const float* __restrict__ b,
                                             float* __restrict__ y, long ystride){
    long row = blockIdx.x;
    int tid = threadIdx.x;
    const float* xr = x + row * xstride;
    float v0 = xr[tid], v1 = xr[tid + 128], v2 = xr[tid + 256];
    float s = v0 + v1 + v2;
    float ss = v0 * v0 + v1 * v1 + v2 * v2;
    for (int off = 32; off; off >>= 1){ s += __shfl_down(s, off); ss += __shfl_down(ss, off); }
    __shared__ float rs[2], rss[2];
    if ((tid & 63) == 0){ rs[tid >> 6] = s; rss[tid >> 6] = ss; }
    __syncthreads();
    float S = rs[0] + rs[1], SS = rss[0] + rss[1];
    float m = S * (1.0f / 384.0f);
    float var = SS * (1.0f / 384.0f) - m * m;
    float r = rsqrtf(var + 1e-5f);
    float* yr = y + row * ystride;
    yr[tid]       = (v0 - m) * r * w[tid]       + b[tid];
    yr[tid + 128] = (v1 - m) * r * w[tid + 128] + b[tid + 128];
    yr[tid + 256] = (v2 - m) * r * w[tid + 256] + b[tid + 256];
}

// ---------------- LayerNorm, bf16 out (row stride 384) ----------------
__global__ __launch_bounds__(128) void ln384_bf(const float* __restrict__ x,
                                                const float* __restrict__ w, const float* __restrict__ b,
                                                __bf16* __restrict__ y){
    long row = blockIdx.x;
    int tid = threadIdx.x;
    const float* xr = x + row * 384;
    float v0 = xr[tid], v1 = xr[tid + 128], v2 = xr[tid + 256];
    float s = v0 + v1 + v2;
    float ss = v0 * v0 + v1 * v1 + v2 * v2;
    for (int off = 32; off; off >>= 1){ s += __shfl_down(s, off); ss += __shfl_down(ss, off); }
    __shared__ float rs[2], rss[2];
    if ((tid & 63) == 0){ rs[tid >> 6] = s; rss[tid >> 6] = ss; }
    __syncthreads();
    float S = rs[0] + rs[1], SS = rss[0] + rss[1];
    float m = S * (1.0f / 384.0f);
    float var = SS * (1.0f / 384.0f) - m * m;
    float r = rsqrtf(var + 1e-5f);
    __bf16* yr = y + row * 384;
    yr[tid]       = (__bf16)((v0 - m) * r * w[tid]       + b[tid]);
    yr[tid + 128] = (__bf16)((v1 - m) * r * w[tid + 128] + b[tid + 128]);
    yr[tid + 256] = (__bf16)((v2 - m) * r * w[tid + 256] + b[tid + 256]);
}

// LayerNorm writing transposed fp32 output: y[b, d, n]
__global__ __launch_bounds__(128) void ln384_t(const float* __restrict__ x,
                                               const float* __restrict__ w, const float* __restrict__ b,
                                               float* __restrict__ y){
    long row = blockIdx.x;
    int tid = threadIdx.x;
    const float* xr = x + row * 384;
    float v0 = xr[tid], v1 = xr[tid + 128], v2 = xr[tid + 256];
    float s = v0 + v1 + v2;
    float ss = v0 * v0 + v1 * v1 + v2 * v2;
    for (int off = 32; off; off >>= 1){ s += __shfl_down(s, off); ss += __shfl_down(ss, off); }
    __shared__ float rs[2], rss[2];
    if ((tid & 63) == 0){ rs[tid >> 6] = s; rss[tid >> 6] = ss; }
    __syncthreads();
    float S = rs[0] + rs[1], SS = rss[0] + rss[1];
    float m = S * (1.0f / 384.0f);
    float var = SS * (1.0f / 384.0f) - m * m;
    float r = rsqrtf(var + 1e-5f);
    int bb = (int)(row / 196), n = (int)(row % 196);
    float* yb = y + ((long)bb * 384) * 196 + n;
    yb[(long)tid * 196]         = (v0 - m) * r * w[tid]       + b[tid];
    yb[(long)(tid + 128) * 196] = (v1 - m) * r * w[tid + 128] + b[tid + 128];
    yb[(long)(tid + 256) * 196] = (v2 - m) * r * w[tid + 256] + b[tid + 256];
}

// ---------------- bf16 MFMA GEMM, bf16 A and W: C[M,N] = A @ W^T + bias ----------------
// Tile 128x128, BK=32, 4 waves. M%128==0, N%128==0, K%32==0.
// MODE 0: C = acc+bias ; MODE 1: gelu ; MODE 2: C += gamma[col]*(acc+bias) (fp32 C only)
// OUTBF: write C as bf16
template<int MODE, int OUTBF>
__global__ __launch_bounds__(256) void gemm_bb(const __bf16* __restrict__ A, long lda,
                                               const __bf16* __restrict__ W,
                                               const float* __restrict__ bias,
                                               void* __restrict__ Cv, long ldc,
                                               const float* __restrict__ gamma,
                                               int K){
    __shared__ __align__(16) char smem[20480];
    char* Ab = smem;
    char* Bb = smem + 10240;
    const int tid  = threadIdx.x;
    const int lane = tid & 63;
    const int wn   = (tid >> 6) & 1;
    const int wm   = tid >> 7;
    const int row0 = blockIdx.x * 128;
    const int col0 = blockIdx.y * 128;
    const int hi = lane >> 4, lo = lane & 15;
    f32x4 acc[4][4] = {};
    for (int k0 = 0; k0 < K; k0 += 32){
        #pragma unroll
        for (int i = 0; i < 2; i++){
            int p = i * 256 + tid;          // 0..511
            int r = p >> 2, cq = p & 3;     // row, 16B chunk
            bf16x8 va = *reinterpret_cast<const bf16x8*>(A + (long)(row0 + r) * lda + k0 + cq * 8);
            *reinterpret_cast<bf16x8*>(Ab + r * 80 + cq * 16) = va;
            bf16x8 vw = *reinterpret_cast<const bf16x8*>(W + (long)(col0 + r) * K + k0 + cq * 8);
            *reinterpret_cast<bf16x8*>(Bb + r * 80 + cq * 16) = vw;
        }
        __syncthreads();
        bf16x8 af[4], bfr[4];
        #pragma unroll
        for (int m = 0; m < 4; m++)
            af[m] = *reinterpret_cast<const bf16x8*>(Ab + (wm * 64 + m * 16 + lo) * 80 + hi * 16);
        #pragma unroll
        for (int n = 0; n < 4; n++)
            bfr[n] = *reinterpret_cast<const bf16x8*>(Bb + (wn * 64 + n * 16 + lo) * 80 + hi * 16);
        #pragma unroll
        for (int m = 0; m < 4; m++)
            #pragma unroll
            for (int n = 0; n < 4; n++)
                acc[m][n] = __builtin_amdgcn_mfma_f32_16x16x32_bf16(af[m], bfr[n], acc[m][n], 0, 0, 0);
        __syncthreads();
    }
    float* Cf = (float*)Cv;
    __bf16* Cb = (__bf16*)Cv;
    #pragma unroll
    for (int m = 0; m < 4; m++){
        #pragma unroll
        for (int n = 0; n < 4; n++){
            int row = row0 + wm * 64 + m * 16 + hi * 4;
            int col = col0 + wn * 64 + n * 16 + lo;
            float bv = bias[col];
            #pragma unroll
            for (int j = 0; j < 4; j++){
                float v = acc[m][n][j] + bv;
                if (MODE == 1) v = gelu_f(v);
                long ci = (long)(row + j) * ldc + col;
                if (MODE == 2) Cf[ci] += gamma[col] * v;
                else if (OUTBF) Cb[ci] = (__bf16)v;
                else Cf[ci] = v;
            }
        }
    }
}

// ---------------- Tiled fp32 GEMM (CA blocks / head) ----------------
template<int MODE>
__global__ __launch_bounds__(256) void gemm64(const float* __restrict__ A, long lda,
                                              const float* __restrict__ W,
                                              const float* __restrict__ bias,
                                              float* __restrict__ C, long ldc,
                                              const float* __restrict__ gamma,
                                              int M, int N, int K){
    __shared__ float As[16][68];
    __shared__ float Ws[16][68];
    const int tid = threadIdx.x;
    const int row0 = blockIdx.x * 64, col0 = blockIdx.y * 64;
    const int lm = tid >> 2;
    const int lk = (tid & 3) << 2;
    const int ty = tid >> 4, tx = tid & 15;
    float acc[4][4] = {};
    for (int k0 = 0; k0 < K; k0 += 16){
        int gr = row0 + lm;
        float4 va = make_float4(0.f, 0.f, 0.f, 0.f);
        if (gr < M) va = *reinterpret_cast<const float4*>(A + (long)gr * lda + k0 + lk);
        As[lk + 0][lm] = va.x; As[lk + 1][lm] = va.y; As[lk + 2][lm] = va.z; As[lk + 3][lm] = va.w;
        int gc = col0 + lm;
        float4 vw = make_float4(0.f, 0.f, 0.f, 0.f);
        if (gc < N) vw = *reinterpret_cast<const float4*>(W + (long)gc * K + k0 + lk);
        Ws[lk + 0][lm] = vw.x; Ws[lk + 1][lm] = vw.y; Ws[lk + 2][lm] = vw.z; Ws[lk + 3][lm] = vw.w;
        __syncthreads();
        #pragma unroll
        for (int kk = 0; kk < 16; kk++){
            float4 av = *reinterpret_cast<const float4*>(&As[kk][ty << 2]);
            float4 bv = *reinterpret_cast<const float4*>(&Ws[kk][tx << 2]);
            float a0 = av.x, a1 = av.y, a2 = av.z, a3 = av.w;
            float b0 = bv.x, b1 = bv.y, b2 = bv.z, b3 = bv.w;
            acc[0][0] += a0 * b0; acc[0][1] += a0 * b1; acc[0][2] += a0 * b2; acc[0][3] += a0 * b3;
            acc[1][0] += a1 * b0; acc[1][1] += a1 * b1; acc[1][2] += a1 * b2; acc[1][3] += a1 * b3;
            acc[2][0] += a2 * b0; acc[2][1] += a2 * b1; acc[2][2] += a2 * b2; acc[2][3] += a2 * b3;
            acc[3][0] += a3 * b0; acc[3][1] += a3 * b1; acc[3][2] += a3 * b2; acc[3][3] += a3 * b3;
        }
        __syncthreads();
    }
    #pragma unroll
    for (int i = 0; i < 4; i++){
        int row = row0 + (ty << 2) + i;
        if (row >= M) continue;
        #pragma unroll
        for (int j = 0; j < 4; j++){
            int col = col0 + (tx << 2) + j;
            if (col >= N) continue;
            float v = acc[i][j] + bias[col];
            if (MODE == 1) v = gelu_f(v);
            long ci = (long)row * ldc + col;
            if (MODE == 2) C[ci] += gamma[col] * v;
            else C[ci] = v;
        }
    }
}

// ---------------- Implicit-GEMM conv 3x3 stride2 pad1 + eval-BN (+ optional GELU) ----------------
template<int CIT>
__global__ __launch_bounds__(256) void conv_ig(const float* __restrict__ in, const float* __restrict__ w,
                                               const float* __restrict__ g, const float* __restrict__ bb,
                                               float* __restrict__ out,
                                               int Ci, int Hi, int Wi, int Co, int Ho, int Wo,
                                               int do_gelu, int ntx){
    __shared__ float in_t[CIT][17][18];
    __shared__ float w_t[CIT * 9][64];
    const int tid = threadIdx.x;
    const int b   = blockIdx.z;
    const int co0 = blockIdx.y * 64;
    const int oy0 = (blockIdx.x / ntx) * 8;
    const int ox0 = (blockIdx.x % ntx) * 8;
    const int ty = tid >> 4, tx = tid & 15;
    const int py = tx >> 1, px0 = (tx & 1) << 2;
    float acc[4][4] = {};
    const float* inb = in + (long)b * Ci * Hi * Wi;
    for (int cc = 0; cc < Ci; cc += CIT){
        for (int idx = tid; idx < CIT * 289; idx += 256){
            int ci = idx / 289, rem = idx % 289;
            int r = rem / 17, c = rem % 17;
            int iy = oy0 * 2 - 1 + r, ix = ox0 * 2 - 1 + c;
            float v = 0.f;
            if ((unsigned)iy < (unsigned)Hi && (unsigned)ix < (unsigned)Wi)
                v = inb[((long)(cc + ci) * Hi + iy) * Wi + ix];
            in_t[ci][r][c] = v;
        }
        for (int idx = tid; idx < CIT * 9 * 64; idx += 256){
            int k = idx >> 6, j = idx & 63;
            int co = co0 + j;
            float v = 0.f;
            if (co < Co) v = w[((long)co * Ci + cc) * 9 + k];
            w_t[k][j] = v;
        }
        __syncthreads();
        #pragma unroll 2
        for (int ci = 0; ci < CIT; ci++){
            #pragma unroll
            for (int ky = 0; ky < 3; ky++){
                #pragma unroll
                for (int kx = 0; kx < 3; kx++){
                    float a0 = in_t[ci][py * 2 + ky][(px0 + 0) * 2 + kx];
                    float a1 = in_t[ci][py * 2 + ky][(px0 + 1) * 2 + kx];
                    float a2 = in_t[ci][py * 2 + ky][(px0 + 2) * 2 + kx];
                    float a3 = in_t[ci][py * 2 + ky][(px0 + 3) * 2 + kx];
                    float4 wv = *reinterpret_cast<const float4*>(&w_t[ci * 9 + ky * 3 + kx][ty << 2]);
                    acc[0][0] += a0 * wv.x; acc[0][1] += a0 * wv.y; acc[0][2] += a0 * wv.z; acc[0][3] += a0 * wv.w;
                    acc[1][0] += a1 * wv.x; acc[1][1] += a1 * wv.y; acc[1][2] += a1 * wv.z; acc[1][3] += a1 * wv.w;
                    acc[2][0] += a2 * wv.x; acc[2][1] += a2 * wv.y; acc[2][2] += a2 * wv.z; acc[2][3] += a2 * wv.w;
                    acc[3][0] += a3 * wv.x; acc[3][1] += a3 * wv.y; acc[3][2] += a3 * wv.z; acc[3][3] += a3 * wv.w;
                }
            }
        }
        __syncthreads();
    }
    const int oy = oy0 + py;
    #pragma unroll
    for (int j = 0; j < 4; j++){
        int co = co0 + (ty << 2) + j;
        if (co >= Co) continue;
        float scale = g[co] * rsqrtf(1.0f + 1e-5f);
        float bias = bb[co];
        float* ob = out + ((long)(b * Co + co) * Ho + oy) * Wo;
        #pragma unroll
        for (int pi = 0; pi < 4; pi++){
            int ox = ox0 + px0 + pi;
            if (oy < Ho && ox < Wo){
                float v = acc[pi][j] * scale + bias;
                if (do_gelu) v = gelu_f(v);
                ob[ox] = v;
            }
        }
    }
}

// ---------------- positional embedding: pos[n, d] ----------------
__global__ __launch_bounds__(384) void pos_embed(const float* __restrict__ pw, const float* __restrict__ pb,
                                                 float* __restrict__ pos){
    __shared__ float p64[64];
    int n = blockIdx.x;
    int iy = n / 14, ix = n % 14;
    int t = threadIdx.x;
    if (t < 64){
        int axis = t >> 5;
        int c = t & 31;
        int u = c >> 1;
        float coord = (axis == 0) ? (float)(iy + 1) : (float)(ix + 1);
        float val = coord / ((14.0f + 1e-6f) * 6.283185307179586f);
        float T = powf(10000.0f, (float)u / 16.0f);
        float a = val / T;
        p64[t] = (c & 1) ? cosf(a) : sinf(a);
    }
    __syncthreads();
    float acc = 0.f;
    const float* wr = pw + (long)t * 64;
    #pragma unroll 8
    for (int c = 0; c < 64; c++) acc += p64[c] * wr[c];
    pos[n * 384 + t] = acc + pb[t];
}

// t[b,n,d] = c4[b,d,n] + pos[n,d]
__global__ __launch_bounds__(256) void build_t(const float* __restrict__ c4, const float* __restrict__ pos,
                                               float* __restrict__ t){
    long i = (long)blockIdx.x * 256 + threadIdx.x;
    if (i >= (long)B_ * N_ * D_) return;
    int d = (int)(i % 384);
    long bn = i / 384;
    int n = (int)(bn % 196);
    int b = (int)(bn / 196);
    t[i] = c4[((long)b * 384 + d) * 196 + n] + pos[n * 384 + d];
}

// ---------------- XCA attention via MFMA: one block per (b, head) ----------------
// qkv bf16 [b][n][1152]; o bf16 [b][n][384]
__global__ __launch_bounds__(256) void xca2(const __bf16* __restrict__ qkv, const float* __restrict__ temp,
                                            __bf16* __restrict__ o){
    int bh = blockIdx.x;
    int b = bh >> 3, h = bh & 7;
    __shared__ __align__(16) __bf16 qs[48 * 232];
    __shared__ __align__(16) __bf16 ks[48 * 232];
    __shared__ __align__(16) __bf16 vt[208 * 72];
    __shared__ __align__(16) float att[48 * 68];
    __shared__ __align__(16) __bf16 abf[48 * 72];
    __shared__ float inq[48], ink[48];
    const int tid = threadIdx.x;
    const int wid = tid >> 6, lane = tid & 63;
    const int hi = lane >> 4, lo = lane & 15;
    const __bf16* base = qkv + ((long)b * 196) * 1152 + h * 48;
    bf16x8 z8 = {};
    // zero pads: qs/ks cols 196..223, vt cols 48..63 (all rows)
    for (int idx = tid; idx < 48 * 28; idx += 256){
        int d = idx / 28, n = 196 + idx % 28;
        qs[d * 232 + n] = (__bf16)0.f;
        ks[d * 232 + n] = (__bf16)0.f;
    }
    for (int idx = tid; idx < 208 * 2; idx += 256){
        int n = idx >> 1, c = 48 + (idx & 1) * 8;
        *reinterpret_cast<bf16x8*>(vt + n * 72 + c) = z8;
    }
    // stage: Q,K transposed ([d][n]); V direct ([n][e])
    for (int ch = tid; ch < 196 * 6; ch += 256){
        int n = ch / 6, c = ch % 6, d0 = c * 8;
        bf16x8 q8 = *reinterpret_cast<const bf16x8*>(base + (long)n * 1152 + d0);
        bf16x8 k8 = *reinterpret_cast<const bf16x8*>(base + (long)n * 1152 + 384 + d0);
        #pragma unroll
        for (int j = 0; j < 8; j++){
            qs[(d0 + j) * 232 + n] = q8[j];
            ks[(d0 + j) * 232 + n] = k8[j];
        }
        bf16x8 v8 = *reinterpret_cast<const bf16x8*>(base + (long)n * 1152 + 768 + d0);
        *reinterpret_cast<bf16x8*>(vt + n * 72 + d0) = v8;
    }
    __syncthreads();
    // row norms of q, k
    for (int r = wid; r < 48; r += 4){
        float sq = 0.f, sk = 0.f;
        for (int n = lane; n < 196; n += 64){
            float qv = (float)qs[r * 232 + n];
            float kv = (float)ks[r * 232 + n];
            sq += qv * qv; sk += kv * kv;
        }
        for (int off = 32; off; off >>= 1){ sq += __shfl_down(sq, off); sk += __shfl_down(sk, off); }
        if (lane == 0){
            inq[r] = 1.0f / fmaxf(sqrtf(sq), 1e-12f);
            ink[r] = 1.0f / fmaxf(sqrtf(sk), 1e-12f);
        }
    }
    __syncthreads();
    float tempv = temp[h];
    // QK^T: 9 tiles of 16x16, K=224 (7 steps)
    for (int tt = wid; tt < 9; tt += 4){
        int mi = tt / 3, ni = tt % 3;
        f32x4 acc = {};
        #pragma unroll
        for (int k0 = 0; k0 < 224; k0 += 32){
            bf16x8 af = *reinterpret_cast<const bf16x8*>(qs + (mi * 16 + lo) * 232 + k0 + hi * 8);
            bf16x8 bf = *reinterpret_cast<const bf16x8*>(ks + (ni * 16 + lo) * 232 + k0 + hi * 8);
            acc = __builtin_amdgcn_mfma_f32_16x16x32_bf16(af, bf, acc, 0, 0, 0);
        }
        int e = ni * 16 + lo;
        float se = ink[e] * tempv;
        #pragma unroll
        for (int j = 0; j < 4; j++){
            int d = mi * 16 + hi * 4 + j;
            att[d * 68 + e] = acc[j] * inq[d] * se;
        }
    }
    __syncthreads();
    // softmax over e (48) per row d: 4 lanes per row
    if (tid < 192){
        int r = tid >> 2, q4 = tid & 3;
        const float* row = att + r * 68 + q4 * 12;
        float mx = -1e30f;
        #pragma unroll
        for (int i = 0; i < 12; i++) mx = fmaxf(mx, row[i]);
        mx = fmaxf(mx, __shfl_xor(mx, 1));
        mx = fmaxf(mx, __shfl_xor(mx, 2));
        float pv[12]; float sm = 0.f;
        #pragma unroll
        for (int i = 0; i < 12; i++){ pv[i] = expf(row[i] - mx); sm += pv[i]; }
        sm += __shfl_xor(sm, 1);
        sm += __shfl_xor(sm, 2);
        float inv = 1.0f / sm;
        #pragma unroll
        for (int i = 0; i < 12; i++) abf[r * 72 + q4 * 12 + i] = (__bf16)(pv[i] * inv);
    }
    for (int idx = tid; idx < 48 * 3; idx += 256){
        int r = idx / 3, c = 48 + (idx % 3) * 8;
        *reinterpret_cast<bf16x8*>(abf + r * 72 + c) = z8;
    }
    __syncthreads();
    // PV: C[d,n] = sum_e A[d,e] V[e,n]; 3x13 tiles, K=64 (2 steps)
    __bf16* ob = o + ((long)b * 196) * 384 + h * 48;
    for (int tt = wid; tt < 39; tt += 4){
        int mi = tt / 13, ni = tt % 13;
        f32x4 acc = {};
        #pragma unroll
        for (int e0 = 0; e0 < 64; e0 += 32){
            bf16x8 af = *reinterpret_cast<const bf16x8*>(abf + (mi * 16 + lo) * 72 + e0 + hi * 8);
            bf16x8 bf = *reinterpret_cast<const bf16x8*>(vt + (ni * 16 + lo) * 72 + e0 + hi * 8);
            acc = __builtin_amdgcn_mfma_f32_16x16x32_bf16(af, bf, acc, 0, 0, 0);
        }
        int n = ni * 16 + lo;
        if (n < 196){
            #pragma unroll
            for (int j = 0; j < 4; j++){
                int d = mi * 16 + hi * 4 + j;
                ob[(long)n * 384 + d] = (__bf16)acc[j];
            }
        }
    }
}

// ---------------- LPI ----------------
__global__ __launch_bounds__(256) void lpi(const float* __restrict__ ht,
                                           const float* __restrict__ w1, const float* __restrict__ b1,
                                           const float* __restrict__ bng, const float* __restrict__ bnb,
                                           const float* __restrict__ w2, const float* __restrict__ b2,
                                           const float* __restrict__ g3, float* __restrict__ t){
    int bd = blockIdx.x;
    int d = bd % 384, b = bd / 384;
    __shared__ float p[16][16];
    __shared__ float p2[16][16];
    __shared__ float wA[9], wB[9];
    int tt = threadIdx.x;
    int yy = tt / 16, xx = tt % 16;
    p[yy][xx] = 0.f; p2[yy][xx] = 0.f;
    if (tt < 9){ wA[tt] = w1[d * 9 + tt]; wB[tt] = w2[d * 9 + tt]; }
    __syncthreads();
    if (tt < 196){
        int y = tt / 14, x = tt % 14;
        p[y + 1][x + 1] = ht[((long)b * 384 + d) * 196 + tt];
    }
    __syncthreads();
    if (tt < 196){
        int y = tt / 14, x = tt % 14;
        float a = 0.f;
        #pragma unroll
        for (int ky = 0; ky < 3; ky++)
            #pragma unroll
            for (int kx = 0; kx < 3; kx++)
                a += wA[ky * 3 + kx] * p[y + ky][x + kx];
        a += b1[d];
        a = gelu_f(a);
        a = a * (bng[d] * rsqrtf(1.0f + 1e-5f)) + bnb[d];
        p2[y + 1][x + 1] = a;
    }
    __syncthreads();
    if (tt < 196){
        int y = tt / 14, x = tt % 14;
        float a = 0.f;
        #pragma unroll
        for (int ky = 0; ky < 3; ky++)
            #pragma unroll
            for (int kx = 0; kx < 3; kx++)
                a += wB[ky * 3 + kx] * p2[y + ky][x + kx];
        a += b2[d];
        long ti = ((long)b * 196 + tt) * 384 + d;
        t[ti] += g3[d] * a;
    }
}

// ---------------- cls concat ----------------
__global__ __launch_bounds__(256) void concat_cls(const float* __restrict__ t, const float* __restrict__ clstok,
                                                  float* __restrict__ tc){
    long i = (long)blockIdx.x * 256 + threadIdx.x;
    if (i >= (long)B_ * 197 * 384) return;
    int d = (int)(i % 384);
    long bn = i / 384;
    int n = (int)(bn % 197);
    int b = (int)(bn / 197);
    tc[i] = (n == 0) ? clstok[d] : t[((long)b * 196 + (n - 1)) * 384 + d];
}

// ---------------- CA attention ----------------
__global__ __launch_bounds__(256) void ca_attn(const float* __restrict__ qkv, float* __restrict__ clsp){
    int bh = blockIdx.x;
    int b = bh >> 3, h = bh & 7;
    const float* base = qkv + (long)b * 197 * 1152 + h * 48;
    __shared__ float q0[48];
    __shared__ float at2[197];
    __shared__ float smax, ssum;
    int tid = threadIdx.x;
    if (tid < 48) q0[tid] = base[tid];
    __syncthreads();
    if (tid < 197){
        const float* kr = base + (long)tid * 1152 + 384;
        float s = 0.f;
        for (int d = 0; d < 48; d++) s += q0[d] * kr[d];
        at2[tid] = s * rsqrtf(48.0f);
    }
    __syncthreads();
    if (tid == 0){
        float m = -1e30f;
        for (int n = 0; n < 197; n++) m = fmaxf(m, at2[n]);
        smax = m;
    }
    __syncthreads();
    if (tid < 197) at2[tid] = expf(at2[tid] - smax);
    __syncthreads();
    if (tid == 0){
        float s = 0.f;
        for (int n = 0; n < 197; n++) s += at2[n];
        ssum = s;
    }
    __syncthreads();
    if (tid < 48){
        const float* vb = base + 768 + tid;
        float s = 0.f;
        for (int n = 0; n < 197; n++) s += at2[n] * vb[(long)n * 1152];
        clsp[b * 384 + h * 48 + tid] = s / ssum;
    }
}

__global__ __launch_bounds__(256) void ca_update1(const float* __restrict__ clso, const float* __restrict__ hc,
                                                  const float* __restrict__ g1, float* __restrict__ tc){
    long i = (long)blockIdx.x * 256 + threadIdx.x;
    if (i >= (long)B_ * 197 * 384) return;
    int d = (int)(i % 384);
    long bn = i / 384;
    int n = (int)(bn % 197);
    int b = (int)(bn / 197);
    float add = (n == 0) ? clso[b * 384 + d] : hc[i];
    tc[i] += g1[d] * add;
}

__global__ __launch_bounds__(256) void ca_update2(const float* __restrict__ cls2, const float* __restrict__ hc,
                                                  const float* __restrict__ g2, float* __restrict__ tc){
    long i = (long)blockIdx.x * 256 + threadIdx.x;
    if (i >= (long)B_ * 197 * 384) return;
    int d = (int)(i % 384);
    long bn = i / 384;
    int n = (int)(bn % 197);
    int b = (int)(bn / 197);
    float hv = hc[i];
    tc[i] = (n == 0) ? (g2[d] * cls2[b * 384 + d] + hv) : (hv + hv);
}

extern "C" void kernel_launch(void* const* d_in, const int* in_sizes, int n_in,
                              void* d_out, int out_size, void* d_ws, size_t ws_size,
                              hipStream_t stream){
    (void)in_sizes; (void)n_in; (void)out_size; (void)ws_size;
    const float* x      = (const float*)d_in[0];
    const float* clstok = (const float*)d_in[1];
    const float* pos_w  = (const float*)d_in[2];
    const float* pos_b  = (const float*)d_in[3];
    const float* pe_w[4] = {(const float*)d_in[4], (const float*)d_in[7], (const float*)d_in[10], (const float*)d_in[13]};
    const float* pe_g[4] = {(const float*)d_in[5], (const float*)d_in[8], (const float*)d_in[11], (const float*)d_in[14]};
    const float* pe_b[4] = {(const float*)d_in[6], (const float*)d_in[9], (const float*)d_in[12], (const float*)d_in[15]};
    const float* xqkv_w = (const float*)d_in[16];
    const float* xqkv_b = (const float*)d_in[17];
    const float* xproj_w = (const float*)d_in[18];
    const float* xproj_b = (const float*)d_in[19];
    const float* xtemp  = (const float*)d_in[20];
    const float* xn1_w = (const float*)d_in[21];
    const float* xn1_b = (const float*)d_in[22];
    const float* xn2_w = (const float*)d_in[23];
    const float* xn2_b = (const float*)d_in[24];
    const float* xn3_w = (const float*)d_in[25];
    const float* xn3_b = (const float*)d_in[26];
    const float* xfc1_w = (const float*)d_in[27];
    const float* xfc1_b = (const float*)d_in[28];
    const float* xfc2_w = (const float*)d_in[29];
    const float* xfc2_b = (const float*)d_in[30];
    const float* xlpi1_w = (const float*)d_in[31];
    const float* xlpi1_b = (const float*)d_in[32];
    const float* xlpi2_w = (const float*)d_in[33];
    const float* xlpi2_b = (const float*)d_in[34];
    const float* xbn_g = (const float*)d_in[35];
    const float* xbn_b = (const float*)d_in[36];
    const float* xg1 = (const float*)d_in[37];
    const float* xg2 = (const float*)d_in[38];
    const float* xg3 = (const float*)d_in[39];
    const float* cqkv_w = (const float*)d_in[40];
    const float* cqkv_b = (const float*)d_in[41];
    const float* cproj_w = (const float*)d_in[42];
    const float* cproj_b = (const float*)d_in[43];
    const float* cn1_w = (const float*)d_in[44];
    const float* cn1_b = (const float*)d_in[45];
    const float* cn2_w = (const float*)d_in[46];
    const float* cn2_b = (const float*)d_in[47];
    const float* cfc1_w = (const float*)d_in[48];
    const float* cfc1_b = (const float*)d_in[49];
    const float* cfc2_w = (const float*)d_in[50];
    const float* cfc2_b = (const float*)d_in[51];
    const float* cg1 = (const float*)d_in[52];
    const float* cg2 = (const float*)d_in[53];
    const float* norm_w = (const float*)d_in[54];
    const float* norm_b = (const float*)d_in[55];
    const float* head_w = (const float*)d_in[56];
    const float* head_b = (const float*)d_in[57];
    float* outp = (float*)d_out;

    float* ws = (float*)d_ws;
    // bf16 weight copies (float-equiv offsets)
    __bf16* wqkv_bf = (__bf16*)(ws);                    // 10,616,832 bf16
    __bf16* wproj_bf = (__bf16*)(ws + 5308416L);        //  3,538,944
    __bf16* wfc1_bf = (__bf16*)(ws + 7077888L);         // 14,155,776
    __bf16* wfc2_bf = (__bf16*)(ws + 14155776L);        // 14,155,776
    float*  t       = ws + 21233664L;                   //  2,408,448 f32
    float*  pos     = ws + 23642112L;                   //     75,264
    __bf16* h_bf    = (__bf16*)(ws + 23717376L);        //  2,408,448 bf16
    __bf16* qkv_bf  = (__bf16*)(ws + 24921600L);        //  7,225,344 bf16
    __bf16* o_bf    = (__bf16*)(ws + 28534272L);        //  2,408,448 bf16
    float*  ht      = ws + 29738496L;                   //  2,408,448 f32
    __bf16* f1_bf   = (__bf16*)(ws + 32146944L);        //  9,633,792 bf16  (ends 36,963,840 fl)
    // conv scratch (dead after build_t; overlaps weight region in space, not time)
    float* c1 = ws;                                     // 19,267,584
    float* c2 = ws + 19267584L;                         //  9,633,792
    float* c3 = ws;                                     //  4,816,896
    float* c4 = ws + 4816896L;                          //  2,408,448
    // CA phase (weights dead by then)
    float* tc   = ws;                                   //  2,420,736
    float* hc   = ws + 2420736L;                        //  2,420,736
    float* qkvc = ws + 4841472L;                        //  7,262,208
    float* clsp = ws + 12103680L;
    float* clso = clsp + 12288;
    float* f1c  = clso + 12288;
    float* cls2 = f1c + 49152;
    float* clsf = cls2 + 12288;

    // ---- patch embed ----
    {
        dim3 g(14 * 14, 1, 32);
        conv_ig<3><<<g, 256, 0, stream>>>(x, pe_w[0], pe_g[0], pe_b[0], c1,
                                          3, 224, 224, 48, 112, 112, 1, 14);
    }
    {
        dim3 g(7 * 7, 2, 32);
        conv_ig<8><<<g, 256, 0, stream>>>(c1, pe_w[1], pe_g[1], pe_b[1], c2,
                                          48, 112, 112, 96, 56, 56, 1, 7);
    }
    {
        dim3 g(4 * 4, 3, 32);
        conv_ig<8><<<g, 256, 0, stream>>>(c2, pe_w[2], pe_g[2], pe_b[2], c3,
                                          96, 56, 56, 192, 28, 28, 1, 4);
    }
    {
        dim3 g(2 * 2, 6, 32);
        conv_ig<8><<<g, 256, 0, stream>>>(c3, pe_w[3], pe_g[3], pe_b[3], c4,
                                          192, 28, 28, 384, 14, 14, 0, 2);
    }
    pos_embed<<<196, 384, 0, stream>>>(pos_w, pos_b, pos);
    build_t<<<(int)(((long)B_ * N_ * D_) / 256), 256, 0, stream>>>(c4, pos, t);

    // ---- convert XCA weights to bf16 (conv scratch now dead) ----
    {
        long n1 = (long)L_ * 1152 * 384;   // 10,616,832
        long n2 = (long)L_ * 384 * 384;    //  3,538,944
        long n3 = (long)L_ * 1536 * 384;   // 14,155,776
        cvt_bf<<<(int)((n1 + 2047) / 2048), 256, 0, stream>>>(xqkv_w, wqkv_bf, n1);
        cvt_bf<<<(int)((n2 + 2047) / 2048), 256, 0, stream>>>(xproj_w, wproj_bf, n2);
        cvt_bf<<<(int)((n3 + 2047) / 2048), 256, 0, stream>>>(xfc1_w, wfc1_bf, n3);
        cvt_bf<<<(int)((n3 + 2047) / 2048), 256, 0, stream>>>(xfc2_w, wfc2_bf, n3);
    }

    // ---- 24 XCA layers ----
    const int M = B_ * N_;  // 6272 = 49*128
    for (int l = 0; l < L_; l++){
        ln384_bf<<<M, 128, 0, stream>>>(t, xn1_w + l * 384, xn1_b + l * 384, h_bf);
        {
            dim3 g(49, 9);
            gemm_bb<0, 1><<<g, 256, 0, stream>>>(h_bf, 384, wqkv_bf + (long)l * 1152 * 384,
                                                 xqkv_b + l * 1152, qkv_bf, 1152, nullptr, 384);
        }
        xca2<<<B_ * NH_, 256, 0, stream>>>(qkv_bf, xtemp + l * 8, o_bf);
        {
            dim3 g(49, 3);
            gemm_bb<2, 0><<<g, 256, 0, stream>>>(o_bf, 384, wproj_bf + (long)l * 384 * 384,
                                                 xproj_b + l * 384, t, 384, xg1 + l * 384, 384);
        }
        ln384_t<<<M, 128, 0, stream>>>(t, xn3_w + l * 384, xn3_b + l * 384, ht);
        lpi<<<B_ * D_, 256, 0, stream>>>(ht, xlpi1_w + (long)l * 384 * 9, xlpi1_b + l * 384,
                                         xbn_g + l * 384, xbn_b + l * 384,
                                         xlpi2_w + (long)l * 384 * 9, xlpi2_b + l * 384,
                                         xg3 + l * 384, t);
        ln384_bf<<<M, 128, 0, stream>>>(t, xn2_w + l * 384, xn2_b + l * 384, h_bf);
        {
            dim3 g(49, 12);
            gemm_bb<1, 1><<<g, 256, 0, stream>>>(h_bf, 384, wfc1_bf + (long)l * 1536 * 384,
                                                 xfc1_b + l * 1536, f1_bf, 1536, nullptr, 384);
        }
        {
            dim3 g(49, 3);
            gemm_bb<2, 0><<<g, 256, 0, stream>>>(f1_bf, 1536, wfc2_bf + (long)l * 1536 * 384,
                                                 xfc2_b + l * 384, t, 384, xg2 + l * 384, 1536);
        }
    }

    // ---- cls concat + 2 CA blocks (fp32) ----
    const long NC = (long)B_ * 197 * 384;
    concat_cls<<<(int)(NC / 256), 256, 0, stream>>>(t, clstok, tc);
    const int MC = B_ * 197;  // 6304
    for (int i = 0; i < 2; i++){
        ln384<<<MC, 128, 0, stream>>>(tc, 384, cn1_w + i * 384, cn1_b + i * 384, hc, 384);
        {
            dim3 g((MC + 63) / 64, 1152 / 64);
            gemm64<0><<<g, 256, 0, stream>>>(hc, 384, cqkv_w + (long)i * 1152 * 384, cqkv_b + i * 1152,
                                             qkvc, 1152, nullptr, MC, 1152, 384);
        }
        ca_attn<<<B_ * NH_, 256, 0, stream>>>(qkvc, clsp);
        {
            dim3 g(1, 384 / 64);
            gemm64<0><<<g, 256, 0, stream>>>(clsp, 384, cproj_w + (long)i * 384 * 384, cproj_b + i * 384,
                                             clso, 384, nullptr, 32, 384, 384);
        }
        ca_update1<<<(int)(NC / 256), 256, 0, stream>>>(clso, hc, cg1 + i * 384, tc);
        ln384<<<MC, 128, 0, stream>>>(tc, 384, cn2_w + i * 384, cn2_b + i * 384, hc, 384);
        {
            dim3 g(1, 1536 / 64);
            gemm64<1><<<g, 256, 0, stream>>>(hc, (long)197 * 384, cfc1_w + (long)i * 1536 * 384, cfc1_b + i * 1536,
                                             f1c, 1536, nullptr, 32, 1536, 384);
        }
        {
            dim3 g(1, 384 / 64);
            gemm64<0><<<g, 256, 0, stream>>>(f1c, 1536, cfc2_w + (long)i * 384 * 1536, cfc2_b + i * 384,
                                             cls2, 384, nullptr, 32, 384, 1536);
        }
        ca_update2<<<(int)(NC / 256), 256, 0, stream>>>(cls2, hc, cg2 + i * 384, tc);
    }

    // ---- final LN (cls token only) + head ----
    ln384<<<32, 128, 0, stream>>>(tc, (long)197 * 384, norm_w, norm_b, clsf, 384);
    {
        dim3 g(1, (1000 + 63) / 64);
        gemm64<0><<<g, 256, 0, stream>>>(clsf, 384, head_w, head_b, outp, 1000, nullptr, 32, 1000, 384);
    }
}

// Round 5
// 5302.421 us; speedup vs baseline: 3.9633x; 1.2312x over previous
//
#include <hip/hip_runtime.h>
#include <hip/hip_bf16.h>

#define B_ 32
#define D_ 384
#define N_ 196
#define NH_ 8
#define HD_ 48
#define L_ 24

typedef __bf16 bf16x8 __attribute__((ext_vector_type(8)));
typedef __bf16 bf16x4 __attribute__((ext_vector_type(4)));
typedef float f32x4 __attribute__((ext_vector_type(4)));

__device__ __forceinline__ float gelu_f(float v){
    return 0.5f * v * (1.0f + erff(v * 0.70710678118654752f));
}

// ---------------- fp32 -> bf16 bulk convert ----------------
__global__ __launch_bounds__(256) void cvt_bf(const float* __restrict__ s, __bf16* __restrict__ d, long n){
    long i = ((long)blockIdx.x * 256 + threadIdx.x) * 8;
    if (i >= n) return;
    float4 a = *reinterpret_cast<const float4*>(s + i);
    float4 b = *reinterpret_cast<const float4*>(s + i + 4);
    bf16x8 r;
    r[0] = (__bf16)a.x; r[1] = (__bf16)a.y; r[2] = (__bf16)a.z; r[3] = (__bf16)a.w;
    r[4] = (__bf16)b.x; r[5] = (__bf16)b.y; r[6] = (__bf16)b.z; r[7] = (__bf16)b.w;
    *reinterpret_cast<bf16x8*>(d + i) = r;
}

// ---------------- conv weight reorder: W'[co][tap*Ci+ci] (bf16, K padded) ----------------
__global__ __launch_bounds__(256) void wprep(const float* __restrict__ w, __bf16* __restrict__ W2,
                                             int Co, int Ci, int Kpad){
    int id = blockIdx.x * 256 + threadIdx.x;
    if (id >= Co * Kpad) return;
    int co = id / Kpad, k = id - co * Kpad;
    float v = 0.f;
    if (k < 9 * Ci){
        int tap = k / Ci, ci = k - tap * Ci;
        v = w[((long)co * Ci + ci) * 9 + tap];
    }
    W2[id] = (__bf16)v;
}

// ---------------- im2col for conv1 (fp32 NCHW input) -> A[pix][32] bf16 ----------------
__global__ __launch_bounds__(256) void im2col_x(const float* __restrict__ x, __bf16* __restrict__ A){
    int id = blockIdx.x * 256 + threadIdx.x;
    if (id >= 401408) return;
    int ox = id % 112; int t1 = id / 112; int oy = t1 % 112; int b = t1 / 112;
    __bf16 buf[32];
    #pragma unroll
    for (int i = 0; i < 32; i++) buf[i] = (__bf16)0.f;
    const float* xb = x + (long)b * 3 * 224 * 224;
    #pragma unroll
    for (int tap = 0; tap < 9; tap++){
        int ky = tap / 3, kx = tap % 3;
        int iy = oy * 2 - 1 + ky, ix = ox * 2 - 1 + kx;
        if ((unsigned)iy < 224u && (unsigned)ix < 224u){
            #pragma unroll
            for (int ci = 0; ci < 3; ci++)
                buf[tap * 3 + ci] = (__bf16)xb[((long)ci * 224 + iy) * 224 + ix];
        }
    }
    __bf16* dst = A + (long)id * 32;
    #pragma unroll
    for (int i = 0; i < 4; i++)
        *reinterpret_cast<bf16x8*>(dst + i * 8) = *reinterpret_cast<bf16x8*>(buf + i * 8);
}

// ---------------- im2col from bf16 [pix][C] rows -> A[pixout][Kpad] ----------------
__global__ __launch_bounds__(256) void im2col_bf(const __bf16* __restrict__ in, __bf16* __restrict__ A,
                                                 int C, int Hi, int Wi, int Ho, int Wo, int Kpad, int total){
    int id = blockIdx.x * 256 + threadIdx.x;
    if (id >= total) return;
    int tap = id % 9; int pix = id / 9;
    int ox = pix % Wo; int t1 = pix / Wo; int oy = t1 % Ho; int b = t1 / Ho;
    int ky = tap / 3, kx = tap % 3;
    int iy = oy * 2 - 1 + ky, ix = ox * 2 - 1 + kx;
    __bf16* dst = A + (long)pix * Kpad + tap * C;
    if ((unsigned)iy < (unsigned)Hi && (unsigned)ix < (unsigned)Wi){
        const __bf16* src = in + ((long)(b * Hi + iy) * Wi + ix) * C;
        for (int c = 0; c < C; c += 8)
            *reinterpret_cast<bf16x8*>(dst + c) = *reinterpret_cast<const bf16x8*>(src + c);
    } else {
        bf16x8 z{};
        for (int c = 0; c < C; c += 8) *reinterpret_cast<bf16x8*>(dst + c) = z;
    }
    if (tap == 0){
        bf16x8 z{};
        for (int c = 9 * C; c < Kpad; c += 8)
            *reinterpret_cast<bf16x8*>(A + (long)pix * Kpad + c) = z;
    }
}

// ---------------- conv GEMM: C[M,N] = A[M,Kpad] @ W[N,Kpad]^T, fused BN (+GELU / +pos) ----------------
// Tile 128x128, 4 waves. M%128==0. N guarded. POSOUT: fp32 out ldc=384 with pos add.
template<int GELU, int POSOUT>
__global__ __launch_bounds__(256) void gemm_conv(const __bf16* __restrict__ A, int Kpad,
                                                 const __bf16* __restrict__ W,
                                                 const float* __restrict__ g, const float* __restrict__ bb,
                                                 void* __restrict__ Cv, int N,
                                                 const float* __restrict__ pos){
    __shared__ __align__(16) char smem[20480];
    char* Ab = smem;
    char* Bb = smem + 10240;
    const int tid  = threadIdx.x;
    const int lane = tid & 63;
    const int wn   = (tid >> 6) & 1;
    const int wm   = tid >> 7;
    const int row0 = blockIdx.x * 128;
    const int col0 = blockIdx.y * 128;
    const int hi = lane >> 4, lo = lane & 15;
    f32x4 acc[4][4] = {};
    for (int k0 = 0; k0 < Kpad; k0 += 32){
        #pragma unroll
        for (int i = 0; i < 2; i++){
            int p = i * 256 + tid;
            int r = p >> 2, cq = p & 3;
            bf16x8 va = *reinterpret_cast<const bf16x8*>(A + (long)(row0 + r) * Kpad + k0 + cq * 8);
            *reinterpret_cast<bf16x8*>(Ab + r * 80 + cq * 16) = va;
            int gc = col0 + r;
            bf16x8 vw{};
            if (gc < N) vw = *reinterpret_cast<const bf16x8*>(W + (long)gc * Kpad + k0 + cq * 8);
            *reinterpret_cast<bf16x8*>(Bb + r * 80 + cq * 16) = vw;
        }
        __syncthreads();
        bf16x8 af[4], bfr[4];
        #pragma unroll
        for (int m = 0; m < 4; m++)
            af[m] = *reinterpret_cast<const bf16x8*>(Ab + (wm * 64 + m * 16 + lo) * 80 + hi * 16);
        #pragma unroll
        for (int n = 0; n < 4; n++)
            bfr[n] = *reinterpret_cast<const bf16x8*>(Bb + (wn * 64 + n * 16 + lo) * 80 + hi * 16);
        #pragma unroll
        for (int m = 0; m < 4; m++)
            #pragma unroll
            for (int n = 0; n < 4; n++)
                acc[m][n] = __builtin_amdgcn_mfma_f32_16x16x32_bf16(af[m], bfr[n], acc[m][n], 0, 0, 0);
        __syncthreads();
    }
    float* Cf = (float*)Cv;
    __bf16* Cb = (__bf16*)Cv;
    #pragma unroll
    for (int m = 0; m < 4; m++){
        #pragma unroll
        for (int n = 0; n < 4; n++){
            int row = row0 + wm * 64 + m * 16 + hi * 4;
            int col = col0 + wn * 64 + n * 16 + lo;
            if (col >= N) continue;
            float scale = g[col] * rsqrtf(1.0f + 1e-5f);
            float bv = bb[col];
            #pragma unroll
            for (int j = 0; j < 4; j++){
                float v = acc[m][n][j] * scale + bv;
                if (GELU) v = gelu_f(v);
                if (POSOUT)
                    Cf[(long)(row + j) * 384 + col] = v + pos[((row + j) % 196) * 384 + col];
                else
                    Cb[(long)(row + j) * N + col] = (__bf16)v;
            }
        }
    }
}

// ---------------- LayerNorm over D=384, fp32 out ----------------
__global__ __launch_bounds__(128) void ln384(const float* __restrict__ x, long xstride,
                                             const float* __restrict__ w, const float* __restrict__ b,
                                             float* __restrict__ y, long ystride){
    long row = blockIdx.x;
    int tid = threadIdx.x;
    const float* xr = x + row * xstride;
    float v0 = xr[tid], v1 = xr[tid + 128], v2 = xr[tid + 256];
    float s = v0 + v1 + v2;
    float ss = v0 * v0 + v1 * v1 + v2 * v2;
    for (int off = 32; off; off >>= 1){ s += __shfl_down(s, off); ss += __shfl_down(ss, off); }
    __shared__ float rs[2], rss[2];
    if ((tid & 63) == 0){ rs[tid >> 6] = s; rss[tid >> 6] = ss; }
    __syncthreads();
    float S = rs[0] + rs[1], SS = rss[0] + rss[1];
    float m = S * (1.0f / 384.0f);
    float var = SS * (1.0f / 384.0f) - m * m;
    float r = rsqrtf(var + 1e-5f);
    float* yr = y + row * ystride;
    yr[tid]       = (v0 - m) * r * w[tid]       + b[tid];
    yr[tid + 128] = (v1 - m) * r * w[tid + 128] + b[tid + 128];
    yr[tid + 256] = (v2 - m) * r * w[tid + 256] + b[tid + 256];
}

// ---------------- LayerNorm, bf16 out ----------------
__global__ __launch_bounds__(128) void ln384_bf(const float* __restrict__ x,
                                                const float* __restrict__ w, const float* __restrict__ b,
                                                __bf16* __restrict__ y){
    long row = blockIdx.x;
    int tid = threadIdx.x;
    const float* xr = x + row * 384;
    float v0 = xr[tid], v1 = xr[tid + 128], v2 = xr[tid + 256];
    float s = v0 + v1 + v2;
    float ss = v0 * v0 + v1 * v1 + v2 * v2;
    for (int off = 32; off; off >>= 1){ s += __shfl_down(s, off); ss += __shfl_down(ss, off); }
    __shared__ float rs[2], rss[2];
    if ((tid & 63) == 0){ rs[tid >> 6] = s; rss[tid >> 6] = ss; }
    __syncthreads();
    float S = rs[0] + rs[1], SS = rss[0] + rss[1];
    float m = S * (1.0f / 384.0f);
    float var = SS * (1.0f / 384.0f) - m * m;
    float r = rsqrtf(var + 1e-5f);
    __bf16* yr = y + row * 384;
    yr[tid]       = (__bf16)((v0 - m) * r * w[tid]       + b[tid]);
    yr[tid + 128] = (__bf16)((v1 - m) * r * w[tid + 128] + b[tid + 128]);
    yr[tid + 256] = (__bf16)((v2 - m) * r * w[tid + 256] + b[tid + 256]);
}

// LayerNorm writing transposed fp32 output: y[b, d, n]
__global__ __launch_bounds__(128) void ln384_t(const float* __restrict__ x,
                                               const float* __restrict__ w, const float* __restrict__ b,
                                               float* __restrict__ y){
    long row = blockIdx.x;
    int tid = threadIdx.x;
    const float* xr = x + row * 384;
    float v0 = xr[tid], v1 = xr[tid + 128], v2 = xr[tid + 256];
    float s = v0 + v1 + v2;
    float ss = v0 * v0 + v1 * v1 + v2 * v2;
    for (int off = 32; off; off >>= 1){ s += __shfl_down(s, off); ss += __shfl_down(ss, off); }
    __shared__ float rs[2], rss[2];
    if ((tid & 63) == 0){ rs[tid >> 6] = s; rss[tid >> 6] = ss; }
    __syncthreads();
    float S = rs[0] + rs[1], SS = rss[0] + rss[1];
    float m = S * (1.0f / 384.0f);
    float var = SS * (1.0f / 384.0f) - m * m;
    float r = rsqrtf(var + 1e-5f);
    int bb = (int)(row / 196), n = (int)(row % 196);
    float* yb = y + ((long)bb * 384) * 196 + n;
    yb[(long)tid * 196]         = (v0 - m) * r * w[tid]       + b[tid];
    yb[(long)(tid + 128) * 196] = (v1 - m) * r * w[tid + 128] + b[tid + 128];
    yb[(long)(tid + 256) * 196] = (v2 - m) * r * w[tid + 256] + b[tid + 256];
}

// ---------------- bf16 MFMA GEMM, 64x128 tile, 4 waves: C[M,N] = A @ W^T + bias ----------------
// MODE 0: C=acc+bias; 1: gelu; 2: C += gamma[col]*(acc+bias) (fp32 C).
// OUTBF: bf16 C. ACVT: A is fp32, convert during staging. GUARD: row guards vs M.
template<int MODE, int OUTBF, int ACVT, int GUARD>
__global__ __launch_bounds__(256) void gemm_bb2(const void* __restrict__ Av, long lda,
                                                const __bf16* __restrict__ W,
                                                const float* __restrict__ bias,
                                                void* __restrict__ Cv, long ldc,
                                                const float* __restrict__ gamma,
                                                int K, int M){
    __shared__ __align__(16) char smem[15360];
    char* Ab = smem;            // 64 rows x 80B
    char* Bb = smem + 5120;     // 128 rows x 80B
    const int tid = threadIdx.x;
    const int lane = tid & 63;
    const int wn = tid >> 6;    // 0..3
    const int row0 = blockIdx.x * 64;
    const int col0 = blockIdx.y * 128;
    const int hi = lane >> 4, lo = lane & 15;
    const __bf16* Abf = (const __bf16*)Av;
    const float* Af = (const float*)Av;
    f32x4 acc[4][2] = {};
    for (int k0 = 0; k0 < K; k0 += 32){
        {
            int r = tid >> 2, cq = tid & 3;
            int grow = row0 + r;
            bf16x8 va{};
            if (!GUARD || grow < M){
                if (ACVT){
                    float4 a0 = *reinterpret_cast<const float4*>(Af + (long)grow * lda + k0 + cq * 8);
                    float4 a1 = *reinterpret_cast<const float4*>(Af + (long)grow * lda + k0 + cq * 8 + 4);
                    va[0] = (__bf16)a0.x; va[1] = (__bf16)a0.y; va[2] = (__bf16)a0.z; va[3] = (__bf16)a0.w;
                    va[4] = (__bf16)a1.x; va[5] = (__bf16)a1.y; va[6] = (__bf16)a1.z; va[7] = (__bf16)a1.w;
                } else {
                    va = *reinterpret_cast<const bf16x8*>(Abf + (long)grow * lda + k0 + cq * 8);
                }
            }
            *reinterpret_cast<bf16x8*>(Ab + r * 80 + cq * 16) = va;
        }
        #pragma unroll
        for (int i = 0; i < 2; i++){
            int p = i * 256 + tid;
            int r = p >> 2, cq = p & 3;
            bf16x8 vw = *reinterpret_cast<const bf16x8*>(W + (long)(col0 + r) * K + k0 + cq * 8);
            *reinterpret_cast<bf16x8*>(Bb + r * 80 + cq * 16) = vw;
        }
        __syncthreads();
        bf16x8 af[4], bfr[2];
        #pragma unroll
        for (int m = 0; m < 4; m++)
            af[m] = *reinterpret_cast<const bf16x8*>(Ab + (m * 16 + lo) * 80 + hi * 16);
        #pragma unroll
        for (int n = 0; n < 2; n++)
            bfr[n] = *reinterpret_cast<const bf16x8*>(Bb + (wn * 32 + n * 16 + lo) * 80 + hi * 16);
        #pragma unroll
        for (int m = 0; m < 4; m++)
            #pragma unroll
            for (int n = 0; n < 2; n++)
                acc[m][n] = __builtin_amdgcn_mfma_f32_16x16x32_bf16(af[m], bfr[n], acc[m][n], 0, 0, 0);
        __syncthreads();
    }
    float* Cf = (float*)Cv;
    __bf16* Cb = (__bf16*)Cv;
    #pragma unroll
    for (int m = 0; m < 4; m++){
        #pragma unroll
        for (int n = 0; n < 2; n++){
            int row = row0 + m * 16 + hi * 4;
            int col = col0 + wn * 32 + n * 16 + lo;
            float bv = bias[col];
            #pragma unroll
            for (int j = 0; j < 4; j++){
                if (GUARD && (row + j) >= M) continue;
                float v = acc[m][n][j] + bv;
                if (MODE == 1) v = gelu_f(v);
                long ci = (long)(row + j) * ldc + col;
                if (MODE == 2) Cf[ci] += gamma[col] * v;
                else if (OUTBF) Cb[ci] = (__bf16)v;
                else Cf[ci] = v;
            }
        }
    }
}

// ---------------- Tiled fp32 GEMM (small CA gemms / head) ----------------
template<int MODE>
__global__ __launch_bounds__(256) void gemm64(const float* __restrict__ A, long lda,
                                              const float* __restrict__ W,
                                              const float* __restrict__ bias,
                                              float* __restrict__ C, long ldc,
                                              const float* __restrict__ gamma,
                                              int M, int N, int K){
    __shared__ float As[16][68];
    __shared__ float Ws[16][68];
    const int tid = threadIdx.x;
    const int row0 = blockIdx.x * 64, col0 = blockIdx.y * 64;
    const int lm = tid >> 2;
    const int lk = (tid & 3) << 2;
    const int ty = tid >> 4, tx = tid & 15;
    float acc[4][4] = {};
    for (int k0 = 0; k0 < K; k0 += 16){
        int gr = row0 + lm;
        float4 va = make_float4(0.f, 0.f, 0.f, 0.f);
        if (gr < M) va = *reinterpret_cast<const float4*>(A + (long)gr * lda + k0 + lk);
        As[lk + 0][lm] = va.x; As[lk + 1][lm] = va.y; As[lk + 2][lm] = va.z; As[lk + 3][lm] = va.w;
        int gc = col0 + lm;
        float4 vw = make_float4(0.f, 0.f, 0.f, 0.f);
        if (gc < N) vw = *reinterpret_cast<const float4*>(W + (long)gc * K + k0 + lk);
        Ws[lk + 0][lm] = vw.x; Ws[lk + 1][lm] = vw.y; Ws[lk + 2][lm] = vw.z; Ws[lk + 3][lm] = vw.w;
        __syncthreads();
        #pragma unroll
        for (int kk = 0; kk < 16; kk++){
            float4 av = *reinterpret_cast<const float4*>(&As[kk][ty << 2]);
            float4 bv = *reinterpret_cast<const float4*>(&Ws[kk][tx << 2]);
            float a0 = av.x, a1 = av.y, a2 = av.z, a3 = av.w;
            float b0 = bv.x, b1 = bv.y, b2 = bv.z, b3 = bv.w;
            acc[0][0] += a0 * b0; acc[0][1] += a0 * b1; acc[0][2] += a0 * b2; acc[0][3] += a0 * b3;
            acc[1][0] += a1 * b0; acc[1][1] += a1 * b1; acc[1][2] += a1 * b2; acc[1][3] += a1 * b3;
            acc[2][0] += a2 * b0; acc[2][1] += a2 * b1; acc[2][2] += a2 * b2; acc[2][3] += a2 * b3;
            acc[3][0] += a3 * b0; acc[3][1] += a3 * b1; acc[3][2] += a3 * b2; acc[3][3] += a3 * b3;
        }
        __syncthreads();
    }
    #pragma unroll
    for (int i = 0; i < 4; i++){
        int row = row0 + (ty << 2) + i;
        if (row >= M) continue;
        #pragma unroll
        for (int j = 0; j < 4; j++){
            int col = col0 + (tx << 2) + j;
            if (col >= N) continue;
            float v = acc[i][j] + bias[col];
            if (MODE == 1) v = gelu_f(v);
            long ci = (long)row * ldc + col;
            if (MODE == 2) C[ci] += gamma[col] * v;
            else C[ci] = v;
        }
    }
}

// ---------------- positional embedding: pos[n, d] ----------------
__global__ __launch_bounds__(384) void pos_embed(const float* __restrict__ pw, const float* __restrict__ pb,
                                                 float* __restrict__ pos){
    __shared__ float p64[64];
    int n = blockIdx.x;
    int iy = n / 14, ix = n % 14;
    int t = threadIdx.x;
    if (t < 64){
        int axis = t >> 5;
        int c = t & 31;
        int u = c >> 1;
        float coord = (axis == 0) ? (float)(iy + 1) : (float)(ix + 1);
        float val = coord / ((14.0f + 1e-6f) * 6.283185307179586f);
        float T = powf(10000.0f, (float)u / 16.0f);
        float a = val / T;
        p64[t] = (c & 1) ? cosf(a) : sinf(a);
    }
    __syncthreads();
    float acc = 0.f;
    const float* wr = pw + (long)t * 64;
    #pragma unroll 8
    for (int c = 0; c < 64; c++) acc += p64[c] * wr[c];
    pos[n * 384 + t] = acc + pb[t];
}

// ---------------- XCA attention via MFMA: one block per (b, head) ----------------
__global__ __launch_bounds__(256) void xca2(const __bf16* __restrict__ qkv, const float* __restrict__ temp,
                                            __bf16* __restrict__ o){
    int bh = blockIdx.x;
    int b = bh >> 3, h = bh & 7;
    __shared__ __align__(16) __bf16 qs[48 * 232];
    __shared__ __align__(16) __bf16 ks[48 * 232];
    __shared__ __align__(16) __bf16 vt[208 * 72];
    __shared__ __align__(16) float att[48 * 68];
    __shared__ __align__(16) __bf16 abf[48 * 72];
    __shared__ float inq[48], ink[48];
    const int tid = threadIdx.x;
    const int wid = tid >> 6, lane = tid & 63;
    const int hi = lane >> 4, lo = lane & 15;
    const __bf16* base = qkv + ((long)b * 196) * 1152 + h * 48;
    bf16x8 z8 = {};
    for (int idx = tid; idx < 48 * 28; idx += 256){
        int d = idx / 28, n = 196 + idx % 28;
        qs[d * 232 + n] = (__bf16)0.f;
        ks[d * 232 + n] = (__bf16)0.f;
    }
    for (int idx = tid; idx < 208 * 2; idx += 256){
        int n = idx >> 1, c = 48 + (idx & 1) * 8;
        *reinterpret_cast<bf16x8*>(vt + n * 72 + c) = z8;
    }
    for (int ch = tid; ch < 196 * 6; ch += 256){
        int n = ch / 6, c = ch % 6, d0 = c * 8;
        bf16x8 q8 = *reinterpret_cast<const bf16x8*>(base + (long)n * 1152 + d0);
        bf16x8 k8 = *reinterpret_cast<const bf16x8*>(base + (long)n * 1152 + 384 + d0);
        #pragma unroll
        for (int j = 0; j < 8; j++){
            qs[(d0 + j) * 232 + n] = q8[j];
            ks[(d0 + j) * 232 + n] = k8[j];
        }
        bf16x8 v8 = *reinterpret_cast<const bf16x8*>(base + (long)n * 1152 + 768 + d0);
        *reinterpret_cast<bf16x8*>(vt + n * 72 + d0) = v8;
    }
    __syncthreads();
    for (int r = wid; r < 48; r += 4){
        float sq = 0.f, sk = 0.f;
        for (int n = lane; n < 196; n += 64){
            float qv = (float)qs[r * 232 + n];
            float kv = (float)ks[r * 232 + n];
            sq += qv * qv; sk += kv * kv;
        }
        for (int off = 32; off; off >>= 1){ sq += __shfl_down(sq, off); sk += __shfl_down(sk, off); }
        if (lane == 0){
            inq[r] = 1.0f / fmaxf(sqrtf(sq), 1e-12f);
            ink[r] = 1.0f / fmaxf(sqrtf(sk), 1e-12f);
        }
    }
    __syncthreads();
    float tempv = temp[h];
    for (int tt = wid; tt < 9; tt += 4){
        int mi = tt / 3, ni = tt % 3;
        f32x4 acc = {};
        #pragma unroll
        for (int k0 = 0; k0 < 224; k0 += 32){
            bf16x8 af = *reinterpret_cast<const bf16x8*>(qs + (mi * 16 + lo) * 232 + k0 + hi * 8);
            bf16x8 bf = *reinterpret_cast<const bf16x8*>(ks + (ni * 16 + lo) * 232 + k0 + hi * 8);
            acc = __builtin_amdgcn_mfma_f32_16x16x32_bf16(af, bf, acc, 0, 0, 0);
        }
        int e = ni * 16 + lo;
        float se = ink[e] * tempv;
        #pragma unroll
        for (int j = 0; j < 4; j++){
            int d = mi * 16 + hi * 4 + j;
            att[d * 68 + e] = acc[j] * inq[d] * se;
        }
    }
    __syncthreads();
    if (tid < 192){
        int r = tid >> 2, q4 = tid & 3;
        const float* row = att + r * 68 + q4 * 12;
        float mx = -1e30f;
        #pragma unroll
        for (int i = 0; i < 12; i++) mx = fmaxf(mx, row[i]);
        mx = fmaxf(mx, __shfl_xor(mx, 1));
        mx = fmaxf(mx, __shfl_xor(mx, 2));
        float pv[12]; float sm = 0.f;
        #pragma unroll
        for (int i = 0; i < 12; i++){ pv[i] = expf(row[i] - mx); sm += pv[i]; }
        sm += __shfl_xor(sm, 1);
        sm += __shfl_xor(sm, 2);
        float inv = 1.0f / sm;
        #pragma unroll
        for (int i = 0; i < 12; i++) abf[r * 72 + q4 * 12 + i] = (__bf16)(pv[i] * inv);
    }
    for (int idx = tid; idx < 48 * 3; idx += 256){
        int r = idx / 3, c = 48 + (idx % 3) * 8;
        *reinterpret_cast<bf16x8*>(abf + r * 72 + c) = z8;
    }
    __syncthreads();
    __bf16* ob = o + ((long)b * 196) * 384 + h * 48;
    for (int tt = wid; tt < 39; tt += 4){
        int mi = tt / 13, ni = tt % 13;
        f32x4 acc = {};
        #pragma unroll
        for (int e0 = 0; e0 < 64; e0 += 32){
            bf16x8 af = *reinterpret_cast<const bf16x8*>(abf + (mi * 16 + lo) * 72 + e0 + hi * 8);
            bf16x8 bf = *reinterpret_cast<const bf16x8*>(vt + (ni * 16 + lo) * 72 + e0 + hi * 8);
            acc = __builtin_amdgcn_mfma_f32_16x16x32_bf16(af, bf, acc, 0, 0, 0);
        }
        int n = ni * 16 + lo;
        if (n < 196){
            #pragma unroll
            for (int j = 0; j < 4; j++){
                int d = mi * 16 + hi * 4 + j;
                ob[(long)n * 384 + d] = (__bf16)acc[j];
            }
        }
    }
}

// ---------------- LPI ----------------
__global__ __launch_bounds__(256) void lpi(const float* __restrict__ ht,
                                           const float* __restrict__ w1, const float* __restrict__ b1,
                                           const float* __restrict__ bng, const float* __restrict__ bnb,
                                           const float* __restrict__ w2, const float* __restrict__ b2,
                                           const float* __restrict__ g3, float* __restrict__ t){
    int bd = blockIdx.x;
    int d = bd % 384, b = bd / 384;
    __shared__ float p[16][16];
    __shared__ float p2[16][16];
    __shared__ float wA[9], wB[9];
    int tt = threadIdx.x;
    int yy = tt / 16, xx = tt % 16;
    p[yy][xx] = 0.f; p2[yy][xx] = 0.f;
    if (tt < 9){ wA[tt] = w1[d * 9 + tt]; wB[tt] = w2[d * 9 + tt]; }
    __syncthreads();
    if (tt < 196){
        int y = tt / 14, x = tt % 14;
        p[y + 1][x + 1] = ht[((long)b * 384 + d) * 196 + tt];
    }
    __syncthreads();
    if (tt < 196){
        int y = tt / 14, x = tt % 14;
        float a = 0.f;
        #pragma unroll
        for (int ky = 0; ky < 3; ky++)
            #pragma unroll
            for (int kx = 0; kx < 3; kx++)
                a += wA[ky * 3 + kx] * p[y + ky][x + kx];
        a += b1[d];
        a = gelu_f(a);
        a = a * (bng[d] * rsqrtf(1.0f + 1e-5f)) + bnb[d];
        p2[y + 1][x + 1] = a;
    }
    __syncthreads();
    if (tt < 196){
        int y = tt / 14, x = tt % 14;
        float a = 0.f;
        #pragma unroll
        for (int ky = 0; ky < 3; ky++)
            #pragma unroll
            for (int kx = 0; kx < 3; kx++)
                a += wB[ky * 3 + kx] * p2[y + ky][x + kx];
        a += b2[d];
        long ti = ((long)b * 196 + tt) * 384 + d;
        t[ti] += g3[d] * a;
    }
}

// ---------------- cls concat ----------------
__global__ __launch_bounds__(256) void concat_cls(const float* __restrict__ t, const float* __restrict__ clstok,
                                                  float* __restrict__ tc){
    long i = (long)blockIdx.x * 256 + threadIdx.x;
    if (i >= (long)B_ * 197 * 384) return;
    int d = (int)(i % 384);
    long bn = i / 384;
    int n = (int)(bn % 197);
    int b = (int)(bn / 197);
    tc[i] = (n == 0) ? clstok[d] : t[((long)b * 196 + (n - 1)) * 384 + d];
}

// ---------------- CA attention (bf16 qkv) ----------------
__global__ __launch_bounds__(256) void ca_attn(const __bf16* __restrict__ qkv, float* __restrict__ clsp){
    int bh = blockIdx.x;
    int b = bh >> 3, h = bh & 7;
    const __bf16* base = qkv + (long)b * 197 * 1152 + h * 48;
    __shared__ float q0[48];
    __shared__ float at2[197];
    __shared__ float smax, ssum;
    int tid = threadIdx.x;
    if (tid < 48) q0[tid] = (float)base[tid];
    __syncthreads();
    if (tid < 197){
        const __bf16* kr = base + (long)tid * 1152 + 384;
        float s = 0.f;
        for (int d = 0; d < 48; d++) s += q0[d] * (float)kr[d];
        at2[tid] = s * rsqrtf(48.0f);
    }
    __syncthreads();
    if (tid == 0){
        float m = -1e30f;
        for (int n = 0; n < 197; n++) m = fmaxf(m, at2[n]);
        smax = m;
    }
    __syncthreads();
    if (tid < 197) at2[tid] = expf(at2[tid] - smax);
    __syncthreads();
    if (tid == 0){
        float s = 0.f;
        for (int n = 0; n < 197; n++) s += at2[n];
        ssum = s;
    }
    __syncthreads();
    if (tid < 48){
        const __bf16* vb = base + 768 + tid;
        float s = 0.f;
        for (int n = 0; n < 197; n++) s += at2[n] * (float)vb[(long)n * 1152];
        clsp[b * 384 + h * 48 + tid] = s / ssum;
    }
}

__global__ __launch_bounds__(256) void ca_update1(const float* __restrict__ clso, const float* __restrict__ hc,
                                                  const float* __restrict__ g1, float* __restrict__ tc){
    long i = (long)blockIdx.x * 256 + threadIdx.x;
    if (i >= (long)B_ * 197 * 384) return;
    int d = (int)(i % 384);
    long bn = i / 384;
    int n = (int)(bn % 197);
    int b = (int)(bn / 197);
    float add = (n == 0) ? clso[b * 384 + d] : hc[i];
    tc[i] += g1[d] * add;
}

__global__ __launch_bounds__(256) void ca_update2(const float* __restrict__ cls2, const float* __restrict__ hc,
                                                  const float* __restrict__ g2, float* __restrict__ tc){
    long i = (long)blockIdx.x * 256 + threadIdx.x;
    if (i >= (long)B_ * 197 * 384) return;
    int d = (int)(i % 384);
    long bn = i / 384;
    int n = (int)(bn % 197);
    int b = (int)(bn / 197);
    float hv = hc[i];
    tc[i] = (n == 0) ? (g2[d] * cls2[b * 384 + d] + hv) : (hv + hv);
}

extern "C" void kernel_launch(void* const* d_in, const int* in_sizes, int n_in,
                              void* d_out, int out_size, void* d_ws, size_t ws_size,
                              hipStream_t stream){
    (void)in_sizes; (void)n_in; (void)out_size; (void)ws_size;
    const float* x      = (const float*)d_in[0];
    const float* clstok = (const float*)d_in[1];
    const float* pos_w  = (const float*)d_in[2];
    const float* pos_b  = (const float*)d_in[3];
    const float* pe_w[4] = {(const float*)d_in[4], (const float*)d_in[7], (const float*)d_in[10], (const float*)d_in[13]};
    const float* pe_g[4] = {(const float*)d_in[5], (const float*)d_in[8], (const float*)d_in[11], (const float*)d_in[14]};
    const float* pe_b[4] = {(const float*)d_in[6], (const float*)d_in[9], (const float*)d_in[12], (const float*)d_in[15]};
    const float* xqkv_w = (const float*)d_in[16];
    const float* xqkv_b = (const float*)d_in[17];
    const float* xproj_w = (const float*)d_in[18];
    const float* xproj_b = (const float*)d_in[19];
    const float* xtemp  = (const float*)d_in[20];
    const float* xn1_w = (const float*)d_in[21];
    const float* xn1_b = (const float*)d_in[22];
    const float* xn2_w = (const float*)d_in[23];
    const float* xn2_b = (const float*)d_in[24];
    const float* xn3_w = (const float*)d_in[25];
    const float* xn3_b = (const float*)d_in[26];
    const float* xfc1_w = (const float*)d_in[27];
    const float* xfc1_b = (const float*)d_in[28];
    const float* xfc2_w = (const float*)d_in[29];
    const float* xfc2_b = (const float*)d_in[30];
    const float* xlpi1_w = (const float*)d_in[31];
    const float* xlpi1_b = (const float*)d_in[32];
    const float* xlpi2_w = (const float*)d_in[33];
    const float* xlpi2_b = (const float*)d_in[34];
    const float* xbn_g = (const float*)d_in[35];
    const float* xbn_b = (const float*)d_in[36];
    const float* xg1 = (const float*)d_in[37];
    const float* xg2 = (const float*)d_in[38];
    const float* xg3 = (const float*)d_in[39];
    const float* cqkv_w = (const float*)d_in[40];
    const float* cqkv_b = (const float*)d_in[41];
    const float* cproj_w = (const float*)d_in[42];
    const float* cproj_b = (const float*)d_in[43];
    const float* cn1_w = (const float*)d_in[44];
    const float* cn1_b = (const float*)d_in[45];
    const float* cn2_w = (const float*)d_in[46];
    const float* cn2_b = (const float*)d_in[47];
    const float* cfc1_w = (const float*)d_in[48];
    const float* cfc1_b = (const float*)d_in[49];
    const float* cfc2_w = (const float*)d_in[50];
    const float* cfc2_b = (const float*)d_in[51];
    const float* cg1 = (const float*)d_in[52];
    const float* cg2 = (const float*)d_in[53];
    const float* norm_w = (const float*)d_in[54];
    const float* norm_b = (const float*)d_in[55];
    const float* head_w = (const float*)d_in[56];
    const float* head_b = (const float*)d_in[57];
    float* outp = (float*)d_out;

    float* ws = (float*)d_ws;
    // ---- conv phase buffers (float-unit offsets; aliased in time) ----
    __bf16* A1   = (__bf16*)(ws);                 // 401408x32
    __bf16* A2   = (__bf16*)(ws);                 // 100352x448
    __bf16* A3   = (__bf16*)(ws);                 // 25088x896
    __bf16* A4   = (__bf16*)(ws);                 // 6272x1728
    __bf16* out1 = (__bf16*)(ws + 22500000L);     // 401408x48
    __bf16* out2 = (__bf16*)(ws + 22500000L);     // 100352x96
    __bf16* out3 = (__bf16*)(ws + 27400000L);     // 25088x192
    __bf16* wcv  = (__bf16*)(ws + 36000000L);     // conv weights bf16
    __bf16* W1c = wcv;                 // 48x32
    __bf16* W2c = wcv + 1536;          // 96x448
    __bf16* W3c = wcv + 44544;         // 192x896
    __bf16* W4c = wcv + 216576;        // 384x1728
    // ---- XCA phase ----
    __bf16* wqkv_bf = (__bf16*)(ws);
    __bf16* wproj_bf = (__bf16*)(ws + 5308416L);
    __bf16* wfc1_bf = (__bf16*)(ws + 7077888L);
    __bf16* wfc2_bf = (__bf16*)(ws + 14155776L);
    float*  t       = ws + 21233664L;
    float*  pos     = ws + 23642112L;
    __bf16* h_bf    = (__bf16*)(ws + 23717376L);
    __bf16* qkv_bf  = (__bf16*)(ws + 24921600L);
    __bf16* o_bf    = (__bf16*)(ws + 28534272L);
    float*  ht      = ws + 29738496L;
    __bf16* f1_bf   = (__bf16*)(ws + 32146944L);
    // ---- CA phase ----
    float* tc   = ws;
    float* hc   = ws + 2420736L;
    __bf16* qkvc_bf = (__bf16*)(ws + 4841472L);
    float* clsp = ws + 8472576L;
    float* clso = clsp + 12288;
    float* f1c  = clso + 12288;
    float* cls2 = f1c + 49152;
    float* clsf = cls2 + 12288;
    __bf16* cqkv_bf = (__bf16*)(ws + 9000000L);

    // ---- conv weight prep ----
    wprep<<<(48 * 32 + 255) / 256, 256, 0, stream>>>(pe_w[0], W1c, 48, 3, 32);
    wprep<<<(96 * 448 + 255) / 256, 256, 0, stream>>>(pe_w[1], W2c, 96, 48, 448);
    wprep<<<(192 * 896 + 255) / 256, 256, 0, stream>>>(pe_w[2], W3c, 192, 96, 896);
    wprep<<<(384 * 1728 + 255) / 256, 256, 0, stream>>>(pe_w[3], W4c, 384, 192, 1728);

    // ---- patch embed: im2col + MFMA GEMM ----
    im2col_x<<<1568, 256, 0, stream>>>(x, A1);
    { dim3 g(3136, 1); gemm_conv<1, 0><<<g, 256, 0, stream>>>(A1, 32, W1c, pe_g[0], pe_b[0], out1, 48, nullptr); }
    im2col_bf<<<(100352 * 9 + 255) / 256, 256, 0, stream>>>(out1, A2, 48, 112, 112, 56, 56, 448, 100352 * 9);
    { dim3 g(784, 1); gemm_conv<1, 0><<<g, 256, 0, stream>>>(A2, 448, W2c, pe_g[1], pe_b[1], out2, 96, nullptr); }
    im2col_bf<<<(25088 * 9 + 255) / 256, 256, 0, stream>>>(out2, A3, 96, 56, 56, 28, 28, 896, 25088 * 9);
    pos_embed<<<196, 384, 0, stream>>>(pos_w, pos_b, pos);
    { dim3 g(196, 2); gemm_conv<1, 0><<<g, 256, 0, stream>>>(A3, 896, W3c, pe_g[2], pe_b[2], out3, 192, nullptr); }
    im2col_bf<<<(6272 * 9 + 255) / 256, 256, 0, stream>>>(out3, A4, 192, 28, 28, 14, 14, 1728, 6272 * 9);
    { dim3 g(49, 3); gemm_conv<0, 1><<<g, 256, 0, stream>>>(A4, 1728, W4c, pe_g[3], pe_b[3], t, 384, pos); }

    // ---- convert XCA weights to bf16 ----
    {
        long n1 = (long)L_ * 1152 * 384;
        long n2 = (long)L_ * 384 * 384;
        long n3 = (long)L_ * 1536 * 384;
        cvt_bf<<<(int)((n1 + 2047) / 2048), 256, 0, stream>>>(xqkv_w, wqkv_bf, n1);
        cvt_bf<<<(int)((n2 + 2047) / 2048), 256, 0, stream>>>(xproj_w, wproj_bf, n2);
        cvt_bf<<<(int)((n3 + 2047) / 2048), 256, 0, stream>>>(xfc1_w, wfc1_bf, n3);
        cvt_bf<<<(int)((n3 + 2047) / 2048), 256, 0, stream>>>(xfc2_w, wfc2_bf, n3);
    }

    // ---- 24 XCA layers ----
    const int M = B_ * N_;  // 6272 = 98*64
    for (int l = 0; l < L_; l++){
        ln384_bf<<<M, 128, 0, stream>>>(t, xn1_w + l * 384, xn1_b + l * 384, h_bf);
        {
            dim3 g(98, 9);
            gemm_bb2<0, 1, 0, 0><<<g, 256, 0, stream>>>(h_bf, 384, wqkv_bf + (long)l * 1152 * 384,
                                                        xqkv_b + l * 1152, qkv_bf, 1152, nullptr, 384, M);
        }
        xca2<<<B_ * NH_, 256, 0, stream>>>(qkv_bf, xtemp + l * 8, o_bf);
        {
            dim3 g(98, 3);
            gemm_bb2<2, 0, 0, 0><<<g, 256, 0, stream>>>(o_bf, 384, wproj_bf + (long)l * 384 * 384,
                                                        xproj_b + l * 384, t, 384, xg1 + l * 384, 384, M);
        }
        ln384_t<<<M, 128, 0, stream>>>(t, xn3_w + l * 384, xn3_b + l * 384, ht);
        lpi<<<B_ * D_, 256, 0, stream>>>(ht, xlpi1_w + (long)l * 384 * 9, xlpi1_b + l * 384,
                                         xbn_g + l * 384, xbn_b + l * 384,
                                         xlpi2_w + (long)l * 384 * 9, xlpi2_b + l * 384,
                                         xg3 + l * 384, t);
        ln384_bf<<<M, 128, 0, stream>>>(t, xn2_w + l * 384, xn2_b + l * 384, h_bf);
        {
            dim3 g(98, 12);
            gemm_bb2<1, 1, 0, 0><<<g, 256, 0, stream>>>(h_bf, 384, wfc1_bf + (long)l * 1536 * 384,
                                                        xfc1_b + l * 1536, f1_bf, 1536, nullptr, 384, M);
        }
        {
            dim3 g(98, 3);
            gemm_bb2<2, 0, 0, 0><<<g, 256, 0, stream>>>(f1_bf, 1536, wfc2_bf + (long)l * 1536 * 384,
                                                        xfc2_b + l * 384, t, 384, xg2 + l * 384, 1536, M);
        }
    }

    // ---- cls concat + 2 CA blocks ----
    const long NC = (long)B_ * 197 * 384;
    concat_cls<<<(int)(NC / 256), 256, 0, stream>>>(t, clstok, tc);
    {
        long nc = (long)2 * 1152 * 384;
        cvt_bf<<<(int)((nc + 2047) / 2048), 256, 0, stream>>>(cqkv_w, cqkv_bf, nc);
    }
    const int MC = B_ * 197;  // 6304
    for (int i = 0; i < 2; i++){
        ln384<<<MC, 128, 0, stream>>>(tc, 384, cn1_w + i * 384, cn1_b + i * 384, hc, 384);
        {
            dim3 g(99, 9);
            gemm_bb2<0, 1, 1, 1><<<g, 256, 0, stream>>>(hc, 384, cqkv_bf + (long)i * 1152 * 384,
                                                        cqkv_b + i * 1152, qkvc_bf, 1152, nullptr, 384, MC);
        }
        ca_attn<<<B_ * NH_, 256, 0, stream>>>(qkvc_bf, clsp);
        {
            dim3 g(1, 384 / 64);
            gemm64<0><<<g, 256, 0, stream>>>(clsp, 384, cproj_w + (long)i * 384 * 384, cproj_b + i * 384,
                                             clso, 384, nullptr, 32, 384, 384);
        }
        ca_update1<<<(int)(NC / 256), 256, 0, stream>>>(clso, hc, cg1 + i * 384, tc);
        ln384<<<MC, 128, 0, stream>>>(tc, 384, cn2_w + i * 384, cn2_b + i * 384, hc, 384);
        {
            dim3 g(1, 1536 / 64);
            gemm64<1><<<g, 256, 0, stream>>>(hc, (long)197 * 384, cfc1_w + (long)i * 1536 * 384, cfc1_b + i * 1536,
                                             f1c, 1536, nullptr, 32, 1536, 384);
        }
        {
            dim3 g(1, 384 / 64);
            gemm64<0><<<g, 256, 0, stream>>>(f1c, 1536, cfc2_w + (long)i * 384 * 1536, cfc2_b + i * 384,
                                             cls2, 384, nullptr, 32, 384, 1536);
        }
        ca_update2<<<(int)(NC / 256), 256, 0, stream>>>(cls2, hc, cg2 + i * 384, tc);
    }

    // ---- final LN (cls token only) + head ----
    ln384<<<32, 128, 0, stream>>>(tc, (long)197 * 384, norm_w, norm_b, clsf, 384);
    {
        dim3 g(1, (1000 + 63) / 64);
        gemm64<0><<<g, 256, 0, stream>>>(clsf, 384, head_w, head_b, outp, 1000, nullptr, 32, 1000, 384);
    }
}

// Round 6
// 4707.631 us; speedup vs baseline: 4.4641x; 1.1263x over previous
//
#include <hip/hip_runtime.h>
#include <hip/hip_bf16.h>

#define B_ 32
#define D_ 384
#define N_ 196
#define NH_ 8
#define HD_ 48
#define L_ 24

typedef __bf16 bf16x8 __attribute__((ext_vector_type(8)));
typedef float f32x4 __attribute__((ext_vector_type(4)));

__device__ __forceinline__ float gelu_f(float v){
    return 0.5f * v * (1.0f + erff(v * 0.70710678118654752f));
}

// ---------------- fp32 -> bf16 bulk convert ----------------
__global__ __launch_bounds__(256) void cvt_bf(const float* __restrict__ s, __bf16* __restrict__ d, long n){
    long i = ((long)blockIdx.x * 256 + threadIdx.x) * 8;
    if (i >= n) return;
    float4 a = *reinterpret_cast<const float4*>(s + i);
    float4 b = *reinterpret_cast<const float4*>(s + i + 4);
    bf16x8 r;
    r[0] = (__bf16)a.x; r[1] = (__bf16)a.y; r[2] = (__bf16)a.z; r[3] = (__bf16)a.w;
    r[4] = (__bf16)b.x; r[5] = (__bf16)b.y; r[6] = (__bf16)b.z; r[7] = (__bf16)b.w;
    *reinterpret_cast<bf16x8*>(d + i) = r;
}

// fp32 -> bf16 with row padding (zero rows >= rows)
__global__ __launch_bounds__(256) void cvt_pad(const float* __restrict__ s, __bf16* __restrict__ d,
                                               int rows, int K, int rows_pad){
    int id = blockIdx.x * 256 + threadIdx.x;
    if (id >= rows_pad * K) return;
    int r = id / K;
    d[id] = (r < rows) ? (__bf16)s[id] : (__bf16)0.f;
}

// ---------------- conv weight reorder: W'[co][tap*Ci+ci] (bf16, K padded) ----------------
__global__ __launch_bounds__(256) void wprep(const float* __restrict__ w, __bf16* __restrict__ W2,
                                             int Co, int Ci, int Kpad){
    int id = blockIdx.x * 256 + threadIdx.x;
    if (id >= Co * Kpad) return;
    int co = id / Kpad, k = id - co * Kpad;
    float v = 0.f;
    if (k < 9 * Ci){
        int tap = k / Ci, ci = k - tap * Ci;
        v = w[((long)co * Ci + ci) * 9 + tap];
    }
    W2[id] = (__bf16)v;
}

// ---------------- im2col for conv1 (fp32 NCHW input) -> A[pix][32] bf16 ----------------
__global__ __launch_bounds__(256) void im2col_x(const float* __restrict__ x, __bf16* __restrict__ A){
    int id = blockIdx.x * 256 + threadIdx.x;
    if (id >= 401408) return;
    int ox = id % 112; int t1 = id / 112; int oy = t1 % 112; int b = t1 / 112;
    __bf16 buf[32];
    #pragma unroll
    for (int i = 0; i < 32; i++) buf[i] = (__bf16)0.f;
    const float* xb = x + (long)b * 3 * 224 * 224;
    #pragma unroll
    for (int tap = 0; tap < 9; tap++){
        int ky = tap / 3, kx = tap % 3;
        int iy = oy * 2 - 1 + ky, ix = ox * 2 - 1 + kx;
        if ((unsigned)iy < 224u && (unsigned)ix < 224u){
            #pragma unroll
            for (int ci = 0; ci < 3; ci++)
                buf[tap * 3 + ci] = (__bf16)xb[((long)ci * 224 + iy) * 224 + ix];
        }
    }
    __bf16* dst = A + (long)id * 32;
    #pragma unroll
    for (int i = 0; i < 4; i++)
        *reinterpret_cast<bf16x8*>(dst + i * 8) = *reinterpret_cast<bf16x8*>(buf + i * 8);
}

// ---------------- im2col from bf16 [pix][C] rows -> A[pixout][Kpad] ----------------
__global__ __launch_bounds__(256) void im2col_bf(const __bf16* __restrict__ in, __bf16* __restrict__ A,
                                                 int C, int Hi, int Wi, int Ho, int Wo, int Kpad, int total){
    int id = blockIdx.x * 256 + threadIdx.x;
    if (id >= total) return;
    int tap = id % 9; int pix = id / 9;
    int ox = pix % Wo; int t1 = pix / Wo; int oy = t1 % Ho; int b = t1 / Ho;
    int ky = tap / 3, kx = tap % 3;
    int iy = oy * 2 - 1 + ky, ix = ox * 2 - 1 + kx;
    __bf16* dst = A + (long)pix * Kpad + tap * C;
    if ((unsigned)iy < (unsigned)Hi && (unsigned)ix < (unsigned)Wi){
        const __bf16* src = in + ((long)(b * Hi + iy) * Wi + ix) * C;
        for (int c = 0; c < C; c += 8)
            *reinterpret_cast<bf16x8*>(dst + c) = *reinterpret_cast<const bf16x8*>(src + c);
    } else {
        bf16x8 z{};
        for (int c = 0; c < C; c += 8) *reinterpret_cast<bf16x8*>(dst + c) = z;
    }
    if (tap == 0){
        bf16x8 z{};
        for (int c = 9 * C; c < Kpad; c += 8)
            *reinterpret_cast<bf16x8*>(A + (long)pix * Kpad + c) = z;
    }
}

// ---------------- conv GEMM: C[M,N] = A[M,Kpad] @ W[N,Kpad]^T, fused BN (+GELU / +pos) ----------------
template<int GELU, int POSOUT>
__global__ __launch_bounds__(256) void gemm_conv(const __bf16* __restrict__ A, int Kpad,
                                                 const __bf16* __restrict__ W,
                                                 const float* __restrict__ g, const float* __restrict__ bb,
                                                 void* __restrict__ Cv, int N,
                                                 const float* __restrict__ pos){
    __shared__ __align__(16) char smem[20480];
    char* Ab = smem;
    char* Bb = smem + 10240;
    const int tid  = threadIdx.x;
    const int lane = tid & 63;
    const int wn   = (tid >> 6) & 1;
    const int wm   = tid >> 7;
    const int row0 = blockIdx.x * 128;
    const int col0 = blockIdx.y * 128;
    const int hi = lane >> 4, lo = lane & 15;
    f32x4 acc[4][4] = {};
    for (int k0 = 0; k0 < Kpad; k0 += 32){
        #pragma unroll
        for (int i = 0; i < 2; i++){
            int p = i * 256 + tid;
            int r = p >> 2, cq = p & 3;
            bf16x8 va = *reinterpret_cast<const bf16x8*>(A + (long)(row0 + r) * Kpad + k0 + cq * 8);
            *reinterpret_cast<bf16x8*>(Ab + r * 80 + cq * 16) = va;
            int gc = col0 + r;
            bf16x8 vw{};
            if (gc < N) vw = *reinterpret_cast<const bf16x8*>(W + (long)gc * Kpad + k0 + cq * 8);
            *reinterpret_cast<bf16x8*>(Bb + r * 80 + cq * 16) = vw;
        }
        __syncthreads();
        bf16x8 af[4], bfr[4];
        #pragma unroll
        for (int m = 0; m < 4; m++)
            af[m] = *reinterpret_cast<const bf16x8*>(Ab + (wm * 64 + m * 16 + lo) * 80 + hi * 16);
        #pragma unroll
        for (int n = 0; n < 4; n++)
            bfr[n] = *reinterpret_cast<const bf16x8*>(Bb + (wn * 64 + n * 16 + lo) * 80 + hi * 16);
        #pragma unroll
        for (int m = 0; m < 4; m++)
            #pragma unroll
            for (int n = 0; n < 4; n++)
                acc[m][n] = __builtin_amdgcn_mfma_f32_16x16x32_bf16(af[m], bfr[n], acc[m][n], 0, 0, 0);
        __syncthreads();
    }
    float* Cf = (float*)Cv;
    __bf16* Cb = (__bf16*)Cv;
    #pragma unroll
    for (int m = 0; m < 4; m++){
        #pragma unroll
        for (int n = 0; n < 4; n++){
            int row = row0 + wm * 64 + m * 16 + hi * 4;
            int col = col0 + wn * 64 + n * 16 + lo;
            if (col >= N) continue;
            float scale = g[col] * rsqrtf(1.0f + 1e-5f);
            float bv = bb[col];
            #pragma unroll
            for (int j = 0; j < 4; j++){
                float v = acc[m][n][j] * scale + bv;
                if (GELU) v = gelu_f(v);
                if (POSOUT)
                    Cf[(long)(row + j) * 384 + col] = v + pos[((row + j) % 196) * 384 + col];
                else
                    Cb[(long)(row + j) * N + col] = (__bf16)v;
            }
        }
    }
}

// ---------------- LayerNorm over D=384, fp32 out ----------------
__global__ __launch_bounds__(128) void ln384(const float* __restrict__ x, long xstride,
                                             const float* __restrict__ w, const float* __restrict__ b,
                                             float* __restrict__ y, long ystride){
    long row = blockIdx.x;
    int tid = threadIdx.x;
    const float* xr = x + row * xstride;
    float v0 = xr[tid], v1 = xr[tid + 128], v2 = xr[tid + 256];
    float s = v0 + v1 + v2;
    float ss = v0 * v0 + v1 * v1 + v2 * v2;
    for (int off = 32; off; off >>= 1){ s += __shfl_down(s, off); ss += __shfl_down(ss, off); }
    __shared__ float rs[2], rss[2];
    if ((tid & 63) == 0){ rs[tid >> 6] = s; rss[tid >> 6] = ss; }
    __syncthreads();
    float S = rs[0] + rs[1], SS = rss[0] + rss[1];
    float m = S * (1.0f / 384.0f);
    float var = SS * (1.0f / 384.0f) - m * m;
    float r = rsqrtf(var + 1e-5f);
    float* yr = y + row * ystride;
    yr[tid]       = (v0 - m) * r * w[tid]       + b[tid];
    yr[tid + 128] = (v1 - m) * r * w[tid + 128] + b[tid + 128];
    yr[tid + 256] = (v2 - m) * r * w[tid + 256] + b[tid + 256];
}

// ---------------- LayerNorm, bf16 out ----------------
__global__ __launch_bounds__(128) void ln384_bf(const float* __restrict__ x,
                                                const float* __restrict__ w, const float* __restrict__ b,
                                                __bf16* __restrict__ y){
    long row = blockIdx.x;
    int tid = threadIdx.x;
    const float* xr = x + row * 384;
    float v0 = xr[tid], v1 = xr[tid + 128], v2 = xr[tid + 256];
    float s = v0 + v1 + v2;
    float ss = v0 * v0 + v1 * v1 + v2 * v2;
    for (int off = 32; off; off >>= 1){ s += __shfl_down(s, off); ss += __shfl_down(ss, off); }
    __shared__ float rs[2], rss[2];
    if ((tid & 63) == 0){ rs[tid >> 6] = s; rss[tid >> 6] = ss; }
    __syncthreads();
    float S = rs[0] + rs[1], SS = rss[0] + rss[1];
    float m = S * (1.0f / 384.0f);
    float var = SS * (1.0f / 384.0f) - m * m;
    float r = rsqrtf(var + 1e-5f);
    __bf16* yr = y + row * 384;
    yr[tid]       = (__bf16)((v0 - m) * r * w[tid]       + b[tid]);
    yr[tid + 128] = (__bf16)((v1 - m) * r * w[tid + 128] + b[tid + 128]);
    yr[tid + 256] = (__bf16)((v2 - m) * r * w[tid + 256] + b[tid + 256]);
}

// ---------------- split-K reduce + residual + LN3 (transposed out) ----------------
// t += g1*(p0+p1+bias); ht[b,d,n] = LN(t)*n3w+n3b
__global__ __launch_bounds__(128) void proj_red_lnt(const float* __restrict__ pp,
                                                    const float* __restrict__ pbias,
                                                    const float* __restrict__ g1,
                                                    float* __restrict__ t,
                                                    const float* __restrict__ n3w, const float* __restrict__ n3b,
                                                    float* __restrict__ ht){
    long row = blockIdx.x;
    int tid = threadIdx.x;
    const long MT = 6272L * 384;
    float v[3];
    #pragma unroll
    for (int i = 0; i < 3; i++){
        int c = tid + i * 128;
        long idx = row * 384 + c;
        float sacc = pp[idx] + pp[MT + idx] + pbias[c];
        v[i] = t[idx] + g1[c] * sacc;
        t[idx] = v[i];
    }
    float s = v[0] + v[1] + v[2];
    float ss = v[0] * v[0] + v[1] * v[1] + v[2] * v[2];
    for (int off = 32; off; off >>= 1){ s += __shfl_down(s, off); ss += __shfl_down(ss, off); }
    __shared__ float rs[2], rss[2];
    if ((tid & 63) == 0){ rs[tid >> 6] = s; rss[tid >> 6] = ss; }
    __syncthreads();
    float S = rs[0] + rs[1], SS = rss[0] + rss[1];
    float m = S * (1.0f / 384.0f);
    float var = SS * (1.0f / 384.0f) - m * m;
    float r = rsqrtf(var + 1e-5f);
    int b = (int)(row / 196), n = (int)(row % 196);
    float* yb = ht + ((long)b * 384) * 196 + n;
    #pragma unroll
    for (int i = 0; i < 3; i++){
        int c = tid + i * 128;
        yb[(long)c * 196] = (v[i] - m) * r * n3w[c] + n3b[c];
    }
}

// ---------------- split-K reduce + residual + LN1-of-next-layer (bf16 out) ----------------
__global__ __launch_bounds__(128) void fc2_red_ln(const float* __restrict__ pp,
                                                  const float* __restrict__ fbias,
                                                  const float* __restrict__ g2,
                                                  float* __restrict__ t,
                                                  const float* __restrict__ n1w, const float* __restrict__ n1b,
                                                  __bf16* __restrict__ h){
    long row = blockIdx.x;
    int tid = threadIdx.x;
    const long MT = 6272L * 384;
    float v[3];
    #pragma unroll
    for (int i = 0; i < 3; i++){
        int c = tid + i * 128;
        long idx = row * 384 + c;
        float sacc = pp[idx] + pp[MT + idx] + pp[2 * MT + idx] + fbias[c];
        v[i] = t[idx] + g2[c] * sacc;
        t[idx] = v[i];
    }
    float s = v[0] + v[1] + v[2];
    float ss = v[0] * v[0] + v[1] * v[1] + v[2] * v[2];
    for (int off = 32; off; off >>= 1){ s += __shfl_down(s, off); ss += __shfl_down(ss, off); }
    __shared__ float rs[2], rss[2];
    if ((tid & 63) == 0){ rs[tid >> 6] = s; rss[tid >> 6] = ss; }
    __syncthreads();
    float S = rs[0] + rs[1], SS = rss[0] + rss[1];
    float m = S * (1.0f / 384.0f);
    float var = SS * (1.0f / 384.0f) - m * m;
    float r = rsqrtf(var + 1e-5f);
    __bf16* yr = h + row * 384;
    #pragma unroll
    for (int i = 0; i < 3; i++){
        int c = tid + i * 128;
        yr[c] = (__bf16)((v[i] - m) * r * n1w[c] + n1b[c]);
    }
}

// ---------------- bf16 MFMA GEMM, 64x128 tile, 4 waves: C[M,N] = A @ W^T + bias ----------------
// MODE 0: C=acc+bias; 1: gelu; 3: raw partial (no bias). OUTBF: bf16 C.
// ACVT: A fp32, convert on stage. GUARD: row guard vs M. SPLITK: blockIdx.z K-chunk.
// NGUARD: col guard vs Ncols on write.
template<int MODE, int OUTBF, int ACVT, int GUARD, int SPLITK, int NGUARD>
__global__ __launch_bounds__(256) void gemm_bb2(const void* __restrict__ Av, long lda,
                                                const __bf16* __restrict__ W, int Kw,
                                                const float* __restrict__ bias,
                                                void* __restrict__ Cv, long ldc,
                                                int K, int M, int Ncols){
    __shared__ __align__(16) char smem[15360];
    char* Ab = smem;            // 64 rows x 80B
    char* Bb = smem + 5120;     // 128 rows x 80B
    const int tid = threadIdx.x;
    const int lane = tid & 63;
    const int wn = tid >> 6;
    const int row0 = blockIdx.x * 64;
    const int col0 = blockIdx.y * 128;
    const int hi = lane >> 4, lo = lane & 15;
    const int kbase = SPLITK ? blockIdx.z * K : 0;
    const __bf16* Abf = (const __bf16*)Av;
    const float* Af = (const float*)Av;
    f32x4 acc[4][2] = {};
    for (int k0 = 0; k0 < K; k0 += 32){
        {
            int r = tid >> 2, cq = tid & 3;
            int grow = row0 + r;
            bf16x8 va{};
            if (!GUARD || grow < M){
                long ai = (long)grow * lda + kbase + k0 + cq * 8;
                if (ACVT){
                    float4 a0 = *reinterpret_cast<const float4*>(Af + ai);
                    float4 a1 = *reinterpret_cast<const float4*>(Af + ai + 4);
                    va[0] = (__bf16)a0.x; va[1] = (__bf16)a0.y; va[2] = (__bf16)a0.z; va[3] = (__bf16)a0.w;
                    va[4] = (__bf16)a1.x; va[5] = (__bf16)a1.y; va[6] = (__bf16)a1.z; va[7] = (__bf16)a1.w;
                } else {
                    va = *reinterpret_cast<const bf16x8*>(Abf + ai);
                }
            }
            *reinterpret_cast<bf16x8*>(Ab + r * 80 + cq * 16) = va;
        }
        #pragma unroll
        for (int i = 0; i < 2; i++){
            int p = i * 256 + tid;
            int r = p >> 2, cq = p & 3;
            bf16x8 vw = *reinterpret_cast<const bf16x8*>(W + (long)(col0 + r) * Kw + kbase + k0 + cq * 8);
            *reinterpret_cast<bf16x8*>(Bb + r * 80 + cq * 16) = vw;
        }
        __syncthreads();
        bf16x8 af[4], bfr[2];
        #pragma unroll
        for (int m = 0; m < 4; m++)
            af[m] = *reinterpret_cast<const bf16x8*>(Ab + (m * 16 + lo) * 80 + hi * 16);
        #pragma unroll
        for (int n = 0; n < 2; n++)
            bfr[n] = *reinterpret_cast<const bf16x8*>(Bb + (wn * 32 + n * 16 + lo) * 80 + hi * 16);
        #pragma unroll
        for (int m = 0; m < 4; m++)
            #pragma unroll
            for (int n = 0; n < 2; n++)
                acc[m][n] = __builtin_amdgcn_mfma_f32_16x16x32_bf16(af[m], bfr[n], acc[m][n], 0, 0, 0);
        __syncthreads();
    }
    float* Cf = (float*)Cv;
    __bf16* Cb = (__bf16*)Cv;
    if (SPLITK) Cf += (long)blockIdx.z * M * ldc;
    #pragma unroll
    for (int m = 0; m < 4; m++){
        #pragma unroll
        for (int n = 0; n < 2; n++){
            int row = row0 + m * 16 + hi * 4;
            int col = col0 + wn * 32 + n * 16 + lo;
            if (NGUARD && col >= Ncols) continue;
            float bv = (MODE == 3) ? 0.f : bias[col];
            #pragma unroll
            for (int j = 0; j < 4; j++){
                if (GUARD && (row + j) >= M) continue;
                float v = acc[m][n][j] + bv;
                if (MODE == 1) v = gelu_f(v);
                long ci = (long)(row + j) * ldc + col;
                if (OUTBF) Cb[ci] = (__bf16)v;
                else Cf[ci] = v;
            }
        }
    }
}

// ---------------- positional embedding: pos[n, d] ----------------
__global__ __launch_bounds__(384) void pos_embed(const float* __restrict__ pw, const float* __restrict__ pb,
                                                 float* __restrict__ pos){
    __shared__ float p64[64];
    int n = blockIdx.x;
    int iy = n / 14, ix = n % 14;
    int t = threadIdx.x;
    if (t < 64){
        int axis = t >> 5;
        int c = t & 31;
        int u = c >> 1;
        float coord = (axis == 0) ? (float)(iy + 1) : (float)(ix + 1);
        float val = coord / ((14.0f + 1e-6f) * 6.283185307179586f);
        float T = powf(10000.0f, (float)u / 16.0f);
        float a = val / T;
        p64[t] = (c & 1) ? cosf(a) : sinf(a);
    }
    __syncthreads();
    float acc = 0.f;
    const float* wr = pw + (long)t * 64;
    #pragma unroll 8
    for (int c = 0; c < 64; c++) acc += p64[c] * wr[c];
    pos[n * 384 + t] = acc + pb[t];
}

// ---------------- XCA attention via MFMA: one block per (b, head) ----------------
__global__ __launch_bounds__(256) void xca2(const __bf16* __restrict__ qkv, const float* __restrict__ temp,
                                            __bf16* __restrict__ o){
    int bh = blockIdx.x;
    int b = bh >> 3, h = bh & 7;
    __shared__ __align__(16) __bf16 qs[48 * 232];
    __shared__ __align__(16) __bf16 ks[48 * 232];
    __shared__ __align__(16) __bf16 vt[208 * 72];
    __shared__ __align__(16) float att[48 * 68];
    __shared__ __align__(16) __bf16 abf[48 * 72];
    __shared__ float inq[48], ink[48];
    const int tid = threadIdx.x;
    const int wid = tid >> 6, lane = tid & 63;
    const int hi = lane >> 4, lo = lane & 15;
    const __bf16* base = qkv + ((long)b * 196) * 1152 + h * 48;
    bf16x8 z8 = {};
    for (int idx = tid; idx < 48 * 28; idx += 256){
        int d = idx / 28, n = 196 + idx % 28;
        qs[d * 232 + n] = (__bf16)0.f;
        ks[d * 232 + n] = (__bf16)0.f;
    }
    for (int idx = tid; idx < 208 * 2; idx += 256){
        int n = idx >> 1, c = 48 + (idx & 1) * 8;
        *reinterpret_cast<bf16x8*>(vt + n * 72 + c) = z8;
    }
    for (int ch = tid; ch < 196 * 6; ch += 256){
        int n = ch / 6, c = ch % 6, d0 = c * 8;
        bf16x8 q8 = *reinterpret_cast<const bf16x8*>(base + (long)n * 1152 + d0);
        bf16x8 k8 = *reinterpret_cast<const bf16x8*>(base + (long)n * 1152 + 384 + d0);
        #pragma unroll
        for (int j = 0; j < 8; j++){
            qs[(d0 + j) * 232 + n] = q8[j];
            ks[(d0 + j) * 232 + n] = k8[j];
        }
        bf16x8 v8 = *reinterpret_cast<const bf16x8*>(base + (long)n * 1152 + 768 + d0);
        *reinterpret_cast<bf16x8*>(vt + n * 72 + d0) = v8;
    }
    __syncthreads();
    for (int r = wid; r < 48; r += 4){
        float sq = 0.f, sk = 0.f;
        for (int n = lane; n < 196; n += 64){
            float qv = (float)qs[r * 232 + n];
            float kv = (float)ks[r * 232 + n];
            sq += qv * qv; sk += kv * kv;
        }
        for (int off = 32; off; off >>= 1){ sq += __shfl_down(sq, off); sk += __shfl_down(sk, off); }
        if (lane == 0){
            inq[r] = 1.0f / fmaxf(sqrtf(sq), 1e-12f);
            ink[r] = 1.0f / fmaxf(sqrtf(sk), 1e-12f);
        }
    }
    __syncthreads();
    float tempv = temp[h];
    for (int tt = wid; tt < 9; tt += 4){
        int mi = tt / 3, ni = tt % 3;
        f32x4 acc = {};
        #pragma unroll
        for (int k0 = 0; k0 < 224; k0 += 32){
            bf16x8 af = *reinterpret_cast<const bf16x8*>(qs + (mi * 16 + lo) * 232 + k0 + hi * 8);
            bf16x8 bf = *reinterpret_cast<const bf16x8*>(ks + (ni * 16 + lo) * 232 + k0 + hi * 8);
            acc = __builtin_amdgcn_mfma_f32_16x16x32_bf16(af, bf, acc, 0, 0, 0);
        }
        int e = ni * 16 + lo;
        float se = ink[e] * tempv;
        #pragma unroll
        for (int j = 0; j < 4; j++){
            int d = mi * 16 + hi * 4 + j;
            att[d * 68 + e] = acc[j] * inq[d] * se;
        }
    }
    __syncthreads();
    if (tid < 192){
        int r = tid >> 2, q4 = tid & 3;
        const float* row = att + r * 68 + q4 * 12;
        float mx = -1e30f;
        #pragma unroll
        for (int i = 0; i < 12; i++) mx = fmaxf(mx, row[i]);
        mx = fmaxf(mx, __shfl_xor(mx, 1));
        mx = fmaxf(mx, __shfl_xor(mx, 2));
        float pv[12]; float sm = 0.f;
        #pragma unroll
        for (int i = 0; i < 12; i++){ pv[i] = expf(row[i] - mx); sm += pv[i]; }
        sm += __shfl_xor(sm, 1);
        sm += __shfl_xor(sm, 2);
        float inv = 1.0f / sm;
        #pragma unroll
        for (int i = 0; i < 12; i++) abf[r * 72 + q4 * 12 + i] = (__bf16)(pv[i] * inv);
    }
    for (int idx = tid; idx < 48 * 3; idx += 256){
        int r = idx / 3, c = 48 + (idx % 3) * 8;
        *reinterpret_cast<bf16x8*>(abf + r * 72 + c) = z8;
    }
    __syncthreads();
    __bf16* ob = o + ((long)b * 196) * 384 + h * 48;
    for (int tt = wid; tt < 39; tt += 4){
        int mi = tt / 13, ni = tt % 13;
        f32x4 acc = {};
        #pragma unroll
        for (int e0 = 0; e0 < 64; e0 += 32){
            bf16x8 af = *reinterpret_cast<const bf16x8*>(abf + (mi * 16 + lo) * 72 + e0 + hi * 8);
            bf16x8 bf = *reinterpret_cast<const bf16x8*>(vt + (ni * 16 + lo) * 72 + e0 + hi * 8);
            acc = __builtin_amdgcn_mfma_f32_16x16x32_bf16(af, bf, acc, 0, 0, 0);
        }
        int n = ni * 16 + lo;
        if (n < 196){
            #pragma unroll
            for (int j = 0; j < 4; j++){
                int d = mi * 16 + hi * 4 + j;
                ob[(long)n * 384 + d] = (__bf16)acc[j];
            }
        }
    }
}

// ---------------- LPI ----------------
__global__ __launch_bounds__(256) void lpi(const float* __restrict__ ht,
                                           const float* __restrict__ w1, const float* __restrict__ b1,
                                           const float* __restrict__ bng, const float* __restrict__ bnb,
                                           const float* __restrict__ w2, const float* __restrict__ b2,
                                           const float* __restrict__ g3, float* __restrict__ t){
    int bd = blockIdx.x;
    int d = bd % 384, b = bd / 384;
    __shared__ float p[16][16];
    __shared__ float p2[16][16];
    __shared__ float wA[9], wB[9];
    int tt = threadIdx.x;
    int yy = tt / 16, xx = tt % 16;
    p[yy][xx] = 0.f; p2[yy][xx] = 0.f;
    if (tt < 9){ wA[tt] = w1[d * 9 + tt]; wB[tt] = w2[d * 9 + tt]; }
    __syncthreads();
    if (tt < 196){
        int y = tt / 14, x = tt % 14;
        p[y + 1][x + 1] = ht[((long)b * 384 + d) * 196 + tt];
    }
    __syncthreads();
    if (tt < 196){
        int y = tt / 14, x = tt % 14;
        float a = 0.f;
        #pragma unroll
        for (int ky = 0; ky < 3; ky++)
            #pragma unroll
            for (int kx = 0; kx < 3; kx++)
                a += wA[ky * 3 + kx] * p[y + ky][x + kx];
        a += b1[d];
        a = gelu_f(a);
        a = a * (bng[d] * rsqrtf(1.0f + 1e-5f)) + bnb[d];
        p2[y + 1][x + 1] = a;
    }
    __syncthreads();
    if (tt < 196){
        int y = tt / 14, x = tt % 14;
        float a = 0.f;
        #pragma unroll
        for (int ky = 0; ky < 3; ky++)
            #pragma unroll
            for (int kx = 0; kx < 3; kx++)
                a += wB[ky * 3 + kx] * p2[y + ky][x + kx];
        a += b2[d];
        long ti = ((long)b * 196 + tt) * 384 + d;
        t[ti] += g3[d] * a;
    }
}

// ---------------- cls concat ----------------
__global__ __launch_bounds__(256) void concat_cls(const float* __restrict__ t, const float* __restrict__ clstok,
                                                  float* __restrict__ tc){
    long i = (long)blockIdx.x * 256 + threadIdx.x;
    if (i >= (long)B_ * 197 * 384) return;
    int d = (int)(i % 384);
    long bn = i / 384;
    int n = (int)(bn % 197);
    int b = (int)(bn / 197);
    tc[i] = (n == 0) ? clstok[d] : t[((long)b * 196 + (n - 1)) * 384 + d];
}

// ---------------- CA attention (bf16 qkv) ----------------
__global__ __launch_bounds__(256) void ca_attn(const __bf16* __restrict__ qkv, float* __restrict__ clsp){
    int bh = blockIdx.x;
    int b = bh >> 3, h = bh & 7;
    const __bf16* base = qkv + (long)b * 197 * 1152 + h * 48;
    __shared__ float q0[48];
    __shared__ float at2[197];
    __shared__ float smax, ssum;
    int tid = threadIdx.x;
    if (tid < 48) q0[tid] = (float)base[tid];
    __syncthreads();
    if (tid < 197){
        const __bf16* kr = base + (long)tid * 1152 + 384;
        float s = 0.f;
        for (int d = 0; d < 48; d++) s += q0[d] * (float)kr[d];
        at2[tid] = s * rsqrtf(48.0f);
    }
    __syncthreads();
    if (tid == 0){
        float m = -1e30f;
        for (int n = 0; n < 197; n++) m = fmaxf(m, at2[n]);
        smax = m;
    }
    __syncthreads();
    if (tid < 197) at2[tid] = expf(at2[tid] - smax);
    __syncthreads();
    if (tid == 0){
        float s = 0.f;
        for (int n = 0; n < 197; n++) s += at2[n];
        ssum = s;
    }
    __syncthreads();
    if (tid < 48){
        const __bf16* vb = base + 768 + tid;
        float s = 0.f;
        for (int n = 0; n < 197; n++) s += at2[n] * (float)vb[(long)n * 1152];
        clsp[b * 384 + h * 48 + tid] = s / ssum;
    }
}

__global__ __launch_bounds__(256) void ca_update1(const float* __restrict__ clso, const float* __restrict__ hc,
                                                  const float* __restrict__ g1, float* __restrict__ tc){
    long i = (long)blockIdx.x * 256 + threadIdx.x;
    if (i >= (long)B_ * 197 * 384) return;
    int d = (int)(i % 384);
    long bn = i / 384;
    int n = (int)(bn % 197);
    int b = (int)(bn / 197);
    float add = (n == 0) ? clso[b * 384 + d] : hc[i];
    tc[i] += g1[d] * add;
}

__global__ __launch_bounds__(256) void ca_update2(const float* __restrict__ cls2, const float* __restrict__ hc,
                                                  const float* __restrict__ g2, float* __restrict__ tc){
    long i = (long)blockIdx.x * 256 + threadIdx.x;
    if (i >= (long)B_ * 197 * 384) return;
    int d = (int)(i % 384);
    long bn = i / 384;
    int n = (int)(bn % 197);
    int b = (int)(bn / 197);
    float hv = hc[i];
    tc[i] = (n == 0) ? (g2[d] * cls2[b * 384 + d] + hv) : (hv + hv);
}

extern "C" void kernel_launch(void* const* d_in, const int* in_sizes, int n_in,
                              void* d_out, int out_size, void* d_ws, size_t ws_size,
                              hipStream_t stream){
    (void)in_sizes; (void)n_in; (void)out_size; (void)ws_size;
    const float* x      = (const float*)d_in[0];
    const float* clstok = (const float*)d_in[1];
    const float* pos_w  = (const float*)d_in[2];
    const float* pos_b  = (const float*)d_in[3];
    const float* pe_w[4] = {(const float*)d_in[4], (const float*)d_in[7], (const float*)d_in[10], (const float*)d_in[13]};
    const float* pe_g[4] = {(const float*)d_in[5], (const float*)d_in[8], (const float*)d_in[11], (const float*)d_in[14]};
    const float* pe_b[4] = {(const float*)d_in[6], (const float*)d_in[9], (const float*)d_in[12], (const float*)d_in[15]};
    const float* xqkv_w = (const float*)d_in[16];
    const float* xqkv_b = (const float*)d_in[17];
    const float* xproj_w = (const float*)d_in[18];
    const float* xproj_b = (const float*)d_in[19];
    const float* xtemp  = (const float*)d_in[20];
    const float* xn1_w = (const float*)d_in[21];
    const float* xn1_b = (const float*)d_in[22];
    const float* xn2_w = (const float*)d_in[23];
    const float* xn2_b = (const float*)d_in[24];
    const float* xn3_w = (const float*)d_in[25];
    const float* xn3_b = (const float*)d_in[26];
    const float* xfc1_w = (const float*)d_in[27];
    const float* xfc1_b = (const float*)d_in[28];
    const float* xfc2_w = (const float*)d_in[29];
    const float* xfc2_b = (const float*)d_in[30];
    const float* xlpi1_w = (const float*)d_in[31];
    const float* xlpi1_b = (const float*)d_in[32];
    const float* xlpi2_w = (const float*)d_in[33];
    const float* xlpi2_b = (const float*)d_in[34];
    const float* xbn_g = (const float*)d_in[35];
    const float* xbn_b = (const float*)d_in[36];
    const float* xg1 = (const float*)d_in[37];
    const float* xg2 = (const float*)d_in[38];
    const float* xg3 = (const float*)d_in[39];
    const float* cqkv_w = (const float*)d_in[40];
    const float* cqkv_b = (const float*)d_in[41];
    const float* cproj_w = (const float*)d_in[42];
    const float* cproj_b = (const float*)d_in[43];
    const float* cn1_w = (const float*)d_in[44];
    const float* cn1_b = (const float*)d_in[45];
    const float* cn2_w = (const float*)d_in[46];
    const float* cn2_b = (const float*)d_in[47];
    const float* cfc1_w = (const float*)d_in[48];
    const float* cfc1_b = (const float*)d_in[49];
    const float* cfc2_w = (const float*)d_in[50];
    const float* cfc2_b = (const float*)d_in[51];
    const float* cg1 = (const float*)d_in[52];
    const float* cg2 = (const float*)d_in[53];
    const float* norm_w = (const float*)d_in[54];
    const float* norm_b = (const float*)d_in[55];
    const float* head_w = (const float*)d_in[56];
    const float* head_b = (const float*)d_in[57];
    float* outp = (float*)d_out;

    float* ws = (float*)d_ws;
    // ---- conv phase buffers ----
    __bf16* A1   = (__bf16*)(ws);
    __bf16* A2   = (__bf16*)(ws);
    __bf16* A3   = (__bf16*)(ws);
    __bf16* A4   = (__bf16*)(ws);
    __bf16* out1 = (__bf16*)(ws + 22500000L);
    __bf16* out2 = (__bf16*)(ws + 22500000L);
    __bf16* out3 = (__bf16*)(ws + 27400000L);
    __bf16* wcv  = (__bf16*)(ws + 36000000L);
    __bf16* W1c = wcv;
    __bf16* W2c = wcv + 1536;
    __bf16* W3c = wcv + 44544;
    __bf16* W4c = wcv + 216576;
    // ---- XCA phase ----
    __bf16* wqkv_bf = (__bf16*)(ws);
    __bf16* wproj_bf = (__bf16*)(ws + 5308416L);
    __bf16* wfc1_bf = (__bf16*)(ws + 7077888L);
    __bf16* wfc2_bf = (__bf16*)(ws + 14155776L);
    float*  t       = ws + 21233664L;
    float*  pos     = ws + 23642112L;
    __bf16* h_bf    = (__bf16*)(ws + 23717376L);
    __bf16* qkv_bf  = (__bf16*)(ws + 24921600L);
    __bf16* o_bf    = (__bf16*)(ws + 28534272L);
    float*  ht      = ws + 29738496L;
    __bf16* f1_bf   = (__bf16*)(ws + 32146944L);
    float*  pproj   = ws + 32146944L;   // 2 x 2,408,448 fp32 (aliases f1_bf; time-disjoint)
    float*  pfc2    = ws + 24921600L;   // 3 x 2,408,448 fp32 (aliases qkv_bf/o_bf/ht; time-disjoint)
    // ---- CA phase ----
    float* tc   = ws;
    float* hc   = ws + 2420736L;
    __bf16* qkvc_bf = (__bf16*)(ws + 4841472L);
    float* clsp = ws + 8472576L;
    float* clso = clsp + 12288;
    float* f1c  = clso + 12288;
    float* cls2 = f1c + 49152;
    float* clsf = cls2 + 12288;
    __bf16* cqkv_bf  = (__bf16*)(ws + 9000000L);
    __bf16* cproj_bf = (__bf16*)(ws + 9500000L);
    __bf16* cfc1_bf  = (__bf16*)(ws + 9800000L);
    __bf16* cfc2_bf  = (__bf16*)(ws + 10400000L);
    __bf16* headw_bf = (__bf16*)(ws + 11000000L);

    // ---- conv weight prep ----
    wprep<<<(48 * 32 + 255) / 256, 256, 0, stream>>>(pe_w[0], W1c, 48, 3, 32);
    wprep<<<(96 * 448 + 255) / 256, 256, 0, stream>>>(pe_w[1], W2c, 96, 48, 448);
    wprep<<<(192 * 896 + 255) / 256, 256, 0, stream>>>(pe_w[2], W3c, 192, 96, 896);
    wprep<<<(384 * 1728 + 255) / 256, 256, 0, stream>>>(pe_w[3], W4c, 384, 192, 1728);

    // ---- patch embed: im2col + MFMA GEMM ----
    im2col_x<<<1568, 256, 0, stream>>>(x, A1);
    { dim3 g(3136, 1); gemm_conv<1, 0><<<g, 256, 0, stream>>>(A1, 32, W1c, pe_g[0], pe_b[0], out1, 48, nullptr); }
    im2col_bf<<<(100352 * 9 + 255) / 256, 256, 0, stream>>>(out1, A2, 48, 112, 112, 56, 56, 448, 100352 * 9);
    { dim3 g(784, 1); gemm_conv<1, 0><<<g, 256, 0, stream>>>(A2, 448, W2c, pe_g[1], pe_b[1], out2, 96, nullptr); }
    im2col_bf<<<(25088 * 9 + 255) / 256, 256, 0, stream>>>(out2, A3, 96, 56, 56, 28, 28, 896, 25088 * 9);
    pos_embed<<<196, 384, 0, stream>>>(pos_w, pos_b, pos);
    { dim3 g(196, 2); gemm_conv<1, 0><<<g, 256, 0, stream>>>(A3, 896, W3c, pe_g[2], pe_b[2], out3, 192, nullptr); }
    im2col_bf<<<(6272 * 9 + 255) / 256, 256, 0, stream>>>(out3, A4, 192, 28, 28, 14, 14, 1728, 6272 * 9);
    { dim3 g(49, 3); gemm_conv<0, 1><<<g, 256, 0, stream>>>(A4, 1728, W4c, pe_g[3], pe_b[3], t, 384, pos); }

    // ---- convert XCA weights to bf16 ----
    {
        long n1 = (long)L_ * 1152 * 384;
        long n2 = (long)L_ * 384 * 384;
        long n3 = (long)L_ * 1536 * 384;
        cvt_bf<<<(int)((n1 + 2047) / 2048), 256, 0, stream>>>(xqkv_w, wqkv_bf, n1);
        cvt_bf<<<(int)((n2 + 2047) / 2048), 256, 0, stream>>>(xproj_w, wproj_bf, n2);
        cvt_bf<<<(int)((n3 + 2047) / 2048), 256, 0, stream>>>(xfc1_w, wfc1_bf, n3);
        cvt_bf<<<(int)((n3 + 2047) / 2048), 256, 0, stream>>>(xfc2_w, wfc2_bf, n3);
    }

    // ---- 24 XCA layers ----
    const int M = B_ * N_;  // 6272 = 98*64
    ln384_bf<<<M, 128, 0, stream>>>(t, xn1_w, xn1_b, h_bf);   // initial LN1
    for (int l = 0; l < L_; l++){
        {
            dim3 g(98, 9);
            gemm_bb2<0, 1, 0, 0, 0, 0><<<g, 256, 0, stream>>>(h_bf, 384, wqkv_bf + (long)l * 1152 * 384, 384,
                                                              xqkv_b + l * 1152, qkv_bf, 1152, 384, M, 0);
        }
        xca2<<<B_ * NH_, 256, 0, stream>>>(qkv_bf, xtemp + l * 8, o_bf);
        {   // proj split-K=2 -> partials
            dim3 g(98, 3, 2);
            gemm_bb2<3, 0, 0, 0, 1, 0><<<g, 256, 0, stream>>>(o_bf, 384, wproj_bf + (long)l * 384 * 384, 384,
                                                              nullptr, pproj, 384, 192, M, 0);
        }
        proj_red_lnt<<<M, 128, 0, stream>>>(pproj, xproj_b + l * 384, xg1 + l * 384, t,
                                            xn3_w + l * 384, xn3_b + l * 384, ht);
        lpi<<<B_ * D_, 256, 0, stream>>>(ht, xlpi1_w + (long)l * 384 * 9, xlpi1_b + l * 384,
                                         xbn_g + l * 384, xbn_b + l * 384,
                                         xlpi2_w + (long)l * 384 * 9, xlpi2_b + l * 384,
                                         xg3 + l * 384, t);
        ln384_bf<<<M, 128, 0, stream>>>(t, xn2_w + l * 384, xn2_b + l * 384, h_bf);
        {
            dim3 g(98, 12);
            gemm_bb2<1, 1, 0, 0, 0, 0><<<g, 256, 0, stream>>>(h_bf, 384, wfc1_bf + (long)l * 1536 * 384, 384,
                                                              xfc1_b + l * 1536, f1_bf, 1536, 384, M, 0);
        }
        {   // fc2 split-K=3 -> partials
            dim3 g(98, 3, 3);
            gemm_bb2<3, 0, 0, 0, 1, 0><<<g, 256, 0, stream>>>(f1_bf, 1536, wfc2_bf + (long)l * 1536 * 384, 1536,
                                                              nullptr, pfc2, 384, 512, M, 0);
        }
        int ln = (l + 1) % L_;
        fc2_red_ln<<<M, 128, 0, stream>>>(pfc2, xfc2_b + l * 384, xg2 + l * 384, t,
                                          xn1_w + ln * 384, xn1_b + ln * 384, h_bf);
    }

    // ---- cls concat + 2 CA blocks ----
    const long NC = (long)B_ * 197 * 384;
    concat_cls<<<(int)(NC / 256), 256, 0, stream>>>(t, clstok, tc);
    {
        long nc = (long)2 * 1152 * 384;
        cvt_bf<<<(int)((nc + 2047) / 2048), 256, 0, stream>>>(cqkv_w, cqkv_bf, nc);
        long np = (long)2 * 384 * 384;
        cvt_bf<<<(int)((np + 2047) / 2048), 256, 0, stream>>>(cproj_w, cproj_bf, np);
        long nf = (long)2 * 1536 * 384;
        cvt_bf<<<(int)((nf + 2047) / 2048), 256, 0, stream>>>(cfc1_w, cfc1_bf, nf);
        cvt_bf<<<(int)((nf + 2047) / 2048), 256, 0, stream>>>(cfc2_w, cfc2_bf, nf);
        cvt_pad<<<(1024 * 384 + 255) / 256, 256, 0, stream>>>(head_w, headw_bf, 1000, 384, 1024);
    }
    const int MC = B_ * 197;  // 6304
    for (int i = 0; i < 2; i++){
        ln384<<<MC, 128, 0, stream>>>(tc, 384, cn1_w + i * 384, cn1_b + i * 384, hc, 384);
        {
            dim3 g(99, 9);
            gemm_bb2<0, 1, 1, 1, 0, 0><<<g, 256, 0, stream>>>(hc, 384, cqkv_bf + (long)i * 1152 * 384, 384,
                                                              cqkv_b + i * 1152, qkvc_bf, 1152, 384, MC, 0);
        }
        ca_attn<<<B_ * NH_, 256, 0, stream>>>(qkvc_bf, clsp);
        {
            dim3 g(1, 3);
            gemm_bb2<0, 0, 1, 1, 0, 0><<<g, 256, 0, stream>>>(clsp, 384, cproj_bf + (long)i * 384 * 384, 384,
                                                              cproj_b + i * 384, clso, 384, 384, 32, 0);
        }
        ca_update1<<<(int)(NC / 256), 256, 0, stream>>>(clso, hc, cg1 + i * 384, tc);
        ln384<<<MC, 128, 0, stream>>>(tc, 384, cn2_w + i * 384, cn2_b + i * 384, hc, 384);
        {
            dim3 g(1, 12);
            gemm_bb2<1, 0, 1, 1, 0, 0><<<g, 256, 0, stream>>>(hc, (long)197 * 384, cfc1_bf + (long)i * 1536 * 384, 384,
                                                              cfc1_b + i * 1536, f1c, 1536, 384, 32, 0);
        }
        {
            dim3 g(1, 3);
            gemm_bb2<0, 0, 1, 1, 0, 0><<<g, 256, 0, stream>>>(f1c, 1536, cfc2_bf + (long)i * 1536 * 384, 1536,
                                                              cfc2_b + i * 384, cls2, 384, 1536, 32, 0);
        }
        ca_update2<<<(int)(NC / 256), 256, 0, stream>>>(cls2, hc, cg2 + i * 384, tc);
    }

    // ---- final LN (cls token only) + head ----
    ln384<<<32, 128, 0, stream>>>(tc, (long)197 * 384, norm_w, norm_b, clsf, 384);
    {
        dim3 g(1, 8);
        gemm_bb2<0, 0, 1, 1, 0, 1><<<g, 256, 0, stream>>>(clsf, 384, headw_bf, 384,
                                                          head_b, outp, 1000, 384, 32, 1000);
    }
}

// Round 7
// 4589.188 us; speedup vs baseline: 4.5793x; 1.0258x over previous
//
#include <hip/hip_runtime.h>
#include <hip/hip_bf16.h>

#define B_ 32
#define D_ 384
#define N_ 196
#define NH_ 8
#define HD_ 48
#define L_ 24

typedef __bf16 bf16x8 __attribute__((ext_vector_type(8)));
typedef float f32x4 __attribute__((ext_vector_type(4)));

__device__ __forceinline__ float gelu_f(float v){
    return 0.5f * v * (1.0f + erff(v * 0.70710678118654752f));
}

// ---------------- fp32 -> bf16 bulk convert ----------------
__global__ __launch_bounds__(256) void cvt_bf(const float* __restrict__ s, __bf16* __restrict__ d, long n){
    long i = ((long)blockIdx.x * 256 + threadIdx.x) * 8;
    if (i >= n) return;
    float4 a = *reinterpret_cast<const float4*>(s + i);
    float4 b = *reinterpret_cast<const float4*>(s + i + 4);
    bf16x8 r;
    r[0] = (__bf16)a.x; r[1] = (__bf16)a.y; r[2] = (__bf16)a.z; r[3] = (__bf16)a.w;
    r[4] = (__bf16)b.x; r[5] = (__bf16)b.y; r[6] = (__bf16)b.z; r[7] = (__bf16)b.w;
    *reinterpret_cast<bf16x8*>(d + i) = r;
}

// fp32 -> bf16 with row padding (zero rows >= rows)
__global__ __launch_bounds__(256) void cvt_pad(const float* __restrict__ s, __bf16* __restrict__ d,
                                               int rows, int K, int rows_pad){
    int id = blockIdx.x * 256 + threadIdx.x;
    if (id >= rows_pad * K) return;
    int r = id / K;
    d[id] = (r < rows) ? (__bf16)s[id] : (__bf16)0.f;
}

// ---------------- conv weight reorder: W'[co][tap*Ci+ci] (bf16, K padded) ----------------
__global__ __launch_bounds__(256) void wprep(const float* __restrict__ w, __bf16* __restrict__ W2,
                                             int Co, int Ci, int Kpad){
    int id = blockIdx.x * 256 + threadIdx.x;
    if (id >= Co * Kpad) return;
    int co = id / Kpad, k = id - co * Kpad;
    float v = 0.f;
    if (k < 9 * Ci){
        int tap = k / Ci, ci = k - tap * Ci;
        v = w[((long)co * Ci + ci) * 9 + tap];
    }
    W2[id] = (__bf16)v;
}

// ---------------- im2col for conv1 (fp32 NCHW input) -> A[pix][32] bf16 ----------------
__global__ __launch_bounds__(256) void im2col_x(const float* __restrict__ x, __bf16* __restrict__ A){
    int id = blockIdx.x * 256 + threadIdx.x;
    if (id >= 401408) return;
    int ox = id % 112; int t1 = id / 112; int oy = t1 % 112; int b = t1 / 112;
    __bf16 buf[32];
    #pragma unroll
    for (int i = 0; i < 32; i++) buf[i] = (__bf16)0.f;
    const float* xb = x + (long)b * 3 * 224 * 224;
    #pragma unroll
    for (int tap = 0; tap < 9; tap++){
        int ky = tap / 3, kx = tap % 3;
        int iy = oy * 2 - 1 + ky, ix = ox * 2 - 1 + kx;
        if ((unsigned)iy < 224u && (unsigned)ix < 224u){
            #pragma unroll
            for (int ci = 0; ci < 3; ci++)
                buf[tap * 3 + ci] = (__bf16)xb[((long)ci * 224 + iy) * 224 + ix];
        }
    }
    __bf16* dst = A + (long)id * 32;
    #pragma unroll
    for (int i = 0; i < 4; i++)
        *reinterpret_cast<bf16x8*>(dst + i * 8) = *reinterpret_cast<bf16x8*>(buf + i * 8);
}

// ---------------- im2col from bf16 [pix][C] rows -> A[pixout][Kpad] ----------------
__global__ __launch_bounds__(256) void im2col_bf(const __bf16* __restrict__ in, __bf16* __restrict__ A,
                                                 int C, int Hi, int Wi, int Ho, int Wo, int Kpad, int total){
    int id = blockIdx.x * 256 + threadIdx.x;
    if (id >= total) return;
    int tap = id % 9; int pix = id / 9;
    int ox = pix % Wo; int t1 = pix / Wo; int oy = t1 % Ho; int b = t1 / Ho;
    int ky = tap / 3, kx = tap % 3;
    int iy = oy * 2 - 1 + ky, ix = ox * 2 - 1 + kx;
    __bf16* dst = A + (long)pix * Kpad + tap * C;
    if ((unsigned)iy < (unsigned)Hi && (unsigned)ix < (unsigned)Wi){
        const __bf16* src = in + ((long)(b * Hi + iy) * Wi + ix) * C;
        for (int c = 0; c < C; c += 8)
            *reinterpret_cast<bf16x8*>(dst + c) = *reinterpret_cast<const bf16x8*>(src + c);
    } else {
        bf16x8 z{};
        for (int c = 0; c < C; c += 8) *reinterpret_cast<bf16x8*>(dst + c) = z;
    }
    if (tap == 0){
        bf16x8 z{};
        for (int c = 9 * C; c < Kpad; c += 8)
            *reinterpret_cast<bf16x8*>(A + (long)pix * Kpad + c) = z;
    }
}

// ---------------- conv GEMM: C[M,N] = A[M,Kpad] @ W[N,Kpad]^T, fused BN (+GELU / +pos) ----------------
// Tile 128x128, 4 waves, 2-stage register prefetch.
template<int GELU, int POSOUT>
__global__ __launch_bounds__(256) void gemm_conv(const __bf16* __restrict__ A, int Kpad,
                                                 const __bf16* __restrict__ W,
                                                 const float* __restrict__ g, const float* __restrict__ bb,
                                                 void* __restrict__ Cv, int N,
                                                 const float* __restrict__ pos){
    __shared__ __align__(16) char smem[20480];
    char* Ab = smem;
    char* Bb = smem + 10240;
    const int tid  = threadIdx.x;
    const int lane = tid & 63;
    const int wn   = (tid >> 6) & 1;
    const int wm   = tid >> 7;
    const int row0 = blockIdx.x * 128;
    const int col0 = blockIdx.y * 128;
    const int hi = lane >> 4, lo = lane & 15;
    f32x4 acc[4][4] = {};
    auto loadA = [&](int kk, int i)->bf16x8 {
        int p = i * 256 + tid;
        int r = p >> 2, cq = p & 3;
        return *reinterpret_cast<const bf16x8*>(A + (long)(row0 + r) * Kpad + kk + cq * 8);
    };
    auto loadB = [&](int kk, int i)->bf16x8 {
        int p = i * 256 + tid;
        int r = p >> 2, cq = p & 3;
        int gc = col0 + r;
        bf16x8 vw{};
        if (gc < N) vw = *reinterpret_cast<const bf16x8*>(W + (long)gc * Kpad + kk + cq * 8);
        return vw;
    };
    bf16x8 vaC0 = loadA(0, 0), vaC1 = loadA(0, 1);
    bf16x8 vwC0 = loadB(0, 0), vwC1 = loadB(0, 1);
    for (int k0 = 0; k0 < Kpad; k0 += 32){
        #pragma unroll
        for (int i = 0; i < 2; i++){
            int p = i * 256 + tid;
            int r = p >> 2, cq = p & 3;
            *reinterpret_cast<bf16x8*>(Ab + r * 80 + cq * 16) = i ? vaC1 : vaC0;
            *reinterpret_cast<bf16x8*>(Bb + r * 80 + cq * 16) = i ? vwC1 : vwC0;
        }
        __syncthreads();
        int kn = (k0 + 32 < Kpad) ? k0 + 32 : k0;
        bf16x8 vaN0 = loadA(kn, 0), vaN1 = loadA(kn, 1);
        bf16x8 vwN0 = loadB(kn, 0), vwN1 = loadB(kn, 1);
        bf16x8 af[4], bfr[4];
        #pragma unroll
        for (int m = 0; m < 4; m++)
            af[m] = *reinterpret_cast<const bf16x8*>(Ab + (wm * 64 + m * 16 + lo) * 80 + hi * 16);
        #pragma unroll
        for (int n = 0; n < 4; n++)
            bfr[n] = *reinterpret_cast<const bf16x8*>(Bb + (wn * 64 + n * 16 + lo) * 80 + hi * 16);
        #pragma unroll
        for (int m = 0; m < 4; m++)
            #pragma unroll
            for (int n = 0; n < 4; n++)
                acc[m][n] = __builtin_amdgcn_mfma_f32_16x16x32_bf16(af[m], bfr[n], acc[m][n], 0, 0, 0);
        __syncthreads();
        vaC0 = vaN0; vaC1 = vaN1; vwC0 = vwN0; vwC1 = vwN1;
    }
    float* Cf = (float*)Cv;
    __bf16* Cb = (__bf16*)Cv;
    #pragma unroll
    for (int m = 0; m < 4; m++){
        #pragma unroll
        for (int n = 0; n < 4; n++){
            int row = row0 + wm * 64 + m * 16 + hi * 4;
            int col = col0 + wn * 64 + n * 16 + lo;
            if (col >= N) continue;
            float scale = g[col] * rsqrtf(1.0f + 1e-5f);
            float bv = bb[col];
            #pragma unroll
            for (int j = 0; j < 4; j++){
                float v = acc[m][n][j] * scale + bv;
                if (GELU) v = gelu_f(v);
                if (POSOUT)
                    Cf[(long)(row + j) * 384 + col] = v + pos[((row + j) % 196) * 384 + col];
                else
                    Cb[(long)(row + j) * N + col] = (__bf16)v;
            }
        }
    }
}

// ---------------- LayerNorm over D=384, fp32 out ----------------
__global__ __launch_bounds__(128) void ln384(const float* __restrict__ x, long xstride,
                                             const float* __restrict__ w, const float* __restrict__ b,
                                             float* __restrict__ y, long ystride){
    long row = blockIdx.x;
    int tid = threadIdx.x;
    const float* xr = x + row * xstride;
    float v0 = xr[tid], v1 = xr[tid + 128], v2 = xr[tid + 256];
    float s = v0 + v1 + v2;
    float ss = v0 * v0 + v1 * v1 + v2 * v2;
    for (int off = 32; off; off >>= 1){ s += __shfl_down(s, off); ss += __shfl_down(ss, off); }
    __shared__ float rs[2], rss[2];
    if ((tid & 63) == 0){ rs[tid >> 6] = s; rss[tid >> 6] = ss; }
    __syncthreads();
    float S = rs[0] + rs[1], SS = rss[0] + rss[1];
    float m = S * (1.0f / 384.0f);
    float var = SS * (1.0f / 384.0f) - m * m;
    float r = rsqrtf(var + 1e-5f);
    float* yr = y + row * ystride;
    yr[tid]       = (v0 - m) * r * w[tid]       + b[tid];
    yr[tid + 128] = (v1 - m) * r * w[tid + 128] + b[tid + 128];
    yr[tid + 256] = (v2 - m) * r * w[tid + 256] + b[tid + 256];
}

// ---------------- LayerNorm, bf16 out ----------------
__global__ __launch_bounds__(128) void ln384_bf(const float* __restrict__ x,
                                                const float* __restrict__ w, const float* __restrict__ b,
                                                __bf16* __restrict__ y){
    long row = blockIdx.x;
    int tid = threadIdx.x;
    const float* xr = x + row * 384;
    float v0 = xr[tid], v1 = xr[tid + 128], v2 = xr[tid + 256];
    float s = v0 + v1 + v2;
    float ss = v0 * v0 + v1 * v1 + v2 * v2;
    for (int off = 32; off; off >>= 1){ s += __shfl_down(s, off); ss += __shfl_down(ss, off); }
    __shared__ float rs[2], rss[2];
    if ((tid & 63) == 0){ rs[tid >> 6] = s; rss[tid >> 6] = ss; }
    __syncthreads();
    float S = rs[0] + rs[1], SS = rss[0] + rss[1];
    float m = S * (1.0f / 384.0f);
    float var = SS * (1.0f / 384.0f) - m * m;
    float r = rsqrtf(var + 1e-5f);
    __bf16* yr = y + row * 384;
    yr[tid]       = (__bf16)((v0 - m) * r * w[tid]       + b[tid]);
    yr[tid + 128] = (__bf16)((v1 - m) * r * w[tid + 128] + b[tid + 128]);
    yr[tid + 256] = (__bf16)((v2 - m) * r * w[tid + 256] + b[tid + 256]);
}

// ---------------- split-K reduce + residual + LN3 (transposed out) ----------------
__global__ __launch_bounds__(128) void proj_red_lnt(const float* __restrict__ pp,
                                                    const float* __restrict__ pbias,
                                                    const float* __restrict__ g1,
                                                    float* __restrict__ t,
                                                    const float* __restrict__ n3w, const float* __restrict__ n3b,
                                                    float* __restrict__ ht){
    long row = blockIdx.x;
    int tid = threadIdx.x;
    const long MT = 6272L * 384;
    float v[3];
    #pragma unroll
    for (int i = 0; i < 3; i++){
        int c = tid + i * 128;
        long idx = row * 384 + c;
        float sacc = pp[idx] + pp[MT + idx] + pbias[c];
        v[i] = t[idx] + g1[c] * sacc;
        t[idx] = v[i];
    }
    float s = v[0] + v[1] + v[2];
    float ss = v[0] * v[0] + v[1] * v[1] + v[2] * v[2];
    for (int off = 32; off; off >>= 1){ s += __shfl_down(s, off); ss += __shfl_down(ss, off); }
    __shared__ float rs[2], rss[2];
    if ((tid & 63) == 0){ rs[tid >> 6] = s; rss[tid >> 6] = ss; }
    __syncthreads();
    float S = rs[0] + rs[1], SS = rss[0] + rss[1];
    float m = S * (1.0f / 384.0f);
    float var = SS * (1.0f / 384.0f) - m * m;
    float r = rsqrtf(var + 1e-5f);
    int b = (int)(row / 196), n = (int)(row % 196);
    float* yb = ht + ((long)b * 384) * 196 + n;
    #pragma unroll
    for (int i = 0; i < 3; i++){
        int c = tid + i * 128;
        yb[(long)c * 196] = (v[i] - m) * r * n3w[c] + n3b[c];
    }
}

// ---------------- split-K reduce + residual + LN1-of-next-layer (bf16 out) ----------------
__global__ __launch_bounds__(128) void fc2_red_ln(const float* __restrict__ pp,
                                                  const float* __restrict__ fbias,
                                                  const float* __restrict__ g2,
                                                  float* __restrict__ t,
                                                  const float* __restrict__ n1w, const float* __restrict__ n1b,
                                                  __bf16* __restrict__ h){
    long row = blockIdx.x;
    int tid = threadIdx.x;
    const long MT = 6272L * 384;
    float v[3];
    #pragma unroll
    for (int i = 0; i < 3; i++){
        int c = tid + i * 128;
        long idx = row * 384 + c;
        float sacc = pp[idx] + pp[MT + idx] + pp[2 * MT + idx] + fbias[c];
        v[i] = t[idx] + g2[c] * sacc;
        t[idx] = v[i];
    }
    float s = v[0] + v[1] + v[2];
    float ss = v[0] * v[0] + v[1] * v[1] + v[2] * v[2];
    for (int off = 32; off; off >>= 1){ s += __shfl_down(s, off); ss += __shfl_down(ss, off); }
    __shared__ float rs[2], rss[2];
    if ((tid & 63) == 0){ rs[tid >> 6] = s; rss[tid >> 6] = ss; }
    __syncthreads();
    float S = rs[0] + rs[1], SS = rss[0] + rss[1];
    float m = S * (1.0f / 384.0f);
    float var = SS * (1.0f / 384.0f) - m * m;
    float r = rsqrtf(var + 1e-5f);
    __bf16* yr = h + row * 384;
    #pragma unroll
    for (int i = 0; i < 3; i++){
        int c = tid + i * 128;
        yr[c] = (__bf16)((v[i] - m) * r * n1w[c] + n1b[c]);
    }
}

// ---------------- bf16 MFMA GEMM, 64x128 tile, 4 waves, 2-stage prefetch ----------------
// MODE 0: C=acc+bias; 1: gelu; 3: raw partial (no bias). OUTBF: bf16 C.
// ACVT: A fp32, convert on stage. GUARD: row guard vs M. SPLITK: blockIdx.z K-chunk.
// NGUARD: col guard vs Ncols on write.
template<int MODE, int OUTBF, int ACVT, int GUARD, int SPLITK, int NGUARD>
__global__ __launch_bounds__(256) void gemm_bb2(const void* __restrict__ Av, long lda,
                                                const __bf16* __restrict__ W, int Kw,
                                                const float* __restrict__ bias,
                                                void* __restrict__ Cv, long ldc,
                                                int K, int M, int Ncols){
    __shared__ __align__(16) char smem[15360];
    char* Ab = smem;            // 64 rows x 80B
    char* Bb = smem + 5120;     // 128 rows x 80B
    const int tid = threadIdx.x;
    const int lane = tid & 63;
    const int wn = tid >> 6;
    const int row0 = blockIdx.x * 64;
    const int col0 = blockIdx.y * 128;
    const int hi = lane >> 4, lo = lane & 15;
    const int kbase = SPLITK ? blockIdx.z * K : 0;
    const __bf16* Abf = (const __bf16*)Av;
    const float* Af = (const float*)Av;
    const int r_a = tid >> 2, cq_a = tid & 3;
    f32x4 acc[4][2] = {};
    auto loadA = [&](int kk)->bf16x8 {
        bf16x8 va{};
        int grow = row0 + r_a;
        if (!GUARD || grow < M){
            long ai = (long)grow * lda + kk + cq_a * 8;
            if (ACVT){
                float4 a0 = *reinterpret_cast<const float4*>(Af + ai);
                float4 a1 = *reinterpret_cast<const float4*>(Af + ai + 4);
                va[0] = (__bf16)a0.x; va[1] = (__bf16)a0.y; va[2] = (__bf16)a0.z; va[3] = (__bf16)a0.w;
                va[4] = (__bf16)a1.x; va[5] = (__bf16)a1.y; va[6] = (__bf16)a1.z; va[7] = (__bf16)a1.w;
            } else {
                va = *reinterpret_cast<const bf16x8*>(Abf + ai);
            }
        }
        return va;
    };
    auto loadB = [&](int kk, int i)->bf16x8 {
        int p = i * 256 + tid;
        int r = p >> 2, cq = p & 3;
        return *reinterpret_cast<const bf16x8*>(W + (long)(col0 + r) * Kw + kk + cq * 8);
    };
    bf16x8 vaC = loadA(kbase);
    bf16x8 vwC0 = loadB(kbase, 0), vwC1 = loadB(kbase, 1);
    for (int k0 = 0; k0 < K; k0 += 32){
        *reinterpret_cast<bf16x8*>(Ab + r_a * 80 + cq_a * 16) = vaC;
        #pragma unroll
        for (int i = 0; i < 2; i++){
            int p = i * 256 + tid;
            int r = p >> 2, cq = p & 3;
            *reinterpret_cast<bf16x8*>(Bb + r * 80 + cq * 16) = i ? vwC1 : vwC0;
        }
        __syncthreads();
        int kn = kbase + ((k0 + 32 < K) ? k0 + 32 : k0);
        bf16x8 vaN = loadA(kn);
        bf16x8 vwN0 = loadB(kn, 0), vwN1 = loadB(kn, 1);
        bf16x8 af[4], bfr[2];
        #pragma unroll
        for (int m = 0; m < 4; m++)
            af[m] = *reinterpret_cast<const bf16x8*>(Ab + (m * 16 + lo) * 80 + hi * 16);
        #pragma unroll
        for (int n = 0; n < 2; n++)
            bfr[n] = *reinterpret_cast<const bf16x8*>(Bb + (wn * 32 + n * 16 + lo) * 80 + hi * 16);
        #pragma unroll
        for (int m = 0; m < 4; m++)
            #pragma unroll
            for (int n = 0; n < 2; n++)
                acc[m][n] = __builtin_amdgcn_mfma_f32_16x16x32_bf16(af[m], bfr[n], acc[m][n], 0, 0, 0);
        __syncthreads();
        vaC = vaN; vwC0 = vwN0; vwC1 = vwN1;
    }
    float* Cf = (float*)Cv;
    __bf16* Cb = (__bf16*)Cv;
    if (SPLITK) Cf += (long)blockIdx.z * M * ldc;
    #pragma unroll
    for (int m = 0; m < 4; m++){
        #pragma unroll
        for (int n = 0; n < 2; n++){
            int row = row0 + m * 16 + hi * 4;
            int col = col0 + wn * 32 + n * 16 + lo;
            if (NGUARD && col >= Ncols) continue;
            float bv = (MODE == 3) ? 0.f : bias[col];
            #pragma unroll
            for (int j = 0; j < 4; j++){
                if (GUARD && (row + j) >= M) continue;
                float v = acc[m][n][j] + bv;
                if (MODE == 1) v = gelu_f(v);
                long ci = (long)(row + j) * ldc + col;
                if (OUTBF) Cb[ci] = (__bf16)v;
                else Cf[ci] = v;
            }
        }
    }
}

// ---------------- positional embedding: pos[n, d] ----------------
__global__ __launch_bounds__(384) void pos_embed(const float* __restrict__ pw, const float* __restrict__ pb,
                                                 float* __restrict__ pos){
    __shared__ float p64[64];
    int n = blockIdx.x;
    int iy = n / 14, ix = n % 14;
    int t = threadIdx.x;
    if (t < 64){
        int axis = t >> 5;
        int c = t & 31;
        int u = c >> 1;
        float coord = (axis == 0) ? (float)(iy + 1) : (float)(ix + 1);
        float val = coord / ((14.0f + 1e-6f) * 6.283185307179586f);
        float T = powf(10000.0f, (float)u / 16.0f);
        float a = val / T;
        p64[t] = (c & 1) ? cosf(a) : sinf(a);
    }
    __syncthreads();
    float acc = 0.f;
    const float* wr = pw + (long)t * 64;
    #pragma unroll 8
    for (int c = 0; c < 64; c++) acc += p64[c] * wr[c];
    pos[n * 384 + t] = acc + pb[t];
}

// ---------------- XCA attention via MFMA: one block per (b, head) ----------------
// LDS overlays: att (fp32 48x68) over qs; abf over ks. 75KB total -> 2 blocks/CU.
__global__ __launch_bounds__(256) void xca2(const __bf16* __restrict__ qkv, const float* __restrict__ temp,
                                            __bf16* __restrict__ o){
    __shared__ __align__(16) char smem[74880];
    __bf16* qs = (__bf16*)smem;                 // 48*232*2 = 22272
    __bf16* ks = (__bf16*)(smem + 22272);       // 22272
    __bf16* vt = (__bf16*)(smem + 44544);       // 208*72*2 = 29952
    float* inq = (float*)(smem + 74496);        // 192
    float* ink = (float*)(smem + 74688);        // 192
    float* att = (float*)smem;                  // overlay on qs (48*68*4 = 13056)
    __bf16* abf = (__bf16*)(smem + 22272);      // overlay on ks (48*72*2 = 6912)
    int bh = blockIdx.x;
    int b = bh >> 3, h = bh & 7;
    const int tid = threadIdx.x;
    const int wid = tid >> 6, lane = tid & 63;
    const int hi = lane >> 4, lo = lane & 15;
    const __bf16* base = qkv + ((long)b * 196) * 1152 + h * 48;
    bf16x8 z8 = {};
    for (int idx = tid; idx < 48 * 28; idx += 256){
        int d = idx / 28, n = 196 + idx % 28;
        qs[d * 232 + n] = (__bf16)0.f;
        ks[d * 232 + n] = (__bf16)0.f;
    }
    for (int idx = tid; idx < 208 * 2; idx += 256){
        int n = idx >> 1, c = 48 + (idx & 1) * 8;
        *reinterpret_cast<bf16x8*>(vt + n * 72 + c) = z8;
    }
    for (int ch = tid; ch < 196 * 6; ch += 256){
        int n = ch / 6, c = ch % 6, d0 = c * 8;
        bf16x8 q8 = *reinterpret_cast<const bf16x8*>(base + (long)n * 1152 + d0);
        bf16x8 k8 = *reinterpret_cast<const bf16x8*>(base + (long)n * 1152 + 384 + d0);
        #pragma unroll
        for (int j = 0; j < 8; j++){
            qs[(d0 + j) * 232 + n] = q8[j];
            ks[(d0 + j) * 232 + n] = k8[j];
        }
        bf16x8 v8 = *reinterpret_cast<const bf16x8*>(base + (long)n * 1152 + 768 + d0);
        *reinterpret_cast<bf16x8*>(vt + n * 72 + d0) = v8;
    }
    __syncthreads();
    for (int r = wid; r < 48; r += 4){
        float sq = 0.f, sk = 0.f;
        for (int n = lane; n < 196; n += 64){
            float qv = (float)qs[r * 232 + n];
            float kv = (float)ks[r * 232 + n];
            sq += qv * qv; sk += kv * kv;
        }
        for (int off = 32; off; off >>= 1){ sq += __shfl_down(sq, off); sk += __shfl_down(sk, off); }
        if (lane == 0){
            inq[r] = 1.0f / fmaxf(sqrtf(sq), 1e-12f);
            ink[r] = 1.0f / fmaxf(sqrtf(sk), 1e-12f);
        }
    }
    __syncthreads();
    float tempv = temp[h];
    // QK^T: accumulate tiles in registers (static indexing), then overlay-write
    f32x4 qk0 = {}, qk1 = {}, qk2 = {};
    __builtin_amdgcn_s_setprio(1);
    {
        int mi = wid / 3, ni = wid % 3;
        #pragma unroll
        for (int k0 = 0; k0 < 224; k0 += 32){
            bf16x8 af = *reinterpret_cast<const bf16x8*>(qs + (mi * 16 + lo) * 232 + k0 + hi * 8);
            bf16x8 bf = *reinterpret_cast<const bf16x8*>(ks + (ni * 16 + lo) * 232 + k0 + hi * 8);
            qk0 = __builtin_amdgcn_mfma_f32_16x16x32_bf16(af, bf, qk0, 0, 0, 0);
        }
    }
    {
        int tt = wid + 4;
        int mi = tt / 3, ni = tt % 3;
        #pragma unroll
        for (int k0 = 0; k0 < 224; k0 += 32){
            bf16x8 af = *reinterpret_cast<const bf16x8*>(qs + (mi * 16 + lo) * 232 + k0 + hi * 8);
            bf16x8 bf = *reinterpret_cast<const bf16x8*>(ks + (ni * 16 + lo) * 232 + k0 + hi * 8);
            qk1 = __builtin_amdgcn_mfma_f32_16x16x32_bf16(af, bf, qk1, 0, 0, 0);
        }
    }
    if (wid == 0){
        int mi = 2, ni = 2;  // tile 8
        #pragma unroll
        for (int k0 = 0; k0 < 224; k0 += 32){
            bf16x8 af = *reinterpret_cast<const bf16x8*>(qs + (mi * 16 + lo) * 232 + k0 + hi * 8);
            bf16x8 bf = *reinterpret_cast<const bf16x8*>(ks + (ni * 16 + lo) * 232 + k0 + hi * 8);
            qk2 = __builtin_amdgcn_mfma_f32_16x16x32_bf16(af, bf, qk2, 0, 0, 0);
        }
    }
    __builtin_amdgcn_s_setprio(0);
    __syncthreads();   // qs/ks reads done; overlays become writable
    {
        int mi = wid / 3, ni = wid % 3;
        int e = ni * 16 + lo;
        float se = ink[e] * tempv;
        #pragma unroll
        for (int j = 0; j < 4; j++){
            int d = mi * 16 + hi * 4 + j;
            att[d * 68 + e] = qk0[j] * inq[d] * se;
        }
    }
    {
        int tt = wid + 4;
        int mi = tt / 3, ni = tt % 3;
        int e = ni * 16 + lo;
        float se = ink[e] * tempv;
        #pragma unroll
        for (int j = 0; j < 4; j++){
            int d = mi * 16 + hi * 4 + j;
            att[d * 68 + e] = qk1[j] * inq[d] * se;
        }
    }
    if (wid == 0){
        int e = 2 * 16 + lo;
        float se = ink[e] * tempv;
        #pragma unroll
        for (int j = 0; j < 4; j++){
            int d = 2 * 16 + hi * 4 + j;
            att[d * 68 + e] = qk2[j] * inq[d] * se;
        }
    }
    __syncthreads();
    if (tid < 192){
        int r = tid >> 2, q4 = tid & 3;
        const float* row = att + r * 68 + q4 * 12;
        float mx = -1e30f;
        #pragma unroll
        for (int i = 0; i < 12; i++) mx = fmaxf(mx, row[i]);
        mx = fmaxf(mx, __shfl_xor(mx, 1));
        mx = fmaxf(mx, __shfl_xor(mx, 2));
        float pv[12]; float sm = 0.f;
        #pragma unroll
        for (int i = 0; i < 12; i++){ pv[i] = expf(row[i] - mx); sm += pv[i]; }
        sm += __shfl_xor(sm, 1);
        sm += __shfl_xor(sm, 2);
        float inv = 1.0f / sm;
        #pragma unroll
        for (int i = 0; i < 12; i++) abf[r * 72 + q4 * 12 + i] = (__bf16)(pv[i] * inv);
    }
    for (int idx = tid; idx < 48 * 3; idx += 256){
        int r = idx / 3, c = 48 + (idx % 3) * 8;
        *reinterpret_cast<bf16x8*>(abf + r * 72 + c) = z8;
    }
    __syncthreads();
    __bf16* ob = o + ((long)b * 196) * 384 + h * 48;
    __builtin_amdgcn_s_setprio(1);
    for (int tt = wid; tt < 39; tt += 4){
        int mi = tt / 13, ni = tt % 13;
        f32x4 acc = {};
        #pragma unroll
        for (int e0 = 0; e0 < 64; e0 += 32){
            bf16x8 af = *reinterpret_cast<const bf16x8*>(abf + (mi * 16 + lo) * 72 + e0 + hi * 8);
            bf16x8 bf = *reinterpret_cast<const bf16x8*>(vt + (ni * 16 + lo) * 72 + e0 + hi * 8);
            acc = __builtin_amdgcn_mfma_f32_16x16x32_bf16(af, bf, acc, 0, 0, 0);
        }
        int n = ni * 16 + lo;
        if (n < 196){
            #pragma unroll
            for (int j = 0; j < 4; j++){
                int d = mi * 16 + hi * 4 + j;
                ob[(long)n * 384 + d] = (__bf16)acc[j];
            }
        }
    }
    __builtin_amdgcn_s_setprio(0);
}

// ---------------- LPI ----------------
__global__ __launch_bounds__(256) void lpi(const float* __restrict__ ht,
                                           const float* __restrict__ w1, const float* __restrict__ b1,
                                           const float* __restrict__ bng, const float* __restrict__ bnb,
                                           const float* __restrict__ w2, const float* __restrict__ b2,
                                           const float* __restrict__ g3, float* __restrict__ t){
    int bd = blockIdx.x;
    int d = bd % 384, b = bd / 384;
    __shared__ float p[16][16];
    __shared__ float p2[16][16];
    __shared__ float wA[9], wB[9];
    int tt = threadIdx.x;
    int yy = tt / 16, xx = tt % 16;
    p[yy][xx] = 0.f; p2[yy][xx] = 0.f;
    if (tt < 9){ wA[tt] = w1[d * 9 + tt]; wB[tt] = w2[d * 9 + tt]; }
    __syncthreads();
    if (tt < 196){
        int y = tt / 14, x = tt % 14;
        p[y + 1][x + 1] = ht[((long)b * 384 + d) * 196 + tt];
    }
    __syncthreads();
    if (tt < 196){
        int y = tt / 14, x = tt % 14;
        float a = 0.f;
        #pragma unroll
        for (int ky = 0; ky < 3; ky++)
            #pragma unroll
            for (int kx = 0; kx < 3; kx++)
                a += wA[ky * 3 + kx] * p[y + ky][x + kx];
        a += b1[d];
        a = gelu_f(a);
        a = a * (bng[d] * rsqrtf(1.0f + 1e-5f)) + bnb[d];
        p2[y + 1][x + 1] = a;
    }
    __syncthreads();
    if (tt < 196){
        int y = tt / 14, x = tt % 14;
        float a = 0.f;
        #pragma unroll
        for (int ky = 0; ky < 3; ky++)
            #pragma unroll
            for (int kx = 0; kx < 3; kx++)
                a += wB[ky * 3 + kx] * p2[y + ky][x + kx];
        a += b2[d];
        long ti = ((long)b * 196 + tt) * 384 + d;
        t[ti] += g3[d] * a;
    }
}

// ---------------- cls concat ----------------
__global__ __launch_bounds__(256) void concat_cls(const float* __restrict__ t, const float* __restrict__ clstok,
                                                  float* __restrict__ tc){
    long i = (long)blockIdx.x * 256 + threadIdx.x;
    if (i >= (long)B_ * 197 * 384) return;
    int d = (int)(i % 384);
    long bn = i / 384;
    int n = (int)(bn % 197);
    int b = (int)(bn / 197);
    tc[i] = (n == 0) ? clstok[d] : t[((long)b * 196 + (n - 1)) * 384 + d];
}

// ---------------- CA attention (bf16 qkv) ----------------
__global__ __launch_bounds__(256) void ca_attn(const __bf16* __restrict__ qkv, float* __restrict__ clsp){
    int bh = blockIdx.x;
    int b = bh >> 3, h = bh & 7;
    const __bf16* base = qkv + (long)b * 197 * 1152 + h * 48;
    __shared__ float q0[48];
    __shared__ float at2[197];
    __shared__ float smax, ssum;
    int tid = threadIdx.x;
    if (tid < 48) q0[tid] = (float)base[tid];
    __syncthreads();
    if (tid < 197){
        const __bf16* kr = base + (long)tid * 1152 + 384;
        float s = 0.f;
        for (int d = 0; d < 48; d++) s += q0[d] * (float)kr[d];
        at2[tid] = s * rsqrtf(48.0f);
    }
    __syncthreads();
    if (tid == 0){
        float m = -1e30f;
        for (int n = 0; n < 197; n++) m = fmaxf(m, at2[n]);
        smax = m;
    }
    __syncthreads();
    if (tid < 197) at2[tid] = expf(at2[tid] - smax);
    __syncthreads();
    if (tid == 0){
        float s = 0.f;
        for (int n = 0; n < 197; n++) s += at2[n];
        ssum = s;
    }
    __syncthreads();
    if (tid < 48){
        const __bf16* vb = base + 768 + tid;
        float s = 0.f;
        for (int n = 0; n < 197; n++) s += at2[n] * (float)vb[(long)n * 1152];
        clsp[b * 384 + h * 48 + tid] = s / ssum;
    }
}

__global__ __launch_bounds__(256) void ca_update1(const float* __restrict__ clso, const float* __restrict__ hc,
                                                  const float* __restrict__ g1, float* __restrict__ tc){
    long i = (long)blockIdx.x * 256 + threadIdx.x;
    if (i >= (long)B_ * 197 * 384) return;
    int d = (int)(i % 384);
    long bn = i / 384;
    int n = (int)(bn % 197);
    int b = (int)(bn / 197);
    float add = (n == 0) ? clso[b * 384 + d] : hc[i];
    tc[i] += g1[d] * add;
}

__global__ __launch_bounds__(256) void ca_update2(const float* __restrict__ cls2, const float* __restrict__ hc,
                                                  const float* __restrict__ g2, float* __restrict__ tc){
    long i = (long)blockIdx.x * 256 + threadIdx.x;
    if (i >= (long)B_ * 197 * 384) return;
    int d = (int)(i % 384);
    long bn = i / 384;
    int n = (int)(bn % 197);
    int b = (int)(bn / 197);
    float hv = hc[i];
    tc[i] = (n == 0) ? (g2[d] * cls2[b * 384 + d] + hv) : (hv + hv);
}

extern "C" void kernel_launch(void* const* d_in, const int* in_sizes, int n_in,
                              void* d_out, int out_size, void* d_ws, size_t ws_size,
                              hipStream_t stream){
    (void)in_sizes; (void)n_in; (void)out_size; (void)ws_size;
    const float* x      = (const float*)d_in[0];
    const float* clstok = (const float*)d_in[1];
    const float* pos_w  = (const float*)d_in[2];
    const float* pos_b  = (const float*)d_in[3];
    const float* pe_w[4] = {(const float*)d_in[4], (const float*)d_in[7], (const float*)d_in[10], (const float*)d_in[13]};
    const float* pe_g[4] = {(const float*)d_in[5], (const float*)d_in[8], (const float*)d_in[11], (const float*)d_in[14]};
    const float* pe_b[4] = {(const float*)d_in[6], (const float*)d_in[9], (const float*)d_in[12], (const float*)d_in[15]};
    const float* xqkv_w = (const float*)d_in[16];
    const float* xqkv_b = (const float*)d_in[17];
    const float* xproj_w = (const float*)d_in[18];
    const float* xproj_b = (const float*)d_in[19];
    const float* xtemp  = (const float*)d_in[20];
    const float* xn1_w = (const float*)d_in[21];
    const float* xn1_b = (const float*)d_in[22];
    const float* xn2_w = (const float*)d_in[23];
    const float* xn2_b = (const float*)d_in[24];
    const float* xn3_w = (const float*)d_in[25];
    const float* xn3_b = (const float*)d_in[26];
    const float* xfc1_w = (const float*)d_in[27];
    const float* xfc1_b = (const float*)d_in[28];
    const float* xfc2_w = (const float*)d_in[29];
    const float* xfc2_b = (const float*)d_in[30];
    const float* xlpi1_w = (const float*)d_in[31];
    const float* xlpi1_b = (const float*)d_in[32];
    const float* xlpi2_w = (const float*)d_in[33];
    const float* xlpi2_b = (const float*)d_in[34];
    const float* xbn_g = (const float*)d_in[35];
    const float* xbn_b = (const float*)d_in[36];
    const float* xg1 = (const float*)d_in[37];
    const float* xg2 = (const float*)d_in[38];
    const float* xg3 = (const float*)d_in[39];
    const float* cqkv_w = (const float*)d_in[40];
    const float* cqkv_b = (const float*)d_in[41];
    const float* cproj_w = (const float*)d_in[42];
    const float* cproj_b = (const float*)d_in[43];
    const float* cn1_w = (const float*)d_in[44];
    const float* cn1_b = (const float*)d_in[45];
    const float* cn2_w = (const float*)d_in[46];
    const float* cn2_b = (const float*)d_in[47];
    const float* cfc1_w = (const float*)d_in[48];
    const float* cfc1_b = (const float*)d_in[49];
    const float* cfc2_w = (const float*)d_in[50];
    const float* cfc2_b = (const float*)d_in[51];
    const float* cg1 = (const float*)d_in[52];
    const float* cg2 = (const float*)d_in[53];
    const float* norm_w = (const float*)d_in[54];
    const float* norm_b = (const float*)d_in[55];
    const float* head_w = (const float*)d_in[56];
    const float* head_b = (const float*)d_in[57];
    float* outp = (float*)d_out;

    float* ws = (float*)d_ws;
    // ---- conv phase buffers ----
    __bf16* A1   = (__bf16*)(ws);
    __bf16* A2   = (__bf16*)(ws);
    __bf16* A3   = (__bf16*)(ws);
    __bf16* A4   = (__bf16*)(ws);
    __bf16* out1 = (__bf16*)(ws + 22500000L);
    __bf16* out2 = (__bf16*)(ws + 22500000L);
    __bf16* out3 = (__bf16*)(ws + 27400000L);
    __bf16* wcv  = (__bf16*)(ws + 36000000L);
    __bf16* W1c = wcv;
    __bf16* W2c = wcv + 1536;
    __bf16* W3c = wcv + 44544;
    __bf16* W4c = wcv + 216576;
    // ---- XCA phase ----
    __bf16* wqkv_bf = (__bf16*)(ws);
    __bf16* wproj_bf = (__bf16*)(ws + 5308416L);
    __bf16* wfc1_bf = (__bf16*)(ws + 7077888L);
    __bf16* wfc2_bf = (__bf16*)(ws + 14155776L);
    float*  t       = ws + 21233664L;
    float*  pos     = ws + 23642112L;
    __bf16* h_bf    = (__bf16*)(ws + 23717376L);
    __bf16* qkv_bf  = (__bf16*)(ws + 24921600L);
    __bf16* o_bf    = (__bf16*)(ws + 28534272L);
    float*  ht      = ws + 29738496L;
    __bf16* f1_bf   = (__bf16*)(ws + 32146944L);
    float*  pproj   = ws + 32146944L;   // 2 x 2,408,448 fp32 (aliases f1_bf; time-disjoint)
    float*  pfc2    = ws + 24921600L;   // 3 x 2,408,448 fp32 (aliases qkv_bf/o_bf/ht; time-disjoint)
    // ---- CA phase ----
    float* tc   = ws;
    float* hc   = ws + 2420736L;
    __bf16* qkvc_bf = (__bf16*)(ws + 4841472L);
    float* clsp = ws + 8472576L;
    float* clso = clsp + 12288;
    float* f1c  = clso + 12288;
    float* cls2 = f1c + 49152;
    float* clsf = cls2 + 12288;
    __bf16* cqkv_bf  = (__bf16*)(ws + 9000000L);
    __bf16* cproj_bf = (__bf16*)(ws + 9500000L);
    __bf16* cfc1_bf  = (__bf16*)(ws + 9800000L);
    __bf16* cfc2_bf  = (__bf16*)(ws + 10400000L);
    __bf16* headw_bf = (__bf16*)(ws + 11000000L);

    // ---- conv weight prep ----
    wprep<<<(48 * 32 + 255) / 256, 256, 0, stream>>>(pe_w[0], W1c, 48, 3, 32);
    wprep<<<(96 * 448 + 255) / 256, 256, 0, stream>>>(pe_w[1], W2c, 96, 48, 448);
    wprep<<<(192 * 896 + 255) / 256, 256, 0, stream>>>(pe_w[2], W3c, 192, 96, 896);
    wprep<<<(384 * 1728 + 255) / 256, 256, 0, stream>>>(pe_w[3], W4c, 384, 192, 1728);

    // ---- patch embed: im2col + MFMA GEMM ----
    im2col_x<<<1568, 256, 0, stream>>>(x, A1);
    { dim3 g(3136, 1); gemm_conv<1, 0><<<g, 256, 0, stream>>>(A1, 32, W1c, pe_g[0], pe_b[0], out1, 48, nullptr); }
    im2col_bf<<<(100352 * 9 + 255) / 256, 256, 0, stream>>>(out1, A2, 48, 112, 112, 56, 56, 448, 100352 * 9);
    { dim3 g(784, 1); gemm_conv<1, 0><<<g, 256, 0, stream>>>(A2, 448, W2c, pe_g[1], pe_b[1], out2, 96, nullptr); }
    im2col_bf<<<(25088 * 9 + 255) / 256, 256, 0, stream>>>(out2, A3, 96, 56, 56, 28, 28, 896, 25088 * 9);
    pos_embed<<<196, 384, 0, stream>>>(pos_w, pos_b, pos);
    { dim3 g(196, 2); gemm_conv<1, 0><<<g, 256, 0, stream>>>(A3, 896, W3c, pe_g[2], pe_b[2], out3, 192, nullptr); }
    im2col_bf<<<(6272 * 9 + 255) / 256, 256, 0, stream>>>(out3, A4, 192, 28, 28, 14, 14, 1728, 6272 * 9);
    { dim3 g(49, 3); gemm_conv<0, 1><<<g, 256, 0, stream>>>(A4, 1728, W4c, pe_g[3], pe_b[3], t, 384, pos); }

    // ---- convert XCA weights to bf16 ----
    {
        long n1 = (long)L_ * 1152 * 384;
        long n2 = (long)L_ * 384 * 384;
        long n3 = (long)L_ * 1536 * 384;
        cvt_bf<<<(int)((n1 + 2047) / 2048), 256, 0, stream>>>(xqkv_w, wqkv_bf, n1);
        cvt_bf<<<(int)((n2 + 2047) / 2048), 256, 0, stream>>>(xproj_w, wproj_bf, n2);
        cvt_bf<<<(int)((n3 + 2047) / 2048), 256, 0, stream>>>(xfc1_w, wfc1_bf, n3);
        cvt_bf<<<(int)((n3 + 2047) / 2048), 256, 0, stream>>>(xfc2_w, wfc2_bf, n3);
    }

    // ---- 24 XCA layers ----
    const int M = B_ * N_;  // 6272 = 98*64
    ln384_bf<<<M, 128, 0, stream>>>(t, xn1_w, xn1_b, h_bf);   // initial LN1
    for (int l = 0; l < L_; l++){
        {
            dim3 g(98, 9);
            gemm_bb2<0, 1, 0, 0, 0, 0><<<g, 256, 0, stream>>>(h_bf, 384, wqkv_bf + (long)l * 1152 * 384, 384,
                                                              xqkv_b + l * 1152, qkv_bf, 1152, 384, M, 0);
        }
        xca2<<<B_ * NH_, 256, 0, stream>>>(qkv_bf, xtemp + l * 8, o_bf);
        {   // proj split-K=2 -> partials
            dim3 g(98, 3, 2);
            gemm_bb2<3, 0, 0, 0, 1, 0><<<g, 256, 0, stream>>>(o_bf, 384, wproj_bf + (long)l * 384 * 384, 384,
                                                              nullptr, pproj, 384, 192, M, 0);
        }
        proj_red_lnt<<<M, 128, 0, stream>>>(pproj, xproj_b + l * 384, xg1 + l * 384, t,
                                            xn3_w + l * 384, xn3_b + l * 384, ht);
        lpi<<<B_ * D_, 256, 0, stream>>>(ht, xlpi1_w + (long)l * 384 * 9, xlpi1_b + l * 384,
                                         xbn_g + l * 384, xbn_b + l * 384,
                                         xlpi2_w + (long)l * 384 * 9, xlpi2_b + l * 384,
                                         xg3 + l * 384, t);
        ln384_bf<<<M, 128, 0, stream>>>(t, xn2_w + l * 384, xn2_b + l * 384, h_bf);
        {
            dim3 g(98, 12);
            gemm_bb2<1, 1, 0, 0, 0, 0><<<g, 256, 0, stream>>>(h_bf, 384, wfc1_bf + (long)l * 1536 * 384, 384,
                                                              xfc1_b + l * 1536, f1_bf, 1536, 384, M, 0);
        }
        {   // fc2 split-K=3 -> partials
            dim3 g(98, 3, 3);
            gemm_bb2<3, 0, 0, 0, 1, 0><<<g, 256, 0, stream>>>(f1_bf, 1536, wfc2_bf + (long)l * 1536 * 384, 1536,
                                                              nullptr, pfc2, 384, 512, M, 0);
        }
        int ln = (l + 1) % L_;
        fc2_red_ln<<<M, 128, 0, stream>>>(pfc2, xfc2_b + l * 384, xg2 + l * 384, t,
                                          xn1_w + ln * 384, xn1_b + ln * 384, h_bf);
    }

    // ---- cls concat + 2 CA blocks ----
    const long NC = (long)B_ * 197 * 384;
    concat_cls<<<(int)(NC / 256), 256, 0, stream>>>(t, clstok, tc);
    {
        long nc = (long)2 * 1152 * 384;
        cvt_bf<<<(int)((nc + 2047) / 2048), 256, 0, stream>>>(cqkv_w, cqkv_bf, nc);
        long np = (long)2 * 384 * 384;
        cvt_bf<<<(int)((np + 2047) / 2048), 256, 0, stream>>>(cproj_w, cproj_bf, np);
        long nf = (long)2 * 1536 * 384;
        cvt_bf<<<(int)((nf + 2047) / 2048), 256, 0, stream>>>(cfc1_w, cfc1_bf, nf);
        cvt_bf<<<(int)((nf + 2047) / 2048), 256, 0, stream>>>(cfc2_w, cfc2_bf, nf);
        cvt_pad<<<(1024 * 384 + 255) / 256, 256, 0, stream>>>(head_w, headw_bf, 1000, 384, 1024);
    }
    const int MC = B_ * 197;  // 6304
    for (int i = 0; i < 2; i++){
        ln384<<<MC, 128, 0, stream>>>(tc, 384, cn1_w + i * 384, cn1_b + i * 384, hc, 384);
        {
            dim3 g(99, 9);
            gemm_bb2<0, 1, 1, 1, 0, 0><<<g, 256, 0, stream>>>(hc, 384, cqkv_bf + (long)i * 1152 * 384, 384,
                                                              cqkv_b + i * 1152, qkvc_bf, 1152, 384, MC, 0);
        }
        ca_attn<<<B_ * NH_, 256, 0, stream>>>(qkvc_bf, clsp);
        {
            dim3 g(1, 3);
            gemm_bb2<0, 0, 1, 1, 0, 0><<<g, 256, 0, stream>>>(clsp, 384, cproj_bf + (long)i * 384 * 384, 384,
                                                              cproj_b + i * 384, clso, 384, 384, 32, 0);
        }
        ca_update1<<<(int)(NC / 256), 256, 0, stream>>>(clso, hc, cg1 + i * 384, tc);
        ln384<<<MC, 128, 0, stream>>>(tc, 384, cn2_w + i * 384, cn2_b + i * 384, hc, 384);
        {
            dim3 g(1, 12);
            gemm_bb2<1, 0, 1, 1, 0, 0><<<g, 256, 0, stream>>>(hc, (long)197 * 384, cfc1_bf + (long)i * 1536 * 384, 384,
                                                              cfc1_b + i * 1536, f1c, 1536, 384, 32, 0);
        }
        {
            dim3 g(1, 3);
            gemm_bb2<0, 0, 1, 1, 0, 0><<<g, 256, 0, stream>>>(f1c, 1536, cfc2_bf + (long)i * 1536 * 384, 1536,
                                                              cfc2_b + i * 384, cls2, 384, 1536, 32, 0);
        }
        ca_update2<<<(int)(NC / 256), 256, 0, stream>>>(cls2, hc, cg2 + i * 384, tc);
    }

    // ---- final LN (cls token only) + head ----
    ln384<<<32, 128, 0, stream>>>(tc, (long)197 * 384, norm_w, norm_b, clsf, 384);
    {
        dim3 g(1, 8);
        gemm_bb2<0, 0, 1, 1, 0, 1><<<g, 256, 0, stream>>>(clsf, 384, headw_bf, 384,
                                                          head_b, outp, 1000, 384, 32, 1000);
    }
}

// Round 8
// 4187.654 us; speedup vs baseline: 5.0184x; 1.0959x over previous
//
#include <hip/hip_runtime.h>
#include <hip/hip_bf16.h>

#define B_ 32
#define D_ 384
#define N_ 196
#define NH_ 8
#define HD_ 48
#define L_ 24

typedef __bf16 bf16x8 __attribute__((ext_vector_type(8)));
typedef float f32x4 __attribute__((ext_vector_type(4)));

__device__ __forceinline__ float gelu_f(float v){
    return 0.5f * v * (1.0f + erff(v * 0.70710678118654752f));
}

// ---------------- fp32 -> bf16 bulk convert ----------------
__global__ __launch_bounds__(256) void cvt_bf(const float* __restrict__ s, __bf16* __restrict__ d, long n){
    long i = ((long)blockIdx.x * 256 + threadIdx.x) * 8;
    if (i >= n) return;
    float4 a = *reinterpret_cast<const float4*>(s + i);
    float4 b = *reinterpret_cast<const float4*>(s + i + 4);
    bf16x8 r;
    r[0] = (__bf16)a.x; r[1] = (__bf16)a.y; r[2] = (__bf16)a.z; r[3] = (__bf16)a.w;
    r[4] = (__bf16)b.x; r[5] = (__bf16)b.y; r[6] = (__bf16)b.z; r[7] = (__bf16)b.w;
    *reinterpret_cast<bf16x8*>(d + i) = r;
}

// fp32 -> bf16 with row padding (zero rows >= rows)
__global__ __launch_bounds__(256) void cvt_pad(const float* __restrict__ s, __bf16* __restrict__ d,
                                               int rows, int K, int rows_pad){
    int id = blockIdx.x * 256 + threadIdx.x;
    if (id >= rows_pad * K) return;
    int r = id / K;
    d[id] = (r < rows) ? (__bf16)s[id] : (__bf16)0.f;
}

// ---------------- conv weight reorder: W'[co][tap*Ci+ci] (bf16, K padded) ----------------
__global__ __launch_bounds__(256) void wprep(const float* __restrict__ w, __bf16* __restrict__ W2,
                                             int Co, int Ci, int Kpad){
    int id = blockIdx.x * 256 + threadIdx.x;
    if (id >= Co * Kpad) return;
    int co = id / Kpad, k = id - co * Kpad;
    float v = 0.f;
    if (k < 9 * Ci){
        int tap = k / Ci, ci = k - tap * Ci;
        v = w[((long)co * Ci + ci) * 9 + tap];
    }
    W2[id] = (__bf16)v;
}

// ---------------- im2col for conv1 (fp32 NCHW input) -> A[pix][32] bf16 ----------------
__global__ __launch_bounds__(256) void im2col_x(const float* __restrict__ x, __bf16* __restrict__ A){
    int id = blockIdx.x * 256 + threadIdx.x;
    if (id >= 401408) return;
    int ox = id % 112; int t1 = id / 112; int oy = t1 % 112; int b = t1 / 112;
    __bf16 buf[32];
    #pragma unroll
    for (int i = 0; i < 32; i++) buf[i] = (__bf16)0.f;
    const float* xb = x + (long)b * 3 * 224 * 224;
    #pragma unroll
    for (int tap = 0; tap < 9; tap++){
        int ky = tap / 3, kx = tap % 3;
        int iy = oy * 2 - 1 + ky, ix = ox * 2 - 1 + kx;
        if ((unsigned)iy < 224u && (unsigned)ix < 224u){
            #pragma unroll
            for (int ci = 0; ci < 3; ci++)
                buf[tap * 3 + ci] = (__bf16)xb[((long)ci * 224 + iy) * 224 + ix];
        }
    }
    __bf16* dst = A + (long)id * 32;
    #pragma unroll
    for (int i = 0; i < 4; i++)
        *reinterpret_cast<bf16x8*>(dst + i * 8) = *reinterpret_cast<bf16x8*>(buf + i * 8);
}

// ---------------- im2col from bf16 [pix][C] rows -> A[pixout][Kpad] ----------------
__global__ __launch_bounds__(256) void im2col_bf(const __bf16* __restrict__ in, __bf16* __restrict__ A,
                                                 int C, int Hi, int Wi, int Ho, int Wo, int Kpad, int total){
    int id = blockIdx.x * 256 + threadIdx.x;
    if (id >= total) return;
    int tap = id % 9; int pix = id / 9;
    int ox = pix % Wo; int t1 = pix / Wo; int oy = t1 % Ho; int b = t1 / Ho;
    int ky = tap / 3, kx = tap % 3;
    int iy = oy * 2 - 1 + ky, ix = ox * 2 - 1 + kx;
    __bf16* dst = A + (long)pix * Kpad + tap * C;
    if ((unsigned)iy < (unsigned)Hi && (unsigned)ix < (unsigned)Wi){
        const __bf16* src = in + ((long)(b * Hi + iy) * Wi + ix) * C;
        for (int c = 0; c < C; c += 8)
            *reinterpret_cast<bf16x8*>(dst + c) = *reinterpret_cast<const bf16x8*>(src + c);
    } else {
        bf16x8 z{};
        for (int c = 0; c < C; c += 8) *reinterpret_cast<bf16x8*>(dst + c) = z;
    }
    if (tap == 0){
        bf16x8 z{};
        for (int c = 9 * C; c < Kpad; c += 8)
            *reinterpret_cast<bf16x8*>(A + (long)pix * Kpad + c) = z;
    }
}

// ---------------- conv GEMM: 128x128 tile, 2-stage prefetch, fused BN (+GELU / +pos) ----------------
template<int GELU, int POSOUT>
__global__ __launch_bounds__(256) void gemm_conv(const __bf16* __restrict__ A, int Kpad,
                                                 const __bf16* __restrict__ W,
                                                 const float* __restrict__ g, const float* __restrict__ bb,
                                                 void* __restrict__ Cv, int N,
                                                 const float* __restrict__ pos){
    __shared__ __align__(16) char smem[20480];
    char* Ab = smem;
    char* Bb = smem + 10240;
    const int tid  = threadIdx.x;
    const int lane = tid & 63;
    const int wn   = (tid >> 6) & 1;
    const int wm   = tid >> 7;
    const int row0 = blockIdx.x * 128;
    const int col0 = blockIdx.y * 128;
    const int hi = lane >> 4, lo = lane & 15;
    f32x4 acc[4][4] = {};
    auto loadA = [&](int kk, int i)->bf16x8 {
        int p = i * 256 + tid;
        int r = p >> 2, cq = p & 3;
        return *reinterpret_cast<const bf16x8*>(A + (long)(row0 + r) * Kpad + kk + cq * 8);
    };
    auto loadB = [&](int kk, int i)->bf16x8 {
        int p = i * 256 + tid;
        int r = p >> 2, cq = p & 3;
        int gc = col0 + r;
        bf16x8 vw{};
        if (gc < N) vw = *reinterpret_cast<const bf16x8*>(W + (long)gc * Kpad + kk + cq * 8);
        return vw;
    };
    bf16x8 vaC0 = loadA(0, 0), vaC1 = loadA(0, 1);
    bf16x8 vwC0 = loadB(0, 0), vwC1 = loadB(0, 1);
    for (int k0 = 0; k0 < Kpad; k0 += 32){
        #pragma unroll
        for (int i = 0; i < 2; i++){
            int p = i * 256 + tid;
            int r = p >> 2, cq = p & 3;
            *reinterpret_cast<bf16x8*>(Ab + r * 80 + cq * 16) = i ? vaC1 : vaC0;
            *reinterpret_cast<bf16x8*>(Bb + r * 80 + cq * 16) = i ? vwC1 : vwC0;
        }
        __syncthreads();
        int kn = (k0 + 32 < Kpad) ? k0 + 32 : k0;
        bf16x8 vaN0 = loadA(kn, 0), vaN1 = loadA(kn, 1);
        bf16x8 vwN0 = loadB(kn, 0), vwN1 = loadB(kn, 1);
        bf16x8 af[4], bfr[4];
        #pragma unroll
        for (int m = 0; m < 4; m++)
            af[m] = *reinterpret_cast<const bf16x8*>(Ab + (wm * 64 + m * 16 + lo) * 80 + hi * 16);
        #pragma unroll
        for (int n = 0; n < 4; n++)
            bfr[n] = *reinterpret_cast<const bf16x8*>(Bb + (wn * 64 + n * 16 + lo) * 80 + hi * 16);
        #pragma unroll
        for (int m = 0; m < 4; m++)
            #pragma unroll
            for (int n = 0; n < 4; n++)
                acc[m][n] = __builtin_amdgcn_mfma_f32_16x16x32_bf16(af[m], bfr[n], acc[m][n], 0, 0, 0);
        __syncthreads();
        vaC0 = vaN0; vaC1 = vaN1; vwC0 = vwN0; vwC1 = vwN1;
    }
    float* Cf = (float*)Cv;
    __bf16* Cb = (__bf16*)Cv;
    #pragma unroll
    for (int m = 0; m < 4; m++){
        #pragma unroll
        for (int n = 0; n < 4; n++){
            int row = row0 + wm * 64 + m * 16 + hi * 4;
            int col = col0 + wn * 64 + n * 16 + lo;
            if (col >= N) continue;
            float scale = g[col] * rsqrtf(1.0f + 1e-5f);
            float bv = bb[col];
            #pragma unroll
            for (int j = 0; j < 4; j++){
                float v = acc[m][n][j] * scale + bv;
                if (GELU) v = gelu_f(v);
                if (POSOUT)
                    Cf[(long)(row + j) * 384 + col] = v + pos[((row + j) % 196) * 384 + col];
                else
                    Cb[(long)(row + j) * N + col] = (__bf16)v;
            }
        }
    }
}

// ---------------- LayerNorm over D=384, fp32 out ----------------
__global__ __launch_bounds__(128) void ln384(const float* __restrict__ x, long xstride,
                                             const float* __restrict__ w, const float* __restrict__ b,
                                             float* __restrict__ y, long ystride){
    long row = blockIdx.x;
    int tid = threadIdx.x;
    const float* xr = x + row * xstride;
    float v0 = xr[tid], v1 = xr[tid + 128], v2 = xr[tid + 256];
    float s = v0 + v1 + v2;
    float ss = v0 * v0 + v1 * v1 + v2 * v2;
    for (int off = 32; off; off >>= 1){ s += __shfl_down(s, off); ss += __shfl_down(ss, off); }
    __shared__ float rs[2], rss[2];
    if ((tid & 63) == 0){ rs[tid >> 6] = s; rss[tid >> 6] = ss; }
    __syncthreads();
    float S = rs[0] + rs[1], SS = rss[0] + rss[1];
    float m = S * (1.0f / 384.0f);
    float var = SS * (1.0f / 384.0f) - m * m;
    float r = rsqrtf(var + 1e-5f);
    float* yr = y + row * ystride;
    yr[tid]       = (v0 - m) * r * w[tid]       + b[tid];
    yr[tid + 128] = (v1 - m) * r * w[tid + 128] + b[tid + 128];
    yr[tid + 256] = (v2 - m) * r * w[tid + 256] + b[tid + 256];
}

// ---------------- LayerNorm, bf16 out (for initial LN1) ----------------
__global__ __launch_bounds__(128) void ln384_bf(const float* __restrict__ x,
                                                const float* __restrict__ w, const float* __restrict__ b,
                                                __bf16* __restrict__ y){
    long row = blockIdx.x;
    int tid = threadIdx.x;
    const float* xr = x + row * 384;
    float v0 = xr[tid], v1 = xr[tid + 128], v2 = xr[tid + 256];
    float s = v0 + v1 + v2;
    float ss = v0 * v0 + v1 * v1 + v2 * v2;
    for (int off = 32; off; off >>= 1){ s += __shfl_down(s, off); ss += __shfl_down(ss, off); }
    __shared__ float rs[2], rss[2];
    if ((tid & 63) == 0){ rs[tid >> 6] = s; rss[tid >> 6] = ss; }
    __syncthreads();
    float S = rs[0] + rs[1], SS = rss[0] + rss[1];
    float m = S * (1.0f / 384.0f);
    float var = SS * (1.0f / 384.0f) - m * m;
    float r = rsqrtf(var + 1e-5f);
    __bf16* yr = y + row * 384;
    yr[tid]       = (__bf16)((v0 - m) * r * w[tid]       + b[tid]);
    yr[tid + 128] = (__bf16)((v1 - m) * r * w[tid + 128] + b[tid + 128]);
    yr[tid + 256] = (__bf16)((v2 - m) * r * w[tid + 256] + b[tid + 256]);
}

// ---------------- t += g1*o2 ; ht = LN3(t) transposed ----------------
__global__ __launch_bounds__(128) void proj_res_lnt(const __bf16* __restrict__ o2,
                                                    const float* __restrict__ g1,
                                                    float* __restrict__ t,
                                                    const float* __restrict__ n3w, const float* __restrict__ n3b,
                                                    float* __restrict__ ht){
    long row = blockIdx.x;
    int tid = threadIdx.x;
    float v[3];
    #pragma unroll
    for (int i = 0; i < 3; i++){
        int c = tid + i * 128;
        long idx = row * 384 + c;
        v[i] = t[idx] + g1[c] * (float)o2[idx];
        t[idx] = v[i];
    }
    float s = v[0] + v[1] + v[2];
    float ss = v[0] * v[0] + v[1] * v[1] + v[2] * v[2];
    for (int off = 32; off; off >>= 1){ s += __shfl_down(s, off); ss += __shfl_down(ss, off); }
    __shared__ float rs[2], rss[2];
    if ((tid & 63) == 0){ rs[tid >> 6] = s; rss[tid >> 6] = ss; }
    __syncthreads();
    float S = rs[0] + rs[1], SS = rss[0] + rss[1];
    float m = S * (1.0f / 384.0f);
    float var = SS * (1.0f / 384.0f) - m * m;
    float r = rsqrtf(var + 1e-5f);
    int b = (int)(row / 196), n = (int)(row % 196);
    float* yb = ht + ((long)b * 384) * 196 + n;
    #pragma unroll
    for (int i = 0; i < 3; i++){
        int c = tid + i * 128;
        yb[(long)c * 196] = (v[i] - m) * r * n3w[c] + n3b[c];
    }
}

// ---------------- t += hadd ; h = LN2(t) bf16 ----------------
__global__ __launch_bounds__(128) void ln2res(float* __restrict__ t,
                                              const __bf16* __restrict__ hadd,
                                              const float* __restrict__ n2w, const float* __restrict__ n2b,
                                              __bf16* __restrict__ h){
    long row = blockIdx.x;
    int tid = threadIdx.x;
    float v[3];
    #pragma unroll
    for (int i = 0; i < 3; i++){
        int c = tid + i * 128;
        long idx = row * 384 + c;
        v[i] = t[idx] + (float)hadd[idx];
        t[idx] = v[i];
    }
    float s = v[0] + v[1] + v[2];
    float ss = v[0] * v[0] + v[1] * v[1] + v[2] * v[2];
    for (int off = 32; off; off >>= 1){ s += __shfl_down(s, off); ss += __shfl_down(ss, off); }
    __shared__ float rs[2], rss[2];
    if ((tid & 63) == 0){ rs[tid >> 6] = s; rss[tid >> 6] = ss; }
    __syncthreads();
    float S = rs[0] + rs[1], SS = rss[0] + rss[1];
    float m = S * (1.0f / 384.0f);
    float var = SS * (1.0f / 384.0f) - m * m;
    float r = rsqrtf(var + 1e-5f);
    __bf16* yr = h + row * 384;
    #pragma unroll
    for (int i = 0; i < 3; i++){
        int c = tid + i * 128;
        yr[c] = (__bf16)((v[i] - m) * r * n2w[c] + n2b[c]);
    }
}

// ---------------- t += g2*f2 ; h = LN1next(t) bf16 ----------------
__global__ __launch_bounds__(128) void fc2_res_ln(const __bf16* __restrict__ f2,
                                                  const float* __restrict__ g2,
                                                  float* __restrict__ t,
                                                  const float* __restrict__ n1w, const float* __restrict__ n1b,
                                                  __bf16* __restrict__ h){
    long row = blockIdx.x;
    int tid = threadIdx.x;
    float v[3];
    #pragma unroll
    for (int i = 0; i < 3; i++){
        int c = tid + i * 128;
        long idx = row * 384 + c;
        v[i] = t[idx] + g2[c] * (float)f2[idx];
        t[idx] = v[i];
    }
    float s = v[0] + v[1] + v[2];
    float ss = v[0] * v[0] + v[1] * v[1] + v[2] * v[2];
    for (int off = 32; off; off >>= 1){ s += __shfl_down(s, off); ss += __shfl_down(ss, off); }
    __shared__ float rs[2], rss[2];
    if ((tid & 63) == 0){ rs[tid >> 6] = s; rss[tid >> 6] = ss; }
    __syncthreads();
    float S = rs[0] + rs[1], SS = rss[0] + rss[1];
    float m = S * (1.0f / 384.0f);
    float var = SS * (1.0f / 384.0f) - m * m;
    float r = rsqrtf(var + 1e-5f);
    __bf16* yr = h + row * 384;
    #pragma unroll
    for (int i = 0; i < 3; i++){
        int c = tid + i * 128;
        yr[c] = (__bf16)((v[i] - m) * r * n1w[c] + n1b[c]);
    }
}

// ---------------- bf16 MFMA GEMM, 64x128 tile, 4 waves, 2-stage prefetch ----------------
template<int MODE, int OUTBF, int ACVT, int GUARD, int SPLITK, int NGUARD>
__global__ __launch_bounds__(256) void gemm_bb2(const void* __restrict__ Av, long lda,
                                                const __bf16* __restrict__ W, int Kw,
                                                const float* __restrict__ bias,
                                                void* __restrict__ Cv, long ldc,
                                                int K, int M, int Ncols){
    __shared__ __align__(16) char smem[15360];
    char* Ab = smem;
    char* Bb = smem + 5120;
    const int tid = threadIdx.x;
    const int lane = tid & 63;
    const int wn = tid >> 6;
    const int row0 = blockIdx.x * 64;
    const int col0 = blockIdx.y * 128;
    const int hi = lane >> 4, lo = lane & 15;
    const int kbase = SPLITK ? blockIdx.z * K : 0;
    const __bf16* Abf = (const __bf16*)Av;
    const float* Af = (const float*)Av;
    const int r_a = tid >> 2, cq_a = tid & 3;
    f32x4 acc[4][2] = {};
    auto loadA = [&](int kk)->bf16x8 {
        bf16x8 va{};
        int grow = row0 + r_a;
        if (!GUARD || grow < M){
            long ai = (long)grow * lda + kk + cq_a * 8;
            if (ACVT){
                float4 a0 = *reinterpret_cast<const float4*>(Af + ai);
                float4 a1 = *reinterpret_cast<const float4*>(Af + ai + 4);
                va[0] = (__bf16)a0.x; va[1] = (__bf16)a0.y; va[2] = (__bf16)a0.z; va[3] = (__bf16)a0.w;
                va[4] = (__bf16)a1.x; va[5] = (__bf16)a1.y; va[6] = (__bf16)a1.z; va[7] = (__bf16)a1.w;
            } else {
                va = *reinterpret_cast<const bf16x8*>(Abf + ai);
            }
        }
        return va;
    };
    auto loadB = [&](int kk, int i)->bf16x8 {
        int p = i * 256 + tid;
        int r = p >> 2, cq = p & 3;
        return *reinterpret_cast<const bf16x8*>(W + (long)(col0 + r) * Kw + kk + cq * 8);
    };
    bf16x8 vaC = loadA(kbase);
    bf16x8 vwC0 = loadB(kbase, 0), vwC1 = loadB(kbase, 1);
    for (int k0 = 0; k0 < K; k0 += 32){
        *reinterpret_cast<bf16x8*>(Ab + r_a * 80 + cq_a * 16) = vaC;
        #pragma unroll
        for (int i = 0; i < 2; i++){
            int p = i * 256 + tid;
            int r = p >> 2, cq = p & 3;
            *reinterpret_cast<bf16x8*>(Bb + r * 80 + cq * 16) = i ? vwC1 : vwC0;
        }
        __syncthreads();
        int kn = kbase + ((k0 + 32 < K) ? k0 + 32 : k0);
        bf16x8 vaN = loadA(kn);
        bf16x8 vwN0 = loadB(kn, 0), vwN1 = loadB(kn, 1);
        bf16x8 af[4], bfr[2];
        #pragma unroll
        for (int m = 0; m < 4; m++)
            af[m] = *reinterpret_cast<const bf16x8*>(Ab + (m * 16 + lo) * 80 + hi * 16);
        #pragma unroll
        for (int n = 0; n < 2; n++)
            bfr[n] = *reinterpret_cast<const bf16x8*>(Bb + (wn * 32 + n * 16 + lo) * 80 + hi * 16);
        #pragma unroll
        for (int m = 0; m < 4; m++)
            #pragma unroll
            for (int n = 0; n < 2; n++)
                acc[m][n] = __builtin_amdgcn_mfma_f32_16x16x32_bf16(af[m], bfr[n], acc[m][n], 0, 0, 0);
        __syncthreads();
        vaC = vaN; vwC0 = vwN0; vwC1 = vwN1;
    }
    float* Cf = (float*)Cv;
    __bf16* Cb = (__bf16*)Cv;
    if (SPLITK) Cf += (long)blockIdx.z * M * ldc;
    #pragma unroll
    for (int m = 0; m < 4; m++){
        #pragma unroll
        for (int n = 0; n < 2; n++){
            int row = row0 + m * 16 + hi * 4;
            int col = col0 + wn * 32 + n * 16 + lo;
            if (NGUARD && col >= Ncols) continue;
            float bv = (MODE == 3) ? 0.f : bias[col];
            #pragma unroll
            for (int j = 0; j < 4; j++){
                if (GUARD && (row + j) >= M) continue;
                float v = acc[m][n][j] + bv;
                if (MODE == 1) v = gelu_f(v);
                long ci = (long)(row + j) * ldc + col;
                if (OUTBF) Cb[ci] = (__bf16)v;
                else Cf[ci] = v;
            }
        }
    }
}

// ---------------- bf16 MFMA GEMM, 64x64 tile, 4 waves, 2-stage prefetch, bf16 out ----------------
// C[M,N] = A @ W^T + bias (bf16 out). M%64==0, N%64==0, K%32==0.
__global__ __launch_bounds__(256) void gemm_bb3(const __bf16* __restrict__ A, long lda,
                                                const __bf16* __restrict__ W, int Kw,
                                                const float* __restrict__ bias,
                                                __bf16* __restrict__ C, long ldc,
                                                int K){
    __shared__ __align__(16) char smem[10240];
    char* Ab = smem;            // 64 rows x 80B
    char* Bb = smem + 5120;     // 64 rows x 80B
    const int tid = threadIdx.x;
    const int lane = tid & 63;
    const int wn = tid >> 6;
    const int row0 = blockIdx.x * 64;
    const int col0 = blockIdx.y * 64;
    const int hi = lane >> 4, lo = lane & 15;
    const int r_s = tid >> 2, cq_s = tid & 3;
    f32x4 acc[4] = {};
    auto loadA = [&](int kk)->bf16x8 {
        return *reinterpret_cast<const bf16x8*>(A + (long)(row0 + r_s) * lda + kk + cq_s * 8);
    };
    auto loadB = [&](int kk)->bf16x8 {
        return *reinterpret_cast<const bf16x8*>(W + (long)(col0 + r_s) * Kw + kk + cq_s * 8);
    };
    bf16x8 vaC = loadA(0);
    bf16x8 vwC = loadB(0);
    for (int k0 = 0; k0 < K; k0 += 32){
        *reinterpret_cast<bf16x8*>(Ab + r_s * 80 + cq_s * 16) = vaC;
        *reinterpret_cast<bf16x8*>(Bb + r_s * 80 + cq_s * 16) = vwC;
        __syncthreads();
        int kn = (k0 + 32 < K) ? k0 + 32 : k0;
        bf16x8 vaN = loadA(kn);
        bf16x8 vwN = loadB(kn);
        bf16x8 af[4], bfr;
        #pragma unroll
        for (int m = 0; m < 4; m++)
            af[m] = *reinterpret_cast<const bf16x8*>(Ab + (m * 16 + lo) * 80 + hi * 16);
        bfr = *reinterpret_cast<const bf16x8*>(Bb + (wn * 16 + lo) * 80 + hi * 16);
        #pragma unroll
        for (int m = 0; m < 4; m++)
            acc[m] = __builtin_amdgcn_mfma_f32_16x16x32_bf16(af[m], bfr, acc[m], 0, 0, 0);
        __syncthreads();
        vaC = vaN; vwC = vwN;
    }
    #pragma unroll
    for (int m = 0; m < 4; m++){
        int row = row0 + m * 16 + hi * 4;
        int col = col0 + wn * 16 + lo;
        float bv = bias[col];
        #pragma unroll
        for (int j = 0; j < 4; j++)
            C[(long)(row + j) * ldc + col] = (__bf16)(acc[m][j] + bv);
    }
}

// ---------------- positional embedding: pos[n, d] ----------------
__global__ __launch_bounds__(384) void pos_embed(const float* __restrict__ pw, const float* __restrict__ pb,
                                                 float* __restrict__ pos){
    __shared__ float p64[64];
    int n = blockIdx.x;
    int iy = n / 14, ix = n % 14;
    int t = threadIdx.x;
    if (t < 64){
        int axis = t >> 5;
        int c = t & 31;
        int u = c >> 1;
        float coord = (axis == 0) ? (float)(iy + 1) : (float)(ix + 1);
        float val = coord / ((14.0f + 1e-6f) * 6.283185307179586f);
        float T = powf(10000.0f, (float)u / 16.0f);
        float a = val / T;
        p64[t] = (c & 1) ? cosf(a) : sinf(a);
    }
    __syncthreads();
    float acc = 0.f;
    const float* wr = pw + (long)t * 64;
    #pragma unroll 8
    for (int c = 0; c < 64; c++) acc += p64[c] * wr[c];
    pos[n * 384 + t] = acc + pb[t];
}

// ---------------- XCA attention via MFMA: one block per (b, head) ----------------
__global__ __launch_bounds__(256) void xca2(const __bf16* __restrict__ qkv, const float* __restrict__ temp,
                                            __bf16* __restrict__ o){
    __shared__ __align__(16) char smem[74880];
    __bf16* qs = (__bf16*)smem;
    __bf16* ks = (__bf16*)(smem + 22272);
    __bf16* vt = (__bf16*)(smem + 44544);
    float* inq = (float*)(smem + 74496);
    float* ink = (float*)(smem + 74688);
    float* att = (float*)smem;                  // overlay on qs
    __bf16* abf = (__bf16*)(smem + 22272);      // overlay on ks
    int bh = blockIdx.x;
    int b = bh >> 3, h = bh & 7;
    const int tid = threadIdx.x;
    const int wid = tid >> 6, lane = tid & 63;
    const int hi = lane >> 4, lo = lane & 15;
    const __bf16* base = qkv + ((long)b * 196) * 1152 + h * 48;
    bf16x8 z8 = {};
    for (int idx = tid; idx < 48 * 28; idx += 256){
        int d = idx / 28, n = 196 + idx % 28;
        qs[d * 232 + n] = (__bf16)0.f;
        ks[d * 232 + n] = (__bf16)0.f;
    }
    for (int idx = tid; idx < 208 * 2; idx += 256){
        int n = idx >> 1, c = 48 + (idx & 1) * 8;
        *reinterpret_cast<bf16x8*>(vt + n * 72 + c) = z8;
    }
    for (int ch = tid; ch < 196 * 6; ch += 256){
        int n = ch / 6, c = ch % 6, d0 = c * 8;
        bf16x8 q8 = *reinterpret_cast<const bf16x8*>(base + (long)n * 1152 + d0);
        bf16x8 k8 = *reinterpret_cast<const bf16x8*>(base + (long)n * 1152 + 384 + d0);
        #pragma unroll
        for (int j = 0; j < 8; j++){
            qs[(d0 + j) * 232 + n] = q8[j];
            ks[(d0 + j) * 232 + n] = k8[j];
        }
        bf16x8 v8 = *reinterpret_cast<const bf16x8*>(base + (long)n * 1152 + 768 + d0);
        *reinterpret_cast<bf16x8*>(vt + n * 72 + d0) = v8;
    }
    __syncthreads();
    for (int r = wid; r < 48; r += 4){
        float sq = 0.f, sk = 0.f;
        for (int n = lane; n < 196; n += 64){
            float qv = (float)qs[r * 232 + n];
            float kv = (float)ks[r * 232 + n];
            sq += qv * qv; sk += kv * kv;
        }
        for (int off = 32; off; off >>= 1){ sq += __shfl_down(sq, off); sk += __shfl_down(sk, off); }
        if (lane == 0){
            inq[r] = 1.0f / fmaxf(sqrtf(sq), 1e-12f);
            ink[r] = 1.0f / fmaxf(sqrtf(sk), 1e-12f);
        }
    }
    __syncthreads();
    float tempv = temp[h];
    f32x4 qk0 = {}, qk1 = {}, qk2 = {};
    __builtin_amdgcn_s_setprio(1);
    {
        int mi = wid / 3, ni = wid % 3;
        #pragma unroll
        for (int k0 = 0; k0 < 224; k0 += 32){
            bf16x8 af = *reinterpret_cast<const bf16x8*>(qs + (mi * 16 + lo) * 232 + k0 + hi * 8);
            bf16x8 bf = *reinterpret_cast<const bf16x8*>(ks + (ni * 16 + lo) * 232 + k0 + hi * 8);
            qk0 = __builtin_amdgcn_mfma_f32_16x16x32_bf16(af, bf, qk0, 0, 0, 0);
        }
    }
    {
        int tt = wid + 4;
        int mi = tt / 3, ni = tt % 3;
        #pragma unroll
        for (int k0 = 0; k0 < 224; k0 += 32){
            bf16x8 af = *reinterpret_cast<const bf16x8*>(qs + (mi * 16 + lo) * 232 + k0 + hi * 8);
            bf16x8 bf = *reinterpret_cast<const bf16x8*>(ks + (ni * 16 + lo) * 232 + k0 + hi * 8);
            qk1 = __builtin_amdgcn_mfma_f32_16x16x32_bf16(af, bf, qk1, 0, 0, 0);
        }
    }
    if (wid == 0){
        #pragma unroll
        for (int k0 = 0; k0 < 224; k0 += 32){
            bf16x8 af = *reinterpret_cast<const bf16x8*>(qs + (2 * 16 + lo) * 232 + k0 + hi * 8);
            bf16x8 bf = *reinterpret_cast<const bf16x8*>(ks + (2 * 16 + lo) * 232 + k0 + hi * 8);
            qk2 = __builtin_amdgcn_mfma_f32_16x16x32_bf16(af, bf, qk2, 0, 0, 0);
        }
    }
    __builtin_amdgcn_s_setprio(0);
    __syncthreads();
    {
        int mi = wid / 3, ni = wid % 3;
        int e = ni * 16 + lo;
        float se = ink[e] * tempv;
        #pragma unroll
        for (int j = 0; j < 4; j++){
            int d = mi * 16 + hi * 4 + j;
            att[d * 68 + e] = qk0[j] * inq[d] * se;
        }
    }
    {
        int tt = wid + 4;
        int mi = tt / 3, ni = tt % 3;
        int e = ni * 16 + lo;
        float se = ink[e] * tempv;
        #pragma unroll
        for (int j = 0; j < 4; j++){
            int d = mi * 16 + hi * 4 + j;
            att[d * 68 + e] = qk1[j] * inq[d] * se;
        }
    }
    if (wid == 0){
        int e = 2 * 16 + lo;
        float se = ink[e] * tempv;
        #pragma unroll
        for (int j = 0; j < 4; j++){
            int d = 2 * 16 + hi * 4 + j;
            att[d * 68 + e] = qk2[j] * inq[d] * se;
        }
    }
    __syncthreads();
    if (tid < 192){
        int r = tid >> 2, q4 = tid & 3;
        const float* row = att + r * 68 + q4 * 12;
        float mx = -1e30f;
        #pragma unroll
        for (int i = 0; i < 12; i++) mx = fmaxf(mx, row[i]);
        mx = fmaxf(mx, __shfl_xor(mx, 1));
        mx = fmaxf(mx, __shfl_xor(mx, 2));
        float pv[12]; float sm = 0.f;
        #pragma unroll
        for (int i = 0; i < 12; i++){ pv[i] = expf(row[i] - mx); sm += pv[i]; }
        sm += __shfl_xor(sm, 1);
        sm += __shfl_xor(sm, 2);
        float inv = 1.0f / sm;
        #pragma unroll
        for (int i = 0; i < 12; i++) abf[r * 72 + q4 * 12 + i] = (__bf16)(pv[i] * inv);
    }
    for (int idx = tid; idx < 48 * 3; idx += 256){
        int r = idx / 3, c = 48 + (idx % 3) * 8;
        *reinterpret_cast<bf16x8*>(abf + r * 72 + c) = z8;
    }
    __syncthreads();
    __bf16* ob = o + ((long)b * 196) * 384 + h * 48;
    __builtin_amdgcn_s_setprio(1);
    for (int tt = wid; tt < 39; tt += 4){
        int mi = tt / 13, ni = tt % 13;
        f32x4 acc = {};
        #pragma unroll
        for (int e0 = 0; e0 < 64; e0 += 32){
            bf16x8 af = *reinterpret_cast<const bf16x8*>(abf + (mi * 16 + lo) * 72 + e0 + hi * 8);
            bf16x8 bf = *reinterpret_cast<const bf16x8*>(vt + (ni * 16 + lo) * 72 + e0 + hi * 8);
            acc = __builtin_amdgcn_mfma_f32_16x16x32_bf16(af, bf, acc, 0, 0, 0);
        }
        int n = ni * 16 + lo;
        if (n < 196){
            #pragma unroll
            for (int j = 0; j < 4; j++){
                int d = mi * 16 + hi * 4 + j;
                ob[(long)n * 384 + d] = (__bf16)acc[j];
            }
        }
    }
    __builtin_amdgcn_s_setprio(0);
}

// ---------------- LPI: gated output to hadd (bf16, [b,n,d]), no t RMW ----------------
__global__ __launch_bounds__(256) void lpi_g(const float* __restrict__ ht,
                                             const float* __restrict__ w1, const float* __restrict__ b1,
                                             const float* __restrict__ bng, const float* __restrict__ bnb,
                                             const float* __restrict__ w2, const float* __restrict__ b2,
                                             const float* __restrict__ g3, __bf16* __restrict__ hadd){
    int bd = blockIdx.x;
    int d = bd % 384, b = bd / 384;
    __shared__ float p[16][16];
    __shared__ float p2[16][16];
    __shared__ float wA[9], wB[9];
    int tt = threadIdx.x;
    int yy = tt / 16, xx = tt % 16;
    p[yy][xx] = 0.f; p2[yy][xx] = 0.f;
    if (tt < 9){ wA[tt] = w1[d * 9 + tt]; wB[tt] = w2[d * 9 + tt]; }
    __syncthreads();
    if (tt < 196){
        int y = tt / 14, x = tt % 14;
        p[y + 1][x + 1] = ht[((long)b * 384 + d) * 196 + tt];
    }
    __syncthreads();
    if (tt < 196){
        int y = tt / 14, x = tt % 14;
        float a = 0.f;
        #pragma unroll
        for (int ky = 0; ky < 3; ky++)
            #pragma unroll
            for (int kx = 0; kx < 3; kx++)
                a += wA[ky * 3 + kx] * p[y + ky][x + kx];
        a += b1[d];
        a = gelu_f(a);
        a = a * (bng[d] * rsqrtf(1.0f + 1e-5f)) + bnb[d];
        p2[y + 1][x + 1] = a;
    }
    __syncthreads();
    if (tt < 196){
        int y = tt / 14, x = tt % 14;
        float a = 0.f;
        #pragma unroll
        for (int ky = 0; ky < 3; ky++)
            #pragma unroll
            for (int kx = 0; kx < 3; kx++)
                a += wB[ky * 3 + kx] * p2[y + ky][x + kx];
        a += b2[d];
        hadd[((long)b * 196 + tt) * 384 + d] = (__bf16)(g3[d] * a);
    }
}

// ---------------- cls concat ----------------
__global__ __launch_bounds__(256) void concat_cls(const float* __restrict__ t, const float* __restrict__ clstok,
                                                  float* __restrict__ tc){
    long i = (long)blockIdx.x * 256 + threadIdx.x;
    if (i >= (long)B_ * 197 * 384) return;
    int d = (int)(i % 384);
    long bn = i / 384;
    int n = (int)(bn % 197);
    int b = (int)(bn / 197);
    tc[i] = (n == 0) ? clstok[d] : t[((long)b * 196 + (n - 1)) * 384 + d];
}

// ---------------- CA attention (bf16 qkv) ----------------
__global__ __launch_bounds__(256) void ca_attn(const __bf16* __restrict__ qkv, float* __restrict__ clsp){
    int bh = blockIdx.x;
    int b = bh >> 3, h = bh & 7;
    const __bf16* base = qkv + (long)b * 197 * 1152 + h * 48;
    __shared__ float q0[48];
    __shared__ float at2[197];
    __shared__ float smax, ssum;
    int tid = threadIdx.x;
    if (tid < 48) q0[tid] = (float)base[tid];
    __syncthreads();
    if (tid < 197){
        const __bf16* kr = base + (long)tid * 1152 + 384;
        float s = 0.f;
        for (int d = 0; d < 48; d++) s += q0[d] * (float)kr[d];
        at2[tid] = s * rsqrtf(48.0f);
    }
    __syncthreads();
    if (tid == 0){
        float m = -1e30f;
        for (int n = 0; n < 197; n++) m = fmaxf(m, at2[n]);
        smax = m;
    }
    __syncthreads();
    if (tid < 197) at2[tid] = expf(at2[tid] - smax);
    __syncthreads();
    if (tid == 0){
        float s = 0.f;
        for (int n = 0; n < 197; n++) s += at2[n];
        ssum = s;
    }
    __syncthreads();
    if (tid < 48){
        const __bf16* vb = base + 768 + tid;
        float s = 0.f;
        for (int n = 0; n < 197; n++) s += at2[n] * (float)vb[(long)n * 1152];
        clsp[b * 384 + h * 48 + tid] = s / ssum;
    }
}

__global__ __launch_bounds__(256) void ca_update1(const float* __restrict__ clso, const float* __restrict__ hc,
                                                  const float* __restrict__ g1, float* __restrict__ tc){
    long i = (long)blockIdx.x * 256 + threadIdx.x;
    if (i >= (long)B_ * 197 * 384) return;
    int d = (int)(i % 384);
    long bn = i / 384;
    int n = (int)(bn % 197);
    int b = (int)(bn / 197);
    float add = (n == 0) ? clso[b * 384 + d] : hc[i];
    tc[i] += g1[d] * add;
}

__global__ __launch_bounds__(256) void ca_update2(const float* __restrict__ cls2, const float* __restrict__ hc,
                                                  const float* __restrict__ g2, float* __restrict__ tc){
    long i = (long)blockIdx.x * 256 + threadIdx.x;
    if (i >= (long)B_ * 197 * 384) return;
    int d = (int)(i % 384);
    long bn = i / 384;
    int n = (int)(bn % 197);
    int b = (int)(bn / 197);
    float hv = hc[i];
    tc[i] = (n == 0) ? (g2[d] * cls2[b * 384 + d] + hv) : (hv + hv);
}

extern "C" void kernel_launch(void* const* d_in, const int* in_sizes, int n_in,
                              void* d_out, int out_size, void* d_ws, size_t ws_size,
                              hipStream_t stream){
    (void)in_sizes; (void)n_in; (void)out_size; (void)ws_size;
    const float* x      = (const float*)d_in[0];
    const float* clstok = (const float*)d_in[1];
    const float* pos_w  = (const float*)d_in[2];
    const float* pos_b  = (const float*)d_in[3];
    const float* pe_w[4] = {(const float*)d_in[4], (const float*)d_in[7], (const float*)d_in[10], (const float*)d_in[13]};
    const float* pe_g[4] = {(const float*)d_in[5], (const float*)d_in[8], (const float*)d_in[11], (const float*)d_in[14]};
    const float* pe_b[4] = {(const float*)d_in[6], (const float*)d_in[9], (const float*)d_in[12], (const float*)d_in[15]};
    const float* xqkv_w = (const float*)d_in[16];
    const float* xqkv_b = (const float*)d_in[17];
    const float* xproj_w = (const float*)d_in[18];
    const float* xproj_b = (const float*)d_in[19];
    const float* xtemp  = (const float*)d_in[20];
    const float* xn1_w = (const float*)d_in[21];
    const float* xn1_b = (const float*)d_in[22];
    const float* xn2_w = (const float*)d_in[23];
    const float* xn2_b = (const float*)d_in[24];
    const float* xn3_w = (const float*)d_in[25];
    const float* xn3_b = (const float*)d_in[26];
    const float* xfc1_w = (const float*)d_in[27];
    const float* xfc1_b = (const float*)d_in[28];
    const float* xfc2_w = (const float*)d_in[29];
    const float* xfc2_b = (const float*)d_in[30];
    const float* xlpi1_w = (const float*)d_in[31];
    const float* xlpi1_b = (const float*)d_in[32];
    const float* xlpi2_w = (const float*)d_in[33];
    const float* xlpi2_b = (const float*)d_in[34];
    const float* xbn_g = (const float*)d_in[35];
    const float* xbn_b = (const float*)d_in[36];
    const float* xg1 = (const float*)d_in[37];
    const float* xg2 = (const float*)d_in[38];
    const float* xg3 = (const float*)d_in[39];
    const float* cqkv_w = (const float*)d_in[40];
    const float* cqkv_b = (const float*)d_in[41];
    const float* cproj_w = (const float*)d_in[42];
    const float* cproj_b = (const float*)d_in[43];
    const float* cn1_w = (const float*)d_in[44];
    const float* cn1_b = (const float*)d_in[45];
    const float* cn2_w = (const float*)d_in[46];
    const float* cn2_b = (const float*)d_in[47];
    const float* cfc1_w = (const float*)d_in[48];
    const float* cfc1_b = (const float*)d_in[49];
    const float* cfc2_w = (const float*)d_in[50];
    const float* cfc2_b = (const float*)d_in[51];
    const float* cg1 = (const float*)d_in[52];
    const float* cg2 = (const float*)d_in[53];
    const float* norm_w = (const float*)d_in[54];
    const float* norm_b = (const float*)d_in[55];
    const float* head_w = (const float*)d_in[56];
    const float* head_b = (const float*)d_in[57];
    float* outp = (float*)d_out;

    float* ws = (float*)d_ws;
    // ---- conv phase buffers ----
    __bf16* A1   = (__bf16*)(ws);
    __bf16* A2   = (__bf16*)(ws);
    __bf16* A3   = (__bf16*)(ws);
    __bf16* A4   = (__bf16*)(ws);
    __bf16* out1 = (__bf16*)(ws + 22500000L);
    __bf16* out2 = (__bf16*)(ws + 22500000L);
    __bf16* out3 = (__bf16*)(ws + 27400000L);
    __bf16* wcv  = (__bf16*)(ws + 36000000L);
    __bf16* W1c = wcv;
    __bf16* W2c = wcv + 1536;
    __bf16* W3c = wcv + 44544;
    __bf16* W4c = wcv + 216576;
    // ---- XCA phase ----
    __bf16* wqkv_bf = (__bf16*)(ws);
    __bf16* wproj_bf = (__bf16*)(ws + 5308416L);
    __bf16* wfc1_bf = (__bf16*)(ws + 7077888L);
    __bf16* wfc2_bf = (__bf16*)(ws + 14155776L);
    float*  t       = ws + 21233664L;
    float*  pos     = ws + 23642112L;
    __bf16* h_bf    = (__bf16*)(ws + 23717376L);
    __bf16* qkv_bf  = (__bf16*)(ws + 24921600L);
    __bf16* o_bf    = (__bf16*)(ws + 28534272L);
    float*  ht      = ws + 29738496L;
    __bf16* f1_bf   = (__bf16*)(ws + 32146944L);    // 4,816,896 fl span
    // aliases (time-disjoint within a layer):
    __bf16* o2_bf   = (__bf16*)(ws + 34555392L);    // upper half of f1 span (f1 dead during proj)
    __bf16* f2_bf   = (__bf16*)(ws + 24921600L);    // aliases qkv_bf (dead after xca2)
    __bf16* hadd_bf = (__bf16*)(ws + 28534272L);    // aliases o_bf (dead after proj)
    // ---- CA phase ----
    float* tc   = ws;
    float* hc   = ws + 2420736L;
    __bf16* qkvc_bf = (__bf16*)(ws + 4841472L);
    float* clsp = ws + 8472576L;
    float* clso = clsp + 12288;
    float* f1c  = clso + 12288;
    float* cls2 = f1c + 49152;
    float* clsf = cls2 + 12288;
    __bf16* cqkv_bf  = (__bf16*)(ws + 9000000L);
    __bf16* cproj_bf = (__bf16*)(ws + 9500000L);
    __bf16* cfc1_bf  = (__bf16*)(ws + 9800000L);
    __bf16* cfc2_bf  = (__bf16*)(ws + 10400000L);
    __bf16* headw_bf = (__bf16*)(ws + 11000000L);

    // ---- conv weight prep ----
    wprep<<<(48 * 32 + 255) / 256, 256, 0, stream>>>(pe_w[0], W1c, 48, 3, 32);
    wprep<<<(96 * 448 + 255) / 256, 256, 0, stream>>>(pe_w[1], W2c, 96, 48, 448);
    wprep<<<(192 * 896 + 255) / 256, 256, 0, stream>>>(pe_w[2], W3c, 192, 96, 896);
    wprep<<<(384 * 1728 + 255) / 256, 256, 0, stream>>>(pe_w[3], W4c, 384, 192, 1728);

    // ---- patch embed: im2col + MFMA GEMM ----
    im2col_x<<<1568, 256, 0, stream>>>(x, A1);
    { dim3 g(3136, 1); gemm_conv<1, 0><<<g, 256, 0, stream>>>(A1, 32, W1c, pe_g[0], pe_b[0], out1, 48, nullptr); }
    im2col_bf<<<(100352 * 9 + 255) / 256, 256, 0, stream>>>(out1, A2, 48, 112, 112, 56, 56, 448, 100352 * 9);
    { dim3 g(784, 1); gemm_conv<1, 0><<<g, 256, 0, stream>>>(A2, 448, W2c, pe_g[1], pe_b[1], out2, 96, nullptr); }
    im2col_bf<<<(25088 * 9 + 255) / 256, 256, 0, stream>>>(out2, A3, 96, 56, 56, 28, 28, 896, 25088 * 9);
    pos_embed<<<196, 384, 0, stream>>>(pos_w, pos_b, pos);
    { dim3 g(196, 2); gemm_conv<1, 0><<<g, 256, 0, stream>>>(A3, 896, W3c, pe_g[2], pe_b[2], out3, 192, nullptr); }
    im2col_bf<<<(6272 * 9 + 255) / 256, 256, 0, stream>>>(out3, A4, 192, 28, 28, 14, 14, 1728, 6272 * 9);
    { dim3 g(49, 3); gemm_conv<0, 1><<<g, 256, 0, stream>>>(A4, 1728, W4c, pe_g[3], pe_b[3], t, 384, pos); }

    // ---- convert XCA weights to bf16 ----
    {
        long n1 = (long)L_ * 1152 * 384;
        long n2 = (long)L_ * 384 * 384;
        long n3 = (long)L_ * 1536 * 384;
        cvt_bf<<<(int)((n1 + 2047) / 2048), 256, 0, stream>>>(xqkv_w, wqkv_bf, n1);
        cvt_bf<<<(int)((n2 + 2047) / 2048), 256, 0, stream>>>(xproj_w, wproj_bf, n2);
        cvt_bf<<<(int)((n3 + 2047) / 2048), 256, 0, stream>>>(xfc1_w, wfc1_bf, n3);
        cvt_bf<<<(int)((n3 + 2047) / 2048), 256, 0, stream>>>(xfc2_w, wfc2_bf, n3);
    }

    // ---- 24 XCA layers ----
    const int M = B_ * N_;  // 6272 = 98*64
    ln384_bf<<<M, 128, 0, stream>>>(t, xn1_w, xn1_b, h_bf);   // initial LN1
    for (int l = 0; l < L_; l++){
        {
            dim3 g(98, 9);
            gemm_bb2<0, 1, 0, 0, 0, 0><<<g, 256, 0, stream>>>(h_bf, 384, wqkv_bf + (long)l * 1152 * 384, 384,
                                                              xqkv_b + l * 1152, qkv_bf, 1152, 384, M, 0);
        }
        xca2<<<B_ * NH_, 256, 0, stream>>>(qkv_bf, xtemp + l * 8, o_bf);
        {   // proj: 64x64 tiles, bf16 out (incl bias)
            dim3 g(98, 6);
            gemm_bb3<<<g, 256, 0, stream>>>(o_bf, 384, wproj_bf + (long)l * 384 * 384, 384,
                                            xproj_b + l * 384, o2_bf, 384, 384);
        }
        proj_res_lnt<<<M, 128, 0, stream>>>(o2_bf, xg1 + l * 384, t,
                                            xn3_w + l * 384, xn3_b + l * 384, ht);
        lpi_g<<<B_ * D_, 256, 0, stream>>>(ht, xlpi1_w + (long)l * 384 * 9, xlpi1_b + l * 384,
                                           xbn_g + l * 384, xbn_b + l * 384,
                                           xlpi2_w + (long)l * 384 * 9, xlpi2_b + l * 384,
                                           xg3 + l * 384, hadd_bf);
        ln2res<<<M, 128, 0, stream>>>(t, hadd_bf, xn2_w + l * 384, xn2_b + l * 384, h_bf);
        {
            dim3 g(98, 12);
            gemm_bb2<1, 1, 0, 0, 0, 0><<<g, 256, 0, stream>>>(h_bf, 384, wfc1_bf + (long)l * 1536 * 384, 384,
                                                              xfc1_b + l * 1536, f1_bf, 1536, 384, M, 0);
        }
        {   // fc2: 64x64 tiles, bf16 out (incl bias)
            dim3 g(98, 6);
            gemm_bb3<<<g, 256, 0, stream>>>(f1_bf, 1536, wfc2_bf + (long)l * 1536 * 384, 1536,
                                            xfc2_b + l * 384, f2_bf, 384, 1536);
        }
        int ln = (l + 1) % L_;
        fc2_res_ln<<<M, 128, 0, stream>>>(f2_bf, xg2 + l * 384, t,
                                          xn1_w + ln * 384, xn1_b + ln * 384, h_bf);
    }

    // ---- cls concat + 2 CA blocks ----
    const long NC = (long)B_ * 197 * 384;
    concat_cls<<<(int)(NC / 256), 256, 0, stream>>>(t, clstok, tc);
    {
        long nc = (long)2 * 1152 * 384;
        cvt_bf<<<(int)((nc + 2047) / 2048), 256, 0, stream>>>(cqkv_w, cqkv_bf, nc);
        long np = (long)2 * 384 * 384;
        cvt_bf<<<(int)((np + 2047) / 2048), 256, 0, stream>>>(cproj_w, cproj_bf, np);
        long nf = (long)2 * 1536 * 384;
        cvt_bf<<<(int)((nf + 2047) / 2048), 256, 0, stream>>>(cfc1_w, cfc1_bf, nf);
        cvt_bf<<<(int)((nf + 2047) / 2048), 256, 0, stream>>>(cfc2_w, cfc2_bf, nf);
        cvt_pad<<<(1024 * 384 + 255) / 256, 256, 0, stream>>>(head_w, headw_bf, 1000, 384, 1024);
    }
    const int MC = B_ * 197;  // 6304
    for (int i = 0; i < 2; i++){
        ln384<<<MC, 128, 0, stream>>>(tc, 384, cn1_w + i * 384, cn1_b + i * 384, hc, 384);
        {
            dim3 g(99, 9);
            gemm_bb2<0, 1, 1, 1, 0, 0><<<g, 256, 0, stream>>>(hc, 384, cqkv_bf + (long)i * 1152 * 384, 384,
                                                              cqkv_b + i * 1152, qkvc_bf, 1152, 384, MC, 0);
        }
        ca_attn<<<B_ * NH_, 256, 0, stream>>>(qkvc_bf, clsp);
        {
            dim3 g(1, 3);
            gemm_bb2<0, 0, 1, 1, 0, 0><<<g, 256, 0, stream>>>(clsp, 384, cproj_bf + (long)i * 384 * 384, 384,
                                                              cproj_b + i * 384, clso, 384, 384, 32, 0);
        }
        ca_update1<<<(int)(NC / 256), 256, 0, stream>>>(clso, hc, cg1 + i * 384, tc);
        ln384<<<MC, 128, 0, stream>>>(tc, 384, cn2_w + i * 384, cn2_b + i * 384, hc, 384);
        {
            dim3 g(1, 12);
            gemm_bb2<1, 0, 1, 1, 0, 0><<<g, 256, 0, stream>>>(hc, (long)197 * 384, cfc1_bf + (long)i * 1536 * 384, 384,
                                                              cfc1_b + i * 1536, f1c, 1536, 384, 32, 0);
        }
        {
            dim3 g(1, 3);
            gemm_bb2<0, 0, 1, 1, 0, 0><<<g, 256, 0, stream>>>(f1c, 1536, cfc2_bf + (long)i * 1536 * 384, 1536,
                                                              cfc2_b + i * 384, cls2, 384, 1536, 32, 0);
        }
        ca_update2<<<(int)(NC / 256), 256, 0, stream>>>(cls2, hc, cg2 + i * 384, tc);
    }

    // ---- final LN (cls token only) + head ----
    ln384<<<32, 128, 0, stream>>>(tc, (long)197 * 384, norm_w, norm_b, clsf, 384);
    {
        dim3 g(1, 8);
        gemm_bb2<0, 0, 1, 1, 0, 1><<<g, 256, 0, stream>>>(clsf, 384, headw_bf, 384,
                                                          head_b, outp, 1000, 384, 32, 1000);
    }
}

// Round 9
// 3965.596 us; speedup vs baseline: 5.2994x; 1.0560x over previous
//
#include <hip/hip_runtime.h>
#include <hip/hip_bf16.h>

#define B_ 32
#define D_ 384
#define N_ 196
#define NH_ 8
#define HD_ 48
#define L_ 24

typedef __bf16 bf16x8 __attribute__((ext_vector_type(8)));
typedef __bf16 bf16x4 __attribute__((ext_vector_type(4)));
typedef float f32x4 __attribute__((ext_vector_type(4)));

__device__ __forceinline__ float gelu_f(float v){
    return 0.5f * v * (1.0f + erff(v * 0.70710678118654752f));
}

// ---------------- fp32 -> bf16 bulk convert ----------------
__global__ __launch_bounds__(256) void cvt_bf(const float* __restrict__ s, __bf16* __restrict__ d, long n){
    long i = ((long)blockIdx.x * 256 + threadIdx.x) * 8;
    if (i >= n) return;
    float4 a = *reinterpret_cast<const float4*>(s + i);
    float4 b = *reinterpret_cast<const float4*>(s + i + 4);
    bf16x8 r;
    r[0] = (__bf16)a.x; r[1] = (__bf16)a.y; r[2] = (__bf16)a.z; r[3] = (__bf16)a.w;
    r[4] = (__bf16)b.x; r[5] = (__bf16)b.y; r[6] = (__bf16)b.z; r[7] = (__bf16)b.w;
    *reinterpret_cast<bf16x8*>(d + i) = r;
}

// fp32 -> bf16 with row padding (zero rows >= rows)
__global__ __launch_bounds__(256) void cvt_pad(const float* __restrict__ s, __bf16* __restrict__ d,
                                               int rows, int K, int rows_pad){
    int id = blockIdx.x * 256 + threadIdx.x;
    if (id >= rows_pad * K) return;
    int r = id / K;
    d[id] = (r < rows) ? (__bf16)s[id] : (__bf16)0.f;
}

// ---------------- conv weight reorder: W'[co][tap*Ci+ci] (bf16, K padded) ----------------
__global__ __launch_bounds__(256) void wprep(const float* __restrict__ w, __bf16* __restrict__ W2,
                                             int Co, int Ci, int Kpad){
    int id = blockIdx.x * 256 + threadIdx.x;
    if (id >= Co * Kpad) return;
    int co = id / Kpad, k = id - co * Kpad;
    float v = 0.f;
    if (k < 9 * Ci){
        int tap = k / Ci, ci = k - tap * Ci;
        v = w[((long)co * Ci + ci) * 9 + tap];
    }
    W2[id] = (__bf16)v;
}

// ---------------- im2col for conv1 (fp32 NCHW input) -> A[pix][32] bf16 ----------------
__global__ __launch_bounds__(256) void im2col_x(const float* __restrict__ x, __bf16* __restrict__ A){
    int id = blockIdx.x * 256 + threadIdx.x;
    if (id >= 401408) return;
    int ox = id % 112; int t1 = id / 112; int oy = t1 % 112; int b = t1 / 112;
    __bf16 buf[32];
    #pragma unroll
    for (int i = 0; i < 32; i++) buf[i] = (__bf16)0.f;
    const float* xb = x + (long)b * 3 * 224 * 224;
    #pragma unroll
    for (int tap = 0; tap < 9; tap++){
        int ky = tap / 3, kx = tap % 3;
        int iy = oy * 2 - 1 + ky, ix = ox * 2 - 1 + kx;
        if ((unsigned)iy < 224u && (unsigned)ix < 224u){
            #pragma unroll
            for (int ci = 0; ci < 3; ci++)
                buf[tap * 3 + ci] = (__bf16)xb[((long)ci * 224 + iy) * 224 + ix];
        }
    }
    __bf16* dst = A + (long)id * 32;
    #pragma unroll
    for (int i = 0; i < 4; i++)
        *reinterpret_cast<bf16x8*>(dst + i * 8) = *reinterpret_cast<bf16x8*>(buf + i * 8);
}

// ---------------- im2col from bf16 [pix][C] rows -> A[pixout][Kpad] ----------------
__global__ __launch_bounds__(256) void im2col_bf(const __bf16* __restrict__ in, __bf16* __restrict__ A,
                                                 int C, int Hi, int Wi, int Ho, int Wo, int Kpad, int total){
    int id = blockIdx.x * 256 + threadIdx.x;
    if (id >= total) return;
    int tap = id % 9; int pix = id / 9;
    int ox = pix % Wo; int t1 = pix / Wo; int oy = t1 % Ho; int b = t1 / Ho;
    int ky = tap / 3, kx = tap % 3;
    int iy = oy * 2 - 1 + ky, ix = ox * 2 - 1 + kx;
    __bf16* dst = A + (long)pix * Kpad + tap * C;
    if ((unsigned)iy < (unsigned)Hi && (unsigned)ix < (unsigned)Wi){
        const __bf16* src = in + ((long)(b * Hi + iy) * Wi + ix) * C;
        for (int c = 0; c < C; c += 8)
            *reinterpret_cast<bf16x8*>(dst + c) = *reinterpret_cast<const bf16x8*>(src + c);
    } else {
        bf16x8 z{};
        for (int c = 0; c < C; c += 8) *reinterpret_cast<bf16x8*>(dst + c) = z;
    }
    if (tap == 0){
        bf16x8 z{};
        for (int c = 9 * C; c < Kpad; c += 8)
            *reinterpret_cast<bf16x8*>(A + (long)pix * Kpad + c) = z;
    }
}

// ---------------- conv GEMM: 128x128 tile, 2-stage prefetch, fused BN (+GELU / +pos) ----------------
template<int GELU, int POSOUT>
__global__ __launch_bounds__(256) void gemm_conv(const __bf16* __restrict__ A, int Kpad,
                                                 const __bf16* __restrict__ W,
                                                 const float* __restrict__ g, const float* __restrict__ bb,
                                                 void* __restrict__ Cv, int N,
                                                 const float* __restrict__ pos){
    __shared__ __align__(16) char smem[20480];
    char* Ab = smem;
    char* Bb = smem + 10240;
    const int tid  = threadIdx.x;
    const int lane = tid & 63;
    const int wn   = (tid >> 6) & 1;
    const int wm   = tid >> 7;
    const int row0 = blockIdx.x * 128;
    const int col0 = blockIdx.y * 128;
    const int hi = lane >> 4, lo = lane & 15;
    f32x4 acc[4][4] = {};
    auto loadA = [&](int kk, int i)->bf16x8 {
        int p = i * 256 + tid;
        int r = p >> 2, cq = p & 3;
        return *reinterpret_cast<const bf16x8*>(A + (long)(row0 + r) * Kpad + kk + cq * 8);
    };
    auto loadB = [&](int kk, int i)->bf16x8 {
        int p = i * 256 + tid;
        int r = p >> 2, cq = p & 3;
        int gc = col0 + r;
        bf16x8 vw{};
        if (gc < N) vw = *reinterpret_cast<const bf16x8*>(W + (long)gc * Kpad + kk + cq * 8);
        return vw;
    };
    bf16x8 vaC0 = loadA(0, 0), vaC1 = loadA(0, 1);
    bf16x8 vwC0 = loadB(0, 0), vwC1 = loadB(0, 1);
    for (int k0 = 0; k0 < Kpad; k0 += 32){
        #pragma unroll
        for (int i = 0; i < 2; i++){
            int p = i * 256 + tid;
            int r = p >> 2, cq = p & 3;
            *reinterpret_cast<bf16x8*>(Ab + r * 80 + cq * 16) = i ? vaC1 : vaC0;
            *reinterpret_cast<bf16x8*>(Bb + r * 80 + cq * 16) = i ? vwC1 : vwC0;
        }
        __syncthreads();
        int kn = (k0 + 32 < Kpad) ? k0 + 32 : k0;
        bf16x8 vaN0 = loadA(kn, 0), vaN1 = loadA(kn, 1);
        bf16x8 vwN0 = loadB(kn, 0), vwN1 = loadB(kn, 1);
        bf16x8 af[4], bfr[4];
        #pragma unroll
        for (int m = 0; m < 4; m++)
            af[m] = *reinterpret_cast<const bf16x8*>(Ab + (wm * 64 + m * 16 + lo) * 80 + hi * 16);
        #pragma unroll
        for (int n = 0; n < 4; n++)
            bfr[n] = *reinterpret_cast<const bf16x8*>(Bb + (wn * 64 + n * 16 + lo) * 80 + hi * 16);
        #pragma unroll
        for (int m = 0; m < 4; m++)
            #pragma unroll
            for (int n = 0; n < 4; n++)
                acc[m][n] = __builtin_amdgcn_mfma_f32_16x16x32_bf16(af[m], bfr[n], acc[m][n], 0, 0, 0);
        __syncthreads();
        vaC0 = vaN0; vaC1 = vaN1; vwC0 = vwN0; vwC1 = vwN1;
    }
    float* Cf = (float*)Cv;
    __bf16* Cb = (__bf16*)Cv;
    #pragma unroll
    for (int m = 0; m < 4; m++){
        #pragma unroll
        for (int n = 0; n < 4; n++){
            int row = row0 + wm * 64 + m * 16 + hi * 4;
            int col = col0 + wn * 64 + n * 16 + lo;
            if (col >= N) continue;
            float scale = g[col] * rsqrtf(1.0f + 1e-5f);
            float bv = bb[col];
            #pragma unroll
            for (int j = 0; j < 4; j++){
                float v = acc[m][n][j] * scale + bv;
                if (GELU) v = gelu_f(v);
                if (POSOUT)
                    Cf[(long)(row + j) * 384 + col] = v + pos[((row + j) % 196) * 384 + col];
                else
                    Cb[(long)(row + j) * N + col] = (__bf16)v;
            }
        }
    }
}

// ---------------- LayerNorm over D=384, fp32 out ----------------
__global__ __launch_bounds__(128) void ln384(const float* __restrict__ x, long xstride,
                                             const float* __restrict__ w, const float* __restrict__ b,
                                             float* __restrict__ y, long ystride){
    long row = blockIdx.x;
    int tid = threadIdx.x;
    const float* xr = x + row * xstride;
    float v0 = xr[tid], v1 = xr[tid + 128], v2 = xr[tid + 256];
    float s = v0 + v1 + v2;
    float ss = v0 * v0 + v1 * v1 + v2 * v2;
    for (int off = 32; off; off >>= 1){ s += __shfl_down(s, off); ss += __shfl_down(ss, off); }
    __shared__ float rs[2], rss[2];
    if ((tid & 63) == 0){ rs[tid >> 6] = s; rss[tid >> 6] = ss; }
    __syncthreads();
    float S = rs[0] + rs[1], SS = rss[0] + rss[1];
    float m = S * (1.0f / 384.0f);
    float var = SS * (1.0f / 384.0f) - m * m;
    float r = rsqrtf(var + 1e-5f);
    float* yr = y + row * ystride;
    yr[tid]       = (v0 - m) * r * w[tid]       + b[tid];
    yr[tid + 128] = (v1 - m) * r * w[tid + 128] + b[tid + 128];
    yr[tid + 256] = (v2 - m) * r * w[tid + 256] + b[tid + 256];
}

// ---------------- LayerNorm, bf16 out (for initial LN1) ----------------
__global__ __launch_bounds__(128) void ln384_bf(const float* __restrict__ x,
                                                const float* __restrict__ w, const float* __restrict__ b,
                                                __bf16* __restrict__ y){
    long row = blockIdx.x;
    int tid = threadIdx.x;
    const float* xr = x + row * 384;
    float v0 = xr[tid], v1 = xr[tid + 128], v2 = xr[tid + 256];
    float s = v0 + v1 + v2;
    float ss = v0 * v0 + v1 * v1 + v2 * v2;
    for (int off = 32; off; off >>= 1){ s += __shfl_down(s, off); ss += __shfl_down(ss, off); }
    __shared__ float rs[2], rss[2];
    if ((tid & 63) == 0){ rs[tid >> 6] = s; rss[tid >> 6] = ss; }
    __syncthreads();
    float S = rs[0] + rs[1], SS = rss[0] + rss[1];
    float m = S * (1.0f / 384.0f);
    float var = SS * (1.0f / 384.0f) - m * m;
    float r = rsqrtf(var + 1e-5f);
    __bf16* yr = y + row * 384;
    yr[tid]       = (__bf16)((v0 - m) * r * w[tid]       + b[tid]);
    yr[tid + 128] = (__bf16)((v1 - m) * r * w[tid + 128] + b[tid + 128]);
    yr[tid + 256] = (__bf16)((v2 - m) * r * w[tid + 256] + b[tid + 256]);
}

// ---------------- t += g1*o2 ; ht = LN3(t) transposed (bf16) ----------------
__global__ __launch_bounds__(128) void proj_res_lnt(const __bf16* __restrict__ o2,
                                                    const float* __restrict__ g1,
                                                    float* __restrict__ t,
                                                    const float* __restrict__ n3w, const float* __restrict__ n3b,
                                                    __bf16* __restrict__ ht){
    long row = blockIdx.x;
    int tid = threadIdx.x;
    int c0 = tid * 4;
    float v[4] = {0.f, 0.f, 0.f, 0.f};
    if (tid < 96){
        float4 tv = *reinterpret_cast<const float4*>(t + row * 384 + c0);
        bf16x4 ov = *reinterpret_cast<const bf16x4*>(o2 + row * 384 + c0);
        v[0] = tv.x + g1[c0 + 0] * (float)ov[0];
        v[1] = tv.y + g1[c0 + 1] * (float)ov[1];
        v[2] = tv.z + g1[c0 + 2] * (float)ov[2];
        v[3] = tv.w + g1[c0 + 3] * (float)ov[3];
        *reinterpret_cast<float4*>(t + row * 384 + c0) = make_float4(v[0], v[1], v[2], v[3]);
    }
    float s = v[0] + v[1] + v[2] + v[3];
    float ss = v[0] * v[0] + v[1] * v[1] + v[2] * v[2] + v[3] * v[3];
    for (int off = 32; off; off >>= 1){ s += __shfl_down(s, off); ss += __shfl_down(ss, off); }
    __shared__ float rs[2], rss[2];
    if ((tid & 63) == 0){ rs[tid >> 6] = s; rss[tid >> 6] = ss; }
    __syncthreads();
    float S = rs[0] + rs[1], SS = rss[0] + rss[1];
    float m = S * (1.0f / 384.0f);
    float var = SS * (1.0f / 384.0f) - m * m;
    float r = rsqrtf(var + 1e-5f);
    if (tid < 96){
        int b = (int)(row / 196), n = (int)(row % 196);
        __bf16* yb = ht + ((long)b * 384) * 196 + n;
        #pragma unroll
        for (int j = 0; j < 4; j++){
            int c = c0 + j;
            yb[(long)c * 196] = (__bf16)((v[j] - m) * r * n3w[c] + n3b[c]);
        }
    }
}

// ---------------- t += hadd ; h = LN2(t) bf16 ----------------
__global__ __launch_bounds__(128) void ln2res(float* __restrict__ t,
                                              const __bf16* __restrict__ hadd,
                                              const float* __restrict__ n2w, const float* __restrict__ n2b,
                                              __bf16* __restrict__ h){
    long row = blockIdx.x;
    int tid = threadIdx.x;
    int c0 = tid * 4;
    float v[4] = {0.f, 0.f, 0.f, 0.f};
    if (tid < 96){
        float4 tv = *reinterpret_cast<const float4*>(t + row * 384 + c0);
        bf16x4 hv = *reinterpret_cast<const bf16x4*>(hadd + row * 384 + c0);
        v[0] = tv.x + (float)hv[0];
        v[1] = tv.y + (float)hv[1];
        v[2] = tv.z + (float)hv[2];
        v[3] = tv.w + (float)hv[3];
        *reinterpret_cast<float4*>(t + row * 384 + c0) = make_float4(v[0], v[1], v[2], v[3]);
    }
    float s = v[0] + v[1] + v[2] + v[3];
    float ss = v[0] * v[0] + v[1] * v[1] + v[2] * v[2] + v[3] * v[3];
    for (int off = 32; off; off >>= 1){ s += __shfl_down(s, off); ss += __shfl_down(ss, off); }
    __shared__ float rs[2], rss[2];
    if ((tid & 63) == 0){ rs[tid >> 6] = s; rss[tid >> 6] = ss; }
    __syncthreads();
    float S = rs[0] + rs[1], SS = rss[0] + rss[1];
    float m = S * (1.0f / 384.0f);
    float var = SS * (1.0f / 384.0f) - m * m;
    float r = rsqrtf(var + 1e-5f);
    if (tid < 96){
        bf16x4 o;
        #pragma unroll
        for (int j = 0; j < 4; j++){
            int c = c0 + j;
            o[j] = (__bf16)((v[j] - m) * r * n2w[c] + n2b[c]);
        }
        *reinterpret_cast<bf16x4*>(h + row * 384 + c0) = o;
    }
}

// ---------------- t += g2*f2 ; h = LN1next(t) bf16 ----------------
__global__ __launch_bounds__(128) void fc2_res_ln(const __bf16* __restrict__ f2,
                                                  const float* __restrict__ g2,
                                                  float* __restrict__ t,
                                                  const float* __restrict__ n1w, const float* __restrict__ n1b,
                                                  __bf16* __restrict__ h){
    long row = blockIdx.x;
    int tid = threadIdx.x;
    int c0 = tid * 4;
    float v[4] = {0.f, 0.f, 0.f, 0.f};
    if (tid < 96){
        float4 tv = *reinterpret_cast<const float4*>(t + row * 384 + c0);
        bf16x4 fv = *reinterpret_cast<const bf16x4*>(f2 + row * 384 + c0);
        v[0] = tv.x + g2[c0 + 0] * (float)fv[0];
        v[1] = tv.y + g2[c0 + 1] * (float)fv[1];
        v[2] = tv.z + g2[c0 + 2] * (float)fv[2];
        v[3] = tv.w + g2[c0 + 3] * (float)fv[3];
        *reinterpret_cast<float4*>(t + row * 384 + c0) = make_float4(v[0], v[1], v[2], v[3]);
    }
    float s = v[0] + v[1] + v[2] + v[3];
    float ss = v[0] * v[0] + v[1] * v[1] + v[2] * v[2] + v[3] * v[3];
    for (int off = 32; off; off >>= 1){ s += __shfl_down(s, off); ss += __shfl_down(ss, off); }
    __shared__ float rs[2], rss[2];
    if ((tid & 63) == 0){ rs[tid >> 6] = s; rss[tid >> 6] = ss; }
    __syncthreads();
    float S = rs[0] + rs[1], SS = rss[0] + rss[1];
    float m = S * (1.0f / 384.0f);
    float var = SS * (1.0f / 384.0f) - m * m;
    float r = rsqrtf(var + 1e-5f);
    if (tid < 96){
        bf16x4 o;
        #pragma unroll
        for (int j = 0; j < 4; j++){
            int c = c0 + j;
            o[j] = (__bf16)((v[j] - m) * r * n1w[c] + n1b[c]);
        }
        *reinterpret_cast<bf16x4*>(h + row * 384 + c0) = o;
    }
}

// ---------------- bf16 MFMA GEMM, 64x128 tile, 4 waves, BK=64, 2-stage prefetch ----------------
// MODE 0: C=acc+bias; 1: gelu. OUTBF: bf16 C. ACVT: A fp32 cvt-on-stage.
// GUARD: row guard vs M. NGUARD: col guard vs Ncols. Requires K%64==0.
template<int MODE, int OUTBF, int ACVT, int GUARD, int NGUARD>
__global__ __launch_bounds__(256) void gemm_bb2(const void* __restrict__ Av, long lda,
                                                const __bf16* __restrict__ W, int Kw,
                                                const float* __restrict__ bias,
                                                void* __restrict__ Cv, long ldc,
                                                int K, int M, int Ncols){
    __shared__ __align__(16) char smem[27648];
    char* Ab = smem;            // 64 rows x 144B
    char* Bb = smem + 9216;     // 128 rows x 144B
    const int tid = threadIdx.x;
    const int lane = tid & 63;
    const int wn = tid >> 6;
    const int row0 = blockIdx.x * 64;
    const int col0 = blockIdx.y * 128;
    const int hi = lane >> 4, lo = lane & 15;
    const __bf16* Abf = (const __bf16*)Av;
    const float* Af = (const float*)Av;
    f32x4 acc[4][2] = {};
    auto loadA = [&](int kk, int i)->bf16x8 {
        int p = i * 256 + tid;
        int r = p >> 3, cq = p & 7;
        bf16x8 va{};
        int grow = row0 + r;
        if (!GUARD || grow < M){
            long ai = (long)grow * lda + kk + cq * 8;
            if (ACVT){
                float4 a0 = *reinterpret_cast<const float4*>(Af + ai);
                float4 a1 = *reinterpret_cast<const float4*>(Af + ai + 4);
                va[0] = (__bf16)a0.x; va[1] = (__bf16)a0.y; va[2] = (__bf16)a0.z; va[3] = (__bf16)a0.w;
                va[4] = (__bf16)a1.x; va[5] = (__bf16)a1.y; va[6] = (__bf16)a1.z; va[7] = (__bf16)a1.w;
            } else {
                va = *reinterpret_cast<const bf16x8*>(Abf + ai);
            }
        }
        return va;
    };
    auto loadB = [&](int kk, int i)->bf16x8 {
        int p = i * 256 + tid;
        int r = p >> 3, cq = p & 7;
        return *reinterpret_cast<const bf16x8*>(W + (long)(col0 + r) * Kw + kk + cq * 8);
    };
    bf16x8 vaC[2], vwC[4];
    vaC[0] = loadA(0, 0); vaC[1] = loadA(0, 1);
    #pragma unroll
    for (int i = 0; i < 4; i++) vwC[i] = loadB(0, i);
    for (int k0 = 0; k0 < K; k0 += 64){
        #pragma unroll
        for (int i = 0; i < 2; i++){
            int p = i * 256 + tid;
            int r = p >> 3, cq = p & 7;
            *reinterpret_cast<bf16x8*>(Ab + r * 144 + cq * 16) = vaC[i];
        }
        #pragma unroll
        for (int i = 0; i < 4; i++){
            int p = i * 256 + tid;
            int r = p >> 3, cq = p & 7;
            *reinterpret_cast<bf16x8*>(Bb + r * 144 + cq * 16) = vwC[i];
        }
        __syncthreads();
        int kn = (k0 + 64 < K) ? k0 + 64 : k0;
        bf16x8 vaN[2], vwN[4];
        vaN[0] = loadA(kn, 0); vaN[1] = loadA(kn, 1);
        #pragma unroll
        for (int i = 0; i < 4; i++) vwN[i] = loadB(kn, i);
        bf16x8 af[2][4], bfr[2][2];
        #pragma unroll
        for (int m = 0; m < 4; m++){
            af[0][m] = *reinterpret_cast<const bf16x8*>(Ab + (m * 16 + lo) * 144 + hi * 16);
            af[1][m] = *reinterpret_cast<const bf16x8*>(Ab + (m * 16 + lo) * 144 + 64 + hi * 16);
        }
        #pragma unroll
        for (int n = 0; n < 2; n++){
            bfr[0][n] = *reinterpret_cast<const bf16x8*>(Bb + (wn * 32 + n * 16 + lo) * 144 + hi * 16);
            bfr[1][n] = *reinterpret_cast<const bf16x8*>(Bb + (wn * 32 + n * 16 + lo) * 144 + 64 + hi * 16);
        }
        #pragma unroll
        for (int kc = 0; kc < 2; kc++)
            #pragma unroll
            for (int m = 0; m < 4; m++)
                #pragma unroll
                for (int n = 0; n < 2; n++)
                    acc[m][n] = __builtin_amdgcn_mfma_f32_16x16x32_bf16(af[kc][m], bfr[kc][n], acc[m][n], 0, 0, 0);
        __syncthreads();
        vaC[0] = vaN[0]; vaC[1] = vaN[1];
        #pragma unroll
        for (int i = 0; i < 4; i++) vwC[i] = vwN[i];
    }
    float* Cf = (float*)Cv;
    __bf16* Cb = (__bf16*)Cv;
    #pragma unroll
    for (int m = 0; m < 4; m++){
        #pragma unroll
        for (int n = 0; n < 2; n++){
            int row = row0 + m * 16 + hi * 4;
            int col = col0 + wn * 32 + n * 16 + lo;
            if (NGUARD && col >= Ncols) continue;
            float bv = bias[col];
            #pragma unroll
            for (int j = 0; j < 4; j++){
                if (GUARD && (row + j) >= M) continue;
                float v = acc[m][n][j] + bv;
                if (MODE == 1) v = gelu_f(v);
                long ci = (long)(row + j) * ldc + col;
                if (OUTBF) Cb[ci] = (__bf16)v;
                else Cf[ci] = v;
            }
        }
    }
}

// ---------------- bf16 MFMA GEMM, 64x64 tile, 4 waves, BK=64, 2-stage prefetch, bf16 out ----------------
// C[M,N] = A @ W^T + bias. M%64==0, N%64==0, K%64==0.
__global__ __launch_bounds__(256) void gemm_bb3(const __bf16* __restrict__ A, long lda,
                                                const __bf16* __restrict__ W, int Kw,
                                                const float* __restrict__ bias,
                                                __bf16* __restrict__ C, long ldc,
                                                int K){
    __shared__ __align__(16) char smem[18432];
    char* Ab = smem;            // 64 rows x 144B
    char* Bb = smem + 9216;     // 64 rows x 144B
    const int tid = threadIdx.x;
    const int lane = tid & 63;
    const int wn = tid >> 6;
    const int row0 = blockIdx.x * 64;
    const int col0 = blockIdx.y * 64;
    const int hi = lane >> 4, lo = lane & 15;
    f32x4 acc[4] = {};
    auto loadA = [&](int kk, int i)->bf16x8 {
        int p = i * 256 + tid;
        int r = p >> 3, cq = p & 7;
        return *reinterpret_cast<const bf16x8*>(A + (long)(row0 + r) * lda + kk + cq * 8);
    };
    auto loadB = [&](int kk, int i)->bf16x8 {
        int p = i * 256 + tid;
        int r = p >> 3, cq = p & 7;
        return *reinterpret_cast<const bf16x8*>(W + (long)(col0 + r) * Kw + kk + cq * 8);
    };
    bf16x8 vaC[2], vwC[2];
    vaC[0] = loadA(0, 0); vaC[1] = loadA(0, 1);
    vwC[0] = loadB(0, 0); vwC[1] = loadB(0, 1);
    for (int k0 = 0; k0 < K; k0 += 64){
        #pragma unroll
        for (int i = 0; i < 2; i++){
            int p = i * 256 + tid;
            int r = p >> 3, cq = p & 7;
            *reinterpret_cast<bf16x8*>(Ab + r * 144 + cq * 16) = vaC[i];
            *reinterpret_cast<bf16x8*>(Bb + r * 144 + cq * 16) = vwC[i];
        }
        __syncthreads();
        int kn = (k0 + 64 < K) ? k0 + 64 : k0;
        bf16x8 vaN[2], vwN[2];
        vaN[0] = loadA(kn, 0); vaN[1] = loadA(kn, 1);
        vwN[0] = loadB(kn, 0); vwN[1] = loadB(kn, 1);
        bf16x8 af[2][4], bfr[2];
        #pragma unroll
        for (int m = 0; m < 4; m++){
            af[0][m] = *reinterpret_cast<const bf16x8*>(Ab + (m * 16 + lo) * 144 + hi * 16);
            af[1][m] = *reinterpret_cast<const bf16x8*>(Ab + (m * 16 + lo) * 144 + 64 + hi * 16);
        }
        bfr[0] = *reinterpret_cast<const bf16x8*>(Bb + (wn * 16 + lo) * 144 + hi * 16);
        bfr[1] = *reinterpret_cast<const bf16x8*>(Bb + (wn * 16 + lo) * 144 + 64 + hi * 16);
        #pragma unroll
        for (int kc = 0; kc < 2; kc++)
            #pragma unroll
            for (int m = 0; m < 4; m++)
                acc[m] = __builtin_amdgcn_mfma_f32_16x16x32_bf16(af[kc][m], bfr[kc], acc[m], 0, 0, 0);
        __syncthreads();
        vaC[0] = vaN[0]; vaC[1] = vaN[1]; vwC[0] = vwN[0]; vwC[1] = vwN[1];
    }
    #pragma unroll
    for (int m = 0; m < 4; m++){
        int row = row0 + m * 16 + hi * 4;
        int col = col0 + wn * 16 + lo;
        float bv = bias[col];
        #pragma unroll
        for (int j = 0; j < 4; j++)
            C[(long)(row + j) * ldc + col] = (__bf16)(acc[m][j] + bv);
    }
}

// ---------------- positional embedding: pos[n, d] ----------------
__global__ __launch_bounds__(384) void pos_embed(const float* __restrict__ pw, const float* __restrict__ pb,
                                                 float* __restrict__ pos){
    __shared__ float p64[64];
    int n = blockIdx.x;
    int iy = n / 14, ix = n % 14;
    int t = threadIdx.x;
    if (t < 64){
        int axis = t >> 5;
        int c = t & 31;
        int u = c >> 1;
        float coord = (axis == 0) ? (float)(iy + 1) : (float)(ix + 1);
        float val = coord / ((14.0f + 1e-6f) * 6.283185307179586f);
        float T = powf(10000.0f, (float)u / 16.0f);
        float a = val / T;
        p64[t] = (c & 1) ? cosf(a) : sinf(a);
    }
    __syncthreads();
    float acc = 0.f;
    const float* wr = pw + (long)t * 64;
    #pragma unroll 8
    for (int c = 0; c < 64; c++) acc += p64[c] * wr[c];
    pos[n * 384 + t] = acc + pb[t];
}

// ---------------- XCA attention via MFMA: one block per (b, head) ----------------
__global__ __launch_bounds__(256) void xca2(const __bf16* __restrict__ qkv, const float* __restrict__ temp,
                                            __bf16* __restrict__ o){
    __shared__ __align__(16) char smem[74880];
    __bf16* qs = (__bf16*)smem;
    __bf16* ks = (__bf16*)(smem + 22272);
    __bf16* vt = (__bf16*)(smem + 44544);
    float* inq = (float*)(smem + 74496);
    float* ink = (float*)(smem + 74688);
    float* att = (float*)smem;                  // overlay on qs
    __bf16* abf = (__bf16*)(smem + 22272);      // overlay on ks
    int bh = blockIdx.x;
    int b = bh >> 3, h = bh & 7;
    const int tid = threadIdx.x;
    const int wid = tid >> 6, lane = tid & 63;
    const int hi = lane >> 4, lo = lane & 15;
    const __bf16* base = qkv + ((long)b * 196) * 1152 + h * 48;
    bf16x8 z8 = {};
    for (int idx = tid; idx < 48 * 28; idx += 256){
        int d = idx / 28, n = 196 + idx % 28;
        qs[d * 232 + n] = (__bf16)0.f;
        ks[d * 232 + n] = (__bf16)0.f;
    }
    for (int idx = tid; idx < 208 * 2; idx += 256){
        int n = idx >> 1, c = 48 + (idx & 1) * 8;
        *reinterpret_cast<bf16x8*>(vt + n * 72 + c) = z8;
    }
    for (int ch = tid; ch < 196 * 6; ch += 256){
        int n = ch / 6, c = ch % 6, d0 = c * 8;
        bf16x8 q8 = *reinterpret_cast<const bf16x8*>(base + (long)n * 1152 + d0);
        bf16x8 k8 = *reinterpret_cast<const bf16x8*>(base + (long)n * 1152 + 384 + d0);
        #pragma unroll
        for (int j = 0; j < 8; j++){
            qs[(d0 + j) * 232 + n] = q8[j];
            ks[(d0 + j) * 232 + n] = k8[j];
        }
        bf16x8 v8 = *reinterpret_cast<const bf16x8*>(base + (long)n * 1152 + 768 + d0);
        *reinterpret_cast<bf16x8*>(vt + n * 72 + d0) = v8;
    }
    __syncthreads();
    for (int r = wid; r < 48; r += 4){
        float sq = 0.f, sk = 0.f;
        for (int n = lane; n < 196; n += 64){
            float qv = (float)qs[r * 232 + n];
            float kv = (float)ks[r * 232 + n];
            sq += qv * qv; sk += kv * kv;
        }
        for (int off = 32; off; off >>= 1){ sq += __shfl_down(sq, off); sk += __shfl_down(sk, off); }
        if (lane == 0){
            inq[r] = 1.0f / fmaxf(sqrtf(sq), 1e-12f);
            ink[r] = 1.0f / fmaxf(sqrtf(sk), 1e-12f);
        }
    }
    __syncthreads();
    float tempv = temp[h];
    f32x4 qk0 = {}, qk1 = {}, qk2 = {};
    __builtin_amdgcn_s_setprio(1);
    {
        int mi = wid / 3, ni = wid % 3;
        #pragma unroll
        for (int k0 = 0; k0 < 224; k0 += 32){
            bf16x8 af = *reinterpret_cast<const bf16x8*>(qs + (mi * 16 + lo) * 232 + k0 + hi * 8);
            bf16x8 bf = *reinterpret_cast<const bf16x8*>(ks + (ni * 16 + lo) * 232 + k0 + hi * 8);
            qk0 = __builtin_amdgcn_mfma_f32_16x16x32_bf16(af, bf, qk0, 0, 0, 0);
        }
    }
    {
        int tt = wid + 4;
        int mi = tt / 3, ni = tt % 3;
        #pragma unroll
        for (int k0 = 0; k0 < 224; k0 += 32){
            bf16x8 af = *reinterpret_cast<const bf16x8*>(qs + (mi * 16 + lo) * 232 + k0 + hi * 8);
            bf16x8 bf = *reinterpret_cast<const bf16x8*>(ks + (ni * 16 + lo) * 232 + k0 + hi * 8);
            qk1 = __builtin_amdgcn_mfma_f32_16x16x32_bf16(af, bf, qk1, 0, 0, 0);
        }
    }
    if (wid == 0){
        #pragma unroll
        for (int k0 = 0; k0 < 224; k0 += 32){
            bf16x8 af = *reinterpret_cast<const bf16x8*>(qs + (2 * 16 + lo) * 232 + k0 + hi * 8);
            bf16x8 bf = *reinterpret_cast<const bf16x8*>(ks + (2 * 16 + lo) * 232 + k0 + hi * 8);
            qk2 = __builtin_amdgcn_mfma_f32_16x16x32_bf16(af, bf, qk2, 0, 0, 0);
        }
    }
    __builtin_amdgcn_s_setprio(0);
    __syncthreads();
    {
        int mi = wid / 3, ni = wid % 3;
        int e = ni * 16 + lo;
        float se = ink[e] * tempv;
        #pragma unroll
        for (int j = 0; j < 4; j++){
            int d = mi * 16 + hi * 4 + j;
            att[d * 68 + e] = qk0[j] * inq[d] * se;
        }
    }
    {
        int tt = wid + 4;
        int mi = tt / 3, ni = tt % 3;
        int e = ni * 16 + lo;
        float se = ink[e] * tempv;
        #pragma unroll
        for (int j = 0; j < 4; j++){
            int d = mi * 16 + hi * 4 + j;
            att[d * 68 + e] = qk1[j] * inq[d] * se;
        }
    }
    if (wid == 0){
        int e = 2 * 16 + lo;
        float se = ink[e] * tempv;
        #pragma unroll
        for (int j = 0; j < 4; j++){
            int d = 2 * 16 + hi * 4 + j;
            att[d * 68 + e] = qk2[j] * inq[d] * se;
        }
    }
    __syncthreads();
    if (tid < 192){
        int r = tid >> 2, q4 = tid & 3;
        const float* row = att + r * 68 + q4 * 12;
        float mx = -1e30f;
        #pragma unroll
        for (int i = 0; i < 12; i++) mx = fmaxf(mx, row[i]);
        mx = fmaxf(mx, __shfl_xor(mx, 1));
        mx = fmaxf(mx, __shfl_xor(mx, 2));
        float pv[12]; float sm = 0.f;
        #pragma unroll
        for (int i = 0; i < 12; i++){ pv[i] = expf(row[i] - mx); sm += pv[i]; }
        sm += __shfl_xor(sm, 1);
        sm += __shfl_xor(sm, 2);
        float inv = 1.0f / sm;
        #pragma unroll
        for (int i = 0; i < 12; i++) abf[r * 72 + q4 * 12 + i] = (__bf16)(pv[i] * inv);
    }
    for (int idx = tid; idx < 48 * 3; idx += 256){
        int r = idx / 3, c = 48 + (idx % 3) * 8;
        *reinterpret_cast<bf16x8*>(abf + r * 72 + c) = z8;
    }
    __syncthreads();
    __bf16* ob = o + ((long)b * 196) * 384 + h * 48;
    __builtin_amdgcn_s_setprio(1);
    for (int tt = wid; tt < 39; tt += 4){
        int mi = tt / 13, ni = tt % 13;
        f32x4 acc = {};
        #pragma unroll
        for (int e0 = 0; e0 < 64; e0 += 32){
            bf16x8 af = *reinterpret_cast<const bf16x8*>(abf + (mi * 16 + lo) * 72 + e0 + hi * 8);
            bf16x8 bf = *reinterpret_cast<const bf16x8*>(vt + (ni * 16 + lo) * 72 + e0 + hi * 8);
            acc = __builtin_amdgcn_mfma_f32_16x16x32_bf16(af, bf, acc, 0, 0, 0);
        }
        int n = ni * 16 + lo;
        if (n < 196){
            #pragma unroll
            for (int j = 0; j < 4; j++){
                int d = mi * 16 + hi * 4 + j;
                ob[(long)n * 384 + d] = (__bf16)acc[j];
            }
        }
    }
    __builtin_amdgcn_s_setprio(0);
}

// ---------------- LPI: gated output to hadd (bf16, [b,n,d]), ht bf16 in ----------------
__global__ __launch_bounds__(256) void lpi_g(const __bf16* __restrict__ ht,
                                             const float* __restrict__ w1, const float* __restrict__ b1,
                                             const float* __restrict__ bng, const float* __restrict__ bnb,
                                             const float* __restrict__ w2, const float* __restrict__ b2,
                                             const float* __restrict__ g3, __bf16* __restrict__ hadd){
    int bd = blockIdx.x;
    int d = bd % 384, b = bd / 384;
    __shared__ float p[16][16];
    __shared__ float p2[16][16];
    __shared__ float wA[9], wB[9];
    int tt = threadIdx.x;
    int yy = tt / 16, xx = tt % 16;
    p[yy][xx] = 0.f; p2[yy][xx] = 0.f;
    if (tt < 9){ wA[tt] = w1[d * 9 + tt]; wB[tt] = w2[d * 9 + tt]; }
    __syncthreads();
    if (tt < 196){
        int y = tt / 14, x = tt % 14;
        p[y + 1][x + 1] = (float)ht[((long)b * 384 + d) * 196 + tt];
    }
    __syncthreads();
    if (tt < 196){
        int y = tt / 14, x = tt % 14;
        float a = 0.f;
        #pragma unroll
        for (int ky = 0; ky < 3; ky++)
            #pragma unroll
            for (int kx = 0; kx < 3; kx++)
                a += wA[ky * 3 + kx] * p[y + ky][x + kx];
        a += b1[d];
        a = gelu_f(a);
        a = a * (bng[d] * rsqrtf(1.0f + 1e-5f)) + bnb[d];
        p2[y + 1][x + 1] = a;
    }
    __syncthreads();
    if (tt < 196){
        int y = tt / 14, x = tt % 14;
        float a = 0.f;
        #pragma unroll
        for (int ky = 0; ky < 3; ky++)
            #pragma unroll
            for (int kx = 0; kx < 3; kx++)
                a += wB[ky * 3 + kx] * p2[y + ky][x + kx];
        a += b2[d];
        hadd[((long)b * 196 + tt) * 384 + d] = (__bf16)(g3[d] * a);
    }
}

// ---------------- cls concat ----------------
__global__ __launch_bounds__(256) void concat_cls(const float* __restrict__ t, const float* __restrict__ clstok,
                                                  float* __restrict__ tc){
    long i = (long)blockIdx.x * 256 + threadIdx.x;
    if (i >= (long)B_ * 197 * 384) return;
    int d = (int)(i % 384);
    long bn = i / 384;
    int n = (int)(bn % 197);
    int b = (int)(bn / 197);
    tc[i] = (n == 0) ? clstok[d] : t[((long)b * 196 + (n - 1)) * 384 + d];
}

// ---------------- CA attention (bf16 qkv) ----------------
__global__ __launch_bounds__(256) void ca_attn(const __bf16* __restrict__ qkv, float* __restrict__ clsp){
    int bh = blockIdx.x;
    int b = bh >> 3, h = bh & 7;
    const __bf16* base = qkv + (long)b * 197 * 1152 + h * 48;
    __shared__ float q0[48];
    __shared__ float at2[197];
    __shared__ float smax, ssum;
    int tid = threadIdx.x;
    if (tid < 48) q0[tid] = (float)base[tid];
    __syncthreads();
    if (tid < 197){
        const __bf16* kr = base + (long)tid * 1152 + 384;
        float s = 0.f;
        for (int d = 0; d < 48; d++) s += q0[d] * (float)kr[d];
        at2[tid] = s * rsqrtf(48.0f);
    }
    __syncthreads();
    if (tid == 0){
        float m = -1e30f;
        for (int n = 0; n < 197; n++) m = fmaxf(m, at2[n]);
        smax = m;
    }
    __syncthreads();
    if (tid < 197) at2[tid] = expf(at2[tid] - smax);
    __syncthreads();
    if (tid == 0){
        float s = 0.f;
        for (int n = 0; n < 197; n++) s += at2[n];
        ssum = s;
    }
    __syncthreads();
    if (tid < 48){
        const __bf16* vb = base + 768 + tid;
        float s = 0.f;
        for (int n = 0; n < 197; n++) s += at2[n] * (float)vb[(long)n * 1152];
        clsp[b * 384 + h * 48 + tid] = s / ssum;
    }
}

__global__ __launch_bounds__(256) void ca_update1(const float* __restrict__ clso, const float* __restrict__ hc,
                                                  const float* __restrict__ g1, float* __restrict__ tc){
    long i = (long)blockIdx.x * 256 + threadIdx.x;
    if (i >= (long)B_ * 197 * 384) return;
    int d = (int)(i % 384);
    long bn = i / 384;
    int n = (int)(bn % 197);
    int b = (int)(bn / 197);
    float add = (n == 0) ? clso[b * 384 + d] : hc[i];
    tc[i] += g1[d] * add;
}

__global__ __launch_bounds__(256) void ca_update2(const float* __restrict__ cls2, const float* __restrict__ hc,
                                                  const float* __restrict__ g2, float* __restrict__ tc){
    long i = (long)blockIdx.x * 256 + threadIdx.x;
    if (i >= (long)B_ * 197 * 384) return;
    int d = (int)(i % 384);
    long bn = i / 384;
    int n = (int)(bn % 197);
    int b = (int)(bn / 197);
    float hv = hc[i];
    tc[i] = (n == 0) ? (g2[d] * cls2[b * 384 + d] + hv) : (hv + hv);
}

extern "C" void kernel_launch(void* const* d_in, const int* in_sizes, int n_in,
                              void* d_out, int out_size, void* d_ws, size_t ws_size,
                              hipStream_t stream){
    (void)in_sizes; (void)n_in; (void)out_size; (void)ws_size;
    const float* x      = (const float*)d_in[0];
    const float* clstok = (const float*)d_in[1];
    const float* pos_w  = (const float*)d_in[2];
    const float* pos_b  = (const float*)d_in[3];
    const float* pe_w[4] = {(const float*)d_in[4], (const float*)d_in[7], (const float*)d_in[10], (const float*)d_in[13]};
    const float* pe_g[4] = {(const float*)d_in[5], (const float*)d_in[8], (const float*)d_in[11], (const float*)d_in[14]};
    const float* pe_b[4] = {(const float*)d_in[6], (const float*)d_in[9], (const float*)d_in[12], (const float*)d_in[15]};
    const float* xqkv_w = (const float*)d_in[16];
    const float* xqkv_b = (const float*)d_in[17];
    const float* xproj_w = (const float*)d_in[18];
    const float* xproj_b = (const float*)d_in[19];
    const float* xtemp  = (const float*)d_in[20];
    const float* xn1_w = (const float*)d_in[21];
    const float* xn1_b = (const float*)d_in[22];
    const float* xn2_w = (const float*)d_in[23];
    const float* xn2_b = (const float*)d_in[24];
    const float* xn3_w = (const float*)d_in[25];
    const float* xn3_b = (const float*)d_in[26];
    const float* xfc1_w = (const float*)d_in[27];
    const float* xfc1_b = (const float*)d_in[28];
    const float* xfc2_w = (const float*)d_in[29];
    const float* xfc2_b = (const float*)d_in[30];
    const float* xlpi1_w = (const float*)d_in[31];
    const float* xlpi1_b = (const float*)d_in[32];
    const float* xlpi2_w = (const float*)d_in[33];
    const float* xlpi2_b = (const float*)d_in[34];
    const float* xbn_g = (const float*)d_in[35];
    const float* xbn_b = (const float*)d_in[36];
    const float* xg1 = (const float*)d_in[37];
    const float* xg2 = (const float*)d_in[38];
    const float* xg3 = (const float*)d_in[39];
    const float* cqkv_w = (const float*)d_in[40];
    const float* cqkv_b = (const float*)d_in[41];
    const float* cproj_w = (const float*)d_in[42];
    const float* cproj_b = (const float*)d_in[43];
    const float* cn1_w = (const float*)d_in[44];
    const float* cn1_b = (const float*)d_in[45];
    const float* cn2_w = (const float*)d_in[46];
    const float* cn2_b = (const float*)d_in[47];
    const float* cfc1_w = (const float*)d_in[48];
    const float* cfc1_b = (const float*)d_in[49];
    const float* cfc2_w = (const float*)d_in[50];
    const float* cfc2_b = (const float*)d_in[51];
    const float* cg1 = (const float*)d_in[52];
    const float* cg2 = (const float*)d_in[53];
    const float* norm_w = (const float*)d_in[54];
    const float* norm_b = (const float*)d_in[55];
    const float* head_w = (const float*)d_in[56];
    const float* head_b = (const float*)d_in[57];
    float* outp = (float*)d_out;

    float* ws = (float*)d_ws;
    // ---- conv phase buffers ----
    __bf16* A1   = (__bf16*)(ws);
    __bf16* A2   = (__bf16*)(ws);
    __bf16* A3   = (__bf16*)(ws);
    __bf16* A4   = (__bf16*)(ws);
    __bf16* out1 = (__bf16*)(ws + 22500000L);
    __bf16* out2 = (__bf16*)(ws + 22500000L);
    __bf16* out3 = (__bf16*)(ws + 27400000L);
    __bf16* wcv  = (__bf16*)(ws + 36000000L);
    __bf16* W1c = wcv;
    __bf16* W2c = wcv + 1536;
    __bf16* W3c = wcv + 44544;
    __bf16* W4c = wcv + 216576;
    // ---- XCA phase ----
    __bf16* wqkv_bf = (__bf16*)(ws);
    __bf16* wproj_bf = (__bf16*)(ws + 5308416L);
    __bf16* wfc1_bf = (__bf16*)(ws + 7077888L);
    __bf16* wfc2_bf = (__bf16*)(ws + 14155776L);
    float*  t       = ws + 21233664L;
    float*  pos     = ws + 23642112L;
    __bf16* h_bf    = (__bf16*)(ws + 23717376L);
    __bf16* qkv_bf  = (__bf16*)(ws + 24921600L);
    __bf16* o_bf    = (__bf16*)(ws + 28534272L);
    __bf16* ht_bf   = (__bf16*)(ws + 29738496L);
    __bf16* f1_bf   = (__bf16*)(ws + 32146944L);
    // aliases (time-disjoint within a layer):
    __bf16* o2_bf   = (__bf16*)(ws + 34555392L);
    __bf16* f2_bf   = (__bf16*)(ws + 24921600L);
    __bf16* hadd_bf = (__bf16*)(ws + 28534272L);
    // ---- CA phase ----
    float* tc   = ws;
    float* hc   = ws + 2420736L;
    __bf16* qkvc_bf = (__bf16*)(ws + 4841472L);
    float* clsp = ws + 8472576L;
    float* clso = clsp + 12288;
    float* f1c  = clso + 12288;
    float* cls2 = f1c + 49152;
    float* clsf = cls2 + 12288;
    __bf16* cqkv_bf  = (__bf16*)(ws + 9000000L);
    __bf16* cproj_bf = (__bf16*)(ws + 9500000L);
    __bf16* cfc1_bf  = (__bf16*)(ws + 9800000L);
    __bf16* cfc2_bf  = (__bf16*)(ws + 10400000L);
    __bf16* headw_bf = (__bf16*)(ws + 11000000L);

    // ---- conv weight prep ----
    wprep<<<(48 * 32 + 255) / 256, 256, 0, stream>>>(pe_w[0], W1c, 48, 3, 32);
    wprep<<<(96 * 448 + 255) / 256, 256, 0, stream>>>(pe_w[1], W2c, 96, 48, 448);
    wprep<<<(192 * 896 + 255) / 256, 256, 0, stream>>>(pe_w[2], W3c, 192, 96, 896);
    wprep<<<(384 * 1728 + 255) / 256, 256, 0, stream>>>(pe_w[3], W4c, 384, 192, 1728);

    // ---- patch embed: im2col + MFMA GEMM ----
    im2col_x<<<1568, 256, 0, stream>>>(x, A1);
    { dim3 g(3136, 1); gemm_conv<1, 0><<<g, 256, 0, stream>>>(A1, 32, W1c, pe_g[0], pe_b[0], out1, 48, nullptr); }
    im2col_bf<<<(100352 * 9 + 255) / 256, 256, 0, stream>>>(out1, A2, 48, 112, 112, 56, 56, 448, 100352 * 9);
    { dim3 g(784, 1); gemm_conv<1, 0><<<g, 256, 0, stream>>>(A2, 448, W2c, pe_g[1], pe_b[1], out2, 96, nullptr); }
    im2col_bf<<<(25088 * 9 + 255) / 256, 256, 0, stream>>>(out2, A3, 96, 56, 56, 28, 28, 896, 25088 * 9);
    pos_embed<<<196, 384, 0, stream>>>(pos_w, pos_b, pos);
    { dim3 g(196, 2); gemm_conv<1, 0><<<g, 256, 0, stream>>>(A3, 896, W3c, pe_g[2], pe_b[2], out3, 192, nullptr); }
    im2col_bf<<<(6272 * 9 + 255) / 256, 256, 0, stream>>>(out3, A4, 192, 28, 28, 14, 14, 1728, 6272 * 9);
    { dim3 g(49, 3); gemm_conv<0, 1><<<g, 256, 0, stream>>>(A4, 1728, W4c, pe_g[3], pe_b[3], t, 384, pos); }

    // ---- convert XCA weights to bf16 ----
    {
        long n1 = (long)L_ * 1152 * 384;
        long n2 = (long)L_ * 384 * 384;
        long n3 = (long)L_ * 1536 * 384;
        cvt_bf<<<(int)((n1 + 2047) / 2048), 256, 0, stream>>>(xqkv_w, wqkv_bf, n1);
        cvt_bf<<<(int)((n2 + 2047) / 2048), 256, 0, stream>>>(xproj_w, wproj_bf, n2);
        cvt_bf<<<(int)((n3 + 2047) / 2048), 256, 0, stream>>>(xfc1_w, wfc1_bf, n3);
        cvt_bf<<<(int)((n3 + 2047) / 2048), 256, 0, stream>>>(xfc2_w, wfc2_bf, n3);
    }

    // ---- 24 XCA layers ----
    const int M = B_ * N_;  // 6272 = 98*64
    ln384_bf<<<M, 128, 0, stream>>>(t, xn1_w, xn1_b, h_bf);   // initial LN1
    for (int l = 0; l < L_; l++){
        {
            dim3 g(98, 9);
            gemm_bb2<0, 1, 0, 0, 0><<<g, 256, 0, stream>>>(h_bf, 384, wqkv_bf + (long)l * 1152 * 384, 384,
                                                           xqkv_b + l * 1152, qkv_bf, 1152, 384, M, 0);
        }
        xca2<<<B_ * NH_, 256, 0, stream>>>(qkv_bf, xtemp + l * 8, o_bf);
        {   // proj: 64x64 tiles, bf16 out (incl bias)
            dim3 g(98, 6);
            gemm_bb3<<<g, 256, 0, stream>>>(o_bf, 384, wproj_bf + (long)l * 384 * 384, 384,
                                            xproj_b + l * 384, o2_bf, 384, 384);
        }
        proj_res_lnt<<<M, 128, 0, stream>>>(o2_bf, xg1 + l * 384, t,
                                            xn3_w + l * 384, xn3_b + l * 384, ht_bf);
        lpi_g<<<B_ * D_, 256, 0, stream>>>(ht_bf, xlpi1_w + (long)l * 384 * 9, xlpi1_b + l * 384,
                                           xbn_g + l * 384, xbn_b + l * 384,
                                           xlpi2_w + (long)l * 384 * 9, xlpi2_b + l * 384,
                                           xg3 + l * 384, hadd_bf);
        ln2res<<<M, 128, 0, stream>>>(t, hadd_bf, xn2_w + l * 384, xn2_b + l * 384, h_bf);
        {
            dim3 g(98, 12);
            gemm_bb2<1, 1, 0, 0, 0><<<g, 256, 0, stream>>>(h_bf, 384, wfc1_bf + (long)l * 1536 * 384, 384,
                                                           xfc1_b + l * 1536, f1_bf, 1536, 384, M, 0);
        }
        {   // fc2: 64x64 tiles, bf16 out (incl bias)
            dim3 g(98, 6);
            gemm_bb3<<<g, 256, 0, stream>>>(f1_bf, 1536, wfc2_bf + (long)l * 1536 * 384, 1536,
                                            xfc2_b + l * 384, f2_bf, 384, 1536);
        }
        int ln = (l + 1) % L_;
        fc2_res_ln<<<M, 128, 0, stream>>>(f2_bf, xg2 + l * 384, t,
                                          xn1_w + ln * 384, xn1_b + ln * 384, h_bf);
    }

    // ---- cls concat + 2 CA blocks ----
    const long NC = (long)B_ * 197 * 384;
    concat_cls<<<(int)(NC / 256), 256, 0, stream>>>(t, clstok, tc);
    {
        long nc = (long)2 * 1152 * 384;
        cvt_bf<<<(int)((nc + 2047) / 2048), 256, 0, stream>>>(cqkv_w, cqkv_bf, nc);
        long np = (long)2 * 384 * 384;
        cvt_bf<<<(int)((np + 2047) / 2048), 256, 0, stream>>>(cproj_w, cproj_bf, np);
        long nf = (long)2 * 1536 * 384;
        cvt_bf<<<(int)((nf + 2047) / 2048), 256, 0, stream>>>(cfc1_w, cfc1_bf, nf);
        cvt_bf<<<(int)((nf + 2047) / 2048), 256, 0, stream>>>(cfc2_w, cfc2_bf, nf);
        cvt_pad<<<(1024 * 384 + 255) / 256, 256, 0, stream>>>(head_w, headw_bf, 1000, 384, 1024);
    }
    const int MC = B_ * 197;  // 6304
    for (int i = 0; i < 2; i++){
        ln384<<<MC, 128, 0, stream>>>(tc, 384, cn1_w + i * 384, cn1_b + i * 384, hc, 384);
        {
            dim3 g(99, 9);
            gemm_bb2<0, 1, 1, 1, 0><<<g, 256, 0, stream>>>(hc, 384, cqkv_bf + (long)i * 1152 * 384, 384,
                                                           cqkv_b + i * 1152, qkvc_bf, 1152, 384, MC, 0);
        }
        ca_attn<<<B_ * NH_, 256, 0, stream>>>(qkvc_bf, clsp);
        {
            dim3 g(1, 3);
            gemm_bb2<0, 0, 1, 1, 0><<<g, 256, 0, stream>>>(clsp, 384, cproj_bf + (long)i * 384 * 384, 384,
                                                           cproj_b + i * 384, clso, 384, 384, 32, 0);
        }
        ca_update1<<<(int)(NC / 256), 256, 0, stream>>>(clso, hc, cg1 + i * 384, tc);
        ln384<<<MC, 128, 0, stream>>>(tc, 384, cn2_w + i * 384, cn2_b + i * 384, hc, 384);
        {
            dim3 g(1, 12);
            gemm_bb2<1, 0, 1, 1, 0><<<g, 256, 0, stream>>>(hc, (long)197 * 384, cfc1_bf + (long)i * 1536 * 384, 384,
                                                           cfc1_b + i * 1536, f1c, 1536, 384, 32, 0);
        }
        {
            dim3 g(1, 3);
            gemm_bb2<0, 0, 1, 1, 0><<<g, 256, 0, stream>>>(f1c, 1536, cfc2_bf + (long)i * 1536 * 384, 1536,
                                                           cfc2_b + i * 384, cls2, 384, 1536, 32, 0);
        }
        ca_update2<<<(int)(NC / 256), 256, 0, stream>>>(cls2, hc, cg2 + i * 384, tc);
    }

    // ---- final LN (cls token only) + head ----
    ln384<<<32, 128, 0, stream>>>(tc, (long)197 * 384, norm_w, norm_b, clsf, 384);
    {
        dim3 g(1, 8);
        gemm_bb2<0, 0, 1, 1, 1><<<g, 256, 0, stream>>>(clsf, 384, headw_bf, 384,
                                                       head_b, outp, 1000, 384, 32, 1000);
    }
}

// Round 10
// 3932.249 us; speedup vs baseline: 5.3443x; 1.0085x over previous
//
#include <hip/hip_runtime.h>
#include <hip/hip_bf16.h>

#define B_ 32
#define D_ 384
#define N_ 196
#define NH_ 8
#define HD_ 48
#define L_ 24

typedef __bf16 bf16x8 __attribute__((ext_vector_type(8)));
typedef __bf16 bf16x4 __attribute__((ext_vector_type(4)));
typedef float f32x4 __attribute__((ext_vector_type(4)));

__device__ __forceinline__ float gelu_f(float v){
    return 0.5f * v * (1.0f + erff(v * 0.70710678118654752f));
}

// ---------------- fp32 -> bf16 bulk convert ----------------
__global__ __launch_bounds__(256) void cvt_bf(const float* __restrict__ s, __bf16* __restrict__ d, long n){
    long i = ((long)blockIdx.x * 256 + threadIdx.x) * 8;
    if (i >= n) return;
    float4 a = *reinterpret_cast<const float4*>(s + i);
    float4 b = *reinterpret_cast<const float4*>(s + i + 4);
    bf16x8 r;
    r[0] = (__bf16)a.x; r[1] = (__bf16)a.y; r[2] = (__bf16)a.z; r[3] = (__bf16)a.w;
    r[4] = (__bf16)b.x; r[5] = (__bf16)b.y; r[6] = (__bf16)b.z; r[7] = (__bf16)b.w;
    *reinterpret_cast<bf16x8*>(d + i) = r;
}

// fp32 -> bf16 with row padding (zero rows >= rows)
__global__ __launch_bounds__(256) void cvt_pad(const float* __restrict__ s, __bf16* __restrict__ d,
                                               int rows, int K, int rows_pad){
    int id = blockIdx.x * 256 + threadIdx.x;
    if (id >= rows_pad * K) return;
    int r = id / K;
    d[id] = (r < rows) ? (__bf16)s[id] : (__bf16)0.f;
}

// ---------------- conv weight reorder: W'[co][tap*Ci+ci] (bf16, K padded) ----------------
__global__ __launch_bounds__(256) void wprep(const float* __restrict__ w, __bf16* __restrict__ W2,
                                             int Co, int Ci, int Kpad){
    int id = blockIdx.x * 256 + threadIdx.x;
    if (id >= Co * Kpad) return;
    int co = id / Kpad, k = id - co * Kpad;
    float v = 0.f;
    if (k < 9 * Ci){
        int tap = k / Ci, ci = k - tap * Ci;
        v = w[((long)co * Ci + ci) * 9 + tap];
    }
    W2[id] = (__bf16)v;
}

// ---------------- im2col for conv1 (fp32 NCHW input) -> A[pix][32] bf16 ----------------
__global__ __launch_bounds__(256) void im2col_x(const float* __restrict__ x, __bf16* __restrict__ A){
    int id = blockIdx.x * 256 + threadIdx.x;
    if (id >= 401408) return;
    int ox = id % 112; int t1 = id / 112; int oy = t1 % 112; int b = t1 / 112;
    __bf16 buf[32];
    #pragma unroll
    for (int i = 0; i < 32; i++) buf[i] = (__bf16)0.f;
    const float* xb = x + (long)b * 3 * 224 * 224;
    #pragma unroll
    for (int tap = 0; tap < 9; tap++){
        int ky = tap / 3, kx = tap % 3;
        int iy = oy * 2 - 1 + ky, ix = ox * 2 - 1 + kx;
        if ((unsigned)iy < 224u && (unsigned)ix < 224u){
            #pragma unroll
            for (int ci = 0; ci < 3; ci++)
                buf[tap * 3 + ci] = (__bf16)xb[((long)ci * 224 + iy) * 224 + ix];
        }
    }
    __bf16* dst = A + (long)id * 32;
    #pragma unroll
    for (int i = 0; i < 4; i++)
        *reinterpret_cast<bf16x8*>(dst + i * 8) = *reinterpret_cast<bf16x8*>(buf + i * 8);
}

// ---------------- im2col from bf16 [pix][C] rows -> A[pixout][Kpad] ----------------
__global__ __launch_bounds__(256) void im2col_bf(const __bf16* __restrict__ in, __bf16* __restrict__ A,
                                                 int C, int Hi, int Wi, int Ho, int Wo, int Kpad, int total){
    int id = blockIdx.x * 256 + threadIdx.x;
    if (id >= total) return;
    int tap = id % 9; int pix = id / 9;
    int ox = pix % Wo; int t1 = pix / Wo; int oy = t1 % Ho; int b = t1 / Ho;
    int ky = tap / 3, kx = tap % 3;
    int iy = oy * 2 - 1 + ky, ix = ox * 2 - 1 + kx;
    __bf16* dst = A + (long)pix * Kpad + tap * C;
    if ((unsigned)iy < (unsigned)Hi && (unsigned)ix < (unsigned)Wi){
        const __bf16* src = in + ((long)(b * Hi + iy) * Wi + ix) * C;
        for (int c = 0; c < C; c += 8)
            *reinterpret_cast<bf16x8*>(dst + c) = *reinterpret_cast<const bf16x8*>(src + c);
    } else {
        bf16x8 z{};
        for (int c = 0; c < C; c += 8) *reinterpret_cast<bf16x8*>(dst + c) = z;
    }
    if (tap == 0){
        bf16x8 z{};
        for (int c = 9 * C; c < Kpad; c += 8)
            *reinterpret_cast<bf16x8*>(A + (long)pix * Kpad + c) = z;
    }
}

// ---------------- conv GEMM: 128x128 tile, 2-stage prefetch, fused BN (+GELU / +pos) ----------------
template<int GELU, int POSOUT>
__global__ __launch_bounds__(256) void gemm_conv(const __bf16* __restrict__ A, int Kpad,
                                                 const __bf16* __restrict__ W,
                                                 const float* __restrict__ g, const float* __restrict__ bb,
                                                 void* __restrict__ Cv, int N,
                                                 const float* __restrict__ pos){
    __shared__ __align__(16) char smem[20480];
    char* Ab = smem;
    char* Bb = smem + 10240;
    const int tid  = threadIdx.x;
    const int lane = tid & 63;
    const int wn   = (tid >> 6) & 1;
    const int wm   = tid >> 7;
    const int row0 = blockIdx.x * 128;
    const int col0 = blockIdx.y * 128;
    const int hi = lane >> 4, lo = lane & 15;
    f32x4 acc[4][4] = {};
    auto loadA = [&](int kk, int i)->bf16x8 {
        int p = i * 256 + tid;
        int r = p >> 2, cq = p & 3;
        return *reinterpret_cast<const bf16x8*>(A + (long)(row0 + r) * Kpad + kk + cq * 8);
    };
    auto loadB = [&](int kk, int i)->bf16x8 {
        int p = i * 256 + tid;
        int r = p >> 2, cq = p & 3;
        int gc = col0 + r;
        bf16x8 vw{};
        if (gc < N) vw = *reinterpret_cast<const bf16x8*>(W + (long)gc * Kpad + kk + cq * 8);
        return vw;
    };
    bf16x8 vaC0 = loadA(0, 0), vaC1 = loadA(0, 1);
    bf16x8 vwC0 = loadB(0, 0), vwC1 = loadB(0, 1);
    for (int k0 = 0; k0 < Kpad; k0 += 32){
        #pragma unroll
        for (int i = 0; i < 2; i++){
            int p = i * 256 + tid;
            int r = p >> 2, cq = p & 3;
            *reinterpret_cast<bf16x8*>(Ab + r * 80 + cq * 16) = i ? vaC1 : vaC0;
            *reinterpret_cast<bf16x8*>(Bb + r * 80 + cq * 16) = i ? vwC1 : vwC0;
        }
        __syncthreads();
        int kn = (k0 + 32 < Kpad) ? k0 + 32 : k0;
        bf16x8 vaN0 = loadA(kn, 0), vaN1 = loadA(kn, 1);
        bf16x8 vwN0 = loadB(kn, 0), vwN1 = loadB(kn, 1);
        bf16x8 af[4], bfr[4];
        #pragma unroll
        for (int m = 0; m < 4; m++)
            af[m] = *reinterpret_cast<const bf16x8*>(Ab + (wm * 64 + m * 16 + lo) * 80 + hi * 16);
        #pragma unroll
        for (int n = 0; n < 4; n++)
            bfr[n] = *reinterpret_cast<const bf16x8*>(Bb + (wn * 64 + n * 16 + lo) * 80 + hi * 16);
        #pragma unroll
        for (int m = 0; m < 4; m++)
            #pragma unroll
            for (int n = 0; n < 4; n++)
                acc[m][n] = __builtin_amdgcn_mfma_f32_16x16x32_bf16(af[m], bfr[n], acc[m][n], 0, 0, 0);
        __syncthreads();
        vaC0 = vaN0; vaC1 = vaN1; vwC0 = vwN0; vwC1 = vwN1;
    }
    float* Cf = (float*)Cv;
    __bf16* Cb = (__bf16*)Cv;
    #pragma unroll
    for (int m = 0; m < 4; m++){
        #pragma unroll
        for (int n = 0; n < 4; n++){
            int row = row0 + wm * 64 + m * 16 + hi * 4;
            int col = col0 + wn * 64 + n * 16 + lo;
            if (col >= N) continue;
            float scale = g[col] * rsqrtf(1.0f + 1e-5f);
            float bv = bb[col];
            #pragma unroll
            for (int j = 0; j < 4; j++){
                float v = acc[m][n][j] * scale + bv;
                if (GELU) v = gelu_f(v);
                if (POSOUT)
                    Cf[(long)(row + j) * 384 + col] = v + pos[((row + j) % 196) * 384 + col];
                else
                    Cb[(long)(row + j) * N + col] = (__bf16)v;
            }
        }
    }
}

// ---------------- LayerNorm over D=384, fp32 out ----------------
__global__ __launch_bounds__(128) void ln384(const float* __restrict__ x, long xstride,
                                             const float* __restrict__ w, const float* __restrict__ b,
                                             float* __restrict__ y, long ystride){
    long row = blockIdx.x;
    int tid = threadIdx.x;
    const float* xr = x + row * xstride;
    float v0 = xr[tid], v1 = xr[tid + 128], v2 = xr[tid + 256];
    float s = v0 + v1 + v2;
    float ss = v0 * v0 + v1 * v1 + v2 * v2;
    for (int off = 32; off; off >>= 1){ s += __shfl_down(s, off); ss += __shfl_down(ss, off); }
    __shared__ float rs[2], rss[2];
    if ((tid & 63) == 0){ rs[tid >> 6] = s; rss[tid >> 6] = ss; }
    __syncthreads();
    float S = rs[0] + rs[1], SS = rss[0] + rss[1];
    float m = S * (1.0f / 384.0f);
    float var = SS * (1.0f / 384.0f) - m * m;
    float r = rsqrtf(var + 1e-5f);
    float* yr = y + row * ystride;
    yr[tid]       = (v0 - m) * r * w[tid]       + b[tid];
    yr[tid + 128] = (v1 - m) * r * w[tid + 128] + b[tid + 128];
    yr[tid + 256] = (v2 - m) * r * w[tid + 256] + b[tid + 256];
}

// ---------------- LayerNorm, bf16 out (for initial LN1) ----------------
__global__ __launch_bounds__(128) void ln384_bf(const float* __restrict__ x,
                                                const float* __restrict__ w, const float* __restrict__ b,
                                                __bf16* __restrict__ y){
    long row = blockIdx.x;
    int tid = threadIdx.x;
    const float* xr = x + row * 384;
    float v0 = xr[tid], v1 = xr[tid + 128], v2 = xr[tid + 256];
    float s = v0 + v1 + v2;
    float ss = v0 * v0 + v1 * v1 + v2 * v2;
    for (int off = 32; off; off >>= 1){ s += __shfl_down(s, off); ss += __shfl_down(ss, off); }
    __shared__ float rs[2], rss[2];
    if ((tid & 63) == 0){ rs[tid >> 6] = s; rss[tid >> 6] = ss; }
    __syncthreads();
    float S = rs[0] + rs[1], SS = rss[0] + rss[1];
    float m = S * (1.0f / 384.0f);
    float var = SS * (1.0f / 384.0f) - m * m;
    float r = rsqrtf(var + 1e-5f);
    __bf16* yr = y + row * 384;
    yr[tid]       = (__bf16)((v0 - m) * r * w[tid]       + b[tid]);
    yr[tid + 128] = (__bf16)((v1 - m) * r * w[tid + 128] + b[tid + 128]);
    yr[tid + 256] = (__bf16)((v2 - m) * r * w[tid + 256] + b[tid + 256]);
}

// ---------------- t += g1*o2 ; ht = LN3(t) transposed (bf16) ----------------
__global__ __launch_bounds__(128) void proj_res_lnt(const __bf16* __restrict__ o2,
                                                    const float* __restrict__ g1,
                                                    float* __restrict__ t,
                                                    const float* __restrict__ n3w, const float* __restrict__ n3b,
                                                    __bf16* __restrict__ ht){
    long row = blockIdx.x;
    int tid = threadIdx.x;
    int c0 = tid * 4;
    float v[4] = {0.f, 0.f, 0.f, 0.f};
    if (tid < 96){
        float4 tv = *reinterpret_cast<const float4*>(t + row * 384 + c0);
        bf16x4 ov = *reinterpret_cast<const bf16x4*>(o2 + row * 384 + c0);
        v[0] = tv.x + g1[c0 + 0] * (float)ov[0];
        v[1] = tv.y + g1[c0 + 1] * (float)ov[1];
        v[2] = tv.z + g1[c0 + 2] * (float)ov[2];
        v[3] = tv.w + g1[c0 + 3] * (float)ov[3];
        *reinterpret_cast<float4*>(t + row * 384 + c0) = make_float4(v[0], v[1], v[2], v[3]);
    }
    float s = v[0] + v[1] + v[2] + v[3];
    float ss = v[0] * v[0] + v[1] * v[1] + v[2] * v[2] + v[3] * v[3];
    for (int off = 32; off; off >>= 1){ s += __shfl_down(s, off); ss += __shfl_down(ss, off); }
    __shared__ float rs[2], rss[2];
    if ((tid & 63) == 0){ rs[tid >> 6] = s; rss[tid >> 6] = ss; }
    __syncthreads();
    float S = rs[0] + rs[1], SS = rss[0] + rss[1];
    float m = S * (1.0f / 384.0f);
    float var = SS * (1.0f / 384.0f) - m * m;
    float r = rsqrtf(var + 1e-5f);
    if (tid < 96){
        int b = (int)(row / 196), n = (int)(row % 196);
        __bf16* yb = ht + ((long)b * 384) * 196 + n;
        #pragma unroll
        for (int j = 0; j < 4; j++){
            int c = c0 + j;
            yb[(long)c * 196] = (__bf16)((v[j] - m) * r * n3w[c] + n3b[c]);
        }
    }
}

// ---------------- t += hadd ; h = LN2(t) bf16 ----------------
__global__ __launch_bounds__(128) void ln2res(float* __restrict__ t,
                                              const __bf16* __restrict__ hadd,
                                              const float* __restrict__ n2w, const float* __restrict__ n2b,
                                              __bf16* __restrict__ h){
    long row = blockIdx.x;
    int tid = threadIdx.x;
    int c0 = tid * 4;
    float v[4] = {0.f, 0.f, 0.f, 0.f};
    if (tid < 96){
        float4 tv = *reinterpret_cast<const float4*>(t + row * 384 + c0);
        bf16x4 hv = *reinterpret_cast<const bf16x4*>(hadd + row * 384 + c0);
        v[0] = tv.x + (float)hv[0];
        v[1] = tv.y + (float)hv[1];
        v[2] = tv.z + (float)hv[2];
        v[3] = tv.w + (float)hv[3];
        *reinterpret_cast<float4*>(t + row * 384 + c0) = make_float4(v[0], v[1], v[2], v[3]);
    }
    float s = v[0] + v[1] + v[2] + v[3];
    float ss = v[0] * v[0] + v[1] * v[1] + v[2] * v[2] + v[3] * v[3];
    for (int off = 32; off; off >>= 1){ s += __shfl_down(s, off); ss += __shfl_down(ss, off); }
    __shared__ float rs[2], rss[2];
    if ((tid & 63) == 0){ rs[tid >> 6] = s; rss[tid >> 6] = ss; }
    __syncthreads();
    float S = rs[0] + rs[1], SS = rss[0] + rss[1];
    float m = S * (1.0f / 384.0f);
    float var = SS * (1.0f / 384.0f) - m * m;
    float r = rsqrtf(var + 1e-5f);
    if (tid < 96){
        bf16x4 o;
        #pragma unroll
        for (int j = 0; j < 4; j++){
            int c = c0 + j;
            o[j] = (__bf16)((v[j] - m) * r * n2w[c] + n2b[c]);
        }
        *reinterpret_cast<bf16x4*>(h + row * 384 + c0) = o;
    }
}

// ---------------- t += g2*f2 ; h = LN1next(t) bf16 ----------------
__global__ __launch_bounds__(128) void fc2_res_ln(const __bf16* __restrict__ f2,
                                                  const float* __restrict__ g2,
                                                  float* __restrict__ t,
                                                  const float* __restrict__ n1w, const float* __restrict__ n1b,
                                                  __bf16* __restrict__ h){
    long row = blockIdx.x;
    int tid = threadIdx.x;
    int c0 = tid * 4;
    float v[4] = {0.f, 0.f, 0.f, 0.f};
    if (tid < 96){
        float4 tv = *reinterpret_cast<const float4*>(t + row * 384 + c0);
        bf16x4 fv = *reinterpret_cast<const bf16x4*>(f2 + row * 384 + c0);
        v[0] = tv.x + g2[c0 + 0] * (float)fv[0];
        v[1] = tv.y + g2[c0 + 1] * (float)fv[1];
        v[2] = tv.z + g2[c0 + 2] * (float)fv[2];
        v[3] = tv.w + g2[c0 + 3] * (float)fv[3];
        *reinterpret_cast<float4*>(t + row * 384 + c0) = make_float4(v[0], v[1], v[2], v[3]);
    }
    float s = v[0] + v[1] + v[2] + v[3];
    float ss = v[0] * v[0] + v[1] * v[1] + v[2] * v[2] + v[3] * v[3];
    for (int off = 32; off; off >>= 1){ s += __shfl_down(s, off); ss += __shfl_down(ss, off); }
    __shared__ float rs[2], rss[2];
    if ((tid & 63) == 0){ rs[tid >> 6] = s; rss[tid >> 6] = ss; }
    __syncthreads();
    float S = rs[0] + rs[1], SS = rss[0] + rss[1];
    float m = S * (1.0f / 384.0f);
    float var = SS * (1.0f / 384.0f) - m * m;
    float r = rsqrtf(var + 1e-5f);
    if (tid < 96){
        bf16x4 o;
        #pragma unroll
        for (int j = 0; j < 4; j++){
            int c = c0 + j;
            o[j] = (__bf16)((v[j] - m) * r * n1w[c] + n1b[c]);
        }
        *reinterpret_cast<bf16x4*>(h + row * 384 + c0) = o;
    }
}

// ---------------- bf16 MFMA GEMM, 64x128 tile, 4 waves, BK=64, 2-stage prefetch ----------------
template<int MODE, int OUTBF, int ACVT, int GUARD, int NGUARD>
__global__ __launch_bounds__(256) void gemm_bb2(const void* __restrict__ Av, long lda,
                                                const __bf16* __restrict__ W, int Kw,
                                                const float* __restrict__ bias,
                                                void* __restrict__ Cv, long ldc,
                                                int K, int M, int Ncols){
    __shared__ __align__(16) char smem[27648];
    char* Ab = smem;            // 64 rows x 144B
    char* Bb = smem + 9216;     // 128 rows x 144B
    const int tid = threadIdx.x;
    const int lane = tid & 63;
    const int wn = tid >> 6;
    const int row0 = blockIdx.x * 64;
    const int col0 = blockIdx.y * 128;
    const int hi = lane >> 4, lo = lane & 15;
    const __bf16* Abf = (const __bf16*)Av;
    const float* Af = (const float*)Av;
    f32x4 acc[4][2] = {};
    auto loadA = [&](int kk, int i)->bf16x8 {
        int p = i * 256 + tid;
        int r = p >> 3, cq = p & 7;
        bf16x8 va{};
        int grow = row0 + r;
        if (!GUARD || grow < M){
            long ai = (long)grow * lda + kk + cq * 8;
            if (ACVT){
                float4 a0 = *reinterpret_cast<const float4*>(Af + ai);
                float4 a1 = *reinterpret_cast<const float4*>(Af + ai + 4);
                va[0] = (__bf16)a0.x; va[1] = (__bf16)a0.y; va[2] = (__bf16)a0.z; va[3] = (__bf16)a0.w;
                va[4] = (__bf16)a1.x; va[5] = (__bf16)a1.y; va[6] = (__bf16)a1.z; va[7] = (__bf16)a1.w;
            } else {
                va = *reinterpret_cast<const bf16x8*>(Abf + ai);
            }
        }
        return va;
    };
    auto loadB = [&](int kk, int i)->bf16x8 {
        int p = i * 256 + tid;
        int r = p >> 3, cq = p & 7;
        return *reinterpret_cast<const bf16x8*>(W + (long)(col0 + r) * Kw + kk + cq * 8);
    };
    bf16x8 vaC[2], vwC[4];
    vaC[0] = loadA(0, 0); vaC[1] = loadA(0, 1);
    #pragma unroll
    for (int i = 0; i < 4; i++) vwC[i] = loadB(0, i);
    for (int k0 = 0; k0 < K; k0 += 64){
        #pragma unroll
        for (int i = 0; i < 2; i++){
            int p = i * 256 + tid;
            int r = p >> 3, cq = p & 7;
            *reinterpret_cast<bf16x8*>(Ab + r * 144 + cq * 16) = vaC[i];
        }
        #pragma unroll
        for (int i = 0; i < 4; i++){
            int p = i * 256 + tid;
            int r = p >> 3, cq = p & 7;
            *reinterpret_cast<bf16x8*>(Bb + r * 144 + cq * 16) = vwC[i];
        }
        __syncthreads();
        int kn = (k0 + 64 < K) ? k0 + 64 : k0;
        bf16x8 vaN[2], vwN[4];
        vaN[0] = loadA(kn, 0); vaN[1] = loadA(kn, 1);
        #pragma unroll
        for (int i = 0; i < 4; i++) vwN[i] = loadB(kn, i);
        bf16x8 af[2][4], bfr[2][2];
        #pragma unroll
        for (int m = 0; m < 4; m++){
            af[0][m] = *reinterpret_cast<const bf16x8*>(Ab + (m * 16 + lo) * 144 + hi * 16);
            af[1][m] = *reinterpret_cast<const bf16x8*>(Ab + (m * 16 + lo) * 144 + 64 + hi * 16);
        }
        #pragma unroll
        for (int n = 0; n < 2; n++){
            bfr[0][n] = *reinterpret_cast<const bf16x8*>(Bb + (wn * 32 + n * 16 + lo) * 144 + hi * 16);
            bfr[1][n] = *reinterpret_cast<const bf16x8*>(Bb + (wn * 32 + n * 16 + lo) * 144 + 64 + hi * 16);
        }
        #pragma unroll
        for (int kc = 0; kc < 2; kc++)
            #pragma unroll
            for (int m = 0; m < 4; m++)
                #pragma unroll
                for (int n = 0; n < 2; n++)
                    acc[m][n] = __builtin_amdgcn_mfma_f32_16x16x32_bf16(af[kc][m], bfr[kc][n], acc[m][n], 0, 0, 0);
        __syncthreads();
        vaC[0] = vaN[0]; vaC[1] = vaN[1];
        #pragma unroll
        for (int i = 0; i < 4; i++) vwC[i] = vwN[i];
    }
    float* Cf = (float*)Cv;
    __bf16* Cb = (__bf16*)Cv;
    #pragma unroll
    for (int m = 0; m < 4; m++){
        #pragma unroll
        for (int n = 0; n < 2; n++){
            int row = row0 + m * 16 + hi * 4;
            int col = col0 + wn * 32 + n * 16 + lo;
            if (NGUARD && col >= Ncols) continue;
            float bv = bias[col];
            #pragma unroll
            for (int j = 0; j < 4; j++){
                if (GUARD && (row + j) >= M) continue;
                float v = acc[m][n][j] + bv;
                if (MODE == 1) v = gelu_f(v);
                long ci = (long)(row + j) * ldc + col;
                if (OUTBF) Cb[ci] = (__bf16)v;
                else Cf[ci] = v;
            }
        }
    }
}

// ---------------- bf16 MFMA GEMM, 64x64 tile, 2x2 waves (32x32/wave), BK=64, bf16 out ----------------
// C[M,N] = A @ W^T + bias. M%64==0, N%64==0, K%64==0.
__global__ __launch_bounds__(256) void gemm_bb3(const __bf16* __restrict__ A, long lda,
                                                const __bf16* __restrict__ W, int Kw,
                                                const float* __restrict__ bias,
                                                __bf16* __restrict__ C, long ldc,
                                                int K){
    __shared__ __align__(16) char smem[18432];
    char* Ab = smem;            // 64 rows x 144B
    char* Bb = smem + 9216;     // 64 rows x 144B
    const int tid = threadIdx.x;
    const int lane = tid & 63;
    const int wid = tid >> 6;
    const int wm = wid >> 1, wnn = wid & 1;
    const int row0 = blockIdx.x * 64;
    const int col0 = blockIdx.y * 64;
    const int hi = lane >> 4, lo = lane & 15;
    f32x4 acc[2][2] = {};
    auto loadA = [&](int kk, int i)->bf16x8 {
        int p = i * 256 + tid;
        int r = p >> 3, cq = p & 7;
        return *reinterpret_cast<const bf16x8*>(A + (long)(row0 + r) * lda + kk + cq * 8);
    };
    auto loadB = [&](int kk, int i)->bf16x8 {
        int p = i * 256 + tid;
        int r = p >> 3, cq = p & 7;
        return *reinterpret_cast<const bf16x8*>(W + (long)(col0 + r) * Kw + kk + cq * 8);
    };
    bf16x8 vaC[2], vwC[2];
    vaC[0] = loadA(0, 0); vaC[1] = loadA(0, 1);
    vwC[0] = loadB(0, 0); vwC[1] = loadB(0, 1);
    for (int k0 = 0; k0 < K; k0 += 64){
        #pragma unroll
        for (int i = 0; i < 2; i++){
            int p = i * 256 + tid;
            int r = p >> 3, cq = p & 7;
            *reinterpret_cast<bf16x8*>(Ab + r * 144 + cq * 16) = vaC[i];
            *reinterpret_cast<bf16x8*>(Bb + r * 144 + cq * 16) = vwC[i];
        }
        __syncthreads();
        int kn = (k0 + 64 < K) ? k0 + 64 : k0;
        bf16x8 vaN[2], vwN[2];
        vaN[0] = loadA(kn, 0); vaN[1] = loadA(kn, 1);
        vwN[0] = loadB(kn, 0); vwN[1] = loadB(kn, 1);
        bf16x8 af[2][2], bfr[2][2];
        #pragma unroll
        for (int m = 0; m < 2; m++){
            af[0][m] = *reinterpret_cast<const bf16x8*>(Ab + (wm * 32 + m * 16 + lo) * 144 + hi * 16);
            af[1][m] = *reinterpret_cast<const bf16x8*>(Ab + (wm * 32 + m * 16 + lo) * 144 + 64 + hi * 16);
        }
        #pragma unroll
        for (int n = 0; n < 2; n++){
            bfr[0][n] = *reinterpret_cast<const bf16x8*>(Bb + (wnn * 32 + n * 16 + lo) * 144 + hi * 16);
            bfr[1][n] = *reinterpret_cast<const bf16x8*>(Bb + (wnn * 32 + n * 16 + lo) * 144 + 64 + hi * 16);
        }
        #pragma unroll
        for (int kc = 0; kc < 2; kc++)
            #pragma unroll
            for (int m = 0; m < 2; m++)
                #pragma unroll
                for (int n = 0; n < 2; n++)
                    acc[m][n] = __builtin_amdgcn_mfma_f32_16x16x32_bf16(af[kc][m], bfr[kc][n], acc[m][n], 0, 0, 0);
        __syncthreads();
        vaC[0] = vaN[0]; vaC[1] = vaN[1]; vwC[0] = vwN[0]; vwC[1] = vwN[1];
    }
    #pragma unroll
    for (int m = 0; m < 2; m++){
        #pragma unroll
        for (int n = 0; n < 2; n++){
            int row = row0 + wm * 32 + m * 16 + hi * 4;
            int col = col0 + wnn * 32 + n * 16 + lo;
            float bv = bias[col];
            #pragma unroll
            for (int j = 0; j < 4; j++)
                C[(long)(row + j) * ldc + col] = (__bf16)(acc[m][n][j] + bv);
        }
    }
}

// ---------------- positional embedding: pos[n, d] ----------------
__global__ __launch_bounds__(384) void pos_embed(const float* __restrict__ pw, const float* __restrict__ pb,
                                                 float* __restrict__ pos){
    __shared__ float p64[64];
    int n = blockIdx.x;
    int iy = n / 14, ix = n % 14;
    int t = threadIdx.x;
    if (t < 64){
        int axis = t >> 5;
        int c = t & 31;
        int u = c >> 1;
        float coord = (axis == 0) ? (float)(iy + 1) : (float)(ix + 1);
        float val = coord / ((14.0f + 1e-6f) * 6.283185307179586f);
        float T = powf(10000.0f, (float)u / 16.0f);
        float a = val / T;
        p64[t] = (c & 1) ? cosf(a) : sinf(a);
    }
    __syncthreads();
    float acc = 0.f;
    const float* wr = pw + (long)t * 64;
    #pragma unroll 8
    for (int c = 0; c < 64; c++) acc += p64[c] * wr[c];
    pos[n * 384 + t] = acc + pb[t];
}

// ---------------- XCA attention via MFMA: one block per (b, head); V read from global ----------------
// LDS: qs + ks (transposed [d][n]) only -> ~45KB -> 3 blocks/CU.
__global__ __launch_bounds__(256) void xca2(const __bf16* __restrict__ qkv, const float* __restrict__ temp,
                                            __bf16* __restrict__ o){
    __shared__ __align__(16) char smem[45056];
    __bf16* qs = (__bf16*)smem;                 // 48*232*2 = 22272
    __bf16* ks = (__bf16*)(smem + 22272);       // 22272
    float* inq = (float*)(smem + 44544);        // 192
    float* ink = (float*)(smem + 44736);        // 192
    float* att = (float*)smem;                  // overlay on qs (13056B)
    __bf16* abf = (__bf16*)(smem + 22272);      // overlay on ks (6912B)
    int bh = blockIdx.x;
    int b = bh >> 3, h = bh & 7;
    const int tid = threadIdx.x;
    const int wid = tid >> 6, lane = tid & 63;
    const int hi = lane >> 4, lo = lane & 15;
    const __bf16* base = qkv + ((long)b * 196) * 1152 + h * 48;
    bf16x8 z8 = {};
    for (int idx = tid; idx < 48 * 28; idx += 256){
        int d = idx / 28, n = 196 + idx % 28;
        qs[d * 232 + n] = (__bf16)0.f;
        ks[d * 232 + n] = (__bf16)0.f;
    }
    for (int ch = tid; ch < 196 * 6; ch += 256){
        int n = ch / 6, c = ch % 6, d0 = c * 8;
        bf16x8 q8 = *reinterpret_cast<const bf16x8*>(base + (long)n * 1152 + d0);
        bf16x8 k8 = *reinterpret_cast<const bf16x8*>(base + (long)n * 1152 + 384 + d0);
        #pragma unroll
        for (int j = 0; j < 8; j++){
            qs[(d0 + j) * 232 + n] = q8[j];
            ks[(d0 + j) * 232 + n] = k8[j];
        }
    }
    __syncthreads();
    for (int r = wid; r < 48; r += 4){
        float sq = 0.f, sk = 0.f;
        for (int n = lane; n < 196; n += 64){
            float qv = (float)qs[r * 232 + n];
            float kv = (float)ks[r * 232 + n];
            sq += qv * qv; sk += kv * kv;
        }
        for (int off = 32; off; off >>= 1){ sq += __shfl_down(sq, off); sk += __shfl_down(sk, off); }
        if (lane == 0){
            inq[r] = 1.0f / fmaxf(sqrtf(sq), 1e-12f);
            ink[r] = 1.0f / fmaxf(sqrtf(sk), 1e-12f);
        }
    }
    __syncthreads();
    float tempv = temp[h];
    f32x4 qk0 = {}, qk1 = {}, qk2 = {};
    __builtin_amdgcn_s_setprio(1);
    {
        int mi = wid / 3, ni = wid % 3;
        #pragma unroll
        for (int k0 = 0; k0 < 224; k0 += 32){
            bf16x8 af = *reinterpret_cast<const bf16x8*>(qs + (mi * 16 + lo) * 232 + k0 + hi * 8);
            bf16x8 bf = *reinterpret_cast<const bf16x8*>(ks + (ni * 16 + lo) * 232 + k0 + hi * 8);
            qk0 = __builtin_amdgcn_mfma_f32_16x16x32_bf16(af, bf, qk0, 0, 0, 0);
        }
    }
    {
        int tt = wid + 4;
        int mi = tt / 3, ni = tt % 3;
        #pragma unroll
        for (int k0 = 0; k0 < 224; k0 += 32){
            bf16x8 af = *reinterpret_cast<const bf16x8*>(qs + (mi * 16 + lo) * 232 + k0 + hi * 8);
            bf16x8 bf = *reinterpret_cast<const bf16x8*>(ks + (ni * 16 + lo) * 232 + k0 + hi * 8);
            qk1 = __builtin_amdgcn_mfma_f32_16x16x32_bf16(af, bf, qk1, 0, 0, 0);
        }
    }
    if (wid == 0){
        #pragma unroll
        for (int k0 = 0; k0 < 224; k0 += 32){
            bf16x8 af = *reinterpret_cast<const bf16x8*>(qs + (2 * 16 + lo) * 232 + k0 + hi * 8);
            bf16x8 bf = *reinterpret_cast<const bf16x8*>(ks + (2 * 16 + lo) * 232 + k0 + hi * 8);
            qk2 = __builtin_amdgcn_mfma_f32_16x16x32_bf16(af, bf, qk2, 0, 0, 0);
        }
    }
    __builtin_amdgcn_s_setprio(0);
    __syncthreads();   // qs/ks reads done; overlays writable
    {
        int mi = wid / 3, ni = wid % 3;
        int e = ni * 16 + lo;
        float se = ink[e] * tempv;
        #pragma unroll
        for (int j = 0; j < 4; j++){
            int d = mi * 16 + hi * 4 + j;
            att[d * 68 + e] = qk0[j] * inq[d] * se;
        }
    }
    {
        int tt = wid + 4;
        int mi = tt / 3, ni = tt % 3;
        int e = ni * 16 + lo;
        float se = ink[e] * tempv;
        #pragma unroll
        for (int j = 0; j < 4; j++){
            int d = mi * 16 + hi * 4 + j;
            att[d * 68 + e] = qk1[j] * inq[d] * se;
        }
    }
    if (wid == 0){
        int e = 2 * 16 + lo;
        float se = ink[e] * tempv;
        #pragma unroll
        for (int j = 0; j < 4; j++){
            int d = 2 * 16 + hi * 4 + j;
            att[d * 68 + e] = qk2[j] * inq[d] * se;
        }
    }
    __syncthreads();
    if (tid < 192){
        int r = tid >> 2, q4 = tid & 3;
        const float* row = att + r * 68 + q4 * 12;
        float mx = -1e30f;
        #pragma unroll
        for (int i = 0; i < 12; i++) mx = fmaxf(mx, row[i]);
        mx = fmaxf(mx, __shfl_xor(mx, 1));
        mx = fmaxf(mx, __shfl_xor(mx, 2));
        float pv[12]; float sm = 0.f;
        #pragma unroll
        for (int i = 0; i < 12; i++){ pv[i] = expf(row[i] - mx); sm += pv[i]; }
        sm += __shfl_xor(sm, 1);
        sm += __shfl_xor(sm, 2);
        float inv = 1.0f / sm;
        #pragma unroll
        for (int i = 0; i < 12; i++) abf[r * 72 + q4 * 12 + i] = (__bf16)(pv[i] * inv);
    }
    for (int idx = tid; idx < 48 * 3; idx += 256){
        int r = idx / 3, c = 48 + (idx % 3) * 8;
        *reinterpret_cast<bf16x8*>(abf + r * 72 + c) = z8;
    }
    __syncthreads();
    // PV: A = abf (LDS), B = V read directly from global (qkv[n][768+e], contiguous in e).
    // abf cols 48..63 are zero, so garbage B values at e>=48 (and n>=196 tiles) contribute 0;
    // n>=196 outputs are write-guarded. All addresses stay inside the workspace.
    __bf16* ob = o + ((long)b * 196) * 384 + h * 48;
    __builtin_amdgcn_s_setprio(1);
    for (int tt = wid; tt < 39; tt += 4){
        int mi = tt / 13, ni = tt % 13;
        int nB = ni * 16 + lo;
        const __bf16* vrow = base + (long)nB * 1152 + 768;
        f32x4 acc = {};
        #pragma unroll
        for (int e0 = 0; e0 < 64; e0 += 32){
            bf16x8 af = *reinterpret_cast<const bf16x8*>(abf + (mi * 16 + lo) * 72 + e0 + hi * 8);
            bf16x8 bf = *reinterpret_cast<const bf16x8*>(vrow + e0 + hi * 8);
            acc = __builtin_amdgcn_mfma_f32_16x16x32_bf16(af, bf, acc, 0, 0, 0);
        }
        int n = nB;
        if (n < 196){
            #pragma unroll
            for (int j = 0; j < 4; j++){
                int d = mi * 16 + hi * 4 + j;
                ob[(long)n * 384 + d] = (__bf16)acc[j];
            }
        }
    }
    __builtin_amdgcn_s_setprio(0);
}

// ---------------- LPI: gated output to hadd (bf16, [b,n,d]), ht bf16 in ----------------
__global__ __launch_bounds__(256) void lpi_g(const __bf16* __restrict__ ht,
                                             const float* __restrict__ w1, const float* __restrict__ b1,
                                             const float* __restrict__ bng, const float* __restrict__ bnb,
                                             const float* __restrict__ w2, const float* __restrict__ b2,
                                             const float* __restrict__ g3, __bf16* __restrict__ hadd){
    int bd = blockIdx.x;
    int d = bd % 384, b = bd / 384;
    __shared__ float p[16][16];
    __shared__ float p2[16][16];
    __shared__ float wA[9], wB[9];
    int tt = threadIdx.x;
    int yy = tt / 16, xx = tt % 16;
    p[yy][xx] = 0.f; p2[yy][xx] = 0.f;
    if (tt < 9){ wA[tt] = w1[d * 9 + tt]; wB[tt] = w2[d * 9 + tt]; }
    __syncthreads();
    if (tt < 196){
        int y = tt / 14, x = tt % 14;
        p[y + 1][x + 1] = (float)ht[((long)b * 384 + d) * 196 + tt];
    }
    __syncthreads();
    if (tt < 196){
        int y = tt / 14, x = tt % 14;
        float a = 0.f;
        #pragma unroll
        for (int ky = 0; ky < 3; ky++)
            #pragma unroll
            for (int kx = 0; kx < 3; kx++)
                a += wA[ky * 3 + kx] * p[y + ky][x + kx];
        a += b1[d];
        a = gelu_f(a);
        a = a * (bng[d] * rsqrtf(1.0f + 1e-5f)) + bnb[d];
        p2[y + 1][x + 1] = a;
    }
    __syncthreads();
    if (tt < 196){
        int y = tt / 14, x = tt % 14;
        float a = 0.f;
        #pragma unroll
        for (int ky = 0; ky < 3; ky++)
            #pragma unroll
            for (int kx = 0; kx < 3; kx++)
                a += wB[ky * 3 + kx] * p2[y + ky][x + kx];
        a += b2[d];
        hadd[((long)b * 196 + tt) * 384 + d] = (__bf16)(g3[d] * a);
    }
}

// ---------------- cls concat ----------------
__global__ __launch_bounds__(256) void concat_cls(const float* __restrict__ t, const float* __restrict__ clstok,
                                                  float* __restrict__ tc){
    long i = (long)blockIdx.x * 256 + threadIdx.x;
    if (i >= (long)B_ * 197 * 384) return;
    int d = (int)(i % 384);
    long bn = i / 384;
    int n = (int)(bn % 197);
    int b = (int)(bn / 197);
    tc[i] = (n == 0) ? clstok[d] : t[((long)b * 196 + (n - 1)) * 384 + d];
}

// ---------------- CA attention (bf16 qkv) ----------------
__global__ __launch_bounds__(256) void ca_attn(const __bf16* __restrict__ qkv, float* __restrict__ clsp){
    int bh = blockIdx.x;
    int b = bh >> 3, h = bh & 7;
    const __bf16* base = qkv + (long)b * 197 * 1152 + h * 48;
    __shared__ float q0[48];
    __shared__ float at2[197];
    __shared__ float smax, ssum;
    int tid = threadIdx.x;
    if (tid < 48) q0[tid] = (float)base[tid];
    __syncthreads();
    if (tid < 197){
        const __bf16* kr = base + (long)tid * 1152 + 384;
        float s = 0.f;
        for (int d = 0; d < 48; d++) s += q0[d] * (float)kr[d];
        at2[tid] = s * rsqrtf(48.0f);
    }
    __syncthreads();
    if (tid == 0){
        float m = -1e30f;
        for (int n = 0; n < 197; n++) m = fmaxf(m, at2[n]);
        smax = m;
    }
    __syncthreads();
    if (tid < 197) at2[tid] = expf(at2[tid] - smax);
    __syncthreads();
    if (tid == 0){
        float s = 0.f;
        for (int n = 0; n < 197; n++) s += at2[n];
        ssum = s;
    }
    __syncthreads();
    if (tid < 48){
        const __bf16* vb = base + 768 + tid;
        float s = 0.f;
        for (int n = 0; n < 197; n++) s += at2[n] * (float)vb[(long)n * 1152];
        clsp[b * 384 + h * 48 + tid] = s / ssum;
    }
}

__global__ __launch_bounds__(256) void ca_update1(const float* __restrict__ clso, const float* __restrict__ hc,
                                                  const float* __restrict__ g1, float* __restrict__ tc){
    long i = (long)blockIdx.x * 256 + threadIdx.x;
    if (i >= (long)B_ * 197 * 384) return;
    int d = (int)(i % 384);
    long bn = i / 384;
    int n = (int)(bn % 197);
    int b = (int)(bn / 197);
    float add = (n == 0) ? clso[b * 384 + d] : hc[i];
    tc[i] += g1[d] * add;
}

__global__ __launch_bounds__(256) void ca_update2(const float* __restrict__ cls2, const float* __restrict__ hc,
                                                  const float* __restrict__ g2, float* __restrict__ tc){
    long i = (long)blockIdx.x * 256 + threadIdx.x;
    if (i >= (long)B_ * 197 * 384) return;
    int d = (int)(i % 384);
    long bn = i / 384;
    int n = (int)(bn % 197);
    int b = (int)(bn / 197);
    float hv = hc[i];
    tc[i] = (n == 0) ? (g2[d] * cls2[b * 384 + d] + hv) : (hv + hv);
}

extern "C" void kernel_launch(void* const* d_in, const int* in_sizes, int n_in,
                              void* d_out, int out_size, void* d_ws, size_t ws_size,
                              hipStream_t stream){
    (void)in_sizes; (void)n_in; (void)out_size; (void)ws_size;
    const float* x      = (const float*)d_in[0];
    const float* clstok = (const float*)d_in[1];
    const float* pos_w  = (const float*)d_in[2];
    const float* pos_b  = (const float*)d_in[3];
    const float* pe_w[4] = {(const float*)d_in[4], (const float*)d_in[7], (const float*)d_in[10], (const float*)d_in[13]};
    const float* pe_g[4] = {(const float*)d_in[5], (const float*)d_in[8], (const float*)d_in[11], (const float*)d_in[14]};
    const float* pe_b[4] = {(const float*)d_in[6], (const float*)d_in[9], (const float*)d_in[12], (const float*)d_in[15]};
    const float* xqkv_w = (const float*)d_in[16];
    const float* xqkv_b = (const float*)d_in[17];
    const float* xproj_w = (const float*)d_in[18];
    const float* xproj_b = (const float*)d_in[19];
    const float* xtemp  = (const float*)d_in[20];
    const float* xn1_w = (const float*)d_in[21];
    const float* xn1_b = (const float*)d_in[22];
    const float* xn2_w = (const float*)d_in[23];
    const float* xn2_b = (const float*)d_in[24];
    const float* xn3_w = (const float*)d_in[25];
    const float* xn3_b = (const float*)d_in[26];
    const float* xfc1_w = (const float*)d_in[27];
    const float* xfc1_b = (const float*)d_in[28];
    const float* xfc2_w = (const float*)d_in[29];
    const float* xfc2_b = (const float*)d_in[30];
    const float* xlpi1_w = (const float*)d_in[31];
    const float* xlpi1_b = (const float*)d_in[32];
    const float* xlpi2_w = (const float*)d_in[33];
    const float* xlpi2_b = (const float*)d_in[34];
    const float* xbn_g = (const float*)d_in[35];
    const float* xbn_b = (const float*)d_in[36];
    const float* xg1 = (const float*)d_in[37];
    const float* xg2 = (const float*)d_in[38];
    const float* xg3 = (const float*)d_in[39];
    const float* cqkv_w = (const float*)d_in[40];
    const float* cqkv_b = (const float*)d_in[41];
    const float* cproj_w = (const float*)d_in[42];
    const float* cproj_b = (const float*)d_in[43];
    const float* cn1_w = (const float*)d_in[44];
    const float* cn1_b = (const float*)d_in[45];
    const float* cn2_w = (const float*)d_in[46];
    const float* cn2_b = (const float*)d_in[47];
    const float* cfc1_w = (const float*)d_in[48];
    const float* cfc1_b = (const float*)d_in[49];
    const float* cfc2_w = (const float*)d_in[50];
    const float* cfc2_b = (const float*)d_in[51];
    const float* cg1 = (const float*)d_in[52];
    const float* cg2 = (const float*)d_in[53];
    const float* norm_w = (const float*)d_in[54];
    const float* norm_b = (const float*)d_in[55];
    const float* head_w = (const float*)d_in[56];
    const float* head_b = (const float*)d_in[57];
    float* outp = (float*)d_out;

    float* ws = (float*)d_ws;
    // ---- conv phase buffers ----
    __bf16* A1   = (__bf16*)(ws);
    __bf16* A2   = (__bf16*)(ws);
    __bf16* A3   = (__bf16*)(ws);
    __bf16* A4   = (__bf16*)(ws);
    __bf16* out1 = (__bf16*)(ws + 22500000L);
    __bf16* out2 = (__bf16*)(ws + 22500000L);
    __bf16* out3 = (__bf16*)(ws + 27400000L);
    __bf16* wcv  = (__bf16*)(ws + 36000000L);
    __bf16* W1c = wcv;
    __bf16* W2c = wcv + 1536;
    __bf16* W3c = wcv + 44544;
    __bf16* W4c = wcv + 216576;
    // ---- XCA phase ----
    __bf16* wqkv_bf = (__bf16*)(ws);
    __bf16* wproj_bf = (__bf16*)(ws + 5308416L);
    __bf16* wfc1_bf = (__bf16*)(ws + 7077888L);
    __bf16* wfc2_bf = (__bf16*)(ws + 14155776L);
    float*  t       = ws + 21233664L;
    float*  pos     = ws + 23642112L;
    __bf16* h_bf    = (__bf16*)(ws + 23717376L);
    __bf16* qkv_bf  = (__bf16*)(ws + 24921600L);
    __bf16* o_bf    = (__bf16*)(ws + 28534272L);
    __bf16* ht_bf   = (__bf16*)(ws + 29738496L);
    __bf16* f1_bf   = (__bf16*)(ws + 32146944L);
    // aliases (time-disjoint within a layer):
    __bf16* o2_bf   = (__bf16*)(ws + 34555392L);
    __bf16* f2_bf   = (__bf16*)(ws + 24921600L);
    __bf16* hadd_bf = (__bf16*)(ws + 28534272L);
    // ---- CA phase ----
    float* tc   = ws;
    float* hc   = ws + 2420736L;
    __bf16* qkvc_bf = (__bf16*)(ws + 4841472L);
    float* clsp = ws + 8472576L;
    float* clso = clsp + 12288;
    float* f1c  = clso + 12288;
    float* cls2 = f1c + 49152;
    float* clsf = cls2 + 12288;
    __bf16* cqkv_bf  = (__bf16*)(ws + 9000000L);
    __bf16* cproj_bf = (__bf16*)(ws + 9500000L);
    __bf16* cfc1_bf  = (__bf16*)(ws + 9800000L);
    __bf16* cfc2_bf  = (__bf16*)(ws + 10400000L);
    __bf16* headw_bf = (__bf16*)(ws + 11000000L);

    // ---- conv weight prep ----
    wprep<<<(48 * 32 + 255) / 256, 256, 0, stream>>>(pe_w[0], W1c, 48, 3, 32);
    wprep<<<(96 * 448 + 255) / 256, 256, 0, stream>>>(pe_w[1], W2c, 96, 48, 448);
    wprep<<<(192 * 896 + 255) / 256, 256, 0, stream>>>(pe_w[2], W3c, 192, 96, 896);
    wprep<<<(384 * 1728 + 255) / 256, 256, 0, stream>>>(pe_w[3], W4c, 384, 192, 1728);

    // ---- patch embed: im2col + MFMA GEMM ----
    im2col_x<<<1568, 256, 0, stream>>>(x, A1);
    { dim3 g(3136, 1); gemm_conv<1, 0><<<g, 256, 0, stream>>>(A1, 32, W1c, pe_g[0], pe_b[0], out1, 48, nullptr); }
    im2col_bf<<<(100352 * 9 + 255) / 256, 256, 0, stream>>>(out1, A2, 48, 112, 112, 56, 56, 448, 100352 * 9);
    { dim3 g(784, 1); gemm_conv<1, 0><<<g, 256, 0, stream>>>(A2, 448, W2c, pe_g[1], pe_b[1], out2, 96, nullptr); }
    im2col_bf<<<(25088 * 9 + 255) / 256, 256, 0, stream>>>(out2, A3, 96, 56, 56, 28, 28, 896, 25088 * 9);
    pos_embed<<<196, 384, 0, stream>>>(pos_w, pos_b, pos);
    { dim3 g(196, 2); gemm_conv<1, 0><<<g, 256, 0, stream>>>(A3, 896, W3c, pe_g[2], pe_b[2], out3, 192, nullptr); }
    im2col_bf<<<(6272 * 9 + 255) / 256, 256, 0, stream>>>(out3, A4, 192, 28, 28, 14, 14, 1728, 6272 * 9);
    { dim3 g(49, 3); gemm_conv<0, 1><<<g, 256, 0, stream>>>(A4, 1728, W4c, pe_g[3], pe_b[3], t, 384, pos); }

    // ---- convert XCA weights to bf16 ----
    {
        long n1 = (long)L_ * 1152 * 384;
        long n2 = (long)L_ * 384 * 384;
        long n3 = (long)L_ * 1536 * 384;
        cvt_bf<<<(int)((n1 + 2047) / 2048), 256, 0, stream>>>(xqkv_w, wqkv_bf, n1);
        cvt_bf<<<(int)((n2 + 2047) / 2048), 256, 0, stream>>>(xproj_w, wproj_bf, n2);
        cvt_bf<<<(int)((n3 + 2047) / 2048), 256, 0, stream>>>(xfc1_w, wfc1_bf, n3);
        cvt_bf<<<(int)((n3 + 2047) / 2048), 256, 0, stream>>>(xfc2_w, wfc2_bf, n3);
    }

    // ---- 24 XCA layers ----
    const int M = B_ * N_;  // 6272 = 98*64
    ln384_bf<<<M, 128, 0, stream>>>(t, xn1_w, xn1_b, h_bf);   // initial LN1
    for (int l = 0; l < L_; l++){
        {
            dim3 g(98, 9);
            gemm_bb2<0, 1, 0, 0, 0><<<g, 256, 0, stream>>>(h_bf, 384, wqkv_bf + (long)l * 1152 * 384, 384,
                                                           xqkv_b + l * 1152, qkv_bf, 1152, 384, M, 0);
        }
        xca2<<<B_ * NH_, 256, 0, stream>>>(qkv_bf, xtemp + l * 8, o_bf);
        {   // proj: 64x64 tiles, bf16 out (incl bias)
            dim3 g(98, 6);
            gemm_bb3<<<g, 256, 0, stream>>>(o_bf, 384, wproj_bf + (long)l * 384 * 384, 384,
                                            xproj_b + l * 384, o2_bf, 384, 384);
        }
        proj_res_lnt<<<M, 128, 0, stream>>>(o2_bf, xg1 + l * 384, t,
                                            xn3_w + l * 384, xn3_b + l * 384, ht_bf);
        lpi_g<<<B_ * D_, 256, 0, stream>>>(ht_bf, xlpi1_w + (long)l * 384 * 9, xlpi1_b + l * 384,
                                           xbn_g + l * 384, xbn_b + l * 384,
                                           xlpi2_w + (long)l * 384 * 9, xlpi2_b + l * 384,
                                           xg3 + l * 384, hadd_bf);
        ln2res<<<M, 128, 0, stream>>>(t, hadd_bf, xn2_w + l * 384, xn2_b + l * 384, h_bf);
        {
            dim3 g(98, 12);
            gemm_bb2<1, 1, 0, 0, 0><<<g, 256, 0, stream>>>(h_bf, 384, wfc1_bf + (long)l * 1536 * 384, 384,
                                                           xfc1_b + l * 1536, f1_bf, 1536, 384, M, 0);
        }
        {   // fc2: 64x64 tiles, bf16 out (incl bias)
            dim3 g(98, 6);
            gemm_bb3<<<g, 256, 0, stream>>>(f1_bf, 1536, wfc2_bf + (long)l * 1536 * 384, 1536,
                                            xfc2_b + l * 384, f2_bf, 384, 1536);
        }
        int ln = (l + 1) % L_;
        fc2_res_ln<<<M, 128, 0, stream>>>(f2_bf, xg2 + l * 384, t,
                                          xn1_w + ln * 384, xn1_b + ln * 384, h_bf);
    }

    // ---- cls concat + 2 CA blocks ----
    const long NC = (long)B_ * 197 * 384;
    concat_cls<<<(int)(NC / 256), 256, 0, stream>>>(t, clstok, tc);
    {
        long nc = (long)2 * 1152 * 384;
        cvt_bf<<<(int)((nc + 2047) / 2048), 256, 0, stream>>>(cqkv_w, cqkv_bf, nc);
        long np = (long)2 * 384 * 384;
        cvt_bf<<<(int)((np + 2047) / 2048), 256, 0, stream>>>(cproj_w, cproj_bf, np);
        long nf = (long)2 * 1536 * 384;
        cvt_bf<<<(int)((nf + 2047) / 2048), 256, 0, stream>>>(cfc1_w, cfc1_bf, nf);
        cvt_bf<<<(int)((nf + 2047) / 2048), 256, 0, stream>>>(cfc2_w, cfc2_bf, nf);
        cvt_pad<<<(1024 * 384 + 255) / 256, 256, 0, stream>>>(head_w, headw_bf, 1000, 384, 1024);
    }
    const int MC = B_ * 197;  // 6304
    for (int i = 0; i < 2; i++){
        ln384<<<MC, 128, 0, stream>>>(tc, 384, cn1_w + i * 384, cn1_b + i * 384, hc, 384);
        {
            dim3 g(99, 9);
            gemm_bb2<0, 1, 1, 1, 0><<<g, 256, 0, stream>>>(hc, 384, cqkv_bf + (long)i * 1152 * 384, 384,
                                                           cqkv_b + i * 1152, qkvc_bf, 1152, 384, MC, 0);
        }
        ca_attn<<<B_ * NH_, 256, 0, stream>>>(qkvc_bf, clsp);
        {
            dim3 g(1, 3);
            gemm_bb2<0, 0, 1, 1, 0><<<g, 256, 0, stream>>>(clsp, 384, cproj_bf + (long)i * 384 * 384, 384,
                                                           cproj_b + i * 384, clso, 384, 384, 32, 0);
        }
        ca_update1<<<(int)(NC / 256), 256, 0, stream>>>(clso, hc, cg1 + i * 384, tc);
        ln384<<<MC, 128, 0, stream>>>(tc, 384, cn2_w + i * 384, cn2_b + i * 384, hc, 384);
        {
            dim3 g(1, 12);
            gemm_bb2<1, 0, 1, 1, 0><<<g, 256, 0, stream>>>(hc, (long)197 * 384, cfc1_bf + (long)i * 1536 * 384, 384,
                                                           cfc1_b + i * 1536, f1c, 1536, 384, 32, 0);
        }
        {
            dim3 g(1, 3);
            gemm_bb2<0, 0, 1, 1, 0><<<g, 256, 0, stream>>>(f1c, 1536, cfc2_bf + (long)i * 1536 * 384, 1536,
                                                           cfc2_b + i * 384, cls2, 384, 1536, 32, 0);
        }
        ca_update2<<<(int)(NC / 256), 256, 0, stream>>>(cls2, hc, cg2 + i * 384, tc);
    }

    // ---- final LN (cls token only) + head ----
    ln384<<<32, 128, 0, stream>>>(tc, (long)197 * 384, norm_w, norm_b, clsf, 384);
    {
        dim3 g(1, 8);
        gemm_bb2<0, 0, 1, 1, 1><<<g, 256, 0, stream>>>(clsf, 384, headw_bf, 384,
                                                       head_b, outp, 1000, 384, 32, 1000);
    }
}